// Round 2
// baseline (3720.406 us; speedup 1.0000x reference)
//
#include <hip/hip_runtime.h>
#include <hip/hip_bf16.h>

// ---------------------------------------------------------------------------
// RWKV7 attention block. fp32 compute, bf16 intermediate storage.
// B=8, T=2048, H=1024, NH=16, DK=DV=64, VDIM=1024.
// Workspace budget: EW fp32 64MB + 5x bf16 32MB + H1 10.5MB = ~234.5 MB.
// ---------------------------------------------------------------------------

#define DEVI __device__ __forceinline__

constexpr int TSEQ = 2048;
constexpr int HID  = 1024;
constexpr int BTOT = 16384;   // B*T
constexpr float W_SCALE = -0.6065306597126334f;
constexpr float GN_EPS  = 6.4e-4f;   // 64 * 1e-5

DEVI float4 ld4(const float* p) { return *reinterpret_cast<const float4*>(p); }
DEVI void   st4(float* p, float4 v) { *reinterpret_cast<float4*>(p) = v; }
DEVI float  sigf(float x) { return 1.0f / (1.0f + __expf(-x)); }
DEVI float  f4get(const float4& v, int q) { return q==0?v.x:(q==1?v.y:(q==2?v.z:v.w)); }
// bf16 <-> f32 (RNE pack; no NaN expected in this workload)
DEVI unsigned short bfr(float f) {
    unsigned int u = __float_as_uint(f);
    return (unsigned short)((u + 0x7fffu + ((u >> 16) & 1u)) >> 16);
}
DEVI float bff(unsigned short s) { return __uint_as_float(((unsigned int)s) << 16); }
DEVI void up8(uint4 u, float* f) {
    f[0]=bff((unsigned short)(u.x & 0xffffu)); f[1]=bff((unsigned short)(u.x >> 16));
    f[2]=bff((unsigned short)(u.y & 0xffffu)); f[3]=bff((unsigned short)(u.y >> 16));
    f[4]=bff((unsigned short)(u.z & 0xffffu)); f[5]=bff((unsigned short)(u.z >> 16));
    f[6]=bff((unsigned short)(u.w & 0xffffu)); f[7]=bff((unsigned short)(u.w >> 16));
}

// ---------------------------------------------------------------------------
// Tiled fp32 GEMM:  C[M,N] = epilogue( A'[M,K] @ Bw[N,K]^T )
// MIXA: A'[r,k] = x[r,k] + (x[r-1,k] - x[r,k]) * cvec[k]  (x[-1]=0 per seq)
// OUTBF: store bf16 (ushort). MODE epilogues:
//   0 none | 1 tanh | 2 sigmoid | 3 exp(W_SCALE*sigmoid(d+bias))
//   4 sigmoid(d+bias) | 5 v-mix: a1 + (a2-a1)*sigmoid(d+bias)  (a1 bf16, a2 f32)
// ---------------------------------------------------------------------------
template<int BM, int BN, int BK, int TM, int TN, int MODE, bool MIXA, bool OUTBF>
__global__ __launch_bounds__(256) void gemm_bt(
        const float* __restrict__ A, const float* __restrict__ cvec,
        const float* __restrict__ Bw, void* __restrict__ Cout,
        int M, int N, int K,
        const float* __restrict__ bias,
        const void* __restrict__ aux1, const float* __restrict__ aux2) {
    __shared__ float As[BK][BM + 4];
    __shared__ float Bs[BK][BN + 4];
    const int tid = threadIdx.x;
    const int bm  = blockIdx.y * BM;
    const int bn  = blockIdx.x * BN;
    constexpr int TCOLS = BN / TN;
    const int rg = tid / TCOLS;
    const int cg = tid % TCOLS;

    float acc[TM][TN];
#pragma unroll
    for (int i = 0; i < TM; i++)
#pragma unroll
        for (int j = 0; j < TN; j++) acc[i][j] = 0.f;

    constexpr int ACH = BM * BK / 1024;   // float4 chunks per thread (A)
    constexpr int BCH = BN * BK / 1024;

    for (int k0 = 0; k0 < K; k0 += BK) {
#pragma unroll
        for (int i = 0; i < ACH; i++) {
            int chunk = tid + i * 256;
            int row = chunk / (BK / 4);
            int kc  = (chunk % (BK / 4)) * 4;
            const int gr = bm + row;
            const size_t off = (size_t)gr * K + k0 + kc;
            float4 v;
            if (MIXA) {
                float4 xv = ld4(A + off);
                float4 xp = make_float4(0.f, 0.f, 0.f, 0.f);
                if ((gr & (TSEQ - 1)) != 0) xp = ld4(A + off - HID);
                float4 c = ld4(cvec + k0 + kc);
                v.x = fmaf(xp.x - xv.x, c.x, xv.x);
                v.y = fmaf(xp.y - xv.y, c.y, xv.y);
                v.z = fmaf(xp.z - xv.z, c.z, xv.z);
                v.w = fmaf(xp.w - xv.w, c.w, xv.w);
            } else {
                v = ld4(A + off);
            }
            As[kc + 0][row] = v.x; As[kc + 1][row] = v.y;
            As[kc + 2][row] = v.z; As[kc + 3][row] = v.w;
        }
#pragma unroll
        for (int i = 0; i < BCH; i++) {
            int chunk = tid + i * 256;
            int row = chunk / (BK / 4);
            int kc  = (chunk % (BK / 4)) * 4;
            int gc  = bn + row;
            float4 v = make_float4(0.f, 0.f, 0.f, 0.f);
            if (gc < N) v = ld4(Bw + (size_t)gc * K + k0 + kc);
            Bs[kc + 0][row] = v.x; Bs[kc + 1][row] = v.y;
            Bs[kc + 2][row] = v.z; Bs[kc + 3][row] = v.w;
        }
        __syncthreads();
#pragma unroll
        for (int kk = 0; kk < BK; kk++) {
            float af[TM], bf[TN];
#pragma unroll
            for (int i = 0; i < TM; i++) af[i] = As[kk][rg * TM + i];
#pragma unroll
            for (int j = 0; j < TN; j++) bf[j] = Bs[kk][cg * TN + j];
#pragma unroll
            for (int i = 0; i < TM; i++)
#pragma unroll
                for (int j = 0; j < TN; j++)
                    acc[i][j] = fmaf(af[i], bf[j], acc[i][j]);
        }
        __syncthreads();
    }

#pragma unroll
    for (int i = 0; i < TM; i++) {
        const int r = bm + rg * TM + i;
#pragma unroll
        for (int u = 0; u < TN / 4; u++) {
            const int c0 = bn + cg * TN + u * 4;
            if (c0 >= N) continue;
            float4 bsv = make_float4(0.f, 0.f, 0.f, 0.f);
            float a1f[4] = {0.f, 0.f, 0.f, 0.f};
            float4 a2v = make_float4(0.f, 0.f, 0.f, 0.f);
            if (MODE == 3 || MODE == 4 || MODE == 5) bsv = ld4(bias + c0);
            if (MODE == 5) {
                ushort4 a1u = *reinterpret_cast<const ushort4*>(
                    (const unsigned short*)aux1 + (size_t)r * N + c0);
                a1f[0]=bff(a1u.x); a1f[1]=bff(a1u.y); a1f[2]=bff(a1u.z); a1f[3]=bff(a1u.w);
                a2v = ld4(aux2 + (size_t)r * N + c0);
            }
            float vals[4];
#pragma unroll
            for (int q = 0; q < 4; q++) {
                float d = acc[i][u * 4 + q];
                if (MODE == 1) d = tanhf(d);
                else if (MODE == 2) d = sigf(d);
                else if (MODE == 3) d = __expf(W_SCALE * sigf(d + f4get(bsv, q)));
                else if (MODE == 4) d = sigf(d + f4get(bsv, q));
                else if (MODE == 5) {
                    float v0 = a1f[q];
                    d = fmaf(f4get(a2v, q) - v0, sigf(d + f4get(bsv, q)), v0);
                }
                vals[q] = d;
            }
            if (OUTBF) {
                ushort4 o4;
                o4.x = bfr(vals[0]); o4.y = bfr(vals[1]);
                o4.z = bfr(vals[2]); o4.w = bfr(vals[3]);
                *reinterpret_cast<ushort4*>(
                    (unsigned short*)Cout + (size_t)r * N + c0) = o4;
            } else {
                st4((float*)Cout + (size_t)r * N + c0,
                    make_float4(vals[0], vals[1], vals[2], vals[3]));
            }
        }
    }
}

// ---------------------------------------------------------------------------
// prep: kk = l2norm_per_head(k * k_k); b = kk*a (over a, in place);
//       kn = k * (1 + (a-1)*k_a) (over k, in place)
// grid = BTOT rows, block = 256 (4 channels/thread, 16 threads per head)
// ---------------------------------------------------------------------------
__global__ __launch_bounds__(256) void prep_kernel(
        unsigned short* __restrict__ K16, unsigned short* __restrict__ A16,
        const float* __restrict__ kkc, const float* __restrict__ kac,
        unsigned short* __restrict__ KK16) {
    const int row = blockIdx.x;
    const int c   = threadIdx.x * 4;
    const size_t off = (size_t)row * HID + c;
    ushort4 ku = *reinterpret_cast<const ushort4*>(K16 + off);
    ushort4 au = *reinterpret_cast<const ushort4*>(A16 + off);
    float k[4] = {bff(ku.x), bff(ku.y), bff(ku.z), bff(ku.w)};
    float a[4] = {bff(au.x), bff(au.y), bff(au.z), bff(au.w)};
    float4 kc4 = ld4(kkc + c), ka4 = ld4(kac + c);
    float kr[4];
    kr[0] = k[0]*kc4.x; kr[1] = k[1]*kc4.y; kr[2] = k[2]*kc4.z; kr[3] = k[3]*kc4.w;
    float ss = kr[0]*kr[0] + kr[1]*kr[1] + kr[2]*kr[2] + kr[3]*kr[3];
    ss += __shfl_xor(ss, 1); ss += __shfl_xor(ss, 2);
    ss += __shfl_xor(ss, 4); ss += __shfl_xor(ss, 8);
    const float inv = 1.0f / fmaxf(sqrtf(ss), 1e-12f);
    float kkv[4], bv[4], knv[4];
    float kaf[4] = {ka4.x, ka4.y, ka4.z, ka4.w};
#pragma unroll
    for (int q = 0; q < 4; q++) {
        kkv[q] = kr[q] * inv;
        bv[q]  = kkv[q] * a[q];
        knv[q] = k[q] * fmaf(a[q] - 1.0f, kaf[q], 1.0f);
    }
    ushort4 o;
    o.x = bfr(kkv[0]); o.y = bfr(kkv[1]); o.z = bfr(kkv[2]); o.w = bfr(kkv[3]);
    *reinterpret_cast<ushort4*>(KK16 + off) = o;
    o.x = bfr(bv[0]);  o.y = bfr(bv[1]);  o.z = bfr(bv[2]);  o.w = bfr(bv[3]);
    *reinterpret_cast<ushort4*>(A16 + off) = o;
    o.x = bfr(knv[0]); o.y = bfr(knv[1]); o.z = bfr(knv[2]); o.w = bfr(knv[3]);
    *reinterpret_cast<ushort4*>(K16 + off) = o;
}

// ---------------------------------------------------------------------------
// Sequential delta-rule recurrence + fused bonus.
//   sa = -(kk . S[:,v]);  S[k][v] = S*ew[k] + b[k]*sa + kn[k]*v_t[v]
//   o[v] = sum_k r[k]*S[k][v];  bonus[v] = (sum_k r[k]*kn[k]*r_k[k]) * v_t[v]
// o -> Ob (fp32), bonus -> V16 in place (bf16; column-owned, race-free).
// 1 wave per (v-octet, b, h): grid = 8*128, block = 64.
// Lane l: kq = l&7 (k-octet in regs), vl = l>>3 (column within octet).
// ---------------------------------------------------------------------------
__global__ __launch_bounds__(64) void rec_kernel(
        const unsigned short* __restrict__ R16, const float* __restrict__ EW,
        const unsigned short* __restrict__ KN16, const unsigned short* __restrict__ KK16,
        const unsigned short* __restrict__ B16, unsigned short* __restrict__ V16,
        const float* __restrict__ rkw, float* __restrict__ Ob) {
    const int bid = blockIdx.x;
    const int sp  = bid >> 7;       // v-split 0..7
    const int bh  = bid & 127;
    const int l   = threadIdx.x;
    const int kq  = l & 7;
    const int vl  = l >> 3;
    const int bb  = bh >> 4, hh = bh & 15;
    const size_t rowoff = ((size_t)bb * TSEQ) * HID + hh * 64;
    const int k8 = kq * 8;
    const int vo = sp * 8 + vl;

    float rk[8];
    {
        float4 r0 = ld4(rkw + hh * 64 + k8);
        float4 r1 = ld4(rkw + hh * 64 + k8 + 4);
        rk[0]=r0.x; rk[1]=r0.y; rk[2]=r0.z; rk[3]=r0.w;
        rk[4]=r1.x; rk[5]=r1.y; rk[6]=r1.z; rk[7]=r1.w;
    }

    float S[8];
#pragma unroll
    for (int j = 0; j < 8; j++) S[j] = 0.f;

    uint4 ruA, knA, kkA, buA; float4 e0A, e1A; unsigned short vuA;
    uint4 ruB, knB, kkB, buB; float4 e0B, e1B; unsigned short vuB;

    auto LOAD = [&](uint4& ru, uint4& knu, uint4& kku, uint4& bu,
                    float4& e0, float4& e1, unsigned short& vu, int t) {
        const size_t ok = rowoff + (size_t)t * HID + k8;
        ru  = *reinterpret_cast<const uint4*>(R16  + ok);
        knu = *reinterpret_cast<const uint4*>(KN16 + ok);
        kku = *reinterpret_cast<const uint4*>(KK16 + ok);
        bu  = *reinterpret_cast<const uint4*>(B16  + ok);
        e0  = ld4(EW + ok); e1 = ld4(EW + ok + 4);
        vu  = V16[rowoff + (size_t)t * HID + vo];
    };
    auto STEP = [&](const uint4& ru, const uint4& knu, const uint4& kku,
                    const uint4& bu, const float4& e0, const float4& e1,
                    unsigned short vu, int t) {
        float rv[8], kn[8], kk[8], bb8[8];
        up8(ru, rv); up8(knu, kn); up8(kku, kk); up8(bu, bb8);
        float ew[8] = {e0.x,e0.y,e0.z,e0.w, e1.x,e1.y,e1.z,e1.w};
        const float vvf = bff(vu);
        float sp_ = 0.f;
#pragma unroll
        for (int j = 0; j < 8; j++) sp_ = fmaf(kk[j], S[j], sp_);
        sp_ += __shfl_xor(sp_, 1); sp_ += __shfl_xor(sp_, 2); sp_ += __shfl_xor(sp_, 4);
        const float sa = -sp_;
        float op = 0.f, s3 = 0.f;
#pragma unroll
        for (int j = 0; j < 8; j++) {
            S[j] = fmaf(ew[j], S[j], fmaf(bb8[j], sa, kn[j] * vvf));
            op = fmaf(rv[j], S[j], op);
            s3 = fmaf(rv[j] * kn[j], rk[j], s3);
        }
        op += __shfl_xor(op, 1); op += __shfl_xor(op, 2); op += __shfl_xor(op, 4);
        s3 += __shfl_xor(s3, 1); s3 += __shfl_xor(s3, 2); s3 += __shfl_xor(s3, 4);
        if (kq == 0) {
            const size_t oi = rowoff + (size_t)t * HID + vo;
            Ob[oi] = op;
            V16[oi] = bfr(s3 * vvf);
        }
    };

    LOAD(ruA, knA, kkA, buA, e0A, e1A, vuA, 0);
    for (int t = 0; t < TSEQ; t += 2) {
        LOAD(ruB, knB, kkB, buB, e0B, e1B, vuB, t + 1);
        STEP(ruA, knA, kkA, buA, e0A, e1A, vuA, t);
        if (t + 2 < TSEQ) LOAD(ruA, knA, kkA, buA, e0A, e1A, vuA, t + 2);
        STEP(ruB, knB, kkB, buB, e0B, e1B, vuB, t + 1);
    }
}

// ---------------------------------------------------------------------------
// post: per-head GroupNorm + precomputed bonus + gate -> y (fp32)
// y = ((o-mu)*rsqrt(var+eps)*gn_w + gn_b + bonus) * g
// grid = BTOT rows, block = 256
// ---------------------------------------------------------------------------
__global__ __launch_bounds__(256) void post_kernel(
        const float* __restrict__ Ob, const unsigned short* __restrict__ BN16,
        const float* __restrict__ G, const float* __restrict__ gnw,
        const float* __restrict__ gnb, float* __restrict__ Yb) {
    const int row = blockIdx.x;
    const int c   = threadIdx.x * 4;
    const size_t off = (size_t)row * HID + c;
    float4 o4 = ld4(Ob + off), g4 = ld4(G + off);
    ushort4 bu = *reinterpret_cast<const ushort4*>(BN16 + off);
    float bn[4] = {bff(bu.x), bff(bu.y), bff(bu.z), bff(bu.w)};

    float s1 = o4.x + o4.y + o4.z + o4.w;
    float s2 = o4.x*o4.x + o4.y*o4.y + o4.z*o4.z + o4.w*o4.w;
#pragma unroll
    for (int m = 1; m < 16; m <<= 1) {
        s1 += __shfl_xor(s1, m); s2 += __shfl_xor(s2, m);
    }
    const float mu  = s1 * (1.0f / 64.0f);
    const float var = s2 * (1.0f / 64.0f) - mu * mu;
    const float inv = rsqrtf(var + GN_EPS);
    float4 gw = ld4(gnw + c), gb = ld4(gnb + c);
    float4 y;
    y.x = (fmaf((o4.x - mu) * inv, gw.x, gb.x) + bn[0]) * g4.x;
    y.y = (fmaf((o4.y - mu) * inv, gw.y, gb.y) + bn[1]) * g4.y;
    y.z = (fmaf((o4.z - mu) * inv, gw.z, gb.z) + bn[2]) * g4.z;
    y.w = (fmaf((o4.w - mu) * inv, gw.w, gb.w) + bn[3]) * g4.w;
    st4(Yb + off, y);
}

// ---------------------------------------------------------------------------
extern "C" void kernel_launch(void* const* d_in, const int* in_sizes, int n_in,
                              void* d_out, int out_size, void* d_ws, size_t ws_size,
                              hipStream_t stream) {
    const float* x   = (const float*)d_in[0];
    const float* vf  = (const float*)d_in[1];
    const float* x_r = (const float*)d_in[2];
    const float* x_w = (const float*)d_in[3];
    const float* x_k = (const float*)d_in[4];
    const float* x_v = (const float*)d_in[5];
    const float* x_a = (const float*)d_in[6];
    const float* x_g = (const float*)d_in[7];
    const float* k_k = (const float*)d_in[8];
    const float* k_a = (const float*)d_in[9];
    const float* r_k = (const float*)d_in[10];
    const float* W_r = (const float*)d_in[11];
    const float* W_k = (const float*)d_in[12];
    const float* W_v = (const float*)d_in[13];
    const float* W_o = (const float*)d_in[14];
    const float* wA  = (const float*)d_in[15];
    const float* wB  = (const float*)d_in[16];
    const float* wb  = (const float*)d_in[17];
    const float* aA  = (const float*)d_in[18];
    const float* aB  = (const float*)d_in[19];
    const float* ab  = (const float*)d_in[20];
    const float* vA  = (const float*)d_in[21];
    const float* vB  = (const float*)d_in[22];
    const float* vb  = (const float*)d_in[23];
    const float* gA  = (const float*)d_in[24];
    const float* gB  = (const float*)d_in[25];
    const float* gnw = (const float*)d_in[26];
    const float* gnb = (const float*)d_in[27];
    float* out = (float*)d_out;

    float* ws = (float*)d_ws;
    const size_t SZ = (size_t)BTOT * HID;
    // layout: [EW fp32 SZ][R16|K16|V16|A16|KK16 bf16 5*SZ][H1 fp32 BTOT*160]
    float*          EW   = ws;
    unsigned short* P    = (unsigned short*)(ws + SZ);
    unsigned short* R16  = P;
    unsigned short* K16  = P + 1 * SZ;
    unsigned short* V16  = P + 2 * SZ;
    unsigned short* A16  = P + 3 * SZ;
    unsigned short* KK16 = P + 4 * SZ;
    float*          H1   = ws + SZ + (5 * SZ) / 2;
    float*          G    = EW;         // reuse (ew dead after rec)
    float*          Y    = (float*)P;  // reuse R16+K16 (dead after rec)

    const dim3 blk(256);
    const dim3 gRow(BTOT);
    const dim3 gBig(HID / 128, BTOT / 128);
    const dim3 gL64(1, BTOT / 64);
    const dim3 gL160(3, BTOT / 64);
    const float* np = nullptr;

    // r, k, v0 projections (mix fused into A-load), bf16 outputs
    gemm_bt<128,128,16,8,8,0,true,true><<<gBig, blk, 0, stream>>>(
        x, x_r, W_r, R16, BTOT, HID, HID, np, np, np);
    gemm_bt<128,128,16,8,8,0,true,true><<<gBig, blk, 0, stream>>>(
        x, x_k, W_k, K16, BTOT, HID, HID, np, np, np);
    gemm_bt<128,128,16,8,8,0,true,true><<<gBig, blk, 0, stream>>>(
        x, x_v, W_v, V16, BTOT, HID, HID, np, np, np);
    // v = v0 + (v_first - v0) * sigmoid(lora_v(xv) + vb)
    gemm_bt<64,64,16,4,4,0,true,false><<<gL64, blk, 0, stream>>>(
        x, x_v, vA, H1, BTOT, 64, HID, np, np, np);
    gemm_bt<128,128,16,8,8,5,false,true><<<gBig, blk, 0, stream>>>(
        H1, np, vB, V16, BTOT, HID, 64, vb, V16, vf);
    // ew = exp(W_SCALE * sigmoid(tanh(xw@wA^T)@wB^T + wb))  (fp32)
    gemm_bt<64,64,16,4,4,1,true,false><<<gL64, blk, 0, stream>>>(
        x, x_w, wA, H1, BTOT, 64, HID, np, np, np);
    gemm_bt<128,128,16,8,8,3,false,false><<<gBig, blk, 0, stream>>>(
        H1, np, wB, EW, BTOT, HID, 64, wb, np, np);
    // a = sigmoid(xa@aA^T@aB^T + ab)
    gemm_bt<64,64,16,4,4,0,true,false><<<gL64, blk, 0, stream>>>(
        x, x_a, aA, H1, BTOT, 64, HID, np, np, np);
    gemm_bt<128,128,16,8,8,4,false,true><<<gBig, blk, 0, stream>>>(
        H1, np, aB, A16, BTOT, HID, 64, ab, np, np);
    // kk (normalized) -> KK16, b=kk*a -> A16, kn -> K16
    prep_kernel<<<gRow, blk, 0, stream>>>(K16, A16, k_k, k_a, KK16);
    // recurrence -> o (d_out fp32), bonus -> V16 in place
    rec_kernel<<<dim3(1024), dim3(64), 0, stream>>>(
        R16, EW, K16, KK16, A16, V16, r_k, out);
    // g = sigmoid(xg@gA^T) @ gB^T  (fp32, reuses EW)
    gemm_bt<64,64,16,4,4,2,true,false><<<gL160, blk, 0, stream>>>(
        x, x_g, gA, H1, BTOT, 160, HID, np, np, np);
    gemm_bt<128,128,16,8,8,0,false,false><<<gBig, blk, 0, stream>>>(
        H1, np, gB, G, BTOT, HID, 160, np, np, np);
    // y = (GN(o) + bonus) * g  -> Y (fp32, reuses R16+K16)
    post_kernel<<<gRow, blk, 0, stream>>>(out, V16, G, gnw, gnb, Y);
    // out = y @ W_o^T
    gemm_bt<128,128,16,8,8,0,false,false><<<gBig, blk, 0, stream>>>(
        Y, np, W_o, out, BTOT, HID, HID, np, np, np);
    (void)in_sizes; (void)n_in; (void)out_size; (void)ws_size;
}

// Round 3
// 2150.139 us; speedup vs baseline: 1.7303x; 1.7303x over previous
//
#include <hip/hip_runtime.h>
#include <hip/hip_bf16.h>

// ---------------------------------------------------------------------------
// RWKV7 attention block — Round 3.
// bf16 MFMA GEMMs (m97 structure: 128^2 tile, BK=32, global_load_lds w16),
// token-shift mix fused into A-staging, fp32 decay, re-laid-out recurrence
// (16 k-lanes x 4 v-cols, 2048 waves = 2/SIMD).
// B=8, T=2048, H=1024, NH=16, DK=DV=64, VDIM=1024.
// ws: EW f32 64MB + 5x bf16 160MB + H1 5MB + W16 ~9.9MB = ~239MB.
// ---------------------------------------------------------------------------

#define DEVI __device__ __forceinline__

constexpr int TSEQ = 2048;
constexpr int HID  = 1024;
constexpr int BTOT = 16384;   // B*T
constexpr float W_SCALE = -0.6065306597126334f;
constexpr float GN_EPS  = 6.4e-4f;   // 64 * 1e-5

using s16x8  = __attribute__((ext_vector_type(8))) short;   // 8 bf16 (4 VGPR)
using f32x4v = __attribute__((ext_vector_type(4))) float;   // MFMA acc

DEVI float4 ld4(const float* p) { return *reinterpret_cast<const float4*>(p); }
DEVI void   st4(float* p, float4 v) { *reinterpret_cast<float4*>(p) = v; }
DEVI float  sigf(float x) { return 1.0f / (1.0f + __expf(-x)); }
// bf16 <-> f32 (RNE)
DEVI unsigned short bfr(float f) {
    unsigned int u = __float_as_uint(f);
    return (unsigned short)((u + 0x7fffu + ((u >> 16) & 1u)) >> 16);
}
DEVI float bff(unsigned short s) { return __uint_as_float(((unsigned int)s) << 16); }
DEVI unsigned int pk2(float lo, float hi) {
    return ((unsigned int)bfr(hi) << 16) | (unsigned int)bfr(lo);
}
DEVI void up4(uint2 u, float* f) {
    f[0] = bff((unsigned short)(u.x & 0xffffu)); f[1] = bff((unsigned short)(u.x >> 16));
    f[2] = bff((unsigned short)(u.y & 0xffffu)); f[3] = bff((unsigned short)(u.y >> 16));
}
// async global->LDS, 16B per lane; LDS dest = wave-uniform base + lane*16
DEVI void gl16(const void* g, void* l) {
    __builtin_amdgcn_global_load_lds(
        (const __attribute__((address_space(1))) unsigned int*)g,
        (__attribute__((address_space(3))) unsigned int*)l, 16, 0, 0);
}

// ---------------------------------------------------------------------------
// f32 -> bf16 cast (weights)
// ---------------------------------------------------------------------------
__global__ __launch_bounds__(256) void cast_kernel(
        const float* __restrict__ s, unsigned short* __restrict__ d, int n) {
    int i = (blockIdx.x * 256 + threadIdx.x) * 4;
    if (i >= n) return;
    float4 v = ld4(s + i);
    ushort4 o; o.x = bfr(v.x); o.y = bfr(v.y); o.z = bfr(v.z); o.w = bfr(v.w);
    *reinterpret_cast<ushort4*>(d + i) = o;
}

// ---------------------------------------------------------------------------
// MFMA bf16 GEMM: C[M,N] = epilogue( A'[M,K] @ Bw[N,K]^T ), fp32 accum.
// BK=32, 256 threads. mfma_f32_16x16x32_bf16.
// A frag: row=l&15, k=(l>>4)*8+i ; B frag: col=l&15, same k ;
// D frag: col=l&15, row=(l>>4)*4+q   [guide m89/m91 verified]
// MIXA: A' = x + (x_prev - x)*cvec, computed in regs -> ds_write (bf16).
// else: A is bf16, staged via global_load_lds. B always bf16 + gload_lds.
// MODE: 0 none | 1 tanh | 2 sigmoid | 3 exp(W_SCALE*sig(d+b)) | 4 sig(d+b)
//       | 5 vmix: a1 + (a2-a1)*sig(d+b)
// ---------------------------------------------------------------------------
template<int BM, int BN, int MODE, bool MIXA, bool OUTBF>
__global__ __launch_bounds__(256) void mgemm(
        const void* __restrict__ Ap, const float* __restrict__ cvec,
        const unsigned short* __restrict__ Bw, void* Cout,
        int N, int K,
        const float* __restrict__ bias,
        const unsigned short* aux1, const float* __restrict__ aux2) {
    constexpr int BK = 32;
    constexpr int WM_ = (BN == 128) ? 2 : (BM == 128 ? 4 : 2);
    constexpr int WN_ = (BN == 128) ? 2 : (BM == 128 ? 1 : 2);
    constexpr int WTM = BM / WM_, WTN = BN / WN_;
    constexpr int MF = WTM / 16, NF = WTN / 16;
    constexpr int ACALLS = (BM * BK) / 2048;   // 4KB (=2048 bf16) per 256-thr call
    constexpr int BCALLS = (BN * BK) / 2048;
    __shared__ __align__(16) unsigned short As[BM * BK];
    __shared__ __align__(16) unsigned short Bs[BN * BK];
    const int tid = threadIdx.x;
    const int w = tid >> 6, l = tid & 63;
    const int bm = blockIdx.y * BM, bn = blockIdx.x * BN;
    const int wm = w / WN_, wn = w % WN_;
    const int lr = l & 15, lk = (l >> 4) * 8;

    f32x4v acc[MF][NF];
#pragma unroll
    for (int i = 0; i < MF; i++)
#pragma unroll
        for (int j = 0; j < NF; j++)
#pragma unroll
            for (int q = 0; q < 4; q++) acc[i][j][q] = 0.f;

    for (int k0 = 0; k0 < K; k0 += BK) {
        if (MIXA) {
            const float* Axf = (const float*)Ap;
#pragma unroll
            for (int c = 0; c < ACALLS; c++) {
                int idx = c * 256 + tid;
                int row = idx >> 2, kp = (idx & 3) * 8;
                int gr = bm + row;
                const float* xp = Axf + (size_t)gr * K + k0 + kp;
                float4 x0 = ld4(xp), x1 = ld4(xp + 4);
                float4 p0 = make_float4(0.f,0.f,0.f,0.f), p1 = p0;
                if ((gr & (TSEQ - 1)) != 0) { p0 = ld4(xp - HID); p1 = ld4(xp - HID + 4); }
                float4 c0 = ld4(cvec + k0 + kp), c1 = ld4(cvec + k0 + kp + 4);
                uint4 u;
                u.x = pk2(fmaf(p0.x - x0.x, c0.x, x0.x), fmaf(p0.y - x0.y, c0.y, x0.y));
                u.y = pk2(fmaf(p0.z - x0.z, c0.z, x0.z), fmaf(p0.w - x0.w, c0.w, x0.w));
                u.z = pk2(fmaf(p1.x - x1.x, c1.x, x1.x), fmaf(p1.y - x1.y, c1.y, x1.y));
                u.w = pk2(fmaf(p1.z - x1.z, c1.z, x1.z), fmaf(p1.w - x1.w, c1.w, x1.w));
                *reinterpret_cast<uint4*>(&As[idx * 8]) = u;
            }
        } else {
            const unsigned short* Ab = (const unsigned short*)Ap;
#pragma unroll
            for (int c = 0; c < ACALLS; c++) {
                int idx = c * 256 + tid;
                int row = idx >> 2, kp = (idx & 3) * 8;
                gl16(Ab + (size_t)(bm + row) * K + k0 + kp, &As[c * 2048 + w * 512]);
            }
        }
#pragma unroll
        for (int c = 0; c < BCALLS; c++) {
            int idx = c * 256 + tid;
            int row = idx >> 2, kp = (idx & 3) * 8;
            int gc = bn + row; if (gc > N - 1) gc = N - 1;   // clamp (N=160 tiles)
            gl16(Bw + (size_t)gc * K + k0 + kp, &Bs[c * 2048 + w * 512]);
        }
        __syncthreads();
        s16x8 afx[MF], bfx[NF];
#pragma unroll
        for (int i = 0; i < MF; i++)
            afx[i] = *reinterpret_cast<const s16x8*>(&As[(wm * WTM + i * 16 + lr) * BK + lk]);
#pragma unroll
        for (int j = 0; j < NF; j++)
            bfx[j] = *reinterpret_cast<const s16x8*>(&Bs[(wn * WTN + j * 16 + lr) * BK + lk]);
#pragma unroll
        for (int i = 0; i < MF; i++)
#pragma unroll
            for (int j = 0; j < NF; j++)
                acc[i][j] = __builtin_amdgcn_mfma_f32_16x16x32_bf16(
                    afx[i], bfx[j], acc[i][j], 0, 0, 0);
        __syncthreads();
    }

#pragma unroll
    for (int i = 0; i < MF; i++) {
        const int grow0 = bm + wm * WTM + i * 16 + (l >> 4) * 4;
#pragma unroll
        for (int j = 0; j < NF; j++) {
            const int gcol = bn + wn * WTN + j * 16 + lr;
            if (gcol >= N) continue;
            const float bsv = (MODE == 3 || MODE == 4 || MODE == 5) ? bias[gcol] : 0.f;
#pragma unroll
            for (int q = 0; q < 4; q++) {
                const int grow = grow0 + q;
                float d = acc[i][j][q];
                if (MODE == 1) d = tanhf(d);
                else if (MODE == 2) d = sigf(d);
                else if (MODE == 3) d = __expf(W_SCALE * sigf(d + bsv));
                else if (MODE == 4) d = sigf(d + bsv);
                else if (MODE == 5) {
                    float v0 = bff(aux1[(size_t)grow * N + gcol]);
                    d = fmaf(aux2[(size_t)grow * N + gcol] - v0, sigf(d + bsv), v0);
                }
                if (OUTBF) ((unsigned short*)Cout)[(size_t)grow * N + gcol] = bfr(d);
                else       ((float*)Cout)[(size_t)grow * N + gcol] = d;
            }
        }
    }
}

// ---------------------------------------------------------------------------
// prep: kk = l2norm_per_head(k*k_k) -> KK16; b = kk*a -> A16 (in place);
//       kn = k*(1+(a-1)*k_a) -> K16 (in place)
// ---------------------------------------------------------------------------
__global__ __launch_bounds__(256) void prep_kernel(
        unsigned short* __restrict__ K16, unsigned short* __restrict__ A16,
        const float* __restrict__ kkc, const float* __restrict__ kac,
        unsigned short* __restrict__ KK16) {
    const int row = blockIdx.x;
    const int c   = threadIdx.x * 4;
    const size_t off = (size_t)row * HID + c;
    ushort4 ku = *reinterpret_cast<const ushort4*>(K16 + off);
    ushort4 au = *reinterpret_cast<const ushort4*>(A16 + off);
    float k[4] = {bff(ku.x), bff(ku.y), bff(ku.z), bff(ku.w)};
    float a[4] = {bff(au.x), bff(au.y), bff(au.z), bff(au.w)};
    float4 kc4 = ld4(kkc + c), ka4 = ld4(kac + c);
    float kr[4];
    kr[0] = k[0]*kc4.x; kr[1] = k[1]*kc4.y; kr[2] = k[2]*kc4.z; kr[3] = k[3]*kc4.w;
    float ss = kr[0]*kr[0] + kr[1]*kr[1] + kr[2]*kr[2] + kr[3]*kr[3];
    ss += __shfl_xor(ss, 1); ss += __shfl_xor(ss, 2);
    ss += __shfl_xor(ss, 4); ss += __shfl_xor(ss, 8);
    const float inv = 1.0f / fmaxf(sqrtf(ss), 1e-12f);
    float kaf[4] = {ka4.x, ka4.y, ka4.z, ka4.w};
    float kkv[4], bv[4], knv[4];
#pragma unroll
    for (int q = 0; q < 4; q++) {
        kkv[q] = kr[q] * inv;
        bv[q]  = kkv[q] * a[q];
        knv[q] = k[q] * fmaf(a[q] - 1.0f, kaf[q], 1.0f);
    }
    ushort4 o;
    o.x = bfr(kkv[0]); o.y = bfr(kkv[1]); o.z = bfr(kkv[2]); o.w = bfr(kkv[3]);
    *reinterpret_cast<ushort4*>(KK16 + off) = o;
    o.x = bfr(bv[0]);  o.y = bfr(bv[1]);  o.z = bfr(bv[2]);  o.w = bfr(bv[3]);
    *reinterpret_cast<ushort4*>(A16 + off) = o;
    o.x = bfr(knv[0]); o.y = bfr(knv[1]); o.z = bfr(knv[2]); o.w = bfr(knv[3]);
    *reinterpret_cast<ushort4*>(K16 + off) = o;
}

// ---------------------------------------------------------------------------
// Sequential delta-rule recurrence + fused bonus.  16 k-lanes x 4 v-cols.
// grid = 16*128 single-wave blocks (2048 waves = 2/SIMD).
// lane l: kq=l&15 (4 k at kq*4), vl=l>>4 (col within v-quad); vo=sp*4+vl.
// ---------------------------------------------------------------------------
__global__ __launch_bounds__(64) void rec_kernel(
        const unsigned short* __restrict__ R16, const float* __restrict__ EW,
        const unsigned short* __restrict__ KN16, const unsigned short* __restrict__ KK16,
        const unsigned short* __restrict__ B16, unsigned short* __restrict__ V16,
        const float* __restrict__ rkw, float* __restrict__ Ob) {
    const int bid = blockIdx.x;
    const int sp  = bid >> 7;       // v-split 0..15
    const int bh  = bid & 127;
    const int l   = threadIdx.x;
    const int kq  = l & 15;
    const int vl  = l >> 4;
    const int bb  = bh >> 4, hh = bh & 15;
    const size_t rowoff = ((size_t)bb * TSEQ) * HID + hh * 64;
    const int k4 = kq * 4;
    const int vo = sp * 4 + vl;

    float rk[4];
    { float4 t = ld4(rkw + hh * 64 + k4); rk[0]=t.x; rk[1]=t.y; rk[2]=t.z; rk[3]=t.w; }

    float S[4] = {0.f, 0.f, 0.f, 0.f};

    uint2 ruA, knA, kkA, buA; float4 ewA; unsigned short vuA;
    uint2 ruB, knB, kkB, buB; float4 ewB; unsigned short vuB;

    auto LOAD = [&](uint2& ru, uint2& knu, uint2& kku, uint2& bu,
                    float4& e, unsigned short& vu, int t) {
        const size_t ok = rowoff + (size_t)t * HID + k4;
        ru  = *reinterpret_cast<const uint2*>(R16  + ok);
        knu = *reinterpret_cast<const uint2*>(KN16 + ok);
        kku = *reinterpret_cast<const uint2*>(KK16 + ok);
        bu  = *reinterpret_cast<const uint2*>(B16  + ok);
        e   = ld4(EW + ok);
        vu  = V16[rowoff + (size_t)t * HID + vo];
    };
    auto STEP = [&](uint2 ru, uint2 knu, uint2 kku, uint2 bu,
                    float4 e, unsigned short vu, int t) {
        float rv[4], kn[4], kk[4], bb4[4];
        up4(ru, rv); up4(knu, kn); up4(kku, kk); up4(bu, bb4);
        float ew[4] = {e.x, e.y, e.z, e.w};
        const float vvf = bff(vu);
        float d = 0.f;
#pragma unroll
        for (int j = 0; j < 4; j++) d = fmaf(kk[j], S[j], d);
        d += __shfl_xor(d, 1); d += __shfl_xor(d, 2);
        d += __shfl_xor(d, 4); d += __shfl_xor(d, 8);
        const float sa = -d;
        float op = 0.f, s3 = 0.f;
#pragma unroll
        for (int j = 0; j < 4; j++) {
            S[j] = fmaf(ew[j], S[j], fmaf(bb4[j], sa, kn[j] * vvf));
            op = fmaf(rv[j], S[j], op);
            s3 = fmaf(rv[j] * kn[j], rk[j], s3);
        }
        op += __shfl_xor(op, 1); op += __shfl_xor(op, 2);
        op += __shfl_xor(op, 4); op += __shfl_xor(op, 8);
        s3 += __shfl_xor(s3, 1); s3 += __shfl_xor(s3, 2);
        s3 += __shfl_xor(s3, 4); s3 += __shfl_xor(s3, 8);
        if (kq == 0) {
            const size_t oi = rowoff + (size_t)t * HID + vo;
            Ob[oi]  = op;
            V16[oi] = bfr(s3 * vvf);
        }
    };

    LOAD(ruA, knA, kkA, buA, ewA, vuA, 0);
    for (int t = 0; t < TSEQ; t += 2) {
        LOAD(ruB, knB, kkB, buB, ewB, vuB, t + 1);
        STEP(ruA, knA, kkA, buA, ewA, vuA, t);
        if (t + 2 < TSEQ) LOAD(ruA, knA, kkA, buA, ewA, vuA, t + 2);
        STEP(ruB, knB, kkB, buB, ewB, vuB, t + 1);
    }
}

// ---------------------------------------------------------------------------
// post: y = (GN_perhead(o)*gn_w + gn_b + bonus) * g  -> bf16 Y
// ---------------------------------------------------------------------------
__global__ __launch_bounds__(256) void post_kernel(
        const float* __restrict__ Ob, const unsigned short* __restrict__ BN16,
        const float* __restrict__ G, const float* __restrict__ gnw,
        const float* __restrict__ gnb, unsigned short* __restrict__ Y16) {
    const int row = blockIdx.x;
    const int c   = threadIdx.x * 4;
    const size_t off = (size_t)row * HID + c;
    float4 o4 = ld4(Ob + off), g4 = ld4(G + off);
    ushort4 bu = *reinterpret_cast<const ushort4*>(BN16 + off);
    float bn[4] = {bff(bu.x), bff(bu.y), bff(bu.z), bff(bu.w)};

    float s1 = o4.x + o4.y + o4.z + o4.w;
    float s2 = o4.x*o4.x + o4.y*o4.y + o4.z*o4.z + o4.w*o4.w;
#pragma unroll
    for (int m = 1; m < 16; m <<= 1) {
        s1 += __shfl_xor(s1, m); s2 += __shfl_xor(s2, m);
    }
    const float mu  = s1 * (1.0f / 64.0f);
    const float var = s2 * (1.0f / 64.0f) - mu * mu;
    const float inv = rsqrtf(var + GN_EPS);
    float4 gw = ld4(gnw + c), gb = ld4(gnb + c);
    ushort4 y;
    y.x = bfr((fmaf((o4.x - mu) * inv, gw.x, gb.x) + bn[0]) * g4.x);
    y.y = bfr((fmaf((o4.y - mu) * inv, gw.y, gb.y) + bn[1]) * g4.y);
    y.z = bfr((fmaf((o4.z - mu) * inv, gw.z, gb.z) + bn[2]) * g4.z);
    y.w = bfr((fmaf((o4.w - mu) * inv, gw.w, gb.w) + bn[3]) * g4.w);
    *reinterpret_cast<ushort4*>(Y16 + off) = y;
}

// ---------------------------------------------------------------------------
extern "C" void kernel_launch(void* const* d_in, const int* in_sizes, int n_in,
                              void* d_out, int out_size, void* d_ws, size_t ws_size,
                              hipStream_t stream) {
    const float* x   = (const float*)d_in[0];
    const float* vf  = (const float*)d_in[1];
    const float* x_r = (const float*)d_in[2];
    const float* x_w = (const float*)d_in[3];
    const float* x_k = (const float*)d_in[4];
    const float* x_v = (const float*)d_in[5];
    const float* x_a = (const float*)d_in[6];
    const float* x_g = (const float*)d_in[7];
    const float* k_k = (const float*)d_in[8];
    const float* k_a = (const float*)d_in[9];
    const float* r_k = (const float*)d_in[10];
    const float* W_r = (const float*)d_in[11];
    const float* W_k = (const float*)d_in[12];
    const float* W_v = (const float*)d_in[13];
    const float* W_o = (const float*)d_in[14];
    const float* wA  = (const float*)d_in[15];
    const float* wB  = (const float*)d_in[16];
    const float* wb  = (const float*)d_in[17];
    const float* aA  = (const float*)d_in[18];
    const float* aB  = (const float*)d_in[19];
    const float* ab  = (const float*)d_in[20];
    const float* vA  = (const float*)d_in[21];
    const float* vB  = (const float*)d_in[22];
    const float* vb  = (const float*)d_in[23];
    const float* gA  = (const float*)d_in[24];
    const float* gB  = (const float*)d_in[25];
    const float* gnw = (const float*)d_in[26];
    const float* gnb = (const float*)d_in[27];
    float* out = (float*)d_out;

    float* ws = (float*)d_ws;
    const size_t SZ = (size_t)BTOT * HID;
    const size_t HH = (size_t)HID * HID;
    float*          EW   = ws;                           // fp32 decay -> later G
    unsigned short* P    = (unsigned short*)(ws + SZ);
    unsigned short* R16  = P;             // r        -> later Y (bf16)
    unsigned short* K16  = P + 1 * SZ;    // k -> kn
    unsigned short* V16  = P + 2 * SZ;    // v -> bonus
    unsigned short* A16  = P + 3 * SZ;    // a -> b
    unsigned short* KK16 = P + 4 * SZ;    // kk
    unsigned short* H1   = P + 5 * SZ;    // lora hidden bf16 [BTOT,<=160]
    unsigned short* WR   = H1 + (size_t)BTOT * 160;      // bf16 weights
    unsigned short* Wr16 = WR;
    unsigned short* Wk16 = WR + 1 * HH;
    unsigned short* Wv16 = WR + 2 * HH;
    unsigned short* Wo16 = WR + 3 * HH;
    unsigned short* wA16 = WR + 4 * HH;
    unsigned short* wB16 = wA16 + 65536;
    unsigned short* aA16 = wB16 + 65536;
    unsigned short* aB16 = aA16 + 65536;
    unsigned short* vA16 = aB16 + 65536;
    unsigned short* vB16 = vA16 + 65536;
    unsigned short* gA16 = vB16 + 65536;
    unsigned short* gB16 = gA16 + 163840;
    unsigned short* Y16  = R16;           // reuse
    float*          G    = EW;            // reuse

    const dim3 blk(256);
    const dim3 gBig(8, 128);     // 128x128 tiles over 16384x1024
    const dim3 gL64(1, 256);     // 64x64 tiles, N=64
    const dim3 gL160(3, 256);    // 64x64 tiles, N=160
    const float* np = nullptr;
    const unsigned short* nu = nullptr;

    auto CAST = [&](const float* s, unsigned short* d, int n) {
        cast_kernel<<<dim3((n / 4 + 255) / 256), blk, 0, stream>>>(s, d, n);
    };
    CAST(W_r, Wr16, (int)HH); CAST(W_k, Wk16, (int)HH);
    CAST(W_v, Wv16, (int)HH); CAST(W_o, Wo16, (int)HH);
    CAST(wA, wA16, 65536); CAST(wB, wB16, 65536);
    CAST(aA, aA16, 65536); CAST(aB, aB16, 65536);
    CAST(vA, vA16, 65536); CAST(vB, vB16, 65536);
    CAST(gA, gA16, 163840); CAST(gB, gB16, 163840);

    // r, k, v0 projections (mix fused into A staging)
    mgemm<128,128,0,true,true><<<gBig, blk, 0, stream>>>(
        x, x_r, Wr16, R16, HID, HID, np, nu, np);
    mgemm<128,128,0,true,true><<<gBig, blk, 0, stream>>>(
        x, x_k, Wk16, K16, HID, HID, np, nu, np);
    mgemm<128,128,0,true,true><<<gBig, blk, 0, stream>>>(
        x, x_v, Wv16, V16, HID, HID, np, nu, np);
    // v = v0 + (v_first - v0) * sigmoid(lora_v(xv) + vb)
    mgemm<64,64,0,true,true><<<gL64, blk, 0, stream>>>(
        x, x_v, vA16, H1, 64, HID, np, nu, np);
    mgemm<128,128,5,false,true><<<gBig, blk, 0, stream>>>(
        H1, np, vB16, V16, HID, 64, vb, V16, vf);
    // ew = exp(W_SCALE * sigmoid(tanh(xw@wA^T)@wB^T + wb))  (fp32)
    mgemm<64,64,1,true,true><<<gL64, blk, 0, stream>>>(
        x, x_w, wA16, H1, 64, HID, np, nu, np);
    mgemm<128,128,3,false,false><<<gBig, blk, 0, stream>>>(
        H1, np, wB16, EW, HID, 64, wb, nu, np);
    // a = sigmoid(xa@aA^T@aB^T + ab)
    mgemm<64,64,0,true,true><<<gL64, blk, 0, stream>>>(
        x, x_a, aA16, H1, 64, HID, np, nu, np);
    mgemm<128,128,4,false,true><<<gBig, blk, 0, stream>>>(
        H1, np, aB16, A16, HID, 64, ab, nu, np);
    // kk -> KK16, b -> A16, kn -> K16
    prep_kernel<<<dim3(BTOT), blk, 0, stream>>>(K16, A16, k_k, k_a, KK16);
    // recurrence -> o (d_out f32), bonus -> V16
    rec_kernel<<<dim3(2048), dim3(64), 0, stream>>>(
        R16, EW, K16, KK16, A16, V16, r_k, out);
    // g = sigmoid(xg@gA^T) @ gB^T  (fp32, reuses EW)
    mgemm<64,64,2,true,true><<<gL160, blk, 0, stream>>>(
        x, x_g, gA16, H1, 160, HID, np, nu, np);
    mgemm<128,128,0,false,false><<<gBig, blk, 0, stream>>>(
        H1, np, gB16, G, HID, 160, np, nu, np);
    // y = (GN(o) + bonus) * g -> bf16 Y
    post_kernel<<<dim3(BTOT), blk, 0, stream>>>(out, V16, G, gnw, gnb, Y16);
    // out = y @ W_o^T
    mgemm<128,128,0,false,false><<<gBig, blk, 0, stream>>>(
        Y16, np, Wo16, out, HID, HID, np, nu, np);
    (void)in_sizes; (void)n_in; (void)out_size; (void)ws_size;
}

// Round 4
// 1645.027 us; speedup vs baseline: 2.2616x; 1.3071x over previous
//
#include <hip/hip_runtime.h>
#include <hip/hip_bf16.h>

// ---------------------------------------------------------------------------
// RWKV7 attention block — Round 4.
// bf16 MFMA GEMMs (m97 structure), token-shift mix fused into A-staging.
// Recurrence: 4-wave blocks, CHUNK=32 double-buffered LDS staging via
// global_load_lds (T3 2-phase), bonus moved out of the serial loop into post.
// B=8, T=2048, H=1024, NH=16, DK=DV=64, VDIM=1024.
// ---------------------------------------------------------------------------

#define DEVI __device__ __forceinline__

constexpr int TSEQ = 2048;
constexpr int HID  = 1024;
constexpr int BTOT = 16384;   // B*T
constexpr float W_SCALE = -0.6065306597126334f;
constexpr float GN_EPS  = 6.4e-4f;   // 64 * 1e-5

using s16x8  = __attribute__((ext_vector_type(8))) short;   // 8 bf16 (4 VGPR)
using f32x4v = __attribute__((ext_vector_type(4))) float;   // MFMA acc

DEVI float4 ld4(const float* p) { return *reinterpret_cast<const float4*>(p); }
DEVI void   st4(float* p, float4 v) { *reinterpret_cast<float4*>(p) = v; }
DEVI float  sigf(float x) { return 1.0f / (1.0f + __expf(-x)); }
// bf16 <-> f32 (RNE)
DEVI unsigned short bfr(float f) {
    unsigned int u = __float_as_uint(f);
    return (unsigned short)((u + 0x7fffu + ((u >> 16) & 1u)) >> 16);
}
DEVI float bff(unsigned short s) { return __uint_as_float(((unsigned int)s) << 16); }
DEVI unsigned int pk2(float lo, float hi) {
    return ((unsigned int)bfr(hi) << 16) | (unsigned int)bfr(lo);
}
DEVI void up4(uint2 u, float* f) {
    f[0] = bff((unsigned short)(u.x & 0xffffu)); f[1] = bff((unsigned short)(u.x >> 16));
    f[2] = bff((unsigned short)(u.y & 0xffffu)); f[3] = bff((unsigned short)(u.y >> 16));
}
// async global->LDS, 16B per lane; LDS dest = wave-uniform base + lane*16
DEVI void gl16(const void* g, void* l) {
    __builtin_amdgcn_global_load_lds(
        (const __attribute__((address_space(1))) unsigned int*)g,
        (__attribute__((address_space(3))) unsigned int*)l, 16, 0, 0);
}

// ---------------------------------------------------------------------------
// f32 -> bf16 cast (weights)
// ---------------------------------------------------------------------------
__global__ __launch_bounds__(256) void cast_kernel(
        const float* __restrict__ s, unsigned short* __restrict__ d, int n) {
    int i = (blockIdx.x * 256 + threadIdx.x) * 4;
    if (i >= n) return;
    float4 v = ld4(s + i);
    ushort4 o; o.x = bfr(v.x); o.y = bfr(v.y); o.z = bfr(v.z); o.w = bfr(v.w);
    *reinterpret_cast<ushort4*>(d + i) = o;
}

// ---------------------------------------------------------------------------
// MFMA bf16 GEMM: C[M,N] = epilogue( A'[M,K] @ Bw[N,K]^T ), fp32 accum.
// (unchanged from Round 3 — passed at absmax 4.5e-3)
// ---------------------------------------------------------------------------
template<int BM, int BN, int MODE, bool MIXA, bool OUTBF>
__global__ __launch_bounds__(256) void mgemm(
        const void* __restrict__ Ap, const float* __restrict__ cvec,
        const unsigned short* __restrict__ Bw, void* Cout,
        int N, int K,
        const float* __restrict__ bias,
        const unsigned short* aux1, const float* __restrict__ aux2) {
    constexpr int BK = 32;
    constexpr int WM_ = (BN == 128) ? 2 : (BM == 128 ? 4 : 2);
    constexpr int WN_ = (BN == 128) ? 2 : (BM == 128 ? 1 : 2);
    constexpr int WTM = BM / WM_, WTN = BN / WN_;
    constexpr int MF = WTM / 16, NF = WTN / 16;
    constexpr int ACALLS = (BM * BK) / 2048;
    constexpr int BCALLS = (BN * BK) / 2048;
    __shared__ __align__(16) unsigned short As[BM * BK];
    __shared__ __align__(16) unsigned short Bs[BN * BK];
    const int tid = threadIdx.x;
    const int w = tid >> 6, l = tid & 63;
    const int bm = blockIdx.y * BM, bn = blockIdx.x * BN;
    const int wm = w / WN_, wn = w % WN_;
    const int lr = l & 15, lk = (l >> 4) * 8;

    f32x4v acc[MF][NF];
#pragma unroll
    for (int i = 0; i < MF; i++)
#pragma unroll
        for (int j = 0; j < NF; j++)
#pragma unroll
            for (int q = 0; q < 4; q++) acc[i][j][q] = 0.f;

    for (int k0 = 0; k0 < K; k0 += BK) {
        if (MIXA) {
            const float* Axf = (const float*)Ap;
#pragma unroll
            for (int c = 0; c < ACALLS; c++) {
                int idx = c * 256 + tid;
                int row = idx >> 2, kp = (idx & 3) * 8;
                int gr = bm + row;
                const float* xp = Axf + (size_t)gr * K + k0 + kp;
                float4 x0 = ld4(xp), x1 = ld4(xp + 4);
                float4 p0 = make_float4(0.f,0.f,0.f,0.f), p1 = p0;
                if ((gr & (TSEQ - 1)) != 0) { p0 = ld4(xp - HID); p1 = ld4(xp - HID + 4); }
                float4 c0 = ld4(cvec + k0 + kp), c1 = ld4(cvec + k0 + kp + 4);
                uint4 u;
                u.x = pk2(fmaf(p0.x - x0.x, c0.x, x0.x), fmaf(p0.y - x0.y, c0.y, x0.y));
                u.y = pk2(fmaf(p0.z - x0.z, c0.z, x0.z), fmaf(p0.w - x0.w, c0.w, x0.w));
                u.z = pk2(fmaf(p1.x - x1.x, c1.x, x1.x), fmaf(p1.y - x1.y, c1.y, x1.y));
                u.w = pk2(fmaf(p1.z - x1.z, c1.z, x1.z), fmaf(p1.w - x1.w, c1.w, x1.w));
                *reinterpret_cast<uint4*>(&As[idx * 8]) = u;
            }
        } else {
            const unsigned short* Ab = (const unsigned short*)Ap;
#pragma unroll
            for (int c = 0; c < ACALLS; c++) {
                int idx = c * 256 + tid;
                int row = idx >> 2, kp = (idx & 3) * 8;
                gl16(Ab + (size_t)(bm + row) * K + k0 + kp, &As[c * 2048 + w * 512]);
            }
        }
#pragma unroll
        for (int c = 0; c < BCALLS; c++) {
            int idx = c * 256 + tid;
            int row = idx >> 2, kp = (idx & 3) * 8;
            int gc = bn + row; if (gc > N - 1) gc = N - 1;   // clamp (N=160 tiles)
            gl16(Bw + (size_t)gc * K + k0 + kp, &Bs[c * 2048 + w * 512]);
        }
        __syncthreads();
        s16x8 afx[MF], bfx[NF];
#pragma unroll
        for (int i = 0; i < MF; i++)
            afx[i] = *reinterpret_cast<const s16x8*>(&As[(wm * WTM + i * 16 + lr) * BK + lk]);
#pragma unroll
        for (int j = 0; j < NF; j++)
            bfx[j] = *reinterpret_cast<const s16x8*>(&Bs[(wn * WTN + j * 16 + lr) * BK + lk]);
#pragma unroll
        for (int i = 0; i < MF; i++)
#pragma unroll
            for (int j = 0; j < NF; j++)
                acc[i][j] = __builtin_amdgcn_mfma_f32_16x16x32_bf16(
                    afx[i], bfx[j], acc[i][j], 0, 0, 0);
        __syncthreads();
    }

#pragma unroll
    for (int i = 0; i < MF; i++) {
        const int grow0 = bm + wm * WTM + i * 16 + (l >> 4) * 4;
#pragma unroll
        for (int j = 0; j < NF; j++) {
            const int gcol = bn + wn * WTN + j * 16 + lr;
            if (gcol >= N) continue;
            const float bsv = (MODE == 3 || MODE == 4 || MODE == 5) ? bias[gcol] : 0.f;
#pragma unroll
            for (int q = 0; q < 4; q++) {
                const int grow = grow0 + q;
                float d = acc[i][j][q];
                if (MODE == 1) d = tanhf(d);
                else if (MODE == 2) d = sigf(d);
                else if (MODE == 3) d = __expf(W_SCALE * sigf(d + bsv));
                else if (MODE == 4) d = sigf(d + bsv);
                else if (MODE == 5) {
                    float v0 = bff(aux1[(size_t)grow * N + gcol]);
                    d = fmaf(aux2[(size_t)grow * N + gcol] - v0, sigf(d + bsv), v0);
                }
                if (OUTBF) ((unsigned short*)Cout)[(size_t)grow * N + gcol] = bfr(d);
                else       ((float*)Cout)[(size_t)grow * N + gcol] = d;
            }
        }
    }
}

// ---------------------------------------------------------------------------
// prep (unchanged): kk -> KK16; b = kk*a -> A16; kn -> K16
// ---------------------------------------------------------------------------
__global__ __launch_bounds__(256) void prep_kernel(
        unsigned short* __restrict__ K16, unsigned short* __restrict__ A16,
        const float* __restrict__ kkc, const float* __restrict__ kac,
        unsigned short* __restrict__ KK16) {
    const int row = blockIdx.x;
    const int c   = threadIdx.x * 4;
    const size_t off = (size_t)row * HID + c;
    ushort4 ku = *reinterpret_cast<const ushort4*>(K16 + off);
    ushort4 au = *reinterpret_cast<const ushort4*>(A16 + off);
    float k[4] = {bff(ku.x), bff(ku.y), bff(ku.z), bff(ku.w)};
    float a[4] = {bff(au.x), bff(au.y), bff(au.z), bff(au.w)};
    float4 kc4 = ld4(kkc + c), ka4 = ld4(kac + c);
    float kr[4];
    kr[0] = k[0]*kc4.x; kr[1] = k[1]*kc4.y; kr[2] = k[2]*kc4.z; kr[3] = k[3]*kc4.w;
    float ss = kr[0]*kr[0] + kr[1]*kr[1] + kr[2]*kr[2] + kr[3]*kr[3];
    ss += __shfl_xor(ss, 1); ss += __shfl_xor(ss, 2);
    ss += __shfl_xor(ss, 4); ss += __shfl_xor(ss, 8);
    const float inv = 1.0f / fmaxf(sqrtf(ss), 1e-12f);
    float kaf[4] = {ka4.x, ka4.y, ka4.z, ka4.w};
    float kkv[4], bv[4], knv[4];
#pragma unroll
    for (int q = 0; q < 4; q++) {
        kkv[q] = kr[q] * inv;
        bv[q]  = kkv[q] * a[q];
        knv[q] = k[q] * fmaf(a[q] - 1.0f, kaf[q], 1.0f);
    }
    ushort4 o;
    o.x = bfr(kkv[0]); o.y = bfr(kkv[1]); o.z = bfr(kkv[2]); o.w = bfr(kkv[3]);
    *reinterpret_cast<ushort4*>(KK16 + off) = o;
    o.x = bfr(bv[0]);  o.y = bfr(bv[1]);  o.z = bfr(bv[2]);  o.w = bfr(bv[3]);
    *reinterpret_cast<ushort4*>(A16 + off) = o;
    o.x = bfr(knv[0]); o.y = bfr(knv[1]); o.z = bfr(knv[2]); o.w = bfr(knv[3]);
    *reinterpret_cast<ushort4*>(K16 + off) = o;
}

// ---------------------------------------------------------------------------
// Sequential delta-rule recurrence, CHUNK=32 double-buffered LDS staging.
// Block = 256 thr (4 waves) = one (b,h) x 16 v-cols; grid = 128*4 = 512.
// Wave w, lane l: kq=l&15 (4 k at kq*4), vl=l>>4; vo = spq*16 + w*4 + vl.
// LDS: stK[2][4][32][64] bf16 (R,KN,KK,B) 32KB + stE[2][32][64] f32 16KB
//      + stV[2][32][16] bf16 2KB = 50KB.
// ---------------------------------------------------------------------------
constexpr int RCH = 32;   // chunk length

__global__ __launch_bounds__(256) void rec_kernel(
        const unsigned short* __restrict__ R16, const float* __restrict__ EW,
        const unsigned short* __restrict__ KN16, const unsigned short* __restrict__ KK16,
        const unsigned short* __restrict__ B16, const unsigned short* __restrict__ V16,
        float* __restrict__ Ob) {
    __shared__ __align__(16) unsigned short stK[2][4][RCH][64];
    __shared__ __align__(16) float          stE[2][RCH][64];
    __shared__ __align__(16) unsigned short stV[2][RCH][16];
    const int bid = blockIdx.x;
    const int bh  = bid >> 2;       // (b,h) 0..127
    const int spq = bid & 3;        // v-split quad
    const int tid = threadIdx.x;
    const int w = tid >> 6, l = tid & 63;
    const int kq = l & 15, vl = l >> 4;
    const int bb = bh >> 4, hh = bh & 15;
    const size_t rowoff = ((size_t)bb * TSEQ) * HID + hh * 64;
    const int k4 = kq * 4;
    const int vo = spq * 16 + w * 4 + vl;
    const int colbase = spq * 16;

    // staging source indices (constant per thread)
    const int srow = tid >> 3;               // 0..31 (bf16 tensors)
    const int sk   = (tid & 7) * 8;          // bf16 col
    const int er   = tid >> 4;               // 0..15 (ew f32, per half)
    const int ec   = (tid & 15) * 4;         // f32 col

    auto STAGE = [&](int buf, int t0) {
        const size_t so = rowoff + (size_t)(t0 + srow) * HID + sk;
        gl16(R16  + so, (char*)&stK[buf][0][0][0] + w * 1024);
        gl16(KN16 + so, (char*)&stK[buf][1][0][0] + w * 1024);
        gl16(KK16 + so, (char*)&stK[buf][2][0][0] + w * 1024);
        gl16(B16  + so, (char*)&stK[buf][3][0][0] + w * 1024);
        const size_t eo = rowoff + (size_t)(t0 + er) * HID + ec;
        gl16(EW + eo,                     (char*)&stE[buf][0][0]  + w * 1024);
        gl16(EW + eo + (size_t)16 * HID,  (char*)&stE[buf][16][0] + w * 1024);
        if (tid < 64) {   // wave 0 stages the 16 v-cols
            const size_t vof = rowoff + (size_t)(t0 + (tid >> 1)) * HID
                               + colbase + (tid & 1) * 8;
            gl16(V16 + vof, (char*)&stV[buf][0][0]);
        }
    };

    float S[4] = {0.f, 0.f, 0.f, 0.f};

    STAGE(0, 0);
    asm volatile("s_waitcnt vmcnt(0)" ::: "memory");
    __syncthreads();

    int buf = 0;
    for (int c = 0; c < TSEQ / RCH; c++) {
        if (c + 1 < TSEQ / RCH) STAGE(buf ^ 1, (c + 1) * RCH);
        const int t0 = c * RCH;
#pragma unroll
        for (int s = 0; s < RCH; s++) {
            uint2 kku = *reinterpret_cast<const uint2*>(&stK[buf][2][s][k4]);
            uint2 ru  = *reinterpret_cast<const uint2*>(&stK[buf][0][s][k4]);
            uint2 knu = *reinterpret_cast<const uint2*>(&stK[buf][1][s][k4]);
            uint2 bu  = *reinterpret_cast<const uint2*>(&stK[buf][3][s][k4]);
            float4 e  = *reinterpret_cast<const float4*>(&stE[buf][s][k4]);
            const float vvf = bff(stV[buf][s][w * 4 + vl]);
            float kkf[4], rf[4], knf[4], bf4[4];
            up4(kku, kkf); up4(ru, rf); up4(knu, knf); up4(bu, bf4);
            float ew[4] = {e.x, e.y, e.z, e.w};
            float d = 0.f;
#pragma unroll
            for (int j = 0; j < 4; j++) d = fmaf(kkf[j], S[j], d);
            d += __shfl_xor(d, 1); d += __shfl_xor(d, 2);
            d += __shfl_xor(d, 4); d += __shfl_xor(d, 8);
            const float sa = -d;
            float op = 0.f;
#pragma unroll
            for (int j = 0; j < 4; j++) {
                S[j] = fmaf(ew[j], S[j], fmaf(bf4[j], sa, knf[j] * vvf));
                op = fmaf(rf[j], S[j], op);
            }
            op += __shfl_xor(op, 1); op += __shfl_xor(op, 2);
            op += __shfl_xor(op, 4); op += __shfl_xor(op, 8);
            if (kq == 0) Ob[rowoff + (size_t)(t0 + s) * HID + vo] = op;
        }
        asm volatile("s_waitcnt vmcnt(0)" ::: "memory");
        __syncthreads();
        buf ^= 1;
    }
}

// ---------------------------------------------------------------------------
// post: y = (GN_perhead(o)*gn_w + gn_b + (sum r*kn*r_k)*v) * g  -> bf16 Y
// bonus folded in here (independent of the recurrence state).
// ---------------------------------------------------------------------------
__global__ __launch_bounds__(256) void post_kernel(
        const float* __restrict__ Ob, const unsigned short* __restrict__ R16,
        const unsigned short* __restrict__ KN16, const unsigned short* __restrict__ V16,
        const float* __restrict__ G, const float* __restrict__ rkw,
        const float* __restrict__ gnw, const float* __restrict__ gnb,
        unsigned short* __restrict__ Y16) {
    const int row = blockIdx.x;
    const int tid = threadIdx.x;
    const int c   = tid * 4;
    const size_t off = (size_t)row * HID + c;
    float4 o4 = ld4(Ob + off), g4 = ld4(G + off);
    ushort4 ru = *reinterpret_cast<const ushort4*>(R16 + off);
    ushort4 ku = *reinterpret_cast<const ushort4*>(KN16 + off);
    ushort4 vu = *reinterpret_cast<const ushort4*>(V16 + off);
    float r[4]  = {bff(ru.x), bff(ru.y), bff(ru.z), bff(ru.w)};
    float kn[4] = {bff(ku.x), bff(ku.y), bff(ku.z), bff(ku.w)};
    float v[4]  = {bff(vu.x), bff(vu.y), bff(vu.z), bff(vu.w)};
    const int hh = tid >> 4;
    const int d0 = c & 63;
    float4 rk4 = ld4(rkw + hh * 64 + d0);

    float s1 = o4.x + o4.y + o4.z + o4.w;
    float s2 = o4.x*o4.x + o4.y*o4.y + o4.z*o4.z + o4.w*o4.w;
    float s3 = r[0]*kn[0]*rk4.x + r[1]*kn[1]*rk4.y + r[2]*kn[2]*rk4.z + r[3]*kn[3]*rk4.w;
#pragma unroll
    for (int m = 1; m < 16; m <<= 1) {
        s1 += __shfl_xor(s1, m); s2 += __shfl_xor(s2, m); s3 += __shfl_xor(s3, m);
    }
    const float mu  = s1 * (1.0f / 64.0f);
    const float var = s2 * (1.0f / 64.0f) - mu * mu;
    const float inv = rsqrtf(var + GN_EPS);
    float4 gw = ld4(gnw + c), gb = ld4(gnb + c);
    ushort4 y;
    y.x = bfr((fmaf((o4.x - mu) * inv, gw.x, gb.x) + s3 * v[0]) * g4.x);
    y.y = bfr((fmaf((o4.y - mu) * inv, gw.y, gb.y) + s3 * v[1]) * g4.y);
    y.z = bfr((fmaf((o4.z - mu) * inv, gw.z, gb.z) + s3 * v[2]) * g4.z);
    y.w = bfr((fmaf((o4.w - mu) * inv, gw.w, gb.w) + s3 * v[3]) * g4.w);
    *reinterpret_cast<ushort4*>(Y16 + off) = y;
}

// ---------------------------------------------------------------------------
extern "C" void kernel_launch(void* const* d_in, const int* in_sizes, int n_in,
                              void* d_out, int out_size, void* d_ws, size_t ws_size,
                              hipStream_t stream) {
    const float* x   = (const float*)d_in[0];
    const float* vf  = (const float*)d_in[1];
    const float* x_r = (const float*)d_in[2];
    const float* x_w = (const float*)d_in[3];
    const float* x_k = (const float*)d_in[4];
    const float* x_v = (const float*)d_in[5];
    const float* x_a = (const float*)d_in[6];
    const float* x_g = (const float*)d_in[7];
    const float* k_k = (const float*)d_in[8];
    const float* k_a = (const float*)d_in[9];
    const float* r_k = (const float*)d_in[10];
    const float* W_r = (const float*)d_in[11];
    const float* W_k = (const float*)d_in[12];
    const float* W_v = (const float*)d_in[13];
    const float* W_o = (const float*)d_in[14];
    const float* wA  = (const float*)d_in[15];
    const float* wB  = (const float*)d_in[16];
    const float* wb  = (const float*)d_in[17];
    const float* aA  = (const float*)d_in[18];
    const float* aB  = (const float*)d_in[19];
    const float* ab  = (const float*)d_in[20];
    const float* vA  = (const float*)d_in[21];
    const float* vB  = (const float*)d_in[22];
    const float* vb  = (const float*)d_in[23];
    const float* gA  = (const float*)d_in[24];
    const float* gB  = (const float*)d_in[25];
    const float* gnw = (const float*)d_in[26];
    const float* gnb = (const float*)d_in[27];
    float* out = (float*)d_out;

    float* ws = (float*)d_ws;
    const size_t SZ = (size_t)BTOT * HID;
    const size_t HH = (size_t)HID * HID;
    float*          EW   = ws;                           // fp32 decay -> later G
    unsigned short* P    = (unsigned short*)(ws + SZ);
    unsigned short* R16  = P;             // r        -> later Y (bf16)
    unsigned short* K16  = P + 1 * SZ;    // k -> kn
    unsigned short* V16  = P + 2 * SZ;    // v
    unsigned short* A16  = P + 3 * SZ;    // a -> b
    unsigned short* KK16 = P + 4 * SZ;    // kk
    unsigned short* H1   = P + 5 * SZ;    // lora hidden bf16 [BTOT,<=160]
    unsigned short* WR   = H1 + (size_t)BTOT * 160;      // bf16 weights
    unsigned short* Wr16 = WR;
    unsigned short* Wk16 = WR + 1 * HH;
    unsigned short* Wv16 = WR + 2 * HH;
    unsigned short* Wo16 = WR + 3 * HH;
    unsigned short* wA16 = WR + 4 * HH;
    unsigned short* wB16 = wA16 + 65536;
    unsigned short* aA16 = wB16 + 65536;
    unsigned short* aB16 = aA16 + 65536;
    unsigned short* vA16 = aB16 + 65536;
    unsigned short* vB16 = vA16 + 65536;
    unsigned short* gA16 = vB16 + 65536;
    unsigned short* gB16 = gA16 + 163840;
    unsigned short* Y16  = R16;           // reuse (read/write same-thread)
    float*          G    = EW;            // reuse

    const dim3 blk(256);
    const dim3 gBig(8, 128);     // 128x128 tiles over 16384x1024
    const dim3 gL64(1, 256);     // 64x64 tiles, N=64
    const dim3 gL160(3, 256);    // 64x64 tiles, N=160
    const float* np = nullptr;
    const unsigned short* nu = nullptr;

    auto CAST = [&](const float* s, unsigned short* d, int n) {
        cast_kernel<<<dim3((n / 4 + 255) / 256), blk, 0, stream>>>(s, d, n);
    };
    CAST(W_r, Wr16, (int)HH); CAST(W_k, Wk16, (int)HH);
    CAST(W_v, Wv16, (int)HH); CAST(W_o, Wo16, (int)HH);
    CAST(wA, wA16, 65536); CAST(wB, wB16, 65536);
    CAST(aA, aA16, 65536); CAST(aB, aB16, 65536);
    CAST(vA, vA16, 65536); CAST(vB, vB16, 65536);
    CAST(gA, gA16, 163840); CAST(gB, gB16, 163840);

    // r, k, v0 projections (mix fused into A staging)
    mgemm<128,128,0,true,true><<<gBig, blk, 0, stream>>>(
        x, x_r, Wr16, R16, HID, HID, np, nu, np);
    mgemm<128,128,0,true,true><<<gBig, blk, 0, stream>>>(
        x, x_k, Wk16, K16, HID, HID, np, nu, np);
    mgemm<128,128,0,true,true><<<gBig, blk, 0, stream>>>(
        x, x_v, Wv16, V16, HID, HID, np, nu, np);
    // v = v0 + (v_first - v0) * sigmoid(lora_v(xv) + vb)
    mgemm<64,64,0,true,true><<<gL64, blk, 0, stream>>>(
        x, x_v, vA16, H1, 64, HID, np, nu, np);
    mgemm<128,128,5,false,true><<<gBig, blk, 0, stream>>>(
        H1, np, vB16, V16, HID, 64, vb, V16, vf);
    // ew = exp(W_SCALE * sigmoid(tanh(xw@wA^T)@wB^T + wb))  (fp32)
    mgemm<64,64,1,true,true><<<gL64, blk, 0, stream>>>(
        x, x_w, wA16, H1, 64, HID, np, nu, np);
    mgemm<128,128,3,false,false><<<gBig, blk, 0, stream>>>(
        H1, np, wB16, EW, HID, 64, wb, nu, np);
    // a = sigmoid(xa@aA^T@aB^T + ab)
    mgemm<64,64,0,true,true><<<gL64, blk, 0, stream>>>(
        x, x_a, aA16, H1, 64, HID, np, nu, np);
    mgemm<128,128,4,false,true><<<gBig, blk, 0, stream>>>(
        H1, np, aB16, A16, HID, 64, ab, nu, np);
    // kk -> KK16, b -> A16, kn -> K16
    prep_kernel<<<dim3(BTOT), blk, 0, stream>>>(K16, A16, k_k, k_a, KK16);
    // recurrence -> o (d_out f32); 512 blocks x 4 waves
    rec_kernel<<<dim3(512), blk, 0, stream>>>(
        R16, EW, K16, KK16, A16, V16, out);
    // g = sigmoid(xg@gA^T) @ gB^T  (fp32, reuses EW)
    mgemm<64,64,2,true,true><<<gL160, blk, 0, stream>>>(
        x, x_g, gA16, H1, 160, HID, np, nu, np);
    mgemm<128,128,0,false,false><<<gBig, blk, 0, stream>>>(
        H1, np, gB16, G, HID, 160, np, nu, np);
    // y = (GN(o) + bonus) * g -> bf16 Y
    post_kernel<<<dim3(BTOT), blk, 0, stream>>>(
        out, R16, K16, V16, G, r_k, gnw, gnb, Y16);
    // out = y @ W_o^T
    mgemm<128,128,0,false,false><<<gBig, blk, 0, stream>>>(
        Y16, np, Wo16, out, HID, HID, np, nu, np);
    (void)in_sizes; (void)n_in; (void)out_size; (void)ws_size;
}

// Round 5
// 1512.323 us; speedup vs baseline: 2.4601x; 1.0877x over previous
//
#include <hip/hip_runtime.h>
#include <hip/hip_bf16.h>

// ---------------------------------------------------------------------------
// RWKV7 attention block — Round 5.
// - bf16 MFMA GEMMs, grid swapped so A-tile-sharing blocks co-locate per XCD.
// - Recurrence: dual concurrent shuffle trees (rb/rkn precomputed in prep),
//   XCD-co-located v-split blocks, CHUNK=32 double-buffered LDS staging.
// B=8, T=2048, H=1024, NH=16, DK=DV=64, VDIM=1024.
// ---------------------------------------------------------------------------

#define DEVI __device__ __forceinline__

constexpr int TSEQ = 2048;
constexpr int HID  = 1024;
constexpr int BTOT = 16384;   // B*T
constexpr float W_SCALE = -0.6065306597126334f;
constexpr float GN_EPS  = 6.4e-4f;   // 64 * 1e-5

using s16x8  = __attribute__((ext_vector_type(8))) short;   // 8 bf16 (4 VGPR)
using f32x4v = __attribute__((ext_vector_type(4))) float;   // MFMA acc

DEVI float4 ld4(const float* p) { return *reinterpret_cast<const float4*>(p); }
DEVI void   st4(float* p, float4 v) { *reinterpret_cast<float4*>(p) = v; }
DEVI float  sigf(float x) { return 1.0f / (1.0f + __expf(-x)); }
// bf16 <-> f32 (RNE)
DEVI unsigned short bfr(float f) {
    unsigned int u = __float_as_uint(f);
    return (unsigned short)((u + 0x7fffu + ((u >> 16) & 1u)) >> 16);
}
DEVI float bff(unsigned short s) { return __uint_as_float(((unsigned int)s) << 16); }
DEVI unsigned int pk2(float lo, float hi) {
    return ((unsigned int)bfr(hi) << 16) | (unsigned int)bfr(lo);
}
DEVI void up4(uint2 u, float* f) {
    f[0] = bff((unsigned short)(u.x & 0xffffu)); f[1] = bff((unsigned short)(u.x >> 16));
    f[2] = bff((unsigned short)(u.y & 0xffffu)); f[3] = bff((unsigned short)(u.y >> 16));
}
// async global->LDS, 16B per lane; LDS dest = wave-uniform base + lane*16
DEVI void gl16(const void* g, void* l) {
    __builtin_amdgcn_global_load_lds(
        (const __attribute__((address_space(1))) unsigned int*)g,
        (__attribute__((address_space(3))) unsigned int*)l, 16, 0, 0);
}

// ---------------------------------------------------------------------------
// f32 -> bf16 cast (weights)
// ---------------------------------------------------------------------------
__global__ __launch_bounds__(256) void cast_kernel(
        const float* __restrict__ s, unsigned short* __restrict__ d, int n) {
    int i = (blockIdx.x * 256 + threadIdx.x) * 4;
    if (i >= n) return;
    float4 v = ld4(s + i);
    ushort4 o; o.x = bfr(v.x); o.y = bfr(v.y); o.z = bfr(v.z); o.w = bfr(v.w);
    *reinterpret_cast<ushort4*>(d + i) = o;
}

// ---------------------------------------------------------------------------
// MFMA bf16 GEMM: C[M,N] = epilogue( A'[M,K] @ Bw[N,K]^T ), fp32 accum.
// Grid: x = M-tiles (bm), y = N-tiles (bn) -> linear id = bm + gx*bn,
// XCD = bm%8: all bn-blocks sharing an A-tile land on one XCD (L2 reuse).
// ---------------------------------------------------------------------------
template<int BM, int BN, int MODE, bool MIXA, bool OUTBF>
__global__ __launch_bounds__(256) void mgemm(
        const void* __restrict__ Ap, const float* __restrict__ cvec,
        const unsigned short* __restrict__ Bw, void* Cout,
        int N, int K,
        const float* __restrict__ bias,
        const unsigned short* aux1, const float* __restrict__ aux2) {
    constexpr int BK = 32;
    constexpr int WM_ = (BN == 128) ? 2 : (BM == 128 ? 4 : 2);
    constexpr int WN_ = (BN == 128) ? 2 : (BM == 128 ? 1 : 2);
    constexpr int WTM = BM / WM_, WTN = BN / WN_;
    constexpr int MF = WTM / 16, NF = WTN / 16;
    constexpr int ACALLS = (BM * BK) / 2048;
    constexpr int BCALLS = (BN * BK) / 2048;
    __shared__ __align__(16) unsigned short As[BM * BK];
    __shared__ __align__(16) unsigned short Bs[BN * BK];
    const int tid = threadIdx.x;
    const int w = tid >> 6, l = tid & 63;
    const int bm = blockIdx.x * BM, bn = blockIdx.y * BN;   // swapped mapping
    const int wm = w / WN_, wn = w % WN_;
    const int lr = l & 15, lk = (l >> 4) * 8;

    f32x4v acc[MF][NF];
#pragma unroll
    for (int i = 0; i < MF; i++)
#pragma unroll
        for (int j = 0; j < NF; j++)
#pragma unroll
            for (int q = 0; q < 4; q++) acc[i][j][q] = 0.f;

    for (int k0 = 0; k0 < K; k0 += BK) {
        if (MIXA) {
            const float* Axf = (const float*)Ap;
#pragma unroll
            for (int c = 0; c < ACALLS; c++) {
                int idx = c * 256 + tid;
                int row = idx >> 2, kp = (idx & 3) * 8;
                int gr = bm + row;
                const float* xp = Axf + (size_t)gr * K + k0 + kp;
                float4 x0 = ld4(xp), x1 = ld4(xp + 4);
                float4 p0 = make_float4(0.f,0.f,0.f,0.f), p1 = p0;
                if ((gr & (TSEQ - 1)) != 0) { p0 = ld4(xp - HID); p1 = ld4(xp - HID + 4); }
                float4 c0 = ld4(cvec + k0 + kp), c1 = ld4(cvec + k0 + kp + 4);
                uint4 u;
                u.x = pk2(fmaf(p0.x - x0.x, c0.x, x0.x), fmaf(p0.y - x0.y, c0.y, x0.y));
                u.y = pk2(fmaf(p0.z - x0.z, c0.z, x0.z), fmaf(p0.w - x0.w, c0.w, x0.w));
                u.z = pk2(fmaf(p1.x - x1.x, c1.x, x1.x), fmaf(p1.y - x1.y, c1.y, x1.y));
                u.w = pk2(fmaf(p1.z - x1.z, c1.z, x1.z), fmaf(p1.w - x1.w, c1.w, x1.w));
                *reinterpret_cast<uint4*>(&As[idx * 8]) = u;
            }
        } else {
            const unsigned short* Ab = (const unsigned short*)Ap;
#pragma unroll
            for (int c = 0; c < ACALLS; c++) {
                int idx = c * 256 + tid;
                int row = idx >> 2, kp = (idx & 3) * 8;
                gl16(Ab + (size_t)(bm + row) * K + k0 + kp, &As[c * 2048 + w * 512]);
            }
        }
#pragma unroll
        for (int c = 0; c < BCALLS; c++) {
            int idx = c * 256 + tid;
            int row = idx >> 2, kp = (idx & 3) * 8;
            int gc = bn + row; if (gc > N - 1) gc = N - 1;   // clamp (N=160 tiles)
            gl16(Bw + (size_t)gc * K + k0 + kp, &Bs[c * 2048 + w * 512]);
        }
        __syncthreads();
        s16x8 afx[MF], bfx[NF];
#pragma unroll
        for (int i = 0; i < MF; i++)
            afx[i] = *reinterpret_cast<const s16x8*>(&As[(wm * WTM + i * 16 + lr) * BK + lk]);
#pragma unroll
        for (int j = 0; j < NF; j++)
            bfx[j] = *reinterpret_cast<const s16x8*>(&Bs[(wn * WTN + j * 16 + lr) * BK + lk]);
#pragma unroll
        for (int i = 0; i < MF; i++)
#pragma unroll
            for (int j = 0; j < NF; j++)
                acc[i][j] = __builtin_amdgcn_mfma_f32_16x16x32_bf16(
                    afx[i], bfx[j], acc[i][j], 0, 0, 0);
        __syncthreads();
    }

#pragma unroll
    for (int i = 0; i < MF; i++) {
        const int grow0 = bm + wm * WTM + i * 16 + (l >> 4) * 4;
#pragma unroll
        for (int j = 0; j < NF; j++) {
            const int gcol = bn + wn * WTN + j * 16 + lr;
            if (gcol >= N) continue;
            const float bsv = (MODE == 3 || MODE == 4 || MODE == 5) ? bias[gcol] : 0.f;
#pragma unroll
            for (int q = 0; q < 4; q++) {
                const int grow = grow0 + q;
                float d = acc[i][j][q];
                if (MODE == 1) d = tanhf(d);
                else if (MODE == 2) d = sigf(d);
                else if (MODE == 3) d = __expf(W_SCALE * sigf(d + bsv));
                else if (MODE == 4) d = sigf(d + bsv);
                else if (MODE == 5) {
                    float v0 = bff(aux1[(size_t)grow * N + gcol]);
                    d = fmaf(aux2[(size_t)grow * N + gcol] - v0, sigf(d + bsv), v0);
                }
                if (OUTBF) ((unsigned short*)Cout)[(size_t)grow * N + gcol] = bfr(d);
                else       ((float*)Cout)[(size_t)grow * N + gcol] = d;
            }
        }
    }
}

// ---------------------------------------------------------------------------
// prep: kk -> KK16; b = kk*a -> A16; kn -> K16;
//       rb = sum_k r*b, rkn = sum_k r*kn  -> RBt[bh][t][2] (f32)
// grid = BTOT rows, block = 256 (16 threads per head, 4 ch each)
// ---------------------------------------------------------------------------
__global__ __launch_bounds__(256) void prep_kernel(
        unsigned short* __restrict__ K16, unsigned short* __restrict__ A16,
        const unsigned short* __restrict__ R16,
        const float* __restrict__ kkc, const float* __restrict__ kac,
        unsigned short* __restrict__ KK16, float* __restrict__ RBt) {
    const int row = blockIdx.x;
    const int tid = threadIdx.x;
    const int c   = tid * 4;
    const size_t off = (size_t)row * HID + c;
    ushort4 ku = *reinterpret_cast<const ushort4*>(K16 + off);
    ushort4 au = *reinterpret_cast<const ushort4*>(A16 + off);
    ushort4 ru = *reinterpret_cast<const ushort4*>(R16 + off);
    float k[4] = {bff(ku.x), bff(ku.y), bff(ku.z), bff(ku.w)};
    float a[4] = {bff(au.x), bff(au.y), bff(au.z), bff(au.w)};
    float r[4] = {bff(ru.x), bff(ru.y), bff(ru.z), bff(ru.w)};
    float4 kc4 = ld4(kkc + c), ka4 = ld4(kac + c);
    float kr[4];
    kr[0] = k[0]*kc4.x; kr[1] = k[1]*kc4.y; kr[2] = k[2]*kc4.z; kr[3] = k[3]*kc4.w;
    float ss = kr[0]*kr[0] + kr[1]*kr[1] + kr[2]*kr[2] + kr[3]*kr[3];
    ss += __shfl_xor(ss, 1); ss += __shfl_xor(ss, 2);
    ss += __shfl_xor(ss, 4); ss += __shfl_xor(ss, 8);
    const float inv = 1.0f / fmaxf(sqrtf(ss), 1e-12f);
    float kaf[4] = {ka4.x, ka4.y, ka4.z, ka4.w};
    float kkv[4], bv[4], knv[4];
    float rbp = 0.f, rknp = 0.f;
#pragma unroll
    for (int q = 0; q < 4; q++) {
        kkv[q] = kr[q] * inv;
        bv[q]  = kkv[q] * a[q];
        knv[q] = k[q] * fmaf(a[q] - 1.0f, kaf[q], 1.0f);
        rbp  = fmaf(r[q], bv[q],  rbp);
        rknp = fmaf(r[q], knv[q], rknp);
    }
    ushort4 o;
    o.x = bfr(kkv[0]); o.y = bfr(kkv[1]); o.z = bfr(kkv[2]); o.w = bfr(kkv[3]);
    *reinterpret_cast<ushort4*>(KK16 + off) = o;
    o.x = bfr(bv[0]);  o.y = bfr(bv[1]);  o.z = bfr(bv[2]);  o.w = bfr(bv[3]);
    *reinterpret_cast<ushort4*>(A16 + off) = o;
    o.x = bfr(knv[0]); o.y = bfr(knv[1]); o.z = bfr(knv[2]); o.w = bfr(knv[3]);
    *reinterpret_cast<ushort4*>(K16 + off) = o;
    rbp  += __shfl_xor(rbp, 1);  rknp += __shfl_xor(rknp, 1);
    rbp  += __shfl_xor(rbp, 2);  rknp += __shfl_xor(rknp, 2);
    rbp  += __shfl_xor(rbp, 4);  rknp += __shfl_xor(rknp, 4);
    rbp  += __shfl_xor(rbp, 8);  rknp += __shfl_xor(rknp, 8);
    if ((tid & 15) == 0) {
        const int hh = tid >> 4;
        const int bb = row >> 11, t = row & (TSEQ - 1);
        float2 st; st.x = rbp; st.y = rknp;
        *reinterpret_cast<float2*>(
            &RBt[(((size_t)(bb * 16 + hh)) * TSEQ + t) * 2]) = st;
    }
}

// ---------------------------------------------------------------------------
// Sequential delta-rule recurrence, CHUNK=32 double-buffered LDS staging.
// Dual concurrent trees: t1 = kk.S_prev, t2 = (r*ew).S_prev;
// o = t2 + rb*(-t1) + rkn*v  (rb, rkn precomputed).
// Block = 256 thr (4 waves) = one (b,h) x 16 v-cols; grid = 512,
// bid = spq*128 + bh  ->  all 4 spq of a (b,h) on one XCD (bh%8).
// ---------------------------------------------------------------------------
constexpr int RCH = 32;   // chunk length

__global__ __launch_bounds__(256) void rec_kernel(
        const unsigned short* __restrict__ R16, const float* __restrict__ EW,
        const unsigned short* __restrict__ KN16, const unsigned short* __restrict__ KK16,
        const unsigned short* __restrict__ B16, const unsigned short* __restrict__ V16,
        const float* __restrict__ RBt, float* __restrict__ Ob) {
    __shared__ __align__(16) unsigned short stK[2][4][RCH][64];
    __shared__ __align__(16) float          stE[2][RCH][64];
    __shared__ __align__(16) unsigned short stV[2][RCH][16];
    __shared__ __align__(16) float          stRB[2][RCH][2];
    const int bid = blockIdx.x;
    const int spq = bid >> 7;       // v-split quad (slow index -> XCD co-loc)
    const int bh  = bid & 127;
    const int tid = threadIdx.x;
    const int w = tid >> 6, l = tid & 63;
    const int kq = l & 15, vl = l >> 4;
    const int bb = bh >> 4, hh = bh & 15;
    const size_t rowoff = ((size_t)bb * TSEQ) * HID + hh * 64;
    const size_t rboff  = (size_t)bh * TSEQ * 2;
    const int k4 = kq * 4;
    const int vo = spq * 16 + w * 4 + vl;
    const int colbase = spq * 16;

    const int srow = tid >> 3;               // 0..31 (bf16 tensors)
    const int sk   = (tid & 7) * 8;
    const int er   = tid >> 4;               // 0..15 (ew f32, per half)
    const int ec   = (tid & 15) * 4;

    auto STAGE = [&](int buf, int t0) {
        const size_t so = rowoff + (size_t)(t0 + srow) * HID + sk;
        gl16(R16  + so, (char*)&stK[buf][0][0][0] + w * 1024);
        gl16(KN16 + so, (char*)&stK[buf][1][0][0] + w * 1024);
        gl16(KK16 + so, (char*)&stK[buf][2][0][0] + w * 1024);
        gl16(B16  + so, (char*)&stK[buf][3][0][0] + w * 1024);
        const size_t eo = rowoff + (size_t)(t0 + er) * HID + ec;
        gl16(EW + eo,                     (char*)&stE[buf][0][0]  + w * 1024);
        gl16(EW + eo + (size_t)16 * HID,  (char*)&stE[buf][16][0] + w * 1024);
        if (tid < 64) {   // wave 0: stage the 16 v-cols
            const size_t vof = rowoff + (size_t)(t0 + (tid >> 1)) * HID
                               + colbase + (tid & 1) * 8;
            gl16(V16 + vof, (char*)&stV[buf][0][0]);
        } else if (tid < 80) {   // wave 1 lanes 0..15: stage rb/rkn pairs
            gl16(RBt + rboff + (size_t)t0 * 2 + (tid - 64) * 4,
                 (char*)&stRB[buf][0][0]);
        }
    };

    float S[4] = {0.f, 0.f, 0.f, 0.f};

    STAGE(0, 0);
    asm volatile("s_waitcnt vmcnt(0)" ::: "memory");
    __syncthreads();

    int buf = 0;
    for (int c = 0; c < TSEQ / RCH; c++) {
        if (c + 1 < TSEQ / RCH) STAGE(buf ^ 1, (c + 1) * RCH);
        const int t0 = c * RCH;
#pragma unroll
        for (int s = 0; s < RCH; s++) {
            uint2 kku = *reinterpret_cast<const uint2*>(&stK[buf][2][s][k4]);
            uint2 ru  = *reinterpret_cast<const uint2*>(&stK[buf][0][s][k4]);
            uint2 knu = *reinterpret_cast<const uint2*>(&stK[buf][1][s][k4]);
            uint2 bu  = *reinterpret_cast<const uint2*>(&stK[buf][3][s][k4]);
            float4 e  = *reinterpret_cast<const float4*>(&stE[buf][s][k4]);
            const float vvf = bff(stV[buf][s][w * 4 + vl]);
            const float rb  = stRB[buf][s][0];
            const float rkn = stRB[buf][s][1];
            float kkf[4], rf[4], knf[4], bf4[4];
            up4(kku, kkf); up4(ru, rf); up4(knu, knf); up4(bu, bf4);
            float ew4[4] = {e.x, e.y, e.z, e.w};
            float t1 = 0.f, t2 = 0.f;
#pragma unroll
            for (int j = 0; j < 4; j++) {
                t1 = fmaf(kkf[j], S[j], t1);
                t2 = fmaf(rf[j] * ew4[j], S[j], t2);
            }
            t1 += __shfl_xor(t1, 1); t2 += __shfl_xor(t2, 1);
            t1 += __shfl_xor(t1, 2); t2 += __shfl_xor(t2, 2);
            t1 += __shfl_xor(t1, 4); t2 += __shfl_xor(t2, 4);
            t1 += __shfl_xor(t1, 8); t2 += __shfl_xor(t2, 8);
            const float sa = -t1;
            const float op = fmaf(rb, sa, fmaf(rkn, vvf, t2));
#pragma unroll
            for (int j = 0; j < 4; j++)
                S[j] = fmaf(ew4[j], S[j], fmaf(bf4[j], sa, knf[j] * vvf));
            if (kq == 0) Ob[rowoff + (size_t)(t0 + s) * HID + vo] = op;
        }
        asm volatile("s_waitcnt vmcnt(0)" ::: "memory");
        __syncthreads();
        buf ^= 1;
    }
}

// ---------------------------------------------------------------------------
// post: y = (GN_perhead(o)*gn_w + gn_b + (sum r*kn*r_k)*v) * g  -> bf16 Y
// ---------------------------------------------------------------------------
__global__ __launch_bounds__(256) void post_kernel(
        const float* __restrict__ Ob, const unsigned short* __restrict__ R16,
        const unsigned short* __restrict__ KN16, const unsigned short* __restrict__ V16,
        const float* __restrict__ G, const float* __restrict__ rkw,
        const float* __restrict__ gnw, const float* __restrict__ gnb,
        unsigned short* __restrict__ Y16) {
    const int row = blockIdx.x;
    const int tid = threadIdx.x;
    const int c   = tid * 4;
    const size_t off = (size_t)row * HID + c;
    float4 o4 = ld4(Ob + off), g4 = ld4(G + off);
    ushort4 ru = *reinterpret_cast<const ushort4*>(R16 + off);
    ushort4 ku = *reinterpret_cast<const ushort4*>(KN16 + off);
    ushort4 vu = *reinterpret_cast<const ushort4*>(V16 + off);
    float r[4]  = {bff(ru.x), bff(ru.y), bff(ru.z), bff(ru.w)};
    float kn[4] = {bff(ku.x), bff(ku.y), bff(ku.z), bff(ku.w)};
    float v[4]  = {bff(vu.x), bff(vu.y), bff(vu.z), bff(vu.w)};
    const int hh = tid >> 4;
    const int d0 = c & 63;
    float4 rk4 = ld4(rkw + hh * 64 + d0);

    float s1 = o4.x + o4.y + o4.z + o4.w;
    float s2 = o4.x*o4.x + o4.y*o4.y + o4.z*o4.z + o4.w*o4.w;
    float s3 = r[0]*kn[0]*rk4.x + r[1]*kn[1]*rk4.y + r[2]*kn[2]*rk4.z + r[3]*kn[3]*rk4.w;
#pragma unroll
    for (int m = 1; m < 16; m <<= 1) {
        s1 += __shfl_xor(s1, m); s2 += __shfl_xor(s2, m); s3 += __shfl_xor(s3, m);
    }
    const float mu  = s1 * (1.0f / 64.0f);
    const float var = s2 * (1.0f / 64.0f) - mu * mu;
    const float inv = rsqrtf(var + GN_EPS);
    float4 gw = ld4(gnw + c), gb = ld4(gnb + c);
    ushort4 y;
    y.x = bfr((fmaf((o4.x - mu) * inv, gw.x, gb.x) + s3 * v[0]) * g4.x);
    y.y = bfr((fmaf((o4.y - mu) * inv, gw.y, gb.y) + s3 * v[1]) * g4.y);
    y.z = bfr((fmaf((o4.z - mu) * inv, gw.z, gb.z) + s3 * v[2]) * g4.z);
    y.w = bfr((fmaf((o4.w - mu) * inv, gw.w, gb.w) + s3 * v[3]) * g4.w);
    *reinterpret_cast<ushort4*>(Y16 + off) = y;
}

// ---------------------------------------------------------------------------
extern "C" void kernel_launch(void* const* d_in, const int* in_sizes, int n_in,
                              void* d_out, int out_size, void* d_ws, size_t ws_size,
                              hipStream_t stream) {
    const float* x   = (const float*)d_in[0];
    const float* vf  = (const float*)d_in[1];
    const float* x_r = (const float*)d_in[2];
    const float* x_w = (const float*)d_in[3];
    const float* x_k = (const float*)d_in[4];
    const float* x_v = (const float*)d_in[5];
    const float* x_a = (const float*)d_in[6];
    const float* x_g = (const float*)d_in[7];
    const float* k_k = (const float*)d_in[8];
    const float* k_a = (const float*)d_in[9];
    const float* r_k = (const float*)d_in[10];
    const float* W_r = (const float*)d_in[11];
    const float* W_k = (const float*)d_in[12];
    const float* W_v = (const float*)d_in[13];
    const float* W_o = (const float*)d_in[14];
    const float* wA  = (const float*)d_in[15];
    const float* wB  = (const float*)d_in[16];
    const float* wb  = (const float*)d_in[17];
    const float* aA  = (const float*)d_in[18];
    const float* aB  = (const float*)d_in[19];
    const float* ab  = (const float*)d_in[20];
    const float* vA  = (const float*)d_in[21];
    const float* vB  = (const float*)d_in[22];
    const float* vb  = (const float*)d_in[23];
    const float* gA  = (const float*)d_in[24];
    const float* gB  = (const float*)d_in[25];
    const float* gnw = (const float*)d_in[26];
    const float* gnb = (const float*)d_in[27];
    float* out = (float*)d_out;

    float* ws = (float*)d_ws;
    const size_t SZ = (size_t)BTOT * HID;
    const size_t HH = (size_t)HID * HID;
    float*          EW   = ws;                           // fp32 decay -> later G
    unsigned short* P    = (unsigned short*)(ws + SZ);
    unsigned short* R16  = P;             // r        -> later Y (bf16)
    unsigned short* K16  = P + 1 * SZ;    // k -> kn
    unsigned short* V16  = P + 2 * SZ;    // v
    unsigned short* A16  = P + 3 * SZ;    // a -> b
    unsigned short* KK16 = P + 4 * SZ;    // kk
    unsigned short* H1   = P + 5 * SZ;    // lora hidden bf16 [BTOT,<=160]
    unsigned short* WR   = H1 + (size_t)BTOT * 160;      // bf16 weights
    unsigned short* Wr16 = WR;
    unsigned short* Wk16 = WR + 1 * HH;
    unsigned short* Wv16 = WR + 2 * HH;
    unsigned short* Wo16 = WR + 3 * HH;
    unsigned short* wA16 = WR + 4 * HH;
    unsigned short* wB16 = wA16 + 65536;
    unsigned short* aA16 = wB16 + 65536;
    unsigned short* aB16 = aA16 + 65536;
    unsigned short* vA16 = aB16 + 65536;
    unsigned short* vB16 = vA16 + 65536;
    unsigned short* gA16 = vB16 + 65536;
    unsigned short* gB16 = gA16 + 163840;
    float*          RBt  = (float*)(gB16 + 163840);      // [128][2048][2] f32
    unsigned short* Y16  = R16;           // reuse
    float*          G    = EW;            // reuse

    const dim3 blk(256);
    const dim3 gBig(128, 8);     // x = bm (A-tile co-location per XCD)
    const dim3 gL64(256, 1);
    const dim3 gL160(256, 3);
    const float* np = nullptr;
    const unsigned short* nu = nullptr;

    auto CAST = [&](const float* s, unsigned short* d, int n) {
        cast_kernel<<<dim3((n / 4 + 255) / 256), blk, 0, stream>>>(s, d, n);
    };
    CAST(W_r, Wr16, (int)HH); CAST(W_k, Wk16, (int)HH);
    CAST(W_v, Wv16, (int)HH); CAST(W_o, Wo16, (int)HH);
    CAST(wA, wA16, 65536); CAST(wB, wB16, 65536);
    CAST(aA, aA16, 65536); CAST(aB, aB16, 65536);
    CAST(vA, vA16, 65536); CAST(vB, vB16, 65536);
    CAST(gA, gA16, 163840); CAST(gB, gB16, 163840);

    // r, k, v0 projections (mix fused into A staging)
    mgemm<128,128,0,true,true><<<gBig, blk, 0, stream>>>(
        x, x_r, Wr16, R16, HID, HID, np, nu, np);
    mgemm<128,128,0,true,true><<<gBig, blk, 0, stream>>>(
        x, x_k, Wk16, K16, HID, HID, np, nu, np);
    mgemm<128,128,0,true,true><<<gBig, blk, 0, stream>>>(
        x, x_v, Wv16, V16, HID, HID, np, nu, np);
    // v = v0 + (v_first - v0) * sigmoid(lora_v(xv) + vb)
    mgemm<64,64,0,true,true><<<gL64, blk, 0, stream>>>(
        x, x_v, vA16, H1, 64, HID, np, nu, np);
    mgemm<128,128,5,false,true><<<gBig, blk, 0, stream>>>(
        H1, np, vB16, V16, HID, 64, vb, V16, vf);
    // ew = exp(W_SCALE * sigmoid(tanh(xw@wA^T)@wB^T + wb))  (fp32)
    mgemm<64,64,1,true,true><<<gL64, blk, 0, stream>>>(
        x, x_w, wA16, H1, 64, HID, np, nu, np);
    mgemm<128,128,3,false,false><<<gBig, blk, 0, stream>>>(
        H1, np, wB16, EW, HID, 64, wb, nu, np);
    // a = sigmoid(xa@aA^T@aB^T + ab)
    mgemm<64,64,0,true,true><<<gL64, blk, 0, stream>>>(
        x, x_a, aA16, H1, 64, HID, np, nu, np);
    mgemm<128,128,4,false,true><<<gBig, blk, 0, stream>>>(
        H1, np, aB16, A16, HID, 64, ab, nu, np);
    // kk -> KK16, b -> A16, kn -> K16, rb/rkn -> RBt
    prep_kernel<<<dim3(BTOT), blk, 0, stream>>>(
        K16, A16, R16, k_k, k_a, KK16, RBt);
    // recurrence -> o (d_out f32); 512 blocks x 4 waves
    rec_kernel<<<dim3(512), blk, 0, stream>>>(
        R16, EW, K16, KK16, A16, V16, RBt, out);
    // g = sigmoid(xg@gA^T) @ gB^T  (fp32, reuses EW)
    mgemm<64,64,2,true,true><<<gL160, blk, 0, stream>>>(
        x, x_g, gA16, H1, 160, HID, np, nu, np);
    mgemm<128,128,0,false,false><<<gBig, blk, 0, stream>>>(
        H1, np, gB16, G, HID, 160, np, nu, np);
    // y = (GN(o) + bonus) * g -> bf16 Y
    post_kernel<<<dim3(BTOT), blk, 0, stream>>>(
        out, R16, K16, V16, G, r_k, gnw, gnb, Y16);
    // out = y @ W_o^T
    mgemm<128,128,0,false,false><<<gBig, blk, 0, stream>>>(
        Y16, np, Wo16, out, HID, HID, np, nu, np);
    (void)in_sizes; (void)n_in; (void)out_size; (void)ws_size;
}

// Round 6
// 1509.398 us; speedup vs baseline: 2.4648x; 1.0019x over previous
//
#include <hip/hip_runtime.h>
#include <hip/hip_bf16.h>

// ---------------------------------------------------------------------------
// RWKV7 attention block — Round 6.
// - bf16 MFMA GEMMs (m97 structure), XCD-co-located grids.
// - Recurrence: tree-ahead restructure — sa_{t+1} = -(TREE(S_{t-1}) +
//   cbb_t*sa_t + cbk_t*vv_t); the shuffle tree is off the serial cycle
//   (amortized over 2 steps). cbb/cbk/rb/rkn/s3 precomputed (prep/prep2).
// B=8, T=2048, H=1024, NH=16, DK=DV=64, VDIM=1024.  ws ~247 MB.
// ---------------------------------------------------------------------------

#define DEVI __device__ __forceinline__

constexpr int TSEQ = 2048;
constexpr int HID  = 1024;
constexpr int BTOT = 16384;   // B*T
constexpr float W_SCALE = -0.6065306597126334f;
constexpr float GN_EPS  = 6.4e-4f;   // 64 * 1e-5

using s16x8  = __attribute__((ext_vector_type(8))) short;   // 8 bf16 (4 VGPR)
using f32x4v = __attribute__((ext_vector_type(4))) float;   // MFMA acc

DEVI float4 ld4(const float* p) { return *reinterpret_cast<const float4*>(p); }
DEVI void   st4(float* p, float4 v) { *reinterpret_cast<float4*>(p) = v; }
DEVI float  sigf(float x) { return 1.0f / (1.0f + __expf(-x)); }
// bf16 <-> f32 (RNE)
DEVI unsigned short bfr(float f) {
    unsigned int u = __float_as_uint(f);
    return (unsigned short)((u + 0x7fffu + ((u >> 16) & 1u)) >> 16);
}
DEVI float bff(unsigned short s) { return __uint_as_float(((unsigned int)s) << 16); }
DEVI unsigned int pk2(float lo, float hi) {
    return ((unsigned int)bfr(hi) << 16) | (unsigned int)bfr(lo);
}
DEVI void up4(uint2 u, float* f) {
    f[0] = bff((unsigned short)(u.x & 0xffffu)); f[1] = bff((unsigned short)(u.x >> 16));
    f[2] = bff((unsigned short)(u.y & 0xffffu)); f[3] = bff((unsigned short)(u.y >> 16));
}
// async global->LDS, 16B per lane; LDS dest = wave-uniform base + lane*16
DEVI void gl16(const void* g, void* l) {
    __builtin_amdgcn_global_load_lds(
        (const __attribute__((address_space(1))) unsigned int*)g,
        (__attribute__((address_space(3))) unsigned int*)l, 16, 0, 0);
}

// ---------------------------------------------------------------------------
// f32 -> bf16 cast (weights)
// ---------------------------------------------------------------------------
__global__ __launch_bounds__(256) void cast_kernel(
        const float* __restrict__ s, unsigned short* __restrict__ d, int n) {
    int i = (blockIdx.x * 256 + threadIdx.x) * 4;
    if (i >= n) return;
    float4 v = ld4(s + i);
    ushort4 o; o.x = bfr(v.x); o.y = bfr(v.y); o.z = bfr(v.z); o.w = bfr(v.w);
    *reinterpret_cast<ushort4*>(d + i) = o;
}

// ---------------------------------------------------------------------------
// MFMA bf16 GEMM: C[M,N] = epilogue( A'[M,K] @ Bw[N,K]^T ), fp32 accum.
// (unchanged from Round 5)
// ---------------------------------------------------------------------------
template<int BM, int BN, int MODE, bool MIXA, bool OUTBF>
__global__ __launch_bounds__(256) void mgemm(
        const void* __restrict__ Ap, const float* __restrict__ cvec,
        const unsigned short* __restrict__ Bw, void* Cout,
        int N, int K,
        const float* __restrict__ bias,
        const unsigned short* aux1, const float* __restrict__ aux2) {
    constexpr int BK = 32;
    constexpr int WM_ = (BN == 128) ? 2 : (BM == 128 ? 4 : 2);
    constexpr int WN_ = (BN == 128) ? 2 : (BM == 128 ? 1 : 2);
    constexpr int WTM = BM / WM_, WTN = BN / WN_;
    constexpr int MF = WTM / 16, NF = WTN / 16;
    constexpr int ACALLS = (BM * BK) / 2048;
    constexpr int BCALLS = (BN * BK) / 2048;
    __shared__ __align__(16) unsigned short As[BM * BK];
    __shared__ __align__(16) unsigned short Bs[BN * BK];
    const int tid = threadIdx.x;
    const int w = tid >> 6, l = tid & 63;
    const int bm = blockIdx.x * BM, bn = blockIdx.y * BN;
    const int wm = w / WN_, wn = w % WN_;
    const int lr = l & 15, lk = (l >> 4) * 8;

    f32x4v acc[MF][NF];
#pragma unroll
    for (int i = 0; i < MF; i++)
#pragma unroll
        for (int j = 0; j < NF; j++)
#pragma unroll
            for (int q = 0; q < 4; q++) acc[i][j][q] = 0.f;

    for (int k0 = 0; k0 < K; k0 += BK) {
        if (MIXA) {
            const float* Axf = (const float*)Ap;
#pragma unroll
            for (int c = 0; c < ACALLS; c++) {
                int idx = c * 256 + tid;
                int row = idx >> 2, kp = (idx & 3) * 8;
                int gr = bm + row;
                const float* xp = Axf + (size_t)gr * K + k0 + kp;
                float4 x0 = ld4(xp), x1 = ld4(xp + 4);
                float4 p0 = make_float4(0.f,0.f,0.f,0.f), p1 = p0;
                if ((gr & (TSEQ - 1)) != 0) { p0 = ld4(xp - HID); p1 = ld4(xp - HID + 4); }
                float4 c0 = ld4(cvec + k0 + kp), c1 = ld4(cvec + k0 + kp + 4);
                uint4 u;
                u.x = pk2(fmaf(p0.x - x0.x, c0.x, x0.x), fmaf(p0.y - x0.y, c0.y, x0.y));
                u.y = pk2(fmaf(p0.z - x0.z, c0.z, x0.z), fmaf(p0.w - x0.w, c0.w, x0.w));
                u.z = pk2(fmaf(p1.x - x1.x, c1.x, x1.x), fmaf(p1.y - x1.y, c1.y, x1.y));
                u.w = pk2(fmaf(p1.z - x1.z, c1.z, x1.z), fmaf(p1.w - x1.w, c1.w, x1.w));
                *reinterpret_cast<uint4*>(&As[idx * 8]) = u;
            }
        } else {
            const unsigned short* Ab = (const unsigned short*)Ap;
#pragma unroll
            for (int c = 0; c < ACALLS; c++) {
                int idx = c * 256 + tid;
                int row = idx >> 2, kp = (idx & 3) * 8;
                gl16(Ab + (size_t)(bm + row) * K + k0 + kp, &As[c * 2048 + w * 512]);
            }
        }
#pragma unroll
        for (int c = 0; c < BCALLS; c++) {
            int idx = c * 256 + tid;
            int row = idx >> 2, kp = (idx & 3) * 8;
            int gc = bn + row; if (gc > N - 1) gc = N - 1;   // clamp (N=160 tiles)
            gl16(Bw + (size_t)gc * K + k0 + kp, &Bs[c * 2048 + w * 512]);
        }
        __syncthreads();
        s16x8 afx[MF], bfx[NF];
#pragma unroll
        for (int i = 0; i < MF; i++)
            afx[i] = *reinterpret_cast<const s16x8*>(&As[(wm * WTM + i * 16 + lr) * BK + lk]);
#pragma unroll
        for (int j = 0; j < NF; j++)
            bfx[j] = *reinterpret_cast<const s16x8*>(&Bs[(wn * WTN + j * 16 + lr) * BK + lk]);
#pragma unroll
        for (int i = 0; i < MF; i++)
#pragma unroll
            for (int j = 0; j < NF; j++)
                acc[i][j] = __builtin_amdgcn_mfma_f32_16x16x32_bf16(
                    afx[i], bfx[j], acc[i][j], 0, 0, 0);
        __syncthreads();
    }

#pragma unroll
    for (int i = 0; i < MF; i++) {
        const int grow0 = bm + wm * WTM + i * 16 + (l >> 4) * 4;
#pragma unroll
        for (int j = 0; j < NF; j++) {
            const int gcol = bn + wn * WTN + j * 16 + lr;
            if (gcol >= N) continue;
            const float bsv = (MODE == 3 || MODE == 4 || MODE == 5) ? bias[gcol] : 0.f;
#pragma unroll
            for (int q = 0; q < 4; q++) {
                const int grow = grow0 + q;
                float d = acc[i][j][q];
                if (MODE == 1) d = tanhf(d);
                else if (MODE == 2) d = sigf(d);
                else if (MODE == 3) d = __expf(W_SCALE * sigf(d + bsv));
                else if (MODE == 4) d = sigf(d + bsv);
                else if (MODE == 5) {
                    float v0 = bff(aux1[(size_t)grow * N + gcol]);
                    d = fmaf(aux2[(size_t)grow * N + gcol] - v0, sigf(d + bsv), v0);
                }
                if (OUTBF) ((unsigned short*)Cout)[(size_t)grow * N + gcol] = bfr(d);
                else       ((float*)Cout)[(size_t)grow * N + gcol] = d;
            }
        }
    }
}

// ---------------------------------------------------------------------------
// prep: kk -> KK16; b = kk*a -> A16; kn -> K16; re = r*ew -> R16 (in place);
//       rb = r.b, rkn = r.kn, s3 = sum r*kn*r_k  -> RB[bh][t][{0,1,4}]
// ---------------------------------------------------------------------------
__global__ __launch_bounds__(256) void prep_kernel(
        unsigned short* __restrict__ K16, unsigned short* __restrict__ A16,
        unsigned short* __restrict__ R16, const float* __restrict__ EW,
        const float* __restrict__ kkc, const float* __restrict__ kac,
        const float* __restrict__ rkw,
        unsigned short* __restrict__ KK16, float* __restrict__ RB) {
    const int row = blockIdx.x;
    const int tid = threadIdx.x;
    const int c   = tid * 4;
    const size_t off = (size_t)row * HID + c;
    ushort4 ku = *reinterpret_cast<const ushort4*>(K16 + off);
    ushort4 au = *reinterpret_cast<const ushort4*>(A16 + off);
    ushort4 ru = *reinterpret_cast<const ushort4*>(R16 + off);
    float k[4] = {bff(ku.x), bff(ku.y), bff(ku.z), bff(ku.w)};
    float a[4] = {bff(au.x), bff(au.y), bff(au.z), bff(au.w)};
    float r[4] = {bff(ru.x), bff(ru.y), bff(ru.z), bff(ru.w)};
    float4 ew4 = ld4(EW + off);
    float4 kc4 = ld4(kkc + c), ka4 = ld4(kac + c);
    const int hh = tid >> 4;
    const int d0 = c & 63;
    float4 rk4 = ld4(rkw + hh * 64 + d0);
    float kr[4];
    kr[0] = k[0]*kc4.x; kr[1] = k[1]*kc4.y; kr[2] = k[2]*kc4.z; kr[3] = k[3]*kc4.w;
    float ss = kr[0]*kr[0] + kr[1]*kr[1] + kr[2]*kr[2] + kr[3]*kr[3];
    ss += __shfl_xor(ss, 1); ss += __shfl_xor(ss, 2);
    ss += __shfl_xor(ss, 4); ss += __shfl_xor(ss, 8);
    const float inv = 1.0f / fmaxf(sqrtf(ss), 1e-12f);
    float kaf[4] = {ka4.x, ka4.y, ka4.z, ka4.w};
    float ewf[4] = {ew4.x, ew4.y, ew4.z, ew4.w};
    float rkf[4] = {rk4.x, rk4.y, rk4.z, rk4.w};
    float kkv[4], bv[4], knv[4], rev[4];
    float rb = 0.f, rkn = 0.f, s3 = 0.f;
#pragma unroll
    for (int q = 0; q < 4; q++) {
        kkv[q] = kr[q] * inv;
        bv[q]  = kkv[q] * a[q];
        knv[q] = k[q] * fmaf(a[q] - 1.0f, kaf[q], 1.0f);
        rev[q] = r[q] * ewf[q];
        rb  = fmaf(r[q], bv[q],  rb);
        rkn = fmaf(r[q], knv[q], rkn);
        s3  = fmaf(r[q] * knv[q], rkf[q], s3);
    }
    ushort4 o;
    o.x = bfr(kkv[0]); o.y = bfr(kkv[1]); o.z = bfr(kkv[2]); o.w = bfr(kkv[3]);
    *reinterpret_cast<ushort4*>(KK16 + off) = o;
    o.x = bfr(bv[0]);  o.y = bfr(bv[1]);  o.z = bfr(bv[2]);  o.w = bfr(bv[3]);
    *reinterpret_cast<ushort4*>(A16 + off) = o;
    o.x = bfr(knv[0]); o.y = bfr(knv[1]); o.z = bfr(knv[2]); o.w = bfr(knv[3]);
    *reinterpret_cast<ushort4*>(K16 + off) = o;
    o.x = bfr(rev[0]); o.y = bfr(rev[1]); o.z = bfr(rev[2]); o.w = bfr(rev[3]);
    *reinterpret_cast<ushort4*>(R16 + off) = o;
#pragma unroll
    for (int m = 1; m < 16; m <<= 1) {
        rb += __shfl_xor(rb, m); rkn += __shfl_xor(rkn, m); s3 += __shfl_xor(s3, m);
    }
    if ((tid & 15) == 0) {
        const int bb = row >> 11, t = row & (TSEQ - 1);
        const size_t base = (((size_t)(bb * 16 + hh)) * TSEQ + t) * 8;
        RB[base + 0] = rb; RB[base + 1] = rkn; RB[base + 4] = s3;
    }
}

// ---------------------------------------------------------------------------
// prep2: cbb = kk_{t+1}.b_t, cbk = kk_{t+1}.kn_t -> RB[bh][t][{2,3}]
// (reads post-prep tensors; t = last row of a sequence -> zeros)
// ---------------------------------------------------------------------------
__global__ __launch_bounds__(256) void prep2_kernel(
        const unsigned short* __restrict__ KK16,
        const unsigned short* __restrict__ B16,
        const unsigned short* __restrict__ KN16, float* __restrict__ RB) {
    const int row = blockIdx.x;
    const int tid = threadIdx.x;
    const int c   = tid * 4;
    const int t   = row & (TSEQ - 1);
    float cbb = 0.f, cbk = 0.f;
    if (t < TSEQ - 1) {
        const size_t off  = (size_t)row * HID + c;
        const size_t off1 = off + HID;
        ushort4 k1 = *reinterpret_cast<const ushort4*>(KK16 + off1);
        ushort4 bu = *reinterpret_cast<const ushort4*>(B16 + off);
        ushort4 nu = *reinterpret_cast<const ushort4*>(KN16 + off);
        float kk1[4] = {bff(k1.x), bff(k1.y), bff(k1.z), bff(k1.w)};
        float bv[4]  = {bff(bu.x), bff(bu.y), bff(bu.z), bff(bu.w)};
        float kn[4]  = {bff(nu.x), bff(nu.y), bff(nu.z), bff(nu.w)};
#pragma unroll
        for (int q = 0; q < 4; q++) {
            cbb = fmaf(kk1[q], bv[q], cbb);
            cbk = fmaf(kk1[q], kn[q], cbk);
        }
    }
#pragma unroll
    for (int m = 1; m < 16; m <<= 1) {
        cbb += __shfl_xor(cbb, m); cbk += __shfl_xor(cbk, m);
    }
    if ((tid & 15) == 0) {
        const int hh = tid >> 4;
        const int bb = row >> 11;
        const size_t base = (((size_t)(bb * 16 + hh)) * TSEQ + t) * 8;
        RB[base + 2] = cbb; RB[base + 3] = cbk;
    }
}

// ---------------------------------------------------------------------------
// Recurrence, tree-ahead form. CHUNK=32 double-buffered LDS staging.
//   es = ew*S ; u1 = kk_{t+1}.es ; u2 = re.S     (on S_{t-1})
//   sa_t = -(TREE_{t-1} + cbb_{t-1} sa_{t-1} + cbk_{t-1} vv_{t-1})
//   S_t = es + b sa_t + kn vv ; o_t = tree(u2) + rb sa_t + rkn vv
// Block = 256 thr (4 waves) = one (b,h) x 16 v-cols; bid = spq*128 + bh.
// ---------------------------------------------------------------------------
constexpr int RCH = 32;

__global__ __launch_bounds__(256) void rec_kernel(
        const unsigned short* __restrict__ RE16, const float* __restrict__ EW,
        const unsigned short* __restrict__ KN16, const unsigned short* __restrict__ KK16,
        const unsigned short* __restrict__ B16, const unsigned short* __restrict__ V16,
        const float* __restrict__ RB, float* __restrict__ Ob) {
    __shared__ __align__(16) unsigned short stK[2][4][RCH][64];  // re,kn,kk+1,b
    __shared__ __align__(16) float          stE[2][RCH][64];
    __shared__ __align__(16) unsigned short stV[2][RCH][16];
    __shared__ __align__(16) float          stRB[2][RCH][8];
    const int bid = blockIdx.x;
    const int spq = bid >> 7;
    const int bh  = bid & 127;
    const int tid = threadIdx.x;
    const int w = tid >> 6, l = tid & 63;
    const int kq = l & 15, vl = l >> 4;
    const int bb = bh >> 4, hh = bh & 15;
    const size_t rowoff = ((size_t)bb * TSEQ) * HID + hh * 64;
    const size_t rboff  = (size_t)bh * TSEQ * 8;
    const int k4 = kq * 4;
    const int vo = spq * 16 + w * 4 + vl;
    const int colbase = spq * 16;

    const int srow = tid >> 3;
    const int sk   = (tid & 7) * 8;
    const int er   = tid >> 4;
    const int ec   = (tid & 15) * 4;

    auto STAGE = [&](int buf, int t0) {
        const size_t so = rowoff + (size_t)(t0 + srow) * HID + sk;
        gl16(RE16 + so, (char*)&stK[buf][0][0][0] + w * 1024);
        gl16(KN16 + so, (char*)&stK[buf][1][0][0] + w * 1024);
        int tg = t0 + srow + 1; if (tg > TSEQ - 1) tg = TSEQ - 1;
        gl16(KK16 + rowoff + (size_t)tg * HID + sk,
             (char*)&stK[buf][2][0][0] + w * 1024);
        gl16(B16 + so, (char*)&stK[buf][3][0][0] + w * 1024);
        const size_t eo = rowoff + (size_t)(t0 + er) * HID + ec;
        gl16(EW + eo,                    (char*)&stE[buf][0][0]  + w * 1024);
        gl16(EW + eo + (size_t)16 * HID, (char*)&stE[buf][16][0] + w * 1024);
        if (tid < 64) {
            const size_t vof = rowoff + (size_t)(t0 + (tid >> 1)) * HID
                               + colbase + (tid & 1) * 8;
            gl16(V16 + vof, (char*)&stV[buf][0][0]);
        } else if (tid < 128) {
            gl16(RB + rboff + (size_t)t0 * 8 + (tid - 64) * 4,
                 (char*)&stRB[buf][0][0]);
        }
    };

    float S[4] = {0.f, 0.f, 0.f, 0.f};
    float treeP = 0.f, saP = 0.f, vvP = 0.f, cbbP = 0.f, cbkP = 0.f;

    STAGE(0, 0);
    asm volatile("s_waitcnt vmcnt(0)" ::: "memory");
    __syncthreads();

    int buf = 0;
    for (int c = 0; c < TSEQ / RCH; c++) {
        if (c + 1 < TSEQ / RCH) STAGE(buf ^ 1, (c + 1) * RCH);
        const int t0 = c * RCH;
#pragma unroll
        for (int s = 0; s < RCH; s++) {
            uint2 reu  = *reinterpret_cast<const uint2*>(&stK[buf][0][s][k4]);
            uint2 knu  = *reinterpret_cast<const uint2*>(&stK[buf][1][s][k4]);
            uint2 kk1u = *reinterpret_cast<const uint2*>(&stK[buf][2][s][k4]);
            uint2 bu   = *reinterpret_cast<const uint2*>(&stK[buf][3][s][k4]);
            float4 e   = *reinterpret_cast<const float4*>(&stE[buf][s][k4]);
            const float vv = bff(stV[buf][s][w * 4 + vl]);
            float4 rbv = *reinterpret_cast<const float4*>(&stRB[buf][s][0]);
            float re4[4], kn4[4], kk14[4], b4[4];
            up4(reu, re4); up4(knu, kn4); up4(kk1u, kk14); up4(bu, b4);
            float ew4[4] = {e.x, e.y, e.z, e.w};
            // sa_t from carried values (cheap scalar chain — no tree wait)
            const float sa = -fmaf(cbbP, saP, fmaf(cbkP, vvP, treeP));
            float es[4], u1 = 0.f, u2 = 0.f;
#pragma unroll
            for (int j = 0; j < 4; j++) es[j] = ew4[j] * S[j];
#pragma unroll
            for (int j = 0; j < 4; j++) {
                u1 = fmaf(kk14[j], es[j], u1);
                u2 = fmaf(re4[j],  S[j],  u2);
            }
#pragma unroll
            for (int j = 0; j < 4; j++)
                S[j] = fmaf(b4[j], sa, fmaf(kn4[j], vv, es[j]));
            u1 += __shfl_xor(u1, 1); u2 += __shfl_xor(u2, 1);
            u1 += __shfl_xor(u1, 2); u2 += __shfl_xor(u2, 2);
            u1 += __shfl_xor(u1, 4); u2 += __shfl_xor(u2, 4);
            u1 += __shfl_xor(u1, 8); u2 += __shfl_xor(u2, 8);
            const float o = fmaf(rbv.x, sa, fmaf(rbv.y, vv, u2));
            if (kq == 0) Ob[rowoff + (size_t)(t0 + s) * HID + vo] = o;
            treeP = u1; saP = sa; vvP = vv; cbbP = rbv.z; cbkP = rbv.w;
        }
        asm volatile("s_waitcnt vmcnt(0)" ::: "memory");
        __syncthreads();
        buf ^= 1;
    }
}

// ---------------------------------------------------------------------------
// post: y = (GN_perhead(o)*gn_w + gn_b + s3*v) * g  -> bf16 Y
// ---------------------------------------------------------------------------
__global__ __launch_bounds__(256) void post_kernel(
        const float* __restrict__ Ob, const unsigned short* __restrict__ V16,
        const float* __restrict__ G, const float* __restrict__ RB,
        const float* __restrict__ gnw, const float* __restrict__ gnb,
        unsigned short* __restrict__ Y16) {
    const int row = blockIdx.x;
    const int tid = threadIdx.x;
    const int c   = tid * 4;
    const size_t off = (size_t)row * HID + c;
    float4 o4 = ld4(Ob + off), g4 = ld4(G + off);
    ushort4 vu = *reinterpret_cast<const ushort4*>(V16 + off);
    float v[4]  = {bff(vu.x), bff(vu.y), bff(vu.z), bff(vu.w)};
    const int hh = tid >> 4;
    const int bb = row >> 11, t = row & (TSEQ - 1);
    const float s3 = RB[(((size_t)(bb * 16 + hh)) * TSEQ + t) * 8 + 4];

    float s1 = o4.x + o4.y + o4.z + o4.w;
    float s2 = o4.x*o4.x + o4.y*o4.y + o4.z*o4.z + o4.w*o4.w;
#pragma unroll
    for (int m = 1; m < 16; m <<= 1) {
        s1 += __shfl_xor(s1, m); s2 += __shfl_xor(s2, m);
    }
    const float mu  = s1 * (1.0f / 64.0f);
    const float var = s2 * (1.0f / 64.0f) - mu * mu;
    const float inv = rsqrtf(var + GN_EPS);
    float4 gw = ld4(gnw + c), gb = ld4(gnb + c);
    ushort4 y;
    y.x = bfr((fmaf((o4.x - mu) * inv, gw.x, gb.x) + s3 * v[0]) * g4.x);
    y.y = bfr((fmaf((o4.y - mu) * inv, gw.y, gb.y) + s3 * v[1]) * g4.y);
    y.z = bfr((fmaf((o4.z - mu) * inv, gw.z, gb.z) + s3 * v[2]) * g4.z);
    y.w = bfr((fmaf((o4.w - mu) * inv, gw.w, gb.w) + s3 * v[3]) * g4.w);
    *reinterpret_cast<ushort4*>(Y16 + off) = y;
}

// ---------------------------------------------------------------------------
extern "C" void kernel_launch(void* const* d_in, const int* in_sizes, int n_in,
                              void* d_out, int out_size, void* d_ws, size_t ws_size,
                              hipStream_t stream) {
    const float* x   = (const float*)d_in[0];
    const float* vf  = (const float*)d_in[1];
    const float* x_r = (const float*)d_in[2];
    const float* x_w = (const float*)d_in[3];
    const float* x_k = (const float*)d_in[4];
    const float* x_v = (const float*)d_in[5];
    const float* x_a = (const float*)d_in[6];
    const float* x_g = (const float*)d_in[7];
    const float* k_k = (const float*)d_in[8];
    const float* k_a = (const float*)d_in[9];
    const float* r_k = (const float*)d_in[10];
    const float* W_r = (const float*)d_in[11];
    const float* W_k = (const float*)d_in[12];
    const float* W_v = (const float*)d_in[13];
    const float* W_o = (const float*)d_in[14];
    const float* wA  = (const float*)d_in[15];
    const float* wB  = (const float*)d_in[16];
    const float* wb  = (const float*)d_in[17];
    const float* aA  = (const float*)d_in[18];
    const float* aB  = (const float*)d_in[19];
    const float* ab  = (const float*)d_in[20];
    const float* vA  = (const float*)d_in[21];
    const float* vB  = (const float*)d_in[22];
    const float* vb  = (const float*)d_in[23];
    const float* gA  = (const float*)d_in[24];
    const float* gB  = (const float*)d_in[25];
    const float* gnw = (const float*)d_in[26];
    const float* gnb = (const float*)d_in[27];
    float* out = (float*)d_out;

    float* ws = (float*)d_ws;
    const size_t SZ = (size_t)BTOT * HID;
    const size_t HH = (size_t)HID * HID;
    float*          EW   = ws;                           // fp32 decay -> later G
    unsigned short* P    = (unsigned short*)(ws + SZ);
    unsigned short* R16  = P;             // r -> re   -> later Y (bf16)
    unsigned short* K16  = P + 1 * SZ;    // k -> kn
    unsigned short* V16  = P + 2 * SZ;    // v
    unsigned short* A16  = P + 3 * SZ;    // a -> b
    unsigned short* KK16 = P + 4 * SZ;    // kk
    unsigned short* H1   = P + 5 * SZ;    // lora hidden bf16 [BTOT,<=160]
    unsigned short* WR   = H1 + (size_t)BTOT * 160;      // bf16 weights
    unsigned short* Wr16 = WR;
    unsigned short* Wk16 = WR + 1 * HH;
    unsigned short* Wv16 = WR + 2 * HH;
    unsigned short* Wo16 = WR + 3 * HH;
    unsigned short* wA16 = WR + 4 * HH;
    unsigned short* wB16 = wA16 + 65536;
    unsigned short* aA16 = wB16 + 65536;
    unsigned short* aB16 = aA16 + 65536;
    unsigned short* vA16 = aB16 + 65536;
    unsigned short* vB16 = vA16 + 65536;
    unsigned short* gA16 = vB16 + 65536;
    unsigned short* gB16 = gA16 + 163840;
    float*          RB   = (float*)(gB16 + 163840);      // [128][2048][8] f32
    unsigned short* Y16  = R16;           // reuse
    float*          G    = EW;            // reuse

    const dim3 blk(256);
    const dim3 gBig(128, 8);
    const dim3 gL64(256, 1);
    const dim3 gL160(256, 3);
    const float* np = nullptr;
    const unsigned short* nu = nullptr;

    auto CAST = [&](const float* s, unsigned short* d, int n) {
        cast_kernel<<<dim3((n / 4 + 255) / 256), blk, 0, stream>>>(s, d, n);
    };
    CAST(W_r, Wr16, (int)HH); CAST(W_k, Wk16, (int)HH);
    CAST(W_v, Wv16, (int)HH); CAST(W_o, Wo16, (int)HH);
    CAST(wA, wA16, 65536); CAST(wB, wB16, 65536);
    CAST(aA, aA16, 65536); CAST(aB, aB16, 65536);
    CAST(vA, vA16, 65536); CAST(vB, vB16, 65536);
    CAST(gA, gA16, 163840); CAST(gB, gB16, 163840);

    // r, k, v0 projections (mix fused into A staging)
    mgemm<128,128,0,true,true><<<gBig, blk, 0, stream>>>(
        x, x_r, Wr16, R16, HID, HID, np, nu, np);
    mgemm<128,128,0,true,true><<<gBig, blk, 0, stream>>>(
        x, x_k, Wk16, K16, HID, HID, np, nu, np);
    mgemm<128,128,0,true,true><<<gBig, blk, 0, stream>>>(
        x, x_v, Wv16, V16, HID, HID, np, nu, np);
    // v = v0 + (v_first - v0) * sigmoid(lora_v(xv) + vb)
    mgemm<64,64,0,true,true><<<gL64, blk, 0, stream>>>(
        x, x_v, vA16, H1, 64, HID, np, nu, np);
    mgemm<128,128,5,false,true><<<gBig, blk, 0, stream>>>(
        H1, np, vB16, V16, HID, 64, vb, V16, vf);
    // ew = exp(W_SCALE * sigmoid(tanh(xw@wA^T)@wB^T + wb))  (fp32)
    mgemm<64,64,1,true,true><<<gL64, blk, 0, stream>>>(
        x, x_w, wA16, H1, 64, HID, np, nu, np);
    mgemm<128,128,3,false,false><<<gBig, blk, 0, stream>>>(
        H1, np, wB16, EW, HID, 64, wb, nu, np);
    // a = sigmoid(xa@aA^T@aB^T + ab)
    mgemm<64,64,0,true,true><<<gL64, blk, 0, stream>>>(
        x, x_a, aA16, H1, 64, HID, np, nu, np);
    mgemm<128,128,4,false,true><<<gBig, blk, 0, stream>>>(
        H1, np, aB16, A16, HID, 64, ab, nu, np);
    // prep (kk,b,kn,re,rb,rkn,s3) then prep2 (cbb,cbk)
    prep_kernel<<<dim3(BTOT), blk, 0, stream>>>(
        K16, A16, R16, EW, k_k, k_a, r_k, KK16, RB);
    prep2_kernel<<<dim3(BTOT), blk, 0, stream>>>(KK16, A16, K16, RB);
    // recurrence -> o (d_out f32)
    rec_kernel<<<dim3(512), blk, 0, stream>>>(
        R16, EW, K16, KK16, A16, V16, RB, out);
    // g = sigmoid(xg@gA^T) @ gB^T  (fp32, reuses EW)
    mgemm<64,64,2,true,true><<<gL160, blk, 0, stream>>>(
        x, x_g, gA16, H1, 160, HID, np, nu, np);
    mgemm<128,128,0,false,false><<<gBig, blk, 0, stream>>>(
        H1, np, gB16, G, HID, 160, np, nu, np);
    // y = (GN(o) + s3*v) * g -> bf16 Y
    post_kernel<<<dim3(BTOT), blk, 0, stream>>>(
        out, V16, G, RB, gnw, gnb, Y16);
    // out = y @ W_o^T
    mgemm<128,128,0,false,false><<<gBig, blk, 0, stream>>>(
        Y16, np, Wo16, out, HID, HID, np, nu, np);
    (void)in_sizes; (void)n_in; (void)out_size; (void)ws_size;
}

// Round 7
// 1419.584 us; speedup vs baseline: 2.6208x; 1.0633x over previous
//
#include <hip/hip_runtime.h>
#include <hip/hip_bf16.h>

// ---------------------------------------------------------------------------
// RWKV7 attention block — Round 7.
// - bf16 MFMA GEMMs (m97 structure), XCD-co-located grids (unchanged).
// - Recurrence replaced by CHUNKED delta rule (C=32): per chunk,
//   SA via forward substitution of (I - strict_lower(At@Bt^T)),
//   O = Rt@S + lower_incl(Rt@Bt^T)@SA + lower_incl(Rt@Kt^T)@V,
//   S' = Ed (.) (S + Bt^T@SA + Kt^T@V).  State fp32 in regs, enters MFMA
//   as hi/lo bf16 split. 64 serial chunks, 256 parallel blocks (bh x vhalf).
// B=8, T=2048, H=1024, NH=16, DK=DV=64, VDIM=1024.  ws ~242 MB.
// ---------------------------------------------------------------------------

#define DEVI __device__ __forceinline__

constexpr int TSEQ = 2048;
constexpr int HID  = 1024;
constexpr int BTOT = 16384;   // B*T
constexpr int CCH  = 32;      // chunk length
constexpr int NCH  = TSEQ / CCH;
constexpr float W_SCALE = -0.6065306597126334f;
constexpr float GN_EPS  = 6.4e-4f;   // 64 * 1e-5

using s16x8  = __attribute__((ext_vector_type(8))) short;   // 8 bf16 (4 VGPR)
using f32x4v = __attribute__((ext_vector_type(4))) float;   // MFMA acc

DEVI float4 ld4(const float* p) { return *reinterpret_cast<const float4*>(p); }
DEVI void   st4(float* p, float4 v) { *reinterpret_cast<float4*>(p) = v; }
DEVI float  sigf(float x) { return 1.0f / (1.0f + __expf(-x)); }
// bf16 <-> f32 (RNE)
DEVI unsigned short bfr(float f) {
    unsigned int u = __float_as_uint(f);
    return (unsigned short)((u + 0x7fffu + ((u >> 16) & 1u)) >> 16);
}
DEVI float bff(unsigned short s) { return __uint_as_float(((unsigned int)s) << 16); }
DEVI unsigned int pk2(float lo, float hi) {
    return ((unsigned int)bfr(hi) << 16) | (unsigned int)bfr(lo);
}
DEVI void up8(uint4 u, float* f) {
    f[0]=bff((unsigned short)(u.x & 0xffffu)); f[1]=bff((unsigned short)(u.x >> 16));
    f[2]=bff((unsigned short)(u.y & 0xffffu)); f[3]=bff((unsigned short)(u.y >> 16));
    f[4]=bff((unsigned short)(u.z & 0xffffu)); f[5]=bff((unsigned short)(u.z >> 16));
    f[6]=bff((unsigned short)(u.w & 0xffffu)); f[7]=bff((unsigned short)(u.w >> 16));
}
// async global->LDS
DEVI void gl16(const void* g, void* l) {
    __builtin_amdgcn_global_load_lds(
        (const __attribute__((address_space(1))) unsigned int*)g,
        (__attribute__((address_space(3))) unsigned int*)l, 16, 0, 0);
}
DEVI void gl4(const void* g, void* l) {
    __builtin_amdgcn_global_load_lds(
        (const __attribute__((address_space(1))) unsigned int*)g,
        (__attribute__((address_space(3))) unsigned int*)l, 4, 0, 0);
}

// ---------------------------------------------------------------------------
// f32 -> bf16 cast (weights)
// ---------------------------------------------------------------------------
__global__ __launch_bounds__(256) void cast_kernel(
        const float* __restrict__ s, unsigned short* __restrict__ d, int n) {
    int i = (blockIdx.x * 256 + threadIdx.x) * 4;
    if (i >= n) return;
    float4 v = ld4(s + i);
    ushort4 o; o.x = bfr(v.x); o.y = bfr(v.y); o.z = bfr(v.z); o.w = bfr(v.w);
    *reinterpret_cast<ushort4*>(d + i) = o;
}

// ---------------------------------------------------------------------------
// MFMA bf16 GEMM (as Round 5/6). MODE 6 added: d = W_SCALE*sigmoid(d+bias)
// (log-decay output, no exp).
// ---------------------------------------------------------------------------
template<int BM, int BN, int MODE, bool MIXA, bool OUTBF>
__global__ __launch_bounds__(256) void mgemm(
        const void* __restrict__ Ap, const float* __restrict__ cvec,
        const unsigned short* __restrict__ Bw, void* Cout,
        int N, int K,
        const float* __restrict__ bias,
        const unsigned short* aux1, const float* __restrict__ aux2) {
    constexpr int BK = 32;
    constexpr int WM_ = (BN == 128) ? 2 : (BM == 128 ? 4 : 2);
    constexpr int WN_ = (BN == 128) ? 2 : (BM == 128 ? 1 : 2);
    constexpr int WTM = BM / WM_, WTN = BN / WN_;
    constexpr int MF = WTM / 16, NF = WTN / 16;
    constexpr int ACALLS = (BM * BK) / 2048;
    constexpr int BCALLS = (BN * BK) / 2048;
    __shared__ __align__(16) unsigned short As[BM * BK];
    __shared__ __align__(16) unsigned short Bs[BN * BK];
    const int tid = threadIdx.x;
    const int w = tid >> 6, l = tid & 63;
    const int bm = blockIdx.x * BM, bn = blockIdx.y * BN;
    const int wm = w / WN_, wn = w % WN_;
    const int lr = l & 15, lk = (l >> 4) * 8;

    f32x4v acc[MF][NF];
#pragma unroll
    for (int i = 0; i < MF; i++)
#pragma unroll
        for (int j = 0; j < NF; j++)
#pragma unroll
            for (int q = 0; q < 4; q++) acc[i][j][q] = 0.f;

    for (int k0 = 0; k0 < K; k0 += BK) {
        if (MIXA) {
            const float* Axf = (const float*)Ap;
#pragma unroll
            for (int c = 0; c < ACALLS; c++) {
                int idx = c * 256 + tid;
                int row = idx >> 2, kp = (idx & 3) * 8;
                int gr = bm + row;
                const float* xp = Axf + (size_t)gr * K + k0 + kp;
                float4 x0 = ld4(xp), x1 = ld4(xp + 4);
                float4 p0 = make_float4(0.f,0.f,0.f,0.f), p1 = p0;
                if ((gr & (TSEQ - 1)) != 0) { p0 = ld4(xp - HID); p1 = ld4(xp - HID + 4); }
                float4 c0 = ld4(cvec + k0 + kp), c1 = ld4(cvec + k0 + kp + 4);
                uint4 u;
                u.x = pk2(fmaf(p0.x - x0.x, c0.x, x0.x), fmaf(p0.y - x0.y, c0.y, x0.y));
                u.y = pk2(fmaf(p0.z - x0.z, c0.z, x0.z), fmaf(p0.w - x0.w, c0.w, x0.w));
                u.z = pk2(fmaf(p1.x - x1.x, c1.x, x1.x), fmaf(p1.y - x1.y, c1.y, x1.y));
                u.w = pk2(fmaf(p1.z - x1.z, c1.z, x1.z), fmaf(p1.w - x1.w, c1.w, x1.w));
                *reinterpret_cast<uint4*>(&As[idx * 8]) = u;
            }
        } else {
            const unsigned short* Ab = (const unsigned short*)Ap;
#pragma unroll
            for (int c = 0; c < ACALLS; c++) {
                int idx = c * 256 + tid;
                int row = idx >> 2, kp = (idx & 3) * 8;
                gl16(Ab + (size_t)(bm + row) * K + k0 + kp, &As[c * 2048 + w * 512]);
            }
        }
#pragma unroll
        for (int c = 0; c < BCALLS; c++) {
            int idx = c * 256 + tid;
            int row = idx >> 2, kp = (idx & 3) * 8;
            int gc = bn + row; if (gc > N - 1) gc = N - 1;
            gl16(Bw + (size_t)gc * K + k0 + kp, &Bs[c * 2048 + w * 512]);
        }
        __syncthreads();
        s16x8 afx[MF], bfx[NF];
#pragma unroll
        for (int i = 0; i < MF; i++)
            afx[i] = *reinterpret_cast<const s16x8*>(&As[(wm * WTM + i * 16 + lr) * BK + lk]);
#pragma unroll
        for (int j = 0; j < NF; j++)
            bfx[j] = *reinterpret_cast<const s16x8*>(&Bs[(wn * WTN + j * 16 + lr) * BK + lk]);
#pragma unroll
        for (int i = 0; i < MF; i++)
#pragma unroll
            for (int j = 0; j < NF; j++)
                acc[i][j] = __builtin_amdgcn_mfma_f32_16x16x32_bf16(
                    afx[i], bfx[j], acc[i][j], 0, 0, 0);
        __syncthreads();
    }

#pragma unroll
    for (int i = 0; i < MF; i++) {
        const int grow0 = bm + wm * WTM + i * 16 + (l >> 4) * 4;
#pragma unroll
        for (int j = 0; j < NF; j++) {
            const int gcol = bn + wn * WTN + j * 16 + lr;
            if (gcol >= N) continue;
            const float bsv = (MODE >= 3) ? bias[gcol] : 0.f;
#pragma unroll
            for (int q = 0; q < 4; q++) {
                const int grow = grow0 + q;
                float d = acc[i][j][q];
                if (MODE == 1) d = tanhf(d);
                else if (MODE == 2) d = sigf(d);
                else if (MODE == 3) d = __expf(W_SCALE * sigf(d + bsv));
                else if (MODE == 4) d = sigf(d + bsv);
                else if (MODE == 5) {
                    float v0 = bff(aux1[(size_t)grow * N + gcol]);
                    d = fmaf(aux2[(size_t)grow * N + gcol] - v0, sigf(d + bsv), v0);
                }
                else if (MODE == 6) d = W_SCALE * sigf(d + bsv);
                if (OUTBF) ((unsigned short*)Cout)[(size_t)grow * N + gcol] = bfr(d);
                else       ((float*)Cout)[(size_t)grow * N + gcol] = d;
            }
        }
    }
}

// ---------------------------------------------------------------------------
// prep: kk -> KK16; b = kk*a -> A16; kn -> K16 (in place); r untouched;
//       s3 = sum r*kn*r_k -> SB[bh][t]
// ---------------------------------------------------------------------------
__global__ __launch_bounds__(256) void prep_kernel(
        unsigned short* __restrict__ K16, unsigned short* __restrict__ A16,
        const unsigned short* __restrict__ R16,
        const float* __restrict__ kkc, const float* __restrict__ kac,
        const float* __restrict__ rkw,
        unsigned short* __restrict__ KK16, float* __restrict__ SB) {
    const int row = blockIdx.x;
    const int tid = threadIdx.x;
    const int c   = tid * 4;
    const size_t off = (size_t)row * HID + c;
    ushort4 ku = *reinterpret_cast<const ushort4*>(K16 + off);
    ushort4 au = *reinterpret_cast<const ushort4*>(A16 + off);
    ushort4 ru = *reinterpret_cast<const ushort4*>(R16 + off);
    float k[4] = {bff(ku.x), bff(ku.y), bff(ku.z), bff(ku.w)};
    float a[4] = {bff(au.x), bff(au.y), bff(au.z), bff(au.w)};
    float r[4] = {bff(ru.x), bff(ru.y), bff(ru.z), bff(ru.w)};
    float4 kc4 = ld4(kkc + c), ka4 = ld4(kac + c);
    const int hh = tid >> 4;
    const int d0 = c & 63;
    float4 rk4 = ld4(rkw + hh * 64 + d0);
    float kr[4];
    kr[0] = k[0]*kc4.x; kr[1] = k[1]*kc4.y; kr[2] = k[2]*kc4.z; kr[3] = k[3]*kc4.w;
    float ss = kr[0]*kr[0] + kr[1]*kr[1] + kr[2]*kr[2] + kr[3]*kr[3];
    ss += __shfl_xor(ss, 1); ss += __shfl_xor(ss, 2);
    ss += __shfl_xor(ss, 4); ss += __shfl_xor(ss, 8);
    const float inv = 1.0f / fmaxf(sqrtf(ss), 1e-12f);
    float kaf[4] = {ka4.x, ka4.y, ka4.z, ka4.w};
    float rkf[4] = {rk4.x, rk4.y, rk4.z, rk4.w};
    float kkv[4], bv[4], knv[4];
    float s3 = 0.f;
#pragma unroll
    for (int q = 0; q < 4; q++) {
        kkv[q] = kr[q] * inv;
        bv[q]  = kkv[q] * a[q];
        knv[q] = k[q] * fmaf(a[q] - 1.0f, kaf[q], 1.0f);
        s3  = fmaf(r[q] * knv[q], rkf[q], s3);
    }
    ushort4 o;
    o.x = bfr(kkv[0]); o.y = bfr(kkv[1]); o.z = bfr(kkv[2]); o.w = bfr(kkv[3]);
    *reinterpret_cast<ushort4*>(KK16 + off) = o;
    o.x = bfr(bv[0]);  o.y = bfr(bv[1]);  o.z = bfr(bv[2]);  o.w = bfr(bv[3]);
    *reinterpret_cast<ushort4*>(A16 + off) = o;
    o.x = bfr(knv[0]); o.y = bfr(knv[1]); o.z = bfr(knv[2]); o.w = bfr(knv[3]);
    *reinterpret_cast<ushort4*>(K16 + off) = o;
#pragma unroll
    for (int m = 1; m < 16; m <<= 1) s3 += __shfl_xor(s3, m);
    if ((tid & 15) == 0) {
        const int bb = row >> 11, t = row & (TSEQ - 1);
        SB[((size_t)(bb * 16 + hh)) * TSEQ + t] = s3;
    }
}

// ---------------------------------------------------------------------------
// chunkprep: in-chunk prefix log-decay + in-place scaling (per bh,chunk):
//   At = -kk*e^{cw_prev} -> KK16 ; Bt = b*e^{-cw} -> A16 ;
//   Kt = kn*e^{-cw} -> K16 ; Rt = r*e^{cw} -> R16 ; Ed[bh][ch] = e^{cw_C}
// grid = 128*64 blocks x 64 thr (lane = k)
// ---------------------------------------------------------------------------
__global__ __launch_bounds__(64) void chunkprep_kernel(
        unsigned short* __restrict__ KK16, unsigned short* __restrict__ A16,
        unsigned short* __restrict__ K16, unsigned short* __restrict__ R16,
        const float* __restrict__ WL, float* __restrict__ Ed) {
    const int bid = blockIdx.x;
    const int bh = bid >> 6, ch = bid & 63;
    const int bb = bh >> 4, hh = bh & 15;
    const int k = threadIdx.x;
    size_t off = ((size_t)(bb * TSEQ) + ch * CCH) * HID + hh * 64 + k;
    float cw = 0.f, er = 1.f;
    for (int i = 0; i < CCH; i++, off += HID) {
        float wv = WL[off];
        float cwp = cw; cw += wv;
        float ea = __expf(cwp), ei = __expf(-cw);
        er = __expf(cw);
        KK16[off] = bfr(-bff(KK16[off]) * ea);
        A16[off]  = bfr( bff(A16[off])  * ei);
        K16[off]  = bfr( bff(K16[off])  * ei);
        R16[off]  = bfr( bff(R16[off])  * er);
    }
    Ed[((size_t)bh * NCH + ch) * 64 + k] = er;
}

// ---------------------------------------------------------------------------
// Chunked recurrence. Block = 256 thr (4 waves), one per (vhalf, bh):
// bid = vh*128 + bh. Serial over 64 chunks; state St[v][k] fp32 in regs
// (thread (v, kg) owns 8 k), MFMA via hi/lo bf16 LDS copies.
// ---------------------------------------------------------------------------
__global__ __launch_bounds__(256) void recchunk_kernel(
        const unsigned short* __restrict__ AtG, const unsigned short* __restrict__ BtG,
        const unsigned short* __restrict__ KtG, const unsigned short* __restrict__ RtG,
        const unsigned short* __restrict__ V16, const float* __restrict__ Ed,
        float* __restrict__ Ob) {
    __shared__ __align__(16) unsigned short stT[2][4][CCH][64];  // swizzled rows
    __shared__ __align__(16) unsigned short stV[2][CCH][32];
    __shared__ __align__(16) float stEd[2][64];
    __shared__ __align__(16) unsigned short Shi[32][72], Slo[32][72];
    __shared__ __align__(16) float Mab[32][36], Mak[32][36], Mrb[32][36], Mrk[32][36];
    __shared__ __align__(16) float SAb[32][36], Obf[32][36];

    const int bid = blockIdx.x;
    const int vh = bid >> 7, bh = bid & 127;
    const int tid = threadIdx.x;
    const int w = tid >> 6, l = tid & 63;
    const int bb = bh >> 4, hh = bh & 15;
    const size_t rowoff = ((size_t)bb * TSEQ) * HID + hh * 64;

    // staging lane decomposition (tensor rows: 8 rows/call; swizzle chunk)
    const int r8 = l >> 3, ck = l & 7;
    const int swz8 = (ck ^ r8) * 8;       // element offset of source 16B chunk

    auto STAGE = [&](int buf, int cn) {
        if (cn >= NCH) return;
        const size_t cb = rowoff + (size_t)(cn * CCH) * HID;
        const unsigned short* srcs[4] = {AtG, BtG, KtG, RtG};
        {
            const unsigned short* T = srcs[w];
#pragma unroll
            for (int c = 0; c < 4; c++)
                gl16(T + cb + (size_t)(c * 8 + r8) * HID + swz8,
                     &stT[buf][w][c * 8][0]);
        }
        if (w == 0) {
#pragma unroll
            for (int c = 0; c < 2; c++)
                gl16(V16 + cb + (size_t)(c * 16 + (l >> 2)) * HID + vh * 32 + (l & 3) * 8,
                     &stV[buf][c * 16][0]);
            gl4(Ed + ((size_t)bh * NCH + cn) * 64 + l, &stEd[buf][0]);
        }
    };

    // zero Shi/Slo (+pad)
    {
        uint4 z = make_uint4(0u, 0u, 0u, 0u);
        for (int idx = tid; idx < 32 * 72 / 8; idx += 256) {
            *reinterpret_cast<uint4*>((char*)&Shi[0][0] + idx * 16) = z;
            *reinterpret_cast<uint4*>((char*)&Slo[0][0] + idx * 16) = z;
        }
    }
    STAGE(0, 0);
    asm volatile("s_waitcnt vmcnt(0)" ::: "memory");
    __syncthreads();

    // persistent state: thread (v = tid&31, kg = tid>>5) owns St[8] (k = kg*8..)
    const int sv = tid & 31, kg = tid >> 5;
    float St[8];
#pragma unroll
    for (int q = 0; q < 8; q++) St[q] = 0.f;

    // frag helpers
    auto ldT = [&](int buf, int tn, int mt, int ks) -> s16x8 {
        int row = mt + (l & 15);
        int chv = ((ks >> 3) + (l >> 4)) ^ (row & 7);
        return *reinterpret_cast<const s16x8*>(
            (const char*)&stT[buf][tn][0][0] + row * 128 + chv * 16);
    };
    auto ldS = [&](const unsigned short (*Sx)[72], int nt, int ks) -> s16x8 {
        int row = nt + (l & 15);
        return *reinterpret_cast<const s16x8*>(&Sx[row][ks + (l >> 4) * 8]);
    };
    auto stfrag = [&](float (*M)[36], int mt, int nt, f32x4v acc) {
        int colc = nt + (l & 15);
        int r0 = mt + (l >> 4) * 4;
#pragma unroll
        for (int q = 0; q < 4; q++) M[r0 + q][colc] = acc[q];
    };

    const int i2 = tid >> 3, vq = (tid & 7) * 4;   // ph2/ph4a mapping

    int buf = 0;
    for (int c = 0; c < NCH; c++) {
        STAGE(buf ^ 1, c + 1);
        // ---------------- ph1: MFMA ----------------
        if (w < 2) {
            const int ta = (w == 0) ? 0 : 3;     // At or Rt
            float (*M1)[36] = (w == 0) ? Mab : Mrb;
            float (*M2)[36] = (w == 0) ? Mak : Mrk;
            s16x8 af[2][2];
#pragma unroll
            for (int mi = 0; mi < 2; mi++)
#pragma unroll
                for (int ki = 0; ki < 2; ki++) af[mi][ki] = ldT(buf, ta, mi * 16, ki * 32);
#pragma unroll
            for (int mi = 0; mi < 2; mi++)
#pragma unroll
                for (int ni = 0; ni < 2; ni++) {
                    f32x4v a1, a2;
#pragma unroll
                    for (int q = 0; q < 4; q++) { a1[q] = 0.f; a2[q] = 0.f; }
#pragma unroll
                    for (int ki = 0; ki < 2; ki++) {
                        a1 = __builtin_amdgcn_mfma_f32_16x16x32_bf16(
                            af[mi][ki], ldT(buf, 1, ni * 16, ki * 32), a1, 0, 0, 0);
                        a2 = __builtin_amdgcn_mfma_f32_16x16x32_bf16(
                            af[mi][ki], ldT(buf, 2, ni * 16, ki * 32), a2, 0, 0, 0);
                    }
                    stfrag(M1, mi * 16, ni * 16, a1);
                    stfrag(M2, mi * 16, ni * 16, a2);
                }
        } else {
            const int ta = (w == 2) ? 0 : 3;
            float (*Mo)[36] = (w == 2) ? SAb : Obf;
            s16x8 af[2][2];
#pragma unroll
            for (int mi = 0; mi < 2; mi++)
#pragma unroll
                for (int ki = 0; ki < 2; ki++) af[mi][ki] = ldT(buf, ta, mi * 16, ki * 32);
#pragma unroll
            for (int mi = 0; mi < 2; mi++)
#pragma unroll
                for (int ni = 0; ni < 2; ni++) {
                    f32x4v a1;
#pragma unroll
                    for (int q = 0; q < 4; q++) a1[q] = 0.f;
#pragma unroll
                    for (int ki = 0; ki < 2; ki++) {
                        a1 = __builtin_amdgcn_mfma_f32_16x16x32_bf16(
                            af[mi][ki], ldS(Shi, ni * 16, ki * 32), a1, 0, 0, 0);
                        a1 = __builtin_amdgcn_mfma_f32_16x16x32_bf16(
                            af[mi][ki], ldS(Slo, ni * 16, ki * 32), a1, 0, 0, 0);
                    }
                    stfrag(Mo, mi * 16, ni * 16, a1);
                }
        }
        __syncthreads();
        // ---- ph2: rhs += strictlow(Mak)V ; Obf += lowincl(Mrk)V ----
        {
            float4 rac = *reinterpret_cast<const float4*>(&SAb[i2][vq]);
            float4 ob  = *reinterpret_cast<const float4*>(&Obf[i2][vq]);
            for (int j = 0; j <= i2; j++) {
                float mak = (j < i2) ? Mak[i2][j] : 0.f;
                float mrk = Mrk[i2][j];
                ushort4 vj = *reinterpret_cast<const ushort4*>(&stV[buf][j][vq]);
                float v0 = bff(vj.x), v1 = bff(vj.y), v2 = bff(vj.z), v3 = bff(vj.w);
                rac.x = fmaf(mak, v0, rac.x); rac.y = fmaf(mak, v1, rac.y);
                rac.z = fmaf(mak, v2, rac.z); rac.w = fmaf(mak, v3, rac.w);
                ob.x = fmaf(mrk, v0, ob.x); ob.y = fmaf(mrk, v1, ob.y);
                ob.z = fmaf(mrk, v2, ob.z); ob.w = fmaf(mrk, v3, ob.w);
            }
            *reinterpret_cast<float4*>(&SAb[i2][vq]) = rac;
            *reinterpret_cast<float4*>(&Obf[i2][vq]) = ob;
        }
        __syncthreads();
        // ---- ph3: forward substitution (wave 0; lanes duplicate v) ----
        if (w == 0) {
            const int v = l & 31;
            float sa[32];
#pragma unroll
            for (int i = 0; i < 32; i++) sa[i] = SAb[i][v];
#pragma unroll
            for (int i = 1; i < 32; i++) {
                float p0 = 0.f, p1 = 0.f, p2 = 0.f, p3 = 0.f;
#pragma unroll
                for (int j4 = 0; j4 < 32; j4 += 4) {
                    if (j4 >= i) break;
                    float4 m4 = *reinterpret_cast<const float4*>(&Mab[i][j4]);
                    p0 = fmaf(m4.x, sa[j4], p0);
                    if (j4 + 1 < i) p1 = fmaf(m4.y, sa[j4 + 1], p1);
                    if (j4 + 2 < i) p2 = fmaf(m4.z, sa[j4 + 2], p2);
                    if (j4 + 3 < i) p3 = fmaf(m4.w, sa[j4 + 3], p3);
                }
                sa[i] += (p0 + p1) + (p2 + p3);
            }
            if (l < 32) {
#pragma unroll
                for (int i = 0; i < 32; i++) SAb[i][v] = sa[i];
            }
        }
        __syncthreads();
        // ---- ph4a: O = Obf + lowincl(Mrb)SA -> global ----
        {
            float4 ob = *reinterpret_cast<const float4*>(&Obf[i2][vq]);
            for (int j = 0; j <= i2; j++) {
                float mrb = Mrb[i2][j];
                float4 sj = *reinterpret_cast<const float4*>(&SAb[j][vq]);
                ob.x = fmaf(mrb, sj.x, ob.x); ob.y = fmaf(mrb, sj.y, ob.y);
                ob.z = fmaf(mrb, sj.z, ob.z); ob.w = fmaf(mrb, sj.w, ob.w);
            }
            st4(Ob + rowoff + (size_t)(c * CCH + i2) * HID + vh * 32 + vq, ob);
        }
        // ---- ph4b: state update + hi/lo cast ----
        {
#pragma unroll 8
            for (int j = 0; j < 32; j++) {
                float sav = SAb[j][sv];
                float vv = bff(stV[buf][j][sv]);
                int chsw = (kg ^ (j & 7)) * 16;
                uint4 bu = *reinterpret_cast<const uint4*>(
                    (const char*)&stT[buf][1][0][0] + j * 128 + chsw);
                uint4 kuu = *reinterpret_cast<const uint4*>(
                    (const char*)&stT[buf][2][0][0] + j * 128 + chsw);
                float bt[8], kt[8];
                up8(bu, bt); up8(kuu, kt);
#pragma unroll
                for (int q = 0; q < 8; q++)
                    St[q] = fmaf(bt[q], sav, fmaf(kt[q], vv, St[q]));
            }
            float4 e0 = *reinterpret_cast<const float4*>(&stEd[buf][kg * 8]);
            float4 e1 = *reinterpret_cast<const float4*>(&stEd[buf][kg * 8 + 4]);
            float ed[8] = {e0.x, e0.y, e0.z, e0.w, e1.x, e1.y, e1.z, e1.w};
            unsigned short h[8]; float lo[8];
#pragma unroll
            for (int q = 0; q < 8; q++) {
                St[q] *= ed[q];
                h[q] = bfr(St[q]);
                lo[q] = St[q] - bff(h[q]);
            }
            uint4 uh, ul;
            uh.x = (unsigned)h[0] | ((unsigned)h[1] << 16);
            uh.y = (unsigned)h[2] | ((unsigned)h[3] << 16);
            uh.z = (unsigned)h[4] | ((unsigned)h[5] << 16);
            uh.w = (unsigned)h[6] | ((unsigned)h[7] << 16);
            ul.x = pk2(lo[0], lo[1]); ul.y = pk2(lo[2], lo[3]);
            ul.z = pk2(lo[4], lo[5]); ul.w = pk2(lo[6], lo[7]);
            *reinterpret_cast<uint4*>(&Shi[sv][kg * 8]) = uh;
            *reinterpret_cast<uint4*>(&Slo[sv][kg * 8]) = ul;
        }
        asm volatile("s_waitcnt vmcnt(0)" ::: "memory");
        __syncthreads();
        buf ^= 1;
    }
}

// ---------------------------------------------------------------------------
// post: y = (GN_perhead(o)*gn_w + gn_b + s3*v) * g  -> bf16 Y
// ---------------------------------------------------------------------------
__global__ __launch_bounds__(256) void post_kernel(
        const float* __restrict__ Ob, const unsigned short* __restrict__ V16,
        const float* __restrict__ G, const float* __restrict__ SB,
        const float* __restrict__ gnw, const float* __restrict__ gnb,
        unsigned short* __restrict__ Y16) {
    const int row = blockIdx.x;
    const int tid = threadIdx.x;
    const int c   = tid * 4;
    const size_t off = (size_t)row * HID + c;
    float4 o4 = ld4(Ob + off), g4 = ld4(G + off);
    ushort4 vu = *reinterpret_cast<const ushort4*>(V16 + off);
    float v[4]  = {bff(vu.x), bff(vu.y), bff(vu.z), bff(vu.w)};
    const int hh = tid >> 4;
    const int bb = row >> 11, t = row & (TSEQ - 1);
    const float s3 = SB[((size_t)(bb * 16 + hh)) * TSEQ + t];

    float s1 = o4.x + o4.y + o4.z + o4.w;
    float s2 = o4.x*o4.x + o4.y*o4.y + o4.z*o4.z + o4.w*o4.w;
#pragma unroll
    for (int m = 1; m < 16; m <<= 1) {
        s1 += __shfl_xor(s1, m); s2 += __shfl_xor(s2, m);
    }
    const float mu  = s1 * (1.0f / 64.0f);
    const float var = s2 * (1.0f / 64.0f) - mu * mu;
    const float inv = rsqrtf(var + GN_EPS);
    float4 gw = ld4(gnw + c), gb = ld4(gnb + c);
    ushort4 y;
    y.x = bfr((fmaf((o4.x - mu) * inv, gw.x, gb.x) + s3 * v[0]) * g4.x);
    y.y = bfr((fmaf((o4.y - mu) * inv, gw.y, gb.y) + s3 * v[1]) * g4.y);
    y.z = bfr((fmaf((o4.z - mu) * inv, gw.z, gb.z) + s3 * v[2]) * g4.z);
    y.w = bfr((fmaf((o4.w - mu) * inv, gw.w, gb.w) + s3 * v[3]) * g4.w);
    *reinterpret_cast<ushort4*>(Y16 + off) = y;
}

// ---------------------------------------------------------------------------
extern "C" void kernel_launch(void* const* d_in, const int* in_sizes, int n_in,
                              void* d_out, int out_size, void* d_ws, size_t ws_size,
                              hipStream_t stream) {
    const float* x   = (const float*)d_in[0];
    const float* vf  = (const float*)d_in[1];
    const float* x_r = (const float*)d_in[2];
    const float* x_w = (const float*)d_in[3];
    const float* x_k = (const float*)d_in[4];
    const float* x_v = (const float*)d_in[5];
    const float* x_a = (const float*)d_in[6];
    const float* x_g = (const float*)d_in[7];
    const float* k_k = (const float*)d_in[8];
    const float* k_a = (const float*)d_in[9];
    const float* r_k = (const float*)d_in[10];
    const float* W_r = (const float*)d_in[11];
    const float* W_k = (const float*)d_in[12];
    const float* W_v = (const float*)d_in[13];
    const float* W_o = (const float*)d_in[14];
    const float* wA  = (const float*)d_in[15];
    const float* wB  = (const float*)d_in[16];
    const float* wb  = (const float*)d_in[17];
    const float* aA  = (const float*)d_in[18];
    const float* aB  = (const float*)d_in[19];
    const float* ab  = (const float*)d_in[20];
    const float* vA  = (const float*)d_in[21];
    const float* vB  = (const float*)d_in[22];
    const float* vb  = (const float*)d_in[23];
    const float* gA  = (const float*)d_in[24];
    const float* gB  = (const float*)d_in[25];
    const float* gnw = (const float*)d_in[26];
    const float* gnb = (const float*)d_in[27];
    float* out = (float*)d_out;

    float* ws = (float*)d_ws;
    const size_t SZ = (size_t)BTOT * HID;
    const size_t HH = (size_t)HID * HID;
    float*          WL   = ws;            // log-decay f32 -> later G
    unsigned short* P    = (unsigned short*)(ws + SZ);
    unsigned short* R16  = P;             // r -> Rt  -> later Y (bf16)
    unsigned short* K16  = P + 1 * SZ;    // k -> kn -> Kt
    unsigned short* V16  = P + 2 * SZ;    // v
    unsigned short* A16  = P + 3 * SZ;    // a -> b -> Bt
    unsigned short* KK16 = P + 4 * SZ;    // kk -> At
    unsigned short* H1   = P + 5 * SZ;    // lora hidden bf16 [BTOT,<=160]
    unsigned short* WR   = H1 + (size_t)BTOT * 160;
    unsigned short* Wr16 = WR;
    unsigned short* Wk16 = WR + 1 * HH;
    unsigned short* Wv16 = WR + 2 * HH;
    unsigned short* Wo16 = WR + 3 * HH;
    unsigned short* wA16 = WR + 4 * HH;
    unsigned short* wB16 = wA16 + 65536;
    unsigned short* aA16 = wB16 + 65536;
    unsigned short* aB16 = aA16 + 65536;
    unsigned short* vA16 = aB16 + 65536;
    unsigned short* vB16 = vA16 + 65536;
    unsigned short* gA16 = vB16 + 65536;
    unsigned short* gB16 = gA16 + 163840;
    float*          SB   = (float*)(gB16 + 163840);    // [128][2048] f32 1MB
    float*          Ed   = SB + (size_t)128 * TSEQ;    // [128][64][64] f32 2MB
    unsigned short* Y16  = R16;           // reuse
    float*          G    = WL;            // reuse

    const dim3 blk(256);
    const dim3 gBig(128, 8);
    const dim3 gL64(256, 1);
    const dim3 gL160(256, 3);
    const float* np = nullptr;
    const unsigned short* nu = nullptr;

    auto CAST = [&](const float* s, unsigned short* d, int n) {
        cast_kernel<<<dim3((n / 4 + 255) / 256), blk, 0, stream>>>(s, d, n);
    };
    CAST(W_r, Wr16, (int)HH); CAST(W_k, Wk16, (int)HH);
    CAST(W_v, Wv16, (int)HH); CAST(W_o, Wo16, (int)HH);
    CAST(wA, wA16, 65536); CAST(wB, wB16, 65536);
    CAST(aA, aA16, 65536); CAST(aB, aB16, 65536);
    CAST(vA, vA16, 65536); CAST(vB, vB16, 65536);
    CAST(gA, gA16, 163840); CAST(gB, gB16, 163840);

    // r, k, v0 projections (mix fused into A staging)
    mgemm<128,128,0,true,true><<<gBig, blk, 0, stream>>>(
        x, x_r, Wr16, R16, HID, HID, np, nu, np);
    mgemm<128,128,0,true,true><<<gBig, blk, 0, stream>>>(
        x, x_k, Wk16, K16, HID, HID, np, nu, np);
    mgemm<128,128,0,true,true><<<gBig, blk, 0, stream>>>(
        x, x_v, Wv16, V16, HID, HID, np, nu, np);
    // v = v0 + (v_first - v0) * sigmoid(lora_v(xv) + vb)
    mgemm<64,64,0,true,true><<<gL64, blk, 0, stream>>>(
        x, x_v, vA16, H1, 64, HID, np, nu, np);
    mgemm<128,128,5,false,true><<<gBig, blk, 0, stream>>>(
        H1, np, vB16, V16, HID, 64, vb, V16, vf);
    // w (LOG decay, f32) = W_SCALE * sigmoid(tanh(xw@wA^T)@wB^T + wb)
    mgemm<64,64,1,true,true><<<gL64, blk, 0, stream>>>(
        x, x_w, wA16, H1, 64, HID, np, nu, np);
    mgemm<128,128,6,false,false><<<gBig, blk, 0, stream>>>(
        H1, np, wB16, WL, HID, 64, wb, nu, np);
    // a = sigmoid(xa@aA^T@aB^T + ab)
    mgemm<64,64,0,true,true><<<gL64, blk, 0, stream>>>(
        x, x_a, aA16, H1, 64, HID, np, nu, np);
    mgemm<128,128,4,false,true><<<gBig, blk, 0, stream>>>(
        H1, np, aB16, A16, HID, 64, ab, nu, np);
    // prep (kk,b,kn,s3) then chunkprep (scaled tensors + Ed)
    prep_kernel<<<dim3(BTOT), blk, 0, stream>>>(
        K16, A16, R16, k_k, k_a, r_k, KK16, SB);
    chunkprep_kernel<<<dim3(128 * NCH), dim3(64), 0, stream>>>(
        KK16, A16, K16, R16, WL, Ed);
    // chunked recurrence -> o (d_out f32)
    recchunk_kernel<<<dim3(256), blk, 0, stream>>>(
        KK16, A16, K16, R16, V16, Ed, out);
    // g = sigmoid(xg@gA^T) @ gB^T  (fp32, reuses WL)
    mgemm<64,64,2,true,true><<<gL160, blk, 0, stream>>>(
        x, x_g, gA16, H1, 160, HID, np, nu, np);
    mgemm<128,128,0,false,false><<<gBig, blk, 0, stream>>>(
        H1, np, gB16, G, HID, 160, np, nu, np);
    // y = (GN(o) + s3*v) * g -> bf16 Y
    post_kernel<<<dim3(BTOT), blk, 0, stream>>>(
        out, V16, G, SB, gnw, gnb, Y16);
    // out = y @ W_o^T
    mgemm<128,128,0,false,false><<<gBig, blk, 0, stream>>>(
        Y16, np, Wo16, out, HID, HID, np, nu, np);
    (void)in_sizes; (void)n_in; (void)out_size; (void)ws_size;
}

// Round 8
// 1267.077 us; speedup vs baseline: 2.9362x; 1.1204x over previous
//
#include <hip/hip_runtime.h>
#include <hip/hip_bf16.h>

// ---------------------------------------------------------------------------
// RWKV7 attention block — Round 8.
// Chunked delta rule (C=32) with fully MFMA-ized chunk algebra:
//   masked hi/lo-bf16 M matrices, SA^T from fsub, in-LDS transposes of
//   Bt/Kt/V, state carried in f32 MFMA accumulators (D-layout).
// B=8, T=2048, H=1024, NH=16, DK=DV=64, VDIM=1024.  ws ~247 MB.
// ---------------------------------------------------------------------------

#define DEVI __device__ __forceinline__

constexpr int TSEQ = 2048;
constexpr int HID  = 1024;
constexpr int BTOT = 16384;   // B*T
constexpr int CCH  = 32;      // chunk length
constexpr int NCH  = TSEQ / CCH;
constexpr float W_SCALE = -0.6065306597126334f;
constexpr float GN_EPS  = 6.4e-4f;   // 64 * 1e-5

using s16x8  = __attribute__((ext_vector_type(8))) short;   // 8 bf16 (4 VGPR)
using f32x4v = __attribute__((ext_vector_type(4))) float;   // MFMA acc

DEVI float4 ld4(const float* p) { return *reinterpret_cast<const float4*>(p); }
DEVI void   st4(float* p, float4 v) { *reinterpret_cast<float4*>(p) = v; }
DEVI float  sigf(float x) { return 1.0f / (1.0f + __expf(-x)); }
// bf16 <-> f32 (RNE)
DEVI unsigned short bfr(float f) {
    unsigned int u = __float_as_uint(f);
    return (unsigned short)((u + 0x7fffu + ((u >> 16) & 1u)) >> 16);
}
DEVI float bff(unsigned short s) { return __uint_as_float(((unsigned int)s) << 16); }
DEVI unsigned int pk2(float lo, float hi) {
    return ((unsigned int)bfr(hi) << 16) | (unsigned int)bfr(lo);
}
DEVI s16x8 MFMA_args(s16x8 a, s16x8 b);   // fwd decl dummy (unused)
DEVI f32x4v MF(s16x8 a, s16x8 b, f32x4v c) {
    return __builtin_amdgcn_mfma_f32_16x16x32_bf16(a, b, c, 0, 0, 0);
}
// async global->LDS
DEVI void gl16(const void* g, void* l) {
    __builtin_amdgcn_global_load_lds(
        (const __attribute__((address_space(1))) unsigned int*)g,
        (__attribute__((address_space(3))) unsigned int*)l, 16, 0, 0);
}
DEVI void gl4(const void* g, void* l) {
    __builtin_amdgcn_global_load_lds(
        (const __attribute__((address_space(1))) unsigned int*)g,
        (__attribute__((address_space(3))) unsigned int*)l, 4, 0, 0);
}

// ---------------------------------------------------------------------------
// f32 -> bf16 cast (weights)
// ---------------------------------------------------------------------------
__global__ __launch_bounds__(256) void cast_kernel(
        const float* __restrict__ s, unsigned short* __restrict__ d, int n) {
    int i = (blockIdx.x * 256 + threadIdx.x) * 4;
    if (i >= n) return;
    float4 v = ld4(s + i);
    ushort4 o; o.x = bfr(v.x); o.y = bfr(v.y); o.z = bfr(v.z); o.w = bfr(v.w);
    *reinterpret_cast<ushort4*>(d + i) = o;
}

// ---------------------------------------------------------------------------
// MFMA bf16 GEMM (unchanged from R7). MODE 6: log-decay.
// ---------------------------------------------------------------------------
template<int BM, int BN, int MODE, bool MIXA, bool OUTBF>
__global__ __launch_bounds__(256) void mgemm(
        const void* __restrict__ Ap, const float* __restrict__ cvec,
        const unsigned short* __restrict__ Bw, void* Cout,
        int N, int K,
        const float* __restrict__ bias,
        const unsigned short* aux1, const float* __restrict__ aux2) {
    constexpr int BK = 32;
    constexpr int WM_ = (BN == 128) ? 2 : (BM == 128 ? 4 : 2);
    constexpr int WN_ = (BN == 128) ? 2 : (BM == 128 ? 1 : 2);
    constexpr int WTM = BM / WM_, WTN = BN / WN_;
    constexpr int MF_ = WTM / 16, NF = WTN / 16;
    constexpr int ACALLS = (BM * BK) / 2048;
    constexpr int BCALLS = (BN * BK) / 2048;
    __shared__ __align__(16) unsigned short As[BM * BK];
    __shared__ __align__(16) unsigned short Bs[BN * BK];
    const int tid = threadIdx.x;
    const int w = tid >> 6, l = tid & 63;
    const int bm = blockIdx.x * BM, bn = blockIdx.y * BN;
    const int wm = w / WN_, wn = w % WN_;
    const int lr = l & 15, lk = (l >> 4) * 8;

    f32x4v acc[MF_][NF];
#pragma unroll
    for (int i = 0; i < MF_; i++)
#pragma unroll
        for (int j = 0; j < NF; j++)
#pragma unroll
            for (int q = 0; q < 4; q++) acc[i][j][q] = 0.f;

    for (int k0 = 0; k0 < K; k0 += BK) {
        if (MIXA) {
            const float* Axf = (const float*)Ap;
#pragma unroll
            for (int c = 0; c < ACALLS; c++) {
                int idx = c * 256 + tid;
                int row = idx >> 2, kp = (idx & 3) * 8;
                int gr = bm + row;
                const float* xp = Axf + (size_t)gr * K + k0 + kp;
                float4 x0 = ld4(xp), x1 = ld4(xp + 4);
                float4 p0 = make_float4(0.f,0.f,0.f,0.f), p1 = p0;
                if ((gr & (TSEQ - 1)) != 0) { p0 = ld4(xp - HID); p1 = ld4(xp - HID + 4); }
                float4 c0 = ld4(cvec + k0 + kp), c1 = ld4(cvec + k0 + kp + 4);
                uint4 u;
                u.x = pk2(fmaf(p0.x - x0.x, c0.x, x0.x), fmaf(p0.y - x0.y, c0.y, x0.y));
                u.y = pk2(fmaf(p0.z - x0.z, c0.z, x0.z), fmaf(p0.w - x0.w, c0.w, x0.w));
                u.z = pk2(fmaf(p1.x - x1.x, c1.x, x1.x), fmaf(p1.y - x1.y, c1.y, x1.y));
                u.w = pk2(fmaf(p1.z - x1.z, c1.z, x1.z), fmaf(p1.w - x1.w, c1.w, x1.w));
                *reinterpret_cast<uint4*>(&As[idx * 8]) = u;
            }
        } else {
            const unsigned short* Ab = (const unsigned short*)Ap;
#pragma unroll
            for (int c = 0; c < ACALLS; c++) {
                int idx = c * 256 + tid;
                int row = idx >> 2, kp = (idx & 3) * 8;
                gl16(Ab + (size_t)(bm + row) * K + k0 + kp, &As[c * 2048 + w * 512]);
            }
        }
#pragma unroll
        for (int c = 0; c < BCALLS; c++) {
            int idx = c * 256 + tid;
            int row = idx >> 2, kp = (idx & 3) * 8;
            int gc = bn + row; if (gc > N - 1) gc = N - 1;
            gl16(Bw + (size_t)gc * K + k0 + kp, &Bs[c * 2048 + w * 512]);
        }
        __syncthreads();
        s16x8 afx[MF_], bfx[NF];
#pragma unroll
        for (int i = 0; i < MF_; i++)
            afx[i] = *reinterpret_cast<const s16x8*>(&As[(wm * WTM + i * 16 + lr) * BK + lk]);
#pragma unroll
        for (int j = 0; j < NF; j++)
            bfx[j] = *reinterpret_cast<const s16x8*>(&Bs[(wn * WTN + j * 16 + lr) * BK + lk]);
#pragma unroll
        for (int i = 0; i < MF_; i++)
#pragma unroll
            for (int j = 0; j < NF; j++)
                acc[i][j] = __builtin_amdgcn_mfma_f32_16x16x32_bf16(
                    afx[i], bfx[j], acc[i][j], 0, 0, 0);
        __syncthreads();
    }

#pragma unroll
    for (int i = 0; i < MF_; i++) {
        const int grow0 = bm + wm * WTM + i * 16 + (l >> 4) * 4;
#pragma unroll
        for (int j = 0; j < NF; j++) {
            const int gcol = bn + wn * WTN + j * 16 + lr;
            if (gcol >= N) continue;
            const float bsv = (MODE >= 3) ? bias[gcol] : 0.f;
#pragma unroll
            for (int q = 0; q < 4; q++) {
                const int grow = grow0 + q;
                float d = acc[i][j][q];
                if (MODE == 1) d = tanhf(d);
                else if (MODE == 2) d = sigf(d);
                else if (MODE == 3) d = __expf(W_SCALE * sigf(d + bsv));
                else if (MODE == 4) d = sigf(d + bsv);
                else if (MODE == 5) {
                    float v0 = bff(aux1[(size_t)grow * N + gcol]);
                    d = fmaf(aux2[(size_t)grow * N + gcol] - v0, sigf(d + bsv), v0);
                }
                else if (MODE == 6) d = W_SCALE * sigf(d + bsv);
                if (OUTBF) ((unsigned short*)Cout)[(size_t)grow * N + gcol] = bfr(d);
                else       ((float*)Cout)[(size_t)grow * N + gcol] = d;
            }
        }
    }
}

// ---------------------------------------------------------------------------
// prep (unchanged R7): kk -> KK16; b -> A16; kn -> K16; s3 -> SB
// ---------------------------------------------------------------------------
__global__ __launch_bounds__(256) void prep_kernel(
        unsigned short* __restrict__ K16, unsigned short* __restrict__ A16,
        const unsigned short* __restrict__ R16,
        const float* __restrict__ kkc, const float* __restrict__ kac,
        const float* __restrict__ rkw,
        unsigned short* __restrict__ KK16, float* __restrict__ SB) {
    const int row = blockIdx.x;
    const int tid = threadIdx.x;
    const int c   = tid * 4;
    const size_t off = (size_t)row * HID + c;
    ushort4 ku = *reinterpret_cast<const ushort4*>(K16 + off);
    ushort4 au = *reinterpret_cast<const ushort4*>(A16 + off);
    ushort4 ru = *reinterpret_cast<const ushort4*>(R16 + off);
    float k[4] = {bff(ku.x), bff(ku.y), bff(ku.z), bff(ku.w)};
    float a[4] = {bff(au.x), bff(au.y), bff(au.z), bff(au.w)};
    float r[4] = {bff(ru.x), bff(ru.y), bff(ru.z), bff(ru.w)};
    float4 kc4 = ld4(kkc + c), ka4 = ld4(kac + c);
    const int hh = tid >> 4;
    const int d0 = c & 63;
    float4 rk4 = ld4(rkw + hh * 64 + d0);
    float kr[4];
    kr[0] = k[0]*kc4.x; kr[1] = k[1]*kc4.y; kr[2] = k[2]*kc4.z; kr[3] = k[3]*kc4.w;
    float ss = kr[0]*kr[0] + kr[1]*kr[1] + kr[2]*kr[2] + kr[3]*kr[3];
    ss += __shfl_xor(ss, 1); ss += __shfl_xor(ss, 2);
    ss += __shfl_xor(ss, 4); ss += __shfl_xor(ss, 8);
    const float inv = 1.0f / fmaxf(sqrtf(ss), 1e-12f);
    float kaf[4] = {ka4.x, ka4.y, ka4.z, ka4.w};
    float rkf[4] = {rk4.x, rk4.y, rk4.z, rk4.w};
    float kkv[4], bv[4], knv[4];
    float s3 = 0.f;
#pragma unroll
    for (int q = 0; q < 4; q++) {
        kkv[q] = kr[q] * inv;
        bv[q]  = kkv[q] * a[q];
        knv[q] = k[q] * fmaf(a[q] - 1.0f, kaf[q], 1.0f);
        s3  = fmaf(r[q] * knv[q], rkf[q], s3);
    }
    ushort4 o;
    o.x = bfr(kkv[0]); o.y = bfr(kkv[1]); o.z = bfr(kkv[2]); o.w = bfr(kkv[3]);
    *reinterpret_cast<ushort4*>(KK16 + off) = o;
    o.x = bfr(bv[0]);  o.y = bfr(bv[1]);  o.z = bfr(bv[2]);  o.w = bfr(bv[3]);
    *reinterpret_cast<ushort4*>(A16 + off) = o;
    o.x = bfr(knv[0]); o.y = bfr(knv[1]); o.z = bfr(knv[2]); o.w = bfr(knv[3]);
    *reinterpret_cast<ushort4*>(K16 + off) = o;
#pragma unroll
    for (int m = 1; m < 16; m <<= 1) s3 += __shfl_xor(s3, m);
    if ((tid & 15) == 0) {
        const int bb = row >> 11, t = row & (TSEQ - 1);
        SB[((size_t)(bb * 16 + hh)) * TSEQ + t] = s3;
    }
}

// ---------------------------------------------------------------------------
// chunkprep (unchanged R7): prefix log-decay scaling + Ed
// ---------------------------------------------------------------------------
__global__ __launch_bounds__(64) void chunkprep_kernel(
        unsigned short* __restrict__ KK16, unsigned short* __restrict__ A16,
        unsigned short* __restrict__ K16, unsigned short* __restrict__ R16,
        const float* __restrict__ WL, float* __restrict__ Ed) {
    const int bid = blockIdx.x;
    const int bh = bid >> 6, ch = bid & 63;
    const int bb = bh >> 4, hh = bh & 15;
    const int k = threadIdx.x;
    size_t off = ((size_t)(bb * TSEQ) + ch * CCH) * HID + hh * 64 + k;
    float cw = 0.f, er = 1.f;
    for (int i = 0; i < CCH; i++, off += HID) {
        float wv = WL[off];
        float cwp = cw; cw += wv;
        float ea = __expf(cwp), ei = __expf(-cw);
        er = __expf(cw);
        KK16[off] = bfr(-bff(KK16[off]) * ea);
        A16[off]  = bfr( bff(A16[off])  * ei);
        K16[off]  = bfr( bff(K16[off])  * ei);
        R16[off]  = bfr( bff(R16[off])  * er);
    }
    Ed[((size_t)bh * NCH + ch) * 64 + k] = er;
}

// ---------------------------------------------------------------------------
// Chunked recurrence, MFMA-ized. Block = 256 thr (4 waves), bid = vh*128+bh.
// Per chunk: ph1 (M matrices + At@S + Rt@S via MFMA, masked hi/lo M writes,
// in-LDS transposes of Bt/Kt/V) -> ph2 (Mak/Mrk @ VT) -> fsub (wave0, f32,
// writes SA^T hi/lo) -> ph4 (Mrb@SA^T into O; state += SA^T@BtT + VT@KtT,
// Ed scale, hi/lo writeback). State persists in f32 acc registers.
// ---------------------------------------------------------------------------
__global__ __launch_bounds__(256) void recchunk_kernel(
        const unsigned short* __restrict__ AtG, const unsigned short* __restrict__ BtG,
        const unsigned short* __restrict__ KtG, const unsigned short* __restrict__ RtG,
        const unsigned short* __restrict__ V16, const float* __restrict__ Ed,
        float* __restrict__ Ob) {
    __shared__ __align__(16) unsigned short stT[2][4][CCH][64];   // At,Bt,Kt,Rt (chunk-XOR swz)
    __shared__ __align__(16) unsigned short stV[2][CCH][32];
    __shared__ __align__(16) float stEd[2][64];
    __shared__ __align__(16) unsigned short Shi[32][72], Slo[32][72];
    __shared__ __align__(16) unsigned short BtT[64][40], KtT[64][40];
    __shared__ __align__(16) unsigned short VT[32][40];
    __shared__ __align__(16) float Mab[32][36], SAb[32][36];
    __shared__ __align__(16) unsigned short MakH[32][40], MakL[32][40];
    __shared__ __align__(16) unsigned short MrkH[32][40], MrkL[32][40];
    __shared__ __align__(16) unsigned short MrbH[32][40], MrbL[32][40];
    __shared__ __align__(16) unsigned short SATh[32][40], SATl[32][40];

    const int bid = blockIdx.x;
    const int vh = bid >> 7, bh = bid & 127;
    const int tid = threadIdx.x;
    const int w = tid >> 6, l = tid & 63;
    const int lr = l & 15, lq = l >> 4;
    const int bb = bh >> 4, hh = bh & 15;
    const size_t rowoff = ((size_t)bb * TSEQ) * HID + hh * 64;

    // staging (R7-proven): 8 rows per gl16 call, chunk-XOR pre-swizzled source
    const int r8 = l >> 3, ck = l & 7;
    const int swz8 = (ck ^ r8) * 8;

    auto STAGE = [&](int buf, int cn) {
        if (cn >= NCH) return;
        const size_t cb = rowoff + (size_t)(cn * CCH) * HID;
        const unsigned short* srcs[4] = {AtG, BtG, KtG, RtG};
        {
            const unsigned short* T = srcs[w];
#pragma unroll
            for (int c = 0; c < 4; c++)
                gl16(T + cb + (size_t)(c * 8 + r8) * HID + swz8,
                     &stT[buf][w][c * 8][0]);
        }
        if (w == 0) {
#pragma unroll
            for (int c = 0; c < 2; c++)
                gl16(V16 + cb + (size_t)(c * 16 + (l >> 2)) * HID + vh * 32 + (l & 3) * 8,
                     &stV[buf][c * 16][0]);
            gl4(Ed + ((size_t)bh * NCH + cn) * 64 + l, &stEd[buf][0]);
        }
    };

    // zero state LDS copies
    {
        uint4 z = make_uint4(0u, 0u, 0u, 0u);
        for (int idx = tid; idx < 32 * 72 * 2 / 8; idx += 256) {
            *reinterpret_cast<uint4*>((char*)&Shi[0][0] + idx * 16) = z;
            *reinterpret_cast<uint4*>((char*)&Slo[0][0] + idx * 16) = z;
        }
    }
    STAGE(0, 0);
    asm volatile("s_waitcnt vmcnt(0)" ::: "memory");
    __syncthreads();

    // fragment read helpers
    auto fragT = [&](int bf, int tn, int rbase, int kb) -> s16x8 {
        int row = rbase + lr;
        int chv = ((kb >> 3) + lq) ^ (row & 7);
        return *reinterpret_cast<const s16x8*>(
            (const char*)&stT[bf][tn][0][0] + row * 128 + chv * 16);
    };
    auto fragS = [&](const unsigned short (*Sx)[72], int vbase, int kb) -> s16x8 {
        return *reinterpret_cast<const s16x8*>(&Sx[vbase + lr][kb + lq * 8]);
    };
    auto frag40 = [&](const unsigned short (*T)[40], int rbase) -> s16x8 {
        return *reinterpret_cast<const s16x8*>(&T[rbase + lr][lq * 8]);
    };

    const int mi = w >> 1, ni = w & 1;      // per-wave 16x16 tile of [t][tt]/[t][v]
    f32x4v Sacc[2];                          // state tiles (v-tile s, k-tile w)
#pragma unroll
    for (int s = 0; s < 2; s++)
#pragma unroll
        for (int q = 0; q < 4; q++) Sacc[s][q] = 0.f;
    f32x4v z4; z4[0] = z4[1] = z4[2] = z4[3] = 0.f;

    int buf = 0;
    for (int c = 0; c < NCH; c++) {
        STAGE(buf ^ 1, c + 1);
        // ---- phase A: in-LDS transposes (Bt,Kt,V) + ph1 MFMAs ----
        {
            const int tt = tid & 31, g8 = tid >> 5;        // g8: k-octet / v-quad sel
            const int ch = g8 ^ (tt & 7);
            uint4 bu = *reinterpret_cast<const uint4*>(&stT[buf][1][tt][ch * 8]);
            uint4 ku = *reinterpret_cast<const uint4*>(&stT[buf][2][tt][ch * 8]);
            unsigned int bw[4] = {bu.x, bu.y, bu.z, bu.w};
            unsigned int kw[4] = {ku.x, ku.y, ku.z, ku.w};
#pragma unroll
            for (int e = 0; e < 4; e++) {
                BtT[g8 * 8 + 2 * e][tt]     = (unsigned short)(bw[e] & 0xffffu);
                BtT[g8 * 8 + 2 * e + 1][tt] = (unsigned short)(bw[e] >> 16);
                KtT[g8 * 8 + 2 * e][tt]     = (unsigned short)(kw[e] & 0xffffu);
                KtT[g8 * 8 + 2 * e + 1][tt] = (unsigned short)(kw[e] >> 16);
            }
            ushort4 vu = *reinterpret_cast<const ushort4*>(&stV[buf][tt][g8 * 4]);
            VT[g8 * 4 + 0][tt] = vu.x; VT[g8 * 4 + 1][tt] = vu.y;
            VT[g8 * 4 + 2][tt] = vu.z; VT[g8 * 4 + 3][tt] = vu.w;
        }
        // ph1: M matrices + rhs0/O0
        s16x8 at0 = fragT(buf, 0, mi * 16, 0), at1 = fragT(buf, 0, mi * 16, 32);
        s16x8 rt0 = fragT(buf, 3, mi * 16, 0), rt1 = fragT(buf, 3, mi * 16, 32);
        s16x8 bt0 = fragT(buf, 1, ni * 16, 0), bt1 = fragT(buf, 1, ni * 16, 32);
        s16x8 kt0 = fragT(buf, 2, ni * 16, 0), kt1 = fragT(buf, 2, ni * 16, 32);
        f32x4v mab = MF(at1, bt1, MF(at0, bt0, z4));
        f32x4v mak = MF(at1, kt1, MF(at0, kt0, z4));
        f32x4v mrb = MF(rt1, bt1, MF(rt0, bt0, z4));
        f32x4v mrk = MF(rt1, kt1, MF(rt0, kt0, z4));
        s16x8 sh0 = fragS(Shi, ni * 16, 0), sh1 = fragS(Shi, ni * 16, 32);
        s16x8 sl0 = fragS(Slo, ni * 16, 0), sl1 = fragS(Slo, ni * 16, 32);
        f32x4v rhs = MF(at0, sl0, MF(at1, sl1, MF(at0, sh0, MF(at1, sh1, z4))));
        f32x4v oac = MF(rt0, sl0, MF(rt1, sl1, MF(rt0, sh0, MF(rt1, sh1, z4))));
        // masked M writes (hi/lo bf16; Mab f32)
#pragma unroll
        for (int q = 0; q < 4; q++) {
            const int r = mi * 16 + lq * 4 + q;
            const int cc = ni * 16 + lr;
            Mab[r][cc] = (cc < r) ? mab[q] : 0.f;
            float vv = (cc < r) ? mak[q] : 0.f;
            unsigned short h = bfr(vv);
            MakH[r][cc] = h; MakL[r][cc] = bfr(vv - bff(h));
            vv = (cc <= r) ? mrk[q] : 0.f;
            h = bfr(vv);
            MrkH[r][cc] = h; MrkL[r][cc] = bfr(vv - bff(h));
            vv = (cc <= r) ? mrb[q] : 0.f;
            h = bfr(vv);
            MrbH[r][cc] = h; MrbL[r][cc] = bfr(vv - bff(h));
        }
        __syncthreads();
        // ---- phase C: + strictlow(Mak)@V, lowincl(Mrk)@V ----
        {
            s16x8 vtf = frag40(VT, ni * 16);
            rhs = MF(frag40(MakL, mi * 16), vtf, MF(frag40(MakH, mi * 16), vtf, rhs));
            oac = MF(frag40(MrkL, mi * 16), vtf, MF(frag40(MrkH, mi * 16), vtf, oac));
#pragma unroll
            for (int q = 0; q < 4; q++)
                SAb[mi * 16 + lq * 4 + q][ni * 16 + lr] = rhs[q];
        }
        __syncthreads();
        // ---- phase E: forward substitution (wave 0), writes SA^T hi/lo ----
        if (w == 0) {
            const int v = l & 31;
            float sa[32];
#pragma unroll
            for (int i = 0; i < 32; i++) sa[i] = SAb[i][v];
#pragma unroll
            for (int i = 1; i < 32; i++) {
                float p = 0.f;
#pragma unroll
                for (int j4 = 0; j4 < 32; j4 += 4) {
                    float4 m4 = *reinterpret_cast<const float4*>(&Mab[i][j4]);
                    p = fmaf(m4.x, sa[j4 + 0], p);
                    p = fmaf(m4.y, sa[j4 + 1], p);
                    p = fmaf(m4.z, sa[j4 + 2], p);
                    p = fmaf(m4.w, sa[j4 + 3], p);
                }
                sa[i] += p;
            }
            if (l < 32) {
#pragma unroll
                for (int g = 0; g < 4; g++) {
                    unsigned short hh8[8]; float ll8[8];
#pragma unroll
                    for (int e = 0; e < 8; e++) {
                        hh8[e] = bfr(sa[g * 8 + e]);
                        ll8[e] = sa[g * 8 + e] - bff(hh8[e]);
                    }
                    uint4 uh, ul;
                    uh.x = (unsigned)hh8[0] | ((unsigned)hh8[1] << 16);
                    uh.y = (unsigned)hh8[2] | ((unsigned)hh8[3] << 16);
                    uh.z = (unsigned)hh8[4] | ((unsigned)hh8[5] << 16);
                    uh.w = (unsigned)hh8[6] | ((unsigned)hh8[7] << 16);
                    ul.x = pk2(ll8[0], ll8[1]); ul.y = pk2(ll8[2], ll8[3]);
                    ul.z = pk2(ll8[4], ll8[5]); ul.w = pk2(ll8[6], ll8[7]);
                    *reinterpret_cast<uint4*>(&SATh[v][g * 8]) = uh;
                    *reinterpret_cast<uint4*>(&SATl[v][g * 8]) = ul;
                }
            }
        }
        __syncthreads();
        // ---- phase G: O += lowincl(Mrb)@SA; state update; writes ----
        {
            s16x8 sth = frag40(SATh, ni * 16), stl = frag40(SATl, ni * 16);
            s16x8 rbh = frag40(MrbH, mi * 16), rbl = frag40(MrbL, mi * 16);
            oac = MF(rbl, sth, MF(rbh, stl, MF(rbh, sth, oac)));
#pragma unroll
            for (int q = 0; q < 4; q++) {
                const int t = c * CCH + mi * 16 + lq * 4 + q;
                Ob[rowoff + (size_t)t * HID + vh * 32 + ni * 16 + lr] = oac[q];
            }
            // state tiles (v-tile s, k-tile w)
            s16x8 btf = frag40(BtT, w * 16);
            s16x8 ktf = frag40(KtT, w * 16);
            const float ed = stEd[buf][w * 16 + lr];
#pragma unroll
            for (int s = 0; s < 2; s++) {
                s16x8 sah = frag40(SATh, s * 16), sal = frag40(SATl, s * 16);
                s16x8 vta = frag40(VT, s * 16);
                Sacc[s] = MF(sah, btf, Sacc[s]);
                Sacc[s] = MF(sal, btf, Sacc[s]);
                Sacc[s] = MF(vta, ktf, Sacc[s]);
#pragma unroll
                for (int q = 0; q < 4; q++) {
                    Sacc[s][q] *= ed;
                    unsigned short h = bfr(Sacc[s][q]);
                    Shi[s * 16 + lq * 4 + q][w * 16 + lr] = h;
                    Slo[s * 16 + lq * 4 + q][w * 16 + lr] = bfr(Sacc[s][q] - bff(h));
                }
            }
        }
        asm volatile("s_waitcnt vmcnt(0)" ::: "memory");
        __syncthreads();
        buf ^= 1;
    }
}

// ---------------------------------------------------------------------------
// post (unchanged R7): y = (GN_perhead(o)*gn_w + gn_b + s3*v) * g -> bf16 Y
// ---------------------------------------------------------------------------
__global__ __launch_bounds__(256) void post_kernel(
        const float* __restrict__ Ob, const unsigned short* __restrict__ V16,
        const float* __restrict__ G, const float* __restrict__ SB,
        const float* __restrict__ gnw, const float* __restrict__ gnb,
        unsigned short* __restrict__ Y16) {
    const int row = blockIdx.x;
    const int tid = threadIdx.x;
    const int c   = tid * 4;
    const size_t off = (size_t)row * HID + c;
    float4 o4 = ld4(Ob + off), g4 = ld4(G + off);
    ushort4 vu = *reinterpret_cast<const ushort4*>(V16 + off);
    float v[4]  = {bff(vu.x), bff(vu.y), bff(vu.z), bff(vu.w)};
    const int hh = tid >> 4;
    const int bb = row >> 11, t = row & (TSEQ - 1);
    const float s3 = SB[((size_t)(bb * 16 + hh)) * TSEQ + t];

    float s1 = o4.x + o4.y + o4.z + o4.w;
    float s2 = o4.x*o4.x + o4.y*o4.y + o4.z*o4.z + o4.w*o4.w;
#pragma unroll
    for (int m = 1; m < 16; m <<= 1) {
        s1 += __shfl_xor(s1, m); s2 += __shfl_xor(s2, m);
    }
    const float mu  = s1 * (1.0f / 64.0f);
    const float var = s2 * (1.0f / 64.0f) - mu * mu;
    const float inv = rsqrtf(var + GN_EPS);
    float4 gw = ld4(gnw + c), gb = ld4(gnb + c);
    ushort4 y;
    y.x = bfr((fmaf((o4.x - mu) * inv, gw.x, gb.x) + s3 * v[0]) * g4.x);
    y.y = bfr((fmaf((o4.y - mu) * inv, gw.y, gb.y) + s3 * v[1]) * g4.y);
    y.z = bfr((fmaf((o4.z - mu) * inv, gw.z, gb.z) + s3 * v[2]) * g4.z);
    y.w = bfr((fmaf((o4.w - mu) * inv, gw.w, gb.w) + s3 * v[3]) * g4.w);
    *reinterpret_cast<ushort4*>(Y16 + off) = y;
}

// ---------------------------------------------------------------------------
extern "C" void kernel_launch(void* const* d_in, const int* in_sizes, int n_in,
                              void* d_out, int out_size, void* d_ws, size_t ws_size,
                              hipStream_t stream) {
    const float* x   = (const float*)d_in[0];
    const float* vf  = (const float*)d_in[1];
    const float* x_r = (const float*)d_in[2];
    const float* x_w = (const float*)d_in[3];
    const float* x_k = (const float*)d_in[4];
    const float* x_v = (const float*)d_in[5];
    const float* x_a = (const float*)d_in[6];
    const float* x_g = (const float*)d_in[7];
    const float* k_k = (const float*)d_in[8];
    const float* k_a = (const float*)d_in[9];
    const float* r_k = (const float*)d_in[10];
    const float* W_r = (const float*)d_in[11];
    const float* W_k = (const float*)d_in[12];
    const float* W_v = (const float*)d_in[13];
    const float* W_o = (const float*)d_in[14];
    const float* wA  = (const float*)d_in[15];
    const float* wB  = (const float*)d_in[16];
    const float* wb  = (const float*)d_in[17];
    const float* aA  = (const float*)d_in[18];
    const float* aB  = (const float*)d_in[19];
    const float* ab  = (const float*)d_in[20];
    const float* vA  = (const float*)d_in[21];
    const float* vB  = (const float*)d_in[22];
    const float* vb  = (const float*)d_in[23];
    const float* gA  = (const float*)d_in[24];
    const float* gB  = (const float*)d_in[25];
    const float* gnw = (const float*)d_in[26];
    const float* gnb = (const float*)d_in[27];
    float* out = (float*)d_out;

    float* ws = (float*)d_ws;
    const size_t SZ = (size_t)BTOT * HID;
    const size_t HH = (size_t)HID * HID;
    float*          WL   = ws;            // log-decay f32 -> later G
    unsigned short* P    = (unsigned short*)(ws + SZ);
    unsigned short* R16  = P;             // r -> Rt  -> later Y (bf16)
    unsigned short* K16  = P + 1 * SZ;    // k -> kn -> Kt
    unsigned short* V16  = P + 2 * SZ;    // v
    unsigned short* A16  = P + 3 * SZ;    // a -> b -> Bt
    unsigned short* KK16 = P + 4 * SZ;    // kk -> At
    unsigned short* H1   = P + 5 * SZ;    // lora hidden bf16 [BTOT,<=160]
    unsigned short* WR   = H1 + (size_t)BTOT * 160;
    unsigned short* Wr16 = WR;
    unsigned short* Wk16 = WR + 1 * HH;
    unsigned short* Wv16 = WR + 2 * HH;
    unsigned short* Wo16 = WR + 3 * HH;
    unsigned short* wA16 = WR + 4 * HH;
    unsigned short* wB16 = wA16 + 65536;
    unsigned short* aA16 = wB16 + 65536;
    unsigned short* aB16 = aA16 + 65536;
    unsigned short* vA16 = aB16 + 65536;
    unsigned short* vB16 = vA16 + 65536;
    unsigned short* gA16 = vB16 + 65536;
    unsigned short* gB16 = gA16 + 163840;
    float*          SB   = (float*)(gB16 + 163840);    // [128][2048] f32
    float*          Ed   = SB + (size_t)128 * TSEQ;    // [128][64][64] f32
    unsigned short* Y16  = R16;           // reuse
    float*          G    = WL;            // reuse

    const dim3 blk(256);
    const dim3 gBig(128, 8);
    const dim3 gL64(256, 1);
    const dim3 gL160(256, 3);
    const float* np = nullptr;
    const unsigned short* nu = nullptr;

    auto CAST = [&](const float* s, unsigned short* d, int n) {
        cast_kernel<<<dim3((n / 4 + 255) / 256), blk, 0, stream>>>(s, d, n);
    };
    CAST(W_r, Wr16, (int)HH); CAST(W_k, Wk16, (int)HH);
    CAST(W_v, Wv16, (int)HH); CAST(W_o, Wo16, (int)HH);
    CAST(wA, wA16, 65536); CAST(wB, wB16, 65536);
    CAST(aA, aA16, 65536); CAST(aB, aB16, 65536);
    CAST(vA, vA16, 65536); CAST(vB, vB16, 65536);
    CAST(gA, gA16, 163840); CAST(gB, gB16, 163840);

    // r, k, v0 projections (mix fused into A staging)
    mgemm<128,128,0,true,true><<<gBig, blk, 0, stream>>>(
        x, x_r, Wr16, R16, HID, HID, np, nu, np);
    mgemm<128,128,0,true,true><<<gBig, blk, 0, stream>>>(
        x, x_k, Wk16, K16, HID, HID, np, nu, np);
    mgemm<128,128,0,true,true><<<gBig, blk, 0, stream>>>(
        x, x_v, Wv16, V16, HID, HID, np, nu, np);
    // v = v0 + (v_first - v0) * sigmoid(lora_v(xv) + vb)
    mgemm<64,64,0,true,true><<<gL64, blk, 0, stream>>>(
        x, x_v, vA16, H1, 64, HID, np, nu, np);
    mgemm<128,128,5,false,true><<<gBig, blk, 0, stream>>>(
        H1, np, vB16, V16, HID, 64, vb, V16, vf);
    // w (LOG decay, f32) = W_SCALE * sigmoid(tanh(xw@wA^T)@wB^T + wb)
    mgemm<64,64,1,true,true><<<gL64, blk, 0, stream>>>(
        x, x_w, wA16, H1, 64, HID, np, nu, np);
    mgemm<128,128,6,false,false><<<gBig, blk, 0, stream>>>(
        H1, np, wB16, WL, HID, 64, wb, nu, np);
    // a = sigmoid(xa@aA^T@aB^T + ab)
    mgemm<64,64,0,true,true><<<gL64, blk, 0, stream>>>(
        x, x_a, aA16, H1, 64, HID, np, nu, np);
    mgemm<128,128,4,false,true><<<gBig, blk, 0, stream>>>(
        H1, np, aB16, A16, HID, 64, ab, nu, np);
    // prep then chunkprep
    prep_kernel<<<dim3(BTOT), blk, 0, stream>>>(
        K16, A16, R16, k_k, k_a, r_k, KK16, SB);
    chunkprep_kernel<<<dim3(128 * NCH), dim3(64), 0, stream>>>(
        KK16, A16, K16, R16, WL, Ed);
    // chunked recurrence -> o (d_out f32)
    recchunk_kernel<<<dim3(256), blk, 0, stream>>>(
        KK16, A16, K16, R16, V16, Ed, out);
    // g = sigmoid(xg@gA^T) @ gB^T  (fp32, reuses WL)
    mgemm<64,64,2,true,true><<<gL160, blk, 0, stream>>>(
        x, x_g, gA16, H1, 160, HID, np, nu, np);
    mgemm<128,128,0,false,false><<<gBig, blk, 0, stream>>>(
        H1, np, gB16, G, HID, 160, np, nu, np);
    // y = (GN(o) + s3*v) * g -> bf16 Y
    post_kernel<<<dim3(BTOT), blk, 0, stream>>>(
        out, V16, G, SB, gnw, gnb, Y16);
    // out = y @ W_o^T
    mgemm<128,128,0,false,false><<<gBig, blk, 0, stream>>>(
        Y16, np, Wo16, out, HID, HID, np, nu, np);
    (void)in_sizes; (void)n_in; (void)out_size; (void)ws_size;
}

// Round 10
// 1223.639 us; speedup vs baseline: 3.0404x; 1.0355x over previous
//
#include <hip/hip_runtime.h>
#include <hip/hip_bf16.h>

// ---------------------------------------------------------------------------
// RWKV7 attention block — Round 10 (= R9 with Minv aliased into WL region).
// Chunked delta rule (C=32). (I-L)^-1 precomputed per chunk in a parallel
// minv_kernel (f32 fsub, hi/lo bf16 out, stored in the dead WL region).
// recchunk is pure MFMA + masked writes: no serial phase, pads [42]/[74].
// B=8, T=2048, H=1024, NH=16, DK=DV=64. ws ~242 MB (R7/R8-proven budget).
// ---------------------------------------------------------------------------

#define DEVI __device__ __forceinline__

constexpr int TSEQ = 2048;
constexpr int HID  = 1024;
constexpr int BTOT = 16384;   // B*T
constexpr int CCH  = 32;      // chunk length
constexpr int NCH  = TSEQ / CCH;
constexpr float W_SCALE = -0.6065306597126334f;
constexpr float GN_EPS  = 6.4e-4f;   // 64 * 1e-5

using s16x8  = __attribute__((ext_vector_type(8))) short;   // 8 bf16 (4 VGPR)
using f32x4v = __attribute__((ext_vector_type(4))) float;   // MFMA acc

DEVI float4 ld4(const float* p) { return *reinterpret_cast<const float4*>(p); }
DEVI void   st4(float* p, float4 v) { *reinterpret_cast<float4*>(p) = v; }
DEVI float  sigf(float x) { return 1.0f / (1.0f + __expf(-x)); }
// bf16 <-> f32 (RNE)
DEVI unsigned short bfr(float f) {
    unsigned int u = __float_as_uint(f);
    return (unsigned short)((u + 0x7fffu + ((u >> 16) & 1u)) >> 16);
}
DEVI float bff(unsigned short s) { return __uint_as_float(((unsigned int)s) << 16); }
DEVI unsigned int pk2(float lo, float hi) {
    return ((unsigned int)bfr(hi) << 16) | (unsigned int)bfr(lo);
}
DEVI f32x4v MF(s16x8 a, s16x8 b, f32x4v c) {
    return __builtin_amdgcn_mfma_f32_16x16x32_bf16(a, b, c, 0, 0, 0);
}
// async global->LDS
DEVI void gl16(const void* g, void* l) {
    __builtin_amdgcn_global_load_lds(
        (const __attribute__((address_space(1))) unsigned int*)g,
        (__attribute__((address_space(3))) unsigned int*)l, 16, 0, 0);
}
DEVI void gl4(const void* g, void* l) {
    __builtin_amdgcn_global_load_lds(
        (const __attribute__((address_space(1))) unsigned int*)g,
        (__attribute__((address_space(3))) unsigned int*)l, 4, 0, 0);
}

// ---------------------------------------------------------------------------
// f32 -> bf16 cast (weights)
// ---------------------------------------------------------------------------
__global__ __launch_bounds__(256) void cast_kernel(
        const float* __restrict__ s, unsigned short* __restrict__ d, int n) {
    int i = (blockIdx.x * 256 + threadIdx.x) * 4;
    if (i >= n) return;
    float4 v = ld4(s + i);
    ushort4 o; o.x = bfr(v.x); o.y = bfr(v.y); o.z = bfr(v.z); o.w = bfr(v.w);
    *reinterpret_cast<ushort4*>(d + i) = o;
}

// ---------------------------------------------------------------------------
// MFMA bf16 GEMM (unchanged). MODE 6: log-decay.
// ---------------------------------------------------------------------------
template<int BM, int BN, int MODE, bool MIXA, bool OUTBF>
__global__ __launch_bounds__(256) void mgemm(
        const void* __restrict__ Ap, const float* __restrict__ cvec,
        const unsigned short* __restrict__ Bw, void* Cout,
        int N, int K,
        const float* __restrict__ bias,
        const unsigned short* aux1, const float* __restrict__ aux2) {
    constexpr int BK = 32;
    constexpr int WM_ = (BN == 128) ? 2 : (BM == 128 ? 4 : 2);
    constexpr int WN_ = (BN == 128) ? 2 : (BM == 128 ? 1 : 2);
    constexpr int WTM = BM / WM_, WTN = BN / WN_;
    constexpr int MF_ = WTM / 16, NF = WTN / 16;
    constexpr int ACALLS = (BM * BK) / 2048;
    constexpr int BCALLS = (BN * BK) / 2048;
    __shared__ __align__(16) unsigned short As[BM * BK];
    __shared__ __align__(16) unsigned short Bs[BN * BK];
    const int tid = threadIdx.x;
    const int w = tid >> 6, l = tid & 63;
    const int bm = blockIdx.x * BM, bn = blockIdx.y * BN;
    const int wm = w / WN_, wn = w % WN_;
    const int lr = l & 15, lk = (l >> 4) * 8;

    f32x4v acc[MF_][NF];
#pragma unroll
    for (int i = 0; i < MF_; i++)
#pragma unroll
        for (int j = 0; j < NF; j++)
#pragma unroll
            for (int q = 0; q < 4; q++) acc[i][j][q] = 0.f;

    for (int k0 = 0; k0 < K; k0 += BK) {
        if (MIXA) {
            const float* Axf = (const float*)Ap;
#pragma unroll
            for (int c = 0; c < ACALLS; c++) {
                int idx = c * 256 + tid;
                int row = idx >> 2, kp = (idx & 3) * 8;
                int gr = bm + row;
                const float* xp = Axf + (size_t)gr * K + k0 + kp;
                float4 x0 = ld4(xp), x1 = ld4(xp + 4);
                float4 p0 = make_float4(0.f,0.f,0.f,0.f), p1 = p0;
                if ((gr & (TSEQ - 1)) != 0) { p0 = ld4(xp - HID); p1 = ld4(xp - HID + 4); }
                float4 c0 = ld4(cvec + k0 + kp), c1 = ld4(cvec + k0 + kp + 4);
                uint4 u;
                u.x = pk2(fmaf(p0.x - x0.x, c0.x, x0.x), fmaf(p0.y - x0.y, c0.y, x0.y));
                u.y = pk2(fmaf(p0.z - x0.z, c0.z, x0.z), fmaf(p0.w - x0.w, c0.w, x0.w));
                u.z = pk2(fmaf(p1.x - x1.x, c1.x, x1.x), fmaf(p1.y - x1.y, c1.y, x1.y));
                u.w = pk2(fmaf(p1.z - x1.z, c1.z, x1.z), fmaf(p1.w - x1.w, c1.w, x1.w));
                *reinterpret_cast<uint4*>(&As[idx * 8]) = u;
            }
        } else {
            const unsigned short* Ab = (const unsigned short*)Ap;
#pragma unroll
            for (int c = 0; c < ACALLS; c++) {
                int idx = c * 256 + tid;
                int row = idx >> 2, kp = (idx & 3) * 8;
                gl16(Ab + (size_t)(bm + row) * K + k0 + kp, &As[c * 2048 + w * 512]);
            }
        }
#pragma unroll
        for (int c = 0; c < BCALLS; c++) {
            int idx = c * 256 + tid;
            int row = idx >> 2, kp = (idx & 3) * 8;
            int gc = bn + row; if (gc > N - 1) gc = N - 1;
            gl16(Bw + (size_t)gc * K + k0 + kp, &Bs[c * 2048 + w * 512]);
        }
        __syncthreads();
        s16x8 afx[MF_], bfx[NF];
#pragma unroll
        for (int i = 0; i < MF_; i++)
            afx[i] = *reinterpret_cast<const s16x8*>(&As[(wm * WTM + i * 16 + lr) * BK + lk]);
#pragma unroll
        for (int j = 0; j < NF; j++)
            bfx[j] = *reinterpret_cast<const s16x8*>(&Bs[(wn * WTN + j * 16 + lr) * BK + lk]);
#pragma unroll
        for (int i = 0; i < MF_; i++)
#pragma unroll
            for (int j = 0; j < NF; j++)
                acc[i][j] = __builtin_amdgcn_mfma_f32_16x16x32_bf16(
                    afx[i], bfx[j], acc[i][j], 0, 0, 0);
        __syncthreads();
    }

#pragma unroll
    for (int i = 0; i < MF_; i++) {
        const int grow0 = bm + wm * WTM + i * 16 + (l >> 4) * 4;
#pragma unroll
        for (int j = 0; j < NF; j++) {
            const int gcol = bn + wn * WTN + j * 16 + lr;
            if (gcol >= N) continue;
            const float bsv = (MODE >= 3) ? bias[gcol] : 0.f;
#pragma unroll
            for (int q = 0; q < 4; q++) {
                const int grow = grow0 + q;
                float d = acc[i][j][q];
                if (MODE == 1) d = tanhf(d);
                else if (MODE == 2) d = sigf(d);
                else if (MODE == 3) d = __expf(W_SCALE * sigf(d + bsv));
                else if (MODE == 4) d = sigf(d + bsv);
                else if (MODE == 5) {
                    float v0 = bff(aux1[(size_t)grow * N + gcol]);
                    d = fmaf(aux2[(size_t)grow * N + gcol] - v0, sigf(d + bsv), v0);
                }
                else if (MODE == 6) d = W_SCALE * sigf(d + bsv);
                if (OUTBF) ((unsigned short*)Cout)[(size_t)grow * N + gcol] = bfr(d);
                else       ((float*)Cout)[(size_t)grow * N + gcol] = d;
            }
        }
    }
}

// ---------------------------------------------------------------------------
// prep (unchanged): kk -> KK16; b -> A16; kn -> K16; s3 -> SB
// ---------------------------------------------------------------------------
__global__ __launch_bounds__(256) void prep_kernel(
        unsigned short* __restrict__ K16, unsigned short* __restrict__ A16,
        const unsigned short* __restrict__ R16,
        const float* __restrict__ kkc, const float* __restrict__ kac,
        const float* __restrict__ rkw,
        unsigned short* __restrict__ KK16, float* __restrict__ SB) {
    const int row = blockIdx.x;
    const int tid = threadIdx.x;
    const int c   = tid * 4;
    const size_t off = (size_t)row * HID + c;
    ushort4 ku = *reinterpret_cast<const ushort4*>(K16 + off);
    ushort4 au = *reinterpret_cast<const ushort4*>(A16 + off);
    ushort4 ru = *reinterpret_cast<const ushort4*>(R16 + off);
    float k[4] = {bff(ku.x), bff(ku.y), bff(ku.z), bff(ku.w)};
    float a[4] = {bff(au.x), bff(au.y), bff(au.z), bff(au.w)};
    float r[4] = {bff(ru.x), bff(ru.y), bff(ru.z), bff(ru.w)};
    float4 kc4 = ld4(kkc + c), ka4 = ld4(kac + c);
    const int hh = tid >> 4;
    const int d0 = c & 63;
    float4 rk4 = ld4(rkw + hh * 64 + d0);
    float kr[4];
    kr[0] = k[0]*kc4.x; kr[1] = k[1]*kc4.y; kr[2] = k[2]*kc4.z; kr[3] = k[3]*kc4.w;
    float ss = kr[0]*kr[0] + kr[1]*kr[1] + kr[2]*kr[2] + kr[3]*kr[3];
    ss += __shfl_xor(ss, 1); ss += __shfl_xor(ss, 2);
    ss += __shfl_xor(ss, 4); ss += __shfl_xor(ss, 8);
    const float inv = 1.0f / fmaxf(sqrtf(ss), 1e-12f);
    float kaf[4] = {ka4.x, ka4.y, ka4.z, ka4.w};
    float rkf[4] = {rk4.x, rk4.y, rk4.z, rk4.w};
    float kkv[4], bv[4], knv[4];
    float s3 = 0.f;
#pragma unroll
    for (int q = 0; q < 4; q++) {
        kkv[q] = kr[q] * inv;
        bv[q]  = kkv[q] * a[q];
        knv[q] = k[q] * fmaf(a[q] - 1.0f, kaf[q], 1.0f);
        s3  = fmaf(r[q] * knv[q], rkf[q], s3);
    }
    ushort4 o;
    o.x = bfr(kkv[0]); o.y = bfr(kkv[1]); o.z = bfr(kkv[2]); o.w = bfr(kkv[3]);
    *reinterpret_cast<ushort4*>(KK16 + off) = o;
    o.x = bfr(bv[0]);  o.y = bfr(bv[1]);  o.z = bfr(bv[2]);  o.w = bfr(bv[3]);
    *reinterpret_cast<ushort4*>(A16 + off) = o;
    o.x = bfr(knv[0]); o.y = bfr(knv[1]); o.z = bfr(knv[2]); o.w = bfr(knv[3]);
    *reinterpret_cast<ushort4*>(K16 + off) = o;
#pragma unroll
    for (int m = 1; m < 16; m <<= 1) s3 += __shfl_xor(s3, m);
    if ((tid & 15) == 0) {
        const int bb = row >> 11, t = row & (TSEQ - 1);
        SB[((size_t)(bb * 16 + hh)) * TSEQ + t] = s3;
    }
}

// ---------------------------------------------------------------------------
// chunkprep (unchanged): prefix log-decay scaling + Ed
// ---------------------------------------------------------------------------
__global__ __launch_bounds__(64) void chunkprep_kernel(
        unsigned short* __restrict__ KK16, unsigned short* __restrict__ A16,
        unsigned short* __restrict__ K16, unsigned short* __restrict__ R16,
        const float* __restrict__ WL, float* __restrict__ Ed) {
    const int bid = blockIdx.x;
    const int bh = bid >> 6, ch = bid & 63;
    const int bb = bh >> 4, hh = bh & 15;
    const int k = threadIdx.x;
    size_t off = ((size_t)(bb * TSEQ) + ch * CCH) * HID + hh * 64 + k;
    float cw = 0.f, er = 1.f;
    for (int i = 0; i < CCH; i++, off += HID) {
        float wv = WL[off];
        float cwp = cw; cw += wv;
        float ea = __expf(cwp), ei = __expf(-cw);
        er = __expf(cw);
        KK16[off] = bfr(-bff(KK16[off]) * ea);
        A16[off]  = bfr( bff(A16[off])  * ei);
        K16[off]  = bfr( bff(K16[off])  * ei);
        R16[off]  = bfr( bff(R16[off])  * er);
    }
    Ed[((size_t)bh * NCH + ch) * 64 + k] = er;
}

// ---------------------------------------------------------------------------
// minv: per (bh, chunk): Mab = strict_lower(At@Bt^T) (MFMA, f32), then
// identity-column forward substitution -> Minv = (I-Mab)^-1, stored hi/lo
// bf16 row-major [32 t_out][32 t'].  grid 8192 x 64thr (1 wave).
// NOTE: MvH/MvL live in the dead WL region (written after chunkprep consumed
// WL; read by recchunk; overwritten later by the g-GEMM into G).
// ---------------------------------------------------------------------------
__global__ __launch_bounds__(64) void minv_kernel(
        const unsigned short* __restrict__ AtG, const unsigned short* __restrict__ BtG,
        unsigned short* __restrict__ MvH, unsigned short* __restrict__ MvL) {
    __shared__ __align__(16) unsigned short sA[32][64], sB[32][64];
    __shared__ __align__(16) float Mab[32][36];
    const int bid = blockIdx.x;
    const int bh = bid >> 6, ch = bid & 63;
    const int bb = bh >> 4, hh = bh & 15;
    const size_t cb = ((size_t)bb * TSEQ + ch * CCH) * HID + hh * 64;
    const int l = threadIdx.x;
    const int r8 = l >> 3, k8 = (l & 7) * 8;
#pragma unroll
    for (int cc = 0; cc < 4; cc++) {
        gl16(AtG + cb + (size_t)(cc * 8 + r8) * HID + k8, &sA[cc * 8][0]);
        gl16(BtG + cb + (size_t)(cc * 8 + r8) * HID + k8, &sB[cc * 8][0]);
    }
    asm volatile("s_waitcnt vmcnt(0)" ::: "memory");
    __syncthreads();
    const int lr = l & 15, lq = l >> 4;
    f32x4v z4; z4[0] = z4[1] = z4[2] = z4[3] = 0.f;
#pragma unroll
    for (int mi = 0; mi < 2; mi++)
#pragma unroll
        for (int ni = 0; ni < 2; ni++) {
            s16x8 a0 = *reinterpret_cast<const s16x8*>(&sA[mi * 16 + lr][lq * 8]);
            s16x8 a1 = *reinterpret_cast<const s16x8*>(&sA[mi * 16 + lr][32 + lq * 8]);
            s16x8 b0 = *reinterpret_cast<const s16x8*>(&sB[ni * 16 + lr][lq * 8]);
            s16x8 b1 = *reinterpret_cast<const s16x8*>(&sB[ni * 16 + lr][32 + lq * 8]);
            f32x4v m = MF(a1, b1, MF(a0, b0, z4));
#pragma unroll
            for (int q = 0; q < 4; q++) {
                int r = mi * 16 + lq * 4 + q, cc2 = ni * 16 + lr;
                Mab[r][cc2] = (cc2 < r) ? m[q] : 0.f;
            }
        }
    __syncthreads();
    const int j = l & 31;
    float m[32];
#pragma unroll
    for (int i = 0; i < 32; i++) m[i] = (i == j) ? 1.f : 0.f;
#pragma unroll
    for (int i = 1; i < 32; i++) {
        float p0 = 0.f, p1 = 0.f, p2 = 0.f, p3 = 0.f;
#pragma unroll
        for (int k4_ = 0; k4_ < 32; k4_ += 4) {
            if (k4_ >= i) break;
            float4 L4 = *reinterpret_cast<const float4*>(&Mab[i][k4_]);
            p0 = fmaf(L4.x, m[k4_ + 0], p0);
            if (k4_ + 1 < i) p1 = fmaf(L4.y, m[k4_ + 1], p1);
            if (k4_ + 2 < i) p2 = fmaf(L4.z, m[k4_ + 2], p2);
            if (k4_ + 3 < i) p3 = fmaf(L4.w, m[k4_ + 3], p3);
        }
        m[i] += (p0 + p1) + (p2 + p3);
    }
    if (l < 32) {
        unsigned short* dH = MvH + (size_t)(bh * NCH + ch) * 1024;
        unsigned short* dL = MvL + (size_t)(bh * NCH + ch) * 1024;
#pragma unroll
        for (int i = 0; i < 32; i++) {
            unsigned short h = bfr(m[i]);
            dH[i * 32 + j] = h;
            dL[i * 32 + j] = bfr(m[i] - bff(h));
        }
    }
}

// ---------------------------------------------------------------------------
// Chunked recurrence, no serial phase. Block = 256 thr (4 waves),
// bid = vh*128 + bh. Operand rule: store [out-dim][contraction] contiguous;
// A-frag row=lr, B-frag col=lr. All pads conflict-checked ([42],[74]).
// ---------------------------------------------------------------------------
__global__ __launch_bounds__(256) void recchunk_kernel(
        const unsigned short* __restrict__ AtG, const unsigned short* __restrict__ BtG,
        const unsigned short* __restrict__ KtG, const unsigned short* __restrict__ RtG,
        const unsigned short* __restrict__ V16, const float* __restrict__ Ed,
        const unsigned short* __restrict__ MvH, const unsigned short* __restrict__ MvL,
        float* __restrict__ Ob) {
    __shared__ __align__(16) unsigned short stT[2][4][CCH][64];   // At,Bt,Kt,Rt (XOR swz)
    __shared__ __align__(16) unsigned short stMh[2][32][32], stMl[2][32][32];
    __shared__ __align__(16) unsigned short stV[2][CCH][32];
    __shared__ __align__(16) float stEd[2][64];
    __shared__ __align__(16) unsigned short Shi[32][74], Slo[32][74];   // S^T: [v][k]
    __shared__ __align__(16) unsigned short BtT[64][42], KtT[64][42];   // [k][t]
    __shared__ __align__(16) unsigned short VT[32][42];                 // [v][t]
    __shared__ __align__(16) unsigned short MakH[32][42], MakL[32][42]; // -> SAT after E
    __shared__ __align__(16) unsigned short MrkH[32][42], MrkL[32][42];
    __shared__ __align__(16) unsigned short MrbH[32][42], MrbL[32][42];
    __shared__ __align__(16) unsigned short rhTH[32][42], rhTL[32][42]; // rhs^T [v][t]

    const int bid = blockIdx.x;
    const int vh = bid >> 7, bh = bid & 127;
    const int tid = threadIdx.x;
    const int w = tid >> 6, l = tid & 63;
    const int lr = l & 15, lq = l >> 4;
    const int bb = bh >> 4, hh = bh & 15;
    const size_t rowoff = ((size_t)bb * TSEQ) * HID + hh * 64;
    const int mi = w >> 1, ni = w & 1;

    const int r8 = l >> 3, ck = l & 7;
    const int swz8 = (ck ^ r8) * 8;

    auto STAGE = [&](int buf, int cn) {
        if (cn >= NCH) return;
        const size_t cb = rowoff + (size_t)(cn * CCH) * HID;
        const unsigned short* srcs[4] = {AtG, BtG, KtG, RtG};
        const unsigned short* T = srcs[w];
#pragma unroll
        for (int c = 0; c < 4; c++)
            gl16(T + cb + (size_t)(c * 8 + r8) * HID + swz8, &stT[buf][w][c * 8][0]);
        if (w == 0) {
#pragma unroll
            for (int c = 0; c < 2; c++)
                gl16(V16 + cb + (size_t)(c * 16 + (l >> 2)) * HID + vh * 32 + (l & 3) * 8,
                     &stV[buf][c * 16][0]);
            gl4(Ed + ((size_t)bh * NCH + cn) * 64 + l, &stEd[buf][0]);
        } else if (w == 1) {
#pragma unroll
            for (int c = 0; c < 2; c++)
                gl16(MvH + (size_t)(bh * NCH + cn) * 1024 + c * 512 + l * 8,
                     (char*)&stMh[buf][0][0] + c * 1024);
        } else if (w == 2) {
#pragma unroll
            for (int c = 0; c < 2; c++)
                gl16(MvL + (size_t)(bh * NCH + cn) * 1024 + c * 512 + l * 8,
                     (char*)&stMl[buf][0][0] + c * 1024);
        }
    };

    // zero state
    for (int idx = tid; idx < 32 * 74; idx += 256) {
        ((unsigned short*)Shi)[idx] = 0;
        ((unsigned short*)Slo)[idx] = 0;
    }
    STAGE(0, 0);
    asm volatile("s_waitcnt vmcnt(0)" ::: "memory");
    __syncthreads();

    auto fragT = [&](int bf, int tn, int rbase, int kb) -> s16x8 {
        int row = rbase + lr;
        int chv = ((kb >> 3) + lq) ^ (row & 7);
        return *reinterpret_cast<const s16x8*>(
            (const char*)&stT[bf][tn][0][0] + row * 128 + chv * 16);
    };
    auto fragS = [&](const unsigned short (*Sx)[74], int rbase, int kb) -> s16x8 {
        return *reinterpret_cast<const s16x8*>(&Sx[rbase + lr][kb + lq * 8]);
    };
    auto frag42 = [&](const unsigned short (*T)[42], int rbase) -> s16x8 {
        return *reinterpret_cast<const s16x8*>(&T[rbase + lr][lq * 8]);
    };

    f32x4v Sacc[2];
#pragma unroll
    for (int s = 0; s < 2; s++)
#pragma unroll
        for (int q = 0; q < 4; q++) Sacc[s][q] = 0.f;
    f32x4v z4; z4[0] = z4[1] = z4[2] = z4[3] = 0.f;

    int buf = 0;
    for (int c = 0; c < NCH; c++) {
        STAGE(buf ^ 1, c + 1);
        // ---- transposes: BtT, KtT, VT (all 256 thr) ----
        {
            const int tt = tid & 31, g8 = tid >> 5;
            const int ch = g8 ^ (tt & 7);
            uint4 bu = *reinterpret_cast<const uint4*>(&stT[buf][1][tt][ch * 8]);
            uint4 ku = *reinterpret_cast<const uint4*>(&stT[buf][2][tt][ch * 8]);
            unsigned int bw[4] = {bu.x, bu.y, bu.z, bu.w};
            unsigned int kw[4] = {ku.x, ku.y, ku.z, ku.w};
#pragma unroll
            for (int e = 0; e < 4; e++) {
                BtT[g8 * 8 + 2 * e][tt]     = (unsigned short)(bw[e] & 0xffffu);
                BtT[g8 * 8 + 2 * e + 1][tt] = (unsigned short)(bw[e] >> 16);
                KtT[g8 * 8 + 2 * e][tt]     = (unsigned short)(kw[e] & 0xffffu);
                KtT[g8 * 8 + 2 * e + 1][tt] = (unsigned short)(kw[e] >> 16);
            }
            ushort4 vu = *reinterpret_cast<const ushort4*>(&stV[buf][tt][g8 * 4]);
            VT[g8 * 4 + 0][tt] = vu.x; VT[g8 * 4 + 1][tt] = vu.y;
            VT[g8 * 4 + 2][tt] = vu.z; VT[g8 * 4 + 3][tt] = vu.w;
        }
        // ---- ph1: M products + O0 + rhsT0 ----
        s16x8 atm0 = fragT(buf, 0, mi * 16, 0), atm1 = fragT(buf, 0, mi * 16, 32);
        s16x8 atn0 = fragT(buf, 0, ni * 16, 0), atn1 = fragT(buf, 0, ni * 16, 32);
        s16x8 rt0  = fragT(buf, 3, mi * 16, 0), rt1  = fragT(buf, 3, mi * 16, 32);
        s16x8 bt0  = fragT(buf, 1, ni * 16, 0), bt1  = fragT(buf, 1, ni * 16, 32);
        s16x8 kt0  = fragT(buf, 2, ni * 16, 0), kt1  = fragT(buf, 2, ni * 16, 32);
        s16x8 shn0 = fragS(Shi, ni * 16, 0), shn1 = fragS(Shi, ni * 16, 32);
        s16x8 sln0 = fragS(Slo, ni * 16, 0), sln1 = fragS(Slo, ni * 16, 32);
        s16x8 shm0 = fragS(Shi, mi * 16, 0), shm1 = fragS(Shi, mi * 16, 32);
        s16x8 slm0 = fragS(Slo, mi * 16, 0), slm1 = fragS(Slo, mi * 16, 32);
        f32x4v mak = MF(atm1, kt1, MF(atm0, kt0, z4));
        f32x4v mrk = MF(rt1, kt1, MF(rt0, kt0, z4));
        f32x4v mrb = MF(rt1, bt1, MF(rt0, bt0, z4));
        f32x4v oac = MF(rt1, sln1, MF(rt0, sln0, MF(rt1, shn1, MF(rt0, shn0, z4))));
        f32x4v rhT = MF(slm1, atn1, MF(slm0, atn0, MF(shm1, atn1, MF(shm0, atn0, z4))));
#pragma unroll
        for (int q = 0; q < 4; q++) {
            const int r = mi * 16 + lq * 4 + q, cc = ni * 16 + lr;
            float vv = (cc < r) ? mak[q] : 0.f;
            unsigned short h = bfr(vv);
            MakH[r][cc] = h; MakL[r][cc] = bfr(vv - bff(h));
            vv = (cc <= r) ? mrk[q] : 0.f; h = bfr(vv);
            MrkH[r][cc] = h; MrkL[r][cc] = bfr(vv - bff(h));
            vv = (cc <= r) ? mrb[q] : 0.f; h = bfr(vv);
            MrbH[r][cc] = h; MrbL[r][cc] = bfr(vv - bff(h));
        }
        __syncthreads();
        // ---- C: rhsT += V^T@Mak^T ; O += Mrk@V ; write rhsT hi/lo ----
        {
            s16x8 vtm  = frag42(VT, mi * 16);
            s16x8 vtn  = frag42(VT, ni * 16);
            s16x8 makh = frag42(MakH, ni * 16), makl = frag42(MakL, ni * 16);
            s16x8 mrkh = frag42(MrkH, mi * 16), mrkl = frag42(MrkL, mi * 16);
            rhT = MF(vtm, makl, MF(vtm, makh, rhT));
            oac = MF(mrkl, vtn, MF(mrkh, vtn, oac));
#pragma unroll
            for (int q = 0; q < 4; q++) {
                const int r = mi * 16 + lq * 4 + q, cc = ni * 16 + lr;
                unsigned short h = bfr(rhT[q]);
                rhTH[r][cc] = h; rhTL[r][cc] = bfr(rhT[q] - bff(h));
            }
        }
        __syncthreads();
        // ---- E: SAT = rhsT @ Minv^T (3 MFMAs), write over MakH/L ----
        {
            s16x8 rh0 = frag42(rhTH, mi * 16), rl0 = frag42(rhTL, mi * 16);
            s16x8 mvh = *reinterpret_cast<const s16x8*>(&stMh[buf][ni * 16 + lr][lq * 8]);
            s16x8 mvl = *reinterpret_cast<const s16x8*>(&stMl[buf][ni * 16 + lr][lq * 8]);
            f32x4v sat = MF(rl0, mvh, MF(rh0, mvl, MF(rh0, mvh, z4)));
#pragma unroll
            for (int q = 0; q < 4; q++) {
                const int r = mi * 16 + lq * 4 + q, cc = ni * 16 + lr;
                unsigned short h = bfr(sat[q]);
                MakH[r][cc] = h;
                MakL[r][cc] = bfr(sat[q] - bff(h));
            }
        }
        __syncthreads();
        // ---- G: O += Mrb@SA -> global; state += SA^T@Bt^T + V^T@Kt^T ----
        {
            s16x8 sathn = frag42(MakH, ni * 16), satln = frag42(MakL, ni * 16);
            s16x8 rbh = frag42(MrbH, mi * 16), rbl = frag42(MrbL, mi * 16);
            oac = MF(rbl, sathn, MF(rbh, satln, MF(rbh, sathn, oac)));
#pragma unroll
            for (int q = 0; q < 4; q++) {
                const int t = c * CCH + mi * 16 + lq * 4 + q;
                Ob[rowoff + (size_t)t * HID + vh * 32 + ni * 16 + lr] = oac[q];
            }
            s16x8 btf = frag42(BtT, w * 16);
            s16x8 ktf = frag42(KtT, w * 16);
            const float ed = stEd[buf][w * 16 + lr];
#pragma unroll
            for (int s = 0; s < 2; s++) {
                s16x8 sah = frag42(MakH, s * 16), sal = frag42(MakL, s * 16);
                s16x8 vta = frag42(VT, s * 16);
                Sacc[s] = MF(sah, btf, Sacc[s]);
                Sacc[s] = MF(sal, btf, Sacc[s]);
                Sacc[s] = MF(vta, ktf, Sacc[s]);
#pragma unroll
                for (int q = 0; q < 4; q++) {
                    Sacc[s][q] *= ed;
                    unsigned short h = bfr(Sacc[s][q]);
                    Shi[s * 16 + lq * 4 + q][w * 16 + lr] = h;
                    Slo[s * 16 + lq * 4 + q][w * 16 + lr] = bfr(Sacc[s][q] - bff(h));
                }
            }
        }
        asm volatile("s_waitcnt vmcnt(0)" ::: "memory");
        __syncthreads();
        buf ^= 1;
    }
}

// ---------------------------------------------------------------------------
// post (unchanged): y = (GN_perhead(o)*gn_w + gn_b + s3*v) * g -> bf16 Y
// ---------------------------------------------------------------------------
__global__ __launch_bounds__(256) void post_kernel(
        const float* __restrict__ Ob, const unsigned short* __restrict__ V16,
        const float* __restrict__ G, const float* __restrict__ SB,
        const float* __restrict__ gnw, const float* __restrict__ gnb,
        unsigned short* __restrict__ Y16) {
    const int row = blockIdx.x;
    const int tid = threadIdx.x;
    const int c   = tid * 4;
    const size_t off = (size_t)row * HID + c;
    float4 o4 = ld4(Ob + off), g4 = ld4(G + off);
    ushort4 vu = *reinterpret_cast<const ushort4*>(V16 + off);
    float v[4]  = {bff(vu.x), bff(vu.y), bff(vu.z), bff(vu.w)};
    const int hh = tid >> 4;
    const int bb = row >> 11, t = row & (TSEQ - 1);
    const float s3 = SB[((size_t)(bb * 16 + hh)) * TSEQ + t];

    float s1 = o4.x + o4.y + o4.z + o4.w;
    float s2 = o4.x*o4.x + o4.y*o4.y + o4.z*o4.z + o4.w*o4.w;
#pragma unroll
    for (int m = 1; m < 16; m <<= 1) {
        s1 += __shfl_xor(s1, m); s2 += __shfl_xor(s2, m);
    }
    const float mu  = s1 * (1.0f / 64.0f);
    const float var = s2 * (1.0f / 64.0f) - mu * mu;
    const float inv = rsqrtf(var + GN_EPS);
    float4 gw = ld4(gnw + c), gb = ld4(gnb + c);
    ushort4 y;
    y.x = bfr((fmaf((o4.x - mu) * inv, gw.x, gb.x) + s3 * v[0]) * g4.x);
    y.y = bfr((fmaf((o4.y - mu) * inv, gw.y, gb.y) + s3 * v[1]) * g4.y);
    y.z = bfr((fmaf((o4.z - mu) * inv, gw.z, gb.z) + s3 * v[2]) * g4.z);
    y.w = bfr((fmaf((o4.w - mu) * inv, gw.w, gb.w) + s3 * v[3]) * g4.w);
    *reinterpret_cast<ushort4*>(Y16 + off) = y;
}

// ---------------------------------------------------------------------------
extern "C" void kernel_launch(void* const* d_in, const int* in_sizes, int n_in,
                              void* d_out, int out_size, void* d_ws, size_t ws_size,
                              hipStream_t stream) {
    const float* x   = (const float*)d_in[0];
    const float* vf  = (const float*)d_in[1];
    const float* x_r = (const float*)d_in[2];
    const float* x_w = (const float*)d_in[3];
    const float* x_k = (const float*)d_in[4];
    const float* x_v = (const float*)d_in[5];
    const float* x_a = (const float*)d_in[6];
    const float* x_g = (const float*)d_in[7];
    const float* k_k = (const float*)d_in[8];
    const float* k_a = (const float*)d_in[9];
    const float* r_k = (const float*)d_in[10];
    const float* W_r = (const float*)d_in[11];
    const float* W_k = (const float*)d_in[12];
    const float* W_v = (const float*)d_in[13];
    const float* W_o = (const float*)d_in[14];
    const float* wA  = (const float*)d_in[15];
    const float* wB  = (const float*)d_in[16];
    const float* wb  = (const float*)d_in[17];
    const float* aA  = (const float*)d_in[18];
    const float* aB  = (const float*)d_in[19];
    const float* ab  = (const float*)d_in[20];
    const float* vA  = (const float*)d_in[21];
    const float* vB  = (const float*)d_in[22];
    const float* vb  = (const float*)d_in[23];
    const float* gA  = (const float*)d_in[24];
    const float* gB  = (const float*)d_in[25];
    const float* gnw = (const float*)d_in[26];
    const float* gnb = (const float*)d_in[27];
    float* out = (float*)d_out;

    float* ws = (float*)d_ws;
    const size_t SZ = (size_t)BTOT * HID;
    const size_t HH = (size_t)HID * HID;
    float*          WL   = ws;            // log-decay f32 -> Minv region -> G
    unsigned short* P    = (unsigned short*)(ws + SZ);
    unsigned short* R16  = P;             // r -> Rt  -> later Y (bf16)
    unsigned short* K16  = P + 1 * SZ;    // k -> kn -> Kt
    unsigned short* V16  = P + 2 * SZ;    // v
    unsigned short* A16  = P + 3 * SZ;    // a -> b -> Bt
    unsigned short* KK16 = P + 4 * SZ;    // kk -> At
    unsigned short* H1   = P + 5 * SZ;    // lora hidden bf16 [BTOT,<=160]
    unsigned short* WR   = H1 + (size_t)BTOT * 160;
    unsigned short* Wr16 = WR;
    unsigned short* Wk16 = WR + 1 * HH;
    unsigned short* Wv16 = WR + 2 * HH;
    unsigned short* Wo16 = WR + 3 * HH;
    unsigned short* wA16 = WR + 4 * HH;
    unsigned short* wB16 = wA16 + 65536;
    unsigned short* aA16 = wB16 + 65536;
    unsigned short* aB16 = aA16 + 65536;
    unsigned short* vA16 = aB16 + 65536;
    unsigned short* vB16 = vA16 + 65536;
    unsigned short* gA16 = vB16 + 65536;
    unsigned short* gB16 = gA16 + 163840;
    float*          SB   = (float*)(gB16 + 163840);    // [128][2048] f32
    float*          Ed   = SB + (size_t)128 * TSEQ;    // [128][64][64] f32
    // Minv aliased INTO the WL region (WL dead after chunkprep; G written
    // only after recchunk completes). 32 MB needed <= 64 MB available.
    unsigned short* MinvH = (unsigned short*)WL;
    unsigned short* MinvL = MinvH + (size_t)128 * NCH * 1024;
    unsigned short* Y16  = R16;           // reuse
    float*          G    = WL;            // reuse (after recchunk)

    const dim3 blk(256);
    const dim3 gBig(128, 8);
    const dim3 gL64(256, 1);
    const dim3 gL160(256, 3);
    const float* np = nullptr;
    const unsigned short* nu = nullptr;

    auto CAST = [&](const float* s, unsigned short* d, int n) {
        cast_kernel<<<dim3((n / 4 + 255) / 256), blk, 0, stream>>>(s, d, n);
    };
    CAST(W_r, Wr16, (int)HH); CAST(W_k, Wk16, (int)HH);
    CAST(W_v, Wv16, (int)HH); CAST(W_o, Wo16, (int)HH);
    CAST(wA, wA16, 65536); CAST(wB, wB16, 65536);
    CAST(aA, aA16, 65536); CAST(aB, aB16, 65536);
    CAST(vA, vA16, 65536); CAST(vB, vB16, 65536);
    CAST(gA, gA16, 163840); CAST(gB, gB16, 163840);

    // r, k, v0 projections (mix fused into A staging)
    mgemm<128,128,0,true,true><<<gBig, blk, 0, stream>>>(
        x, x_r, Wr16, R16, HID, HID, np, nu, np);
    mgemm<128,128,0,true,true><<<gBig, blk, 0, stream>>>(
        x, x_k, Wk16, K16, HID, HID, np, nu, np);
    mgemm<128,128,0,true,true><<<gBig, blk, 0, stream>>>(
        x, x_v, Wv16, V16, HID, HID, np, nu, np);
    // v = v0 + (v_first - v0) * sigmoid(lora_v(xv) + vb)
    mgemm<64,64,0,true,true><<<gL64, blk, 0, stream>>>(
        x, x_v, vA16, H1, 64, HID, np, nu, np);
    mgemm<128,128,5,false,true><<<gBig, blk, 0, stream>>>(
        H1, np, vB16, V16, HID, 64, vb, V16, vf);
    // w (LOG decay, f32) = W_SCALE * sigmoid(tanh(xw@wA^T)@wB^T + wb)
    mgemm<64,64,1,true,true><<<gL64, blk, 0, stream>>>(
        x, x_w, wA16, H1, 64, HID, np, nu, np);
    mgemm<128,128,6,false,false><<<gBig, blk, 0, stream>>>(
        H1, np, wB16, WL, HID, 64, wb, nu, np);
    // a = sigmoid(xa@aA^T@aB^T + ab)
    mgemm<64,64,0,true,true><<<gL64, blk, 0, stream>>>(
        x, x_a, aA16, H1, 64, HID, np, nu, np);
    mgemm<128,128,4,false,true><<<gBig, blk, 0, stream>>>(
        H1, np, aB16, A16, HID, 64, ab, nu, np);
    // prep then chunkprep (consumes WL) then minv (writes into WL region)
    prep_kernel<<<dim3(BTOT), blk, 0, stream>>>(
        K16, A16, R16, k_k, k_a, r_k, KK16, SB);
    chunkprep_kernel<<<dim3(128 * NCH), dim3(64), 0, stream>>>(
        KK16, A16, K16, R16, WL, Ed);
    minv_kernel<<<dim3(128 * NCH), dim3(64), 0, stream>>>(
        KK16, A16, MinvH, MinvL);
    // chunked recurrence -> o (d_out f32)
    recchunk_kernel<<<dim3(256), blk, 0, stream>>>(
        KK16, A16, K16, R16, V16, Ed, MinvH, MinvL, out);
    // g = sigmoid(xg@gA^T) @ gB^T  (fp32, overwrites WL/Minv region)
    mgemm<64,64,2,true,true><<<gL160, blk, 0, stream>>>(
        x, x_g, gA16, H1, 160, HID, np, nu, np);
    mgemm<128,128,0,false,false><<<gBig, blk, 0, stream>>>(
        H1, np, gB16, G, HID, 160, np, nu, np);
    // y = (GN(o) + s3*v) * g -> bf16 Y
    post_kernel<<<dim3(BTOT), blk, 0, stream>>>(
        out, V16, G, SB, gnw, gnb, Y16);
    // out = y @ W_o^T
    mgemm<128,128,0,false,false><<<gBig, blk, 0, stream>>>(
        Y16, np, Wo16, out, HID, HID, np, nu, np);
    (void)in_sizes; (void)n_in; (void)out_size; (void)ws_size;
}

// Round 11
// 1212.313 us; speedup vs baseline: 3.0688x; 1.0093x over previous
//
#include <hip/hip_runtime.h>
#include <hip/hip_bf16.h>

// ---------------------------------------------------------------------------
// RWKV7 attention block — Round 11.
// Chunked delta rule (C=32). recchunk split to v-QUARTERS: grid 512 =
// 2 blocks/CU (LDS 77.3KB), hiding barrier/LDS latency via co-resident
// blocks. Minv precomputed (parallel), hi/lo bf16 everywhere on state path.
// B=8, T=2048, H=1024, NH=16, DK=DV=64. ws ~242 MB.
// ---------------------------------------------------------------------------

#define DEVI __device__ __forceinline__

constexpr int TSEQ = 2048;
constexpr int HID  = 1024;
constexpr int BTOT = 16384;   // B*T
constexpr int CCH  = 32;      // chunk length
constexpr int NCH  = TSEQ / CCH;
constexpr float W_SCALE = -0.6065306597126334f;
constexpr float GN_EPS  = 6.4e-4f;   // 64 * 1e-5

using s16x8  = __attribute__((ext_vector_type(8))) short;   // 8 bf16 (4 VGPR)
using f32x4v = __attribute__((ext_vector_type(4))) float;   // MFMA acc

DEVI float4 ld4(const float* p) { return *reinterpret_cast<const float4*>(p); }
DEVI void   st4(float* p, float4 v) { *reinterpret_cast<float4*>(p) = v; }
DEVI float  sigf(float x) { return 1.0f / (1.0f + __expf(-x)); }
// bf16 <-> f32 (RNE)
DEVI unsigned short bfr(float f) {
    unsigned int u = __float_as_uint(f);
    return (unsigned short)((u + 0x7fffu + ((u >> 16) & 1u)) >> 16);
}
DEVI float bff(unsigned short s) { return __uint_as_float(((unsigned int)s) << 16); }
DEVI unsigned int pk2(float lo, float hi) {
    return ((unsigned int)bfr(hi) << 16) | (unsigned int)bfr(lo);
}
DEVI f32x4v MF(s16x8 a, s16x8 b, f32x4v c) {
    return __builtin_amdgcn_mfma_f32_16x16x32_bf16(a, b, c, 0, 0, 0);
}
// async global->LDS
DEVI void gl16(const void* g, void* l) {
    __builtin_amdgcn_global_load_lds(
        (const __attribute__((address_space(1))) unsigned int*)g,
        (__attribute__((address_space(3))) unsigned int*)l, 16, 0, 0);
}
DEVI void gl4(const void* g, void* l) {
    __builtin_amdgcn_global_load_lds(
        (const __attribute__((address_space(1))) unsigned int*)g,
        (__attribute__((address_space(3))) unsigned int*)l, 4, 0, 0);
}

// ---------------------------------------------------------------------------
// f32 -> bf16 cast (weights)
// ---------------------------------------------------------------------------
__global__ __launch_bounds__(256) void cast_kernel(
        const float* __restrict__ s, unsigned short* __restrict__ d, int n) {
    int i = (blockIdx.x * 256 + threadIdx.x) * 4;
    if (i >= n) return;
    float4 v = ld4(s + i);
    ushort4 o; o.x = bfr(v.x); o.y = bfr(v.y); o.z = bfr(v.z); o.w = bfr(v.w);
    *reinterpret_cast<ushort4*>(d + i) = o;
}

// ---------------------------------------------------------------------------
// MFMA bf16 GEMM (unchanged). MODE 6: log-decay.
// ---------------------------------------------------------------------------
template<int BM, int BN, int MODE, bool MIXA, bool OUTBF>
__global__ __launch_bounds__(256) void mgemm(
        const void* __restrict__ Ap, const float* __restrict__ cvec,
        const unsigned short* __restrict__ Bw, void* Cout,
        int N, int K,
        const float* __restrict__ bias,
        const unsigned short* aux1, const float* __restrict__ aux2) {
    constexpr int BK = 32;
    constexpr int WM_ = (BN == 128) ? 2 : (BM == 128 ? 4 : 2);
    constexpr int WN_ = (BN == 128) ? 2 : (BM == 128 ? 1 : 2);
    constexpr int WTM = BM / WM_, WTN = BN / WN_;
    constexpr int MF_ = WTM / 16, NF = WTN / 16;
    constexpr int ACALLS = (BM * BK) / 2048;
    constexpr int BCALLS = (BN * BK) / 2048;
    __shared__ __align__(16) unsigned short As[BM * BK];
    __shared__ __align__(16) unsigned short Bs[BN * BK];
    const int tid = threadIdx.x;
    const int w = tid >> 6, l = tid & 63;
    const int bm = blockIdx.x * BM, bn = blockIdx.y * BN;
    const int wm = w / WN_, wn = w % WN_;
    const int lr = l & 15, lk = (l >> 4) * 8;

    f32x4v acc[MF_][NF];
#pragma unroll
    for (int i = 0; i < MF_; i++)
#pragma unroll
        for (int j = 0; j < NF; j++)
#pragma unroll
            for (int q = 0; q < 4; q++) acc[i][j][q] = 0.f;

    for (int k0 = 0; k0 < K; k0 += BK) {
        if (MIXA) {
            const float* Axf = (const float*)Ap;
#pragma unroll
            for (int c = 0; c < ACALLS; c++) {
                int idx = c * 256 + tid;
                int row = idx >> 2, kp = (idx & 3) * 8;
                int gr = bm + row;
                const float* xp = Axf + (size_t)gr * K + k0 + kp;
                float4 x0 = ld4(xp), x1 = ld4(xp + 4);
                float4 p0 = make_float4(0.f,0.f,0.f,0.f), p1 = p0;
                if ((gr & (TSEQ - 1)) != 0) { p0 = ld4(xp - HID); p1 = ld4(xp - HID + 4); }
                float4 c0 = ld4(cvec + k0 + kp), c1 = ld4(cvec + k0 + kp + 4);
                uint4 u;
                u.x = pk2(fmaf(p0.x - x0.x, c0.x, x0.x), fmaf(p0.y - x0.y, c0.y, x0.y));
                u.y = pk2(fmaf(p0.z - x0.z, c0.z, x0.z), fmaf(p0.w - x0.w, c0.w, x0.w));
                u.z = pk2(fmaf(p1.x - x1.x, c1.x, x1.x), fmaf(p1.y - x1.y, c1.y, x1.y));
                u.w = pk2(fmaf(p1.z - x1.z, c1.z, x1.z), fmaf(p1.w - x1.w, c1.w, x1.w));
                *reinterpret_cast<uint4*>(&As[idx * 8]) = u;
            }
        } else {
            const unsigned short* Ab = (const unsigned short*)Ap;
#pragma unroll
            for (int c = 0; c < ACALLS; c++) {
                int idx = c * 256 + tid;
                int row = idx >> 2, kp = (idx & 3) * 8;
                gl16(Ab + (size_t)(bm + row) * K + k0 + kp, &As[c * 2048 + w * 512]);
            }
        }
#pragma unroll
        for (int c = 0; c < BCALLS; c++) {
            int idx = c * 256 + tid;
            int row = idx >> 2, kp = (idx & 3) * 8;
            int gc = bn + row; if (gc > N - 1) gc = N - 1;
            gl16(Bw + (size_t)gc * K + k0 + kp, &Bs[c * 2048 + w * 512]);
        }
        __syncthreads();
        s16x8 afx[MF_], bfx[NF];
#pragma unroll
        for (int i = 0; i < MF_; i++)
            afx[i] = *reinterpret_cast<const s16x8*>(&As[(wm * WTM + i * 16 + lr) * BK + lk]);
#pragma unroll
        for (int j = 0; j < NF; j++)
            bfx[j] = *reinterpret_cast<const s16x8*>(&Bs[(wn * WTN + j * 16 + lr) * BK + lk]);
#pragma unroll
        for (int i = 0; i < MF_; i++)
#pragma unroll
            for (int j = 0; j < NF; j++)
                acc[i][j] = __builtin_amdgcn_mfma_f32_16x16x32_bf16(
                    afx[i], bfx[j], acc[i][j], 0, 0, 0);
        __syncthreads();
    }

#pragma unroll
    for (int i = 0; i < MF_; i++) {
        const int grow0 = bm + wm * WTM + i * 16 + (l >> 4) * 4;
#pragma unroll
        for (int j = 0; j < NF; j++) {
            const int gcol = bn + wn * WTN + j * 16 + lr;
            if (gcol >= N) continue;
            const float bsv = (MODE >= 3) ? bias[gcol] : 0.f;
#pragma unroll
            for (int q = 0; q < 4; q++) {
                const int grow = grow0 + q;
                float d = acc[i][j][q];
                if (MODE == 1) d = tanhf(d);
                else if (MODE == 2) d = sigf(d);
                else if (MODE == 3) d = __expf(W_SCALE * sigf(d + bsv));
                else if (MODE == 4) d = sigf(d + bsv);
                else if (MODE == 5) {
                    float v0 = bff(aux1[(size_t)grow * N + gcol]);
                    d = fmaf(aux2[(size_t)grow * N + gcol] - v0, sigf(d + bsv), v0);
                }
                else if (MODE == 6) d = W_SCALE * sigf(d + bsv);
                if (OUTBF) ((unsigned short*)Cout)[(size_t)grow * N + gcol] = bfr(d);
                else       ((float*)Cout)[(size_t)grow * N + gcol] = d;
            }
        }
    }
}

// ---------------------------------------------------------------------------
// prep (unchanged): kk -> KK16; b -> A16; kn -> K16; s3 -> SB
// ---------------------------------------------------------------------------
__global__ __launch_bounds__(256) void prep_kernel(
        unsigned short* __restrict__ K16, unsigned short* __restrict__ A16,
        const unsigned short* __restrict__ R16,
        const float* __restrict__ kkc, const float* __restrict__ kac,
        const float* __restrict__ rkw,
        unsigned short* __restrict__ KK16, float* __restrict__ SB) {
    const int row = blockIdx.x;
    const int tid = threadIdx.x;
    const int c   = tid * 4;
    const size_t off = (size_t)row * HID + c;
    ushort4 ku = *reinterpret_cast<const ushort4*>(K16 + off);
    ushort4 au = *reinterpret_cast<const ushort4*>(A16 + off);
    ushort4 ru = *reinterpret_cast<const ushort4*>(R16 + off);
    float k[4] = {bff(ku.x), bff(ku.y), bff(ku.z), bff(ku.w)};
    float a[4] = {bff(au.x), bff(au.y), bff(au.z), bff(au.w)};
    float r[4] = {bff(ru.x), bff(ru.y), bff(ru.z), bff(ru.w)};
    float4 kc4 = ld4(kkc + c), ka4 = ld4(kac + c);
    const int hh = tid >> 4;
    const int d0 = c & 63;
    float4 rk4 = ld4(rkw + hh * 64 + d0);
    float kr[4];
    kr[0] = k[0]*kc4.x; kr[1] = k[1]*kc4.y; kr[2] = k[2]*kc4.z; kr[3] = k[3]*kc4.w;
    float ss = kr[0]*kr[0] + kr[1]*kr[1] + kr[2]*kr[2] + kr[3]*kr[3];
    ss += __shfl_xor(ss, 1); ss += __shfl_xor(ss, 2);
    ss += __shfl_xor(ss, 4); ss += __shfl_xor(ss, 8);
    const float inv = 1.0f / fmaxf(sqrtf(ss), 1e-12f);
    float kaf[4] = {ka4.x, ka4.y, ka4.z, ka4.w};
    float rkf[4] = {rk4.x, rk4.y, rk4.z, rk4.w};
    float kkv[4], bv[4], knv[4];
    float s3 = 0.f;
#pragma unroll
    for (int q = 0; q < 4; q++) {
        kkv[q] = kr[q] * inv;
        bv[q]  = kkv[q] * a[q];
        knv[q] = k[q] * fmaf(a[q] - 1.0f, kaf[q], 1.0f);
        s3  = fmaf(r[q] * knv[q], rkf[q], s3);
    }
    ushort4 o;
    o.x = bfr(kkv[0]); o.y = bfr(kkv[1]); o.z = bfr(kkv[2]); o.w = bfr(kkv[3]);
    *reinterpret_cast<ushort4*>(KK16 + off) = o;
    o.x = bfr(bv[0]);  o.y = bfr(bv[1]);  o.z = bfr(bv[2]);  o.w = bfr(bv[3]);
    *reinterpret_cast<ushort4*>(A16 + off) = o;
    o.x = bfr(knv[0]); o.y = bfr(knv[1]); o.z = bfr(knv[2]); o.w = bfr(knv[3]);
    *reinterpret_cast<ushort4*>(K16 + off) = o;
#pragma unroll
    for (int m = 1; m < 16; m <<= 1) s3 += __shfl_xor(s3, m);
    if ((tid & 15) == 0) {
        const int bb = row >> 11, t = row & (TSEQ - 1);
        SB[((size_t)(bb * 16 + hh)) * TSEQ + t] = s3;
    }
}

// ---------------------------------------------------------------------------
// chunkprep (unchanged): prefix log-decay scaling + Ed
// ---------------------------------------------------------------------------
__global__ __launch_bounds__(64) void chunkprep_kernel(
        unsigned short* __restrict__ KK16, unsigned short* __restrict__ A16,
        unsigned short* __restrict__ K16, unsigned short* __restrict__ R16,
        const float* __restrict__ WL, float* __restrict__ Ed) {
    const int bid = blockIdx.x;
    const int bh = bid >> 6, ch = bid & 63;
    const int bb = bh >> 4, hh = bh & 15;
    const int k = threadIdx.x;
    size_t off = ((size_t)(bb * TSEQ) + ch * CCH) * HID + hh * 64 + k;
    float cw = 0.f, er = 1.f;
    for (int i = 0; i < CCH; i++, off += HID) {
        float wv = WL[off];
        float cwp = cw; cw += wv;
        float ea = __expf(cwp), ei = __expf(-cw);
        er = __expf(cw);
        KK16[off] = bfr(-bff(KK16[off]) * ea);
        A16[off]  = bfr( bff(A16[off])  * ei);
        K16[off]  = bfr( bff(K16[off])  * ei);
        R16[off]  = bfr( bff(R16[off])  * er);
    }
    Ed[((size_t)bh * NCH + ch) * 64 + k] = er;
}

// ---------------------------------------------------------------------------
// minv (unchanged): Minv = (I - strict_lower(At@Bt^T))^-1, hi/lo bf16,
// stored in the dead WL region.
// ---------------------------------------------------------------------------
__global__ __launch_bounds__(64) void minv_kernel(
        const unsigned short* __restrict__ AtG, const unsigned short* __restrict__ BtG,
        unsigned short* __restrict__ MvH, unsigned short* __restrict__ MvL) {
    __shared__ __align__(16) unsigned short sA[32][64], sB[32][64];
    __shared__ __align__(16) float Mab[32][36];
    const int bid = blockIdx.x;
    const int bh = bid >> 6, ch = bid & 63;
    const int bb = bh >> 4, hh = bh & 15;
    const size_t cb = ((size_t)bb * TSEQ + ch * CCH) * HID + hh * 64;
    const int l = threadIdx.x;
    const int r8 = l >> 3, k8 = (l & 7) * 8;
#pragma unroll
    for (int cc = 0; cc < 4; cc++) {
        gl16(AtG + cb + (size_t)(cc * 8 + r8) * HID + k8, &sA[cc * 8][0]);
        gl16(BtG + cb + (size_t)(cc * 8 + r8) * HID + k8, &sB[cc * 8][0]);
    }
    asm volatile("s_waitcnt vmcnt(0)" ::: "memory");
    __syncthreads();
    const int lr = l & 15, lq = l >> 4;
    f32x4v z4; z4[0] = z4[1] = z4[2] = z4[3] = 0.f;
#pragma unroll
    for (int mi = 0; mi < 2; mi++)
#pragma unroll
        for (int ni = 0; ni < 2; ni++) {
            s16x8 a0 = *reinterpret_cast<const s16x8*>(&sA[mi * 16 + lr][lq * 8]);
            s16x8 a1 = *reinterpret_cast<const s16x8*>(&sA[mi * 16 + lr][32 + lq * 8]);
            s16x8 b0 = *reinterpret_cast<const s16x8*>(&sB[ni * 16 + lr][lq * 8]);
            s16x8 b1 = *reinterpret_cast<const s16x8*>(&sB[ni * 16 + lr][32 + lq * 8]);
            f32x4v m = MF(a1, b1, MF(a0, b0, z4));
#pragma unroll
            for (int q = 0; q < 4; q++) {
                int r = mi * 16 + lq * 4 + q, cc2 = ni * 16 + lr;
                Mab[r][cc2] = (cc2 < r) ? m[q] : 0.f;
            }
        }
    __syncthreads();
    const int j = l & 31;
    float m[32];
#pragma unroll
    for (int i = 0; i < 32; i++) m[i] = (i == j) ? 1.f : 0.f;
#pragma unroll
    for (int i = 1; i < 32; i++) {
        float p0 = 0.f, p1 = 0.f, p2 = 0.f, p3 = 0.f;
#pragma unroll
        for (int k4_ = 0; k4_ < 32; k4_ += 4) {
            if (k4_ >= i) break;
            float4 L4 = *reinterpret_cast<const float4*>(&Mab[i][k4_]);
            p0 = fmaf(L4.x, m[k4_ + 0], p0);
            if (k4_ + 1 < i) p1 = fmaf(L4.y, m[k4_ + 1], p1);
            if (k4_ + 2 < i) p2 = fmaf(L4.z, m[k4_ + 2], p2);
            if (k4_ + 3 < i) p3 = fmaf(L4.w, m[k4_ + 3], p3);
        }
        m[i] += (p0 + p1) + (p2 + p3);
    }
    if (l < 32) {
        unsigned short* dH = MvH + (size_t)(bh * NCH + ch) * 1024;
        unsigned short* dL = MvL + (size_t)(bh * NCH + ch) * 1024;
#pragma unroll
        for (int i = 0; i < 32; i++) {
            unsigned short h = bfr(m[i]);
            dH[i * 32 + j] = h;
            dL[i * 32 + j] = bfr(m[i] - bff(h));
        }
    }
}

// ---------------------------------------------------------------------------
// Chunked recurrence, v-QUARTER blocks. Block = 256 thr (4 waves),
// bid = vq*128 + bh (vq in 0..3, 16 v-cols each) -> grid 512 = 2 blocks/CU.
// Wave roles: all waves compute M-product tile (mi=w>>1, ni=w&1);
// ni==0 waves own the O path (t-tile mi), ni==1 waves own rhT/SAT (t-tile mi);
// all 4 waves update the state (k-tile w). LDS 77.3 KB.
// ---------------------------------------------------------------------------
__global__ __launch_bounds__(256) void recchunk_kernel(
        const unsigned short* __restrict__ AtG, const unsigned short* __restrict__ BtG,
        const unsigned short* __restrict__ KtG, const unsigned short* __restrict__ RtG,
        const unsigned short* __restrict__ V16, const float* __restrict__ Ed,
        const unsigned short* __restrict__ MvH, const unsigned short* __restrict__ MvL,
        float* __restrict__ Ob) {
    __shared__ __align__(16) unsigned short stT[2][4][CCH][64];   // At,Bt,Kt,Rt (XOR swz)
    __shared__ __align__(16) unsigned short stMh[2][32][32], stMl[2][32][32];
    __shared__ __align__(16) unsigned short stV[2][CCH][16];
    __shared__ __align__(16) float stEd[2][64];
    __shared__ __align__(16) unsigned short Shi[16][74], Slo[16][74];   // S^T: [v][k]
    __shared__ __align__(16) unsigned short BtT[64][42], KtT[64][42];   // [k][t]
    __shared__ __align__(16) unsigned short VT[16][42];                 // [v][t]
    __shared__ __align__(16) unsigned short MakH[32][42], MakL[32][42]; // rows 0..15 -> SAT after E
    __shared__ __align__(16) unsigned short MrkH[32][42], MrkL[32][42];
    __shared__ __align__(16) unsigned short MrbH[32][42], MrbL[32][42];
    __shared__ __align__(16) unsigned short rhTH[16][42], rhTL[16][42]; // rhs^T [v][t]

    const int bid = blockIdx.x;
    const int vq = bid >> 7, bh = bid & 127;
    const int tid = threadIdx.x;
    const int w = tid >> 6, l = tid & 63;
    const int lr = l & 15, lq = l >> 4;
    const int bb = bh >> 4, hh = bh & 15;
    const size_t rowoff = ((size_t)bb * TSEQ) * HID + hh * 64;
    const int mi = w >> 1, ni = w & 1;

    const int r8 = l >> 3, ck = l & 7;
    const int swz8 = (ck ^ r8) * 8;

    auto STAGE = [&](int buf, int cn) {
        if (cn >= NCH) return;
        const size_t cb = rowoff + (size_t)(cn * CCH) * HID;
        const unsigned short* srcs[4] = {AtG, BtG, KtG, RtG};
        const unsigned short* T = srcs[w];
#pragma unroll
        for (int c = 0; c < 4; c++)
            gl16(T + cb + (size_t)(c * 8 + r8) * HID + swz8, &stT[buf][w][c * 8][0]);
        if (w == 0) {
            // 32 rows x 16 v-cols bf16 = 1024B = one 64-lane call
            gl16(V16 + cb + (size_t)(l >> 1) * HID + vq * 16 + (l & 1) * 8,
                 &stV[buf][0][0]);
            gl4(Ed + ((size_t)bh * NCH + cn) * 64 + l, &stEd[buf][0]);
        } else if (w == 1) {
#pragma unroll
            for (int c = 0; c < 2; c++)
                gl16(MvH + (size_t)(bh * NCH + cn) * 1024 + c * 512 + l * 8,
                     (char*)&stMh[buf][0][0] + c * 1024);
        } else if (w == 2) {
#pragma unroll
            for (int c = 0; c < 2; c++)
                gl16(MvL + (size_t)(bh * NCH + cn) * 1024 + c * 512 + l * 8,
                     (char*)&stMl[buf][0][0] + c * 1024);
        }
    };

    // zero state
    for (int idx = tid; idx < 16 * 74; idx += 256) {
        ((unsigned short*)Shi)[idx] = 0;
        ((unsigned short*)Slo)[idx] = 0;
    }
    STAGE(0, 0);
    asm volatile("s_waitcnt vmcnt(0)" ::: "memory");
    __syncthreads();

    auto fragT = [&](int bf, int tn, int rbase, int kb) -> s16x8 {
        int row = rbase + lr;
        int chv = ((kb >> 3) + lq) ^ (row & 7);
        return *reinterpret_cast<const s16x8*>(
            (const char*)&stT[bf][tn][0][0] + row * 128 + chv * 16);
    };
    auto fragS = [&](const unsigned short (*Sx)[74], int kb) -> s16x8 {
        return *reinterpret_cast<const s16x8*>(&Sx[lr][kb + lq * 8]);
    };
    auto frag42 = [&](const unsigned short (*T)[42], int rbase) -> s16x8 {
        return *reinterpret_cast<const s16x8*>(&T[rbase + lr][lq * 8]);
    };

    f32x4v Sacc;   // state tile [v 0..15][k-tile w]
#pragma unroll
    for (int q = 0; q < 4; q++) Sacc[q] = 0.f;
    f32x4v z4; z4[0] = z4[1] = z4[2] = z4[3] = 0.f;

    int buf = 0;
    for (int c = 0; c < NCH; c++) {
        STAGE(buf ^ 1, c + 1);
        // ---- transposes: BtT, KtT (k-octets by g8), VT (g8<4) ----
        {
            const int tt = tid & 31, g8 = tid >> 5;
            const int ch = g8 ^ (tt & 7);
            uint4 bu = *reinterpret_cast<const uint4*>(&stT[buf][1][tt][ch * 8]);
            uint4 ku = *reinterpret_cast<const uint4*>(&stT[buf][2][tt][ch * 8]);
            unsigned int bw[4] = {bu.x, bu.y, bu.z, bu.w};
            unsigned int kw[4] = {ku.x, ku.y, ku.z, ku.w};
#pragma unroll
            for (int e = 0; e < 4; e++) {
                BtT[g8 * 8 + 2 * e][tt]     = (unsigned short)(bw[e] & 0xffffu);
                BtT[g8 * 8 + 2 * e + 1][tt] = (unsigned short)(bw[e] >> 16);
                KtT[g8 * 8 + 2 * e][tt]     = (unsigned short)(kw[e] & 0xffffu);
                KtT[g8 * 8 + 2 * e + 1][tt] = (unsigned short)(kw[e] >> 16);
            }
            if (g8 < 4) {
                ushort4 vu = *reinterpret_cast<const ushort4*>(&stV[buf][tt][g8 * 4]);
                VT[g8 * 4 + 0][tt] = vu.x; VT[g8 * 4 + 1][tt] = vu.y;
                VT[g8 * 4 + 2][tt] = vu.z; VT[g8 * 4 + 3][tt] = vu.w;
            }
        }
        // ---- ph1: M products (all waves) + O0 (ni==0) / rhT0 (ni==1) ----
        s16x8 atm0 = fragT(buf, 0, mi * 16, 0), atm1 = fragT(buf, 0, mi * 16, 32);
        s16x8 rt0  = fragT(buf, 3, mi * 16, 0), rt1  = fragT(buf, 3, mi * 16, 32);
        s16x8 bt0  = fragT(buf, 1, ni * 16, 0), bt1  = fragT(buf, 1, ni * 16, 32);
        s16x8 kt0  = fragT(buf, 2, ni * 16, 0), kt1  = fragT(buf, 2, ni * 16, 32);
        f32x4v mak = MF(atm1, kt1, MF(atm0, kt0, z4));
        f32x4v mrk = MF(rt1, kt1, MF(rt0, kt0, z4));
        f32x4v mrb = MF(rt1, bt1, MF(rt0, bt0, z4));
        f32x4v oac = z4, rhT = z4;
        {
            s16x8 sh0 = fragS(Shi, 0), sh1 = fragS(Shi, 32);
            s16x8 sl0 = fragS(Slo, 0), sl1 = fragS(Slo, 32);
            if (ni == 0) {
                // oac[t rows mi][v 0..15] = Rt @ S^T
                oac = MF(rt1, sl1, MF(rt0, sl0, MF(rt1, sh1, MF(rt0, sh0, z4))));
            } else {
                // rhT[v 0..15][t cols mi] = S @ At^T
                rhT = MF(sl1, atm1, MF(sl0, atm0, MF(sh1, atm1, MF(sh0, atm0, z4))));
            }
        }
#pragma unroll
        for (int q = 0; q < 4; q++) {
            const int r = mi * 16 + lq * 4 + q, cc = ni * 16 + lr;
            float vv = (cc < r) ? mak[q] : 0.f;
            unsigned short h = bfr(vv);
            MakH[r][cc] = h; MakL[r][cc] = bfr(vv - bff(h));
            vv = (cc <= r) ? mrk[q] : 0.f; h = bfr(vv);
            MrkH[r][cc] = h; MrkL[r][cc] = bfr(vv - bff(h));
            vv = (cc <= r) ? mrb[q] : 0.f; h = bfr(vv);
            MrbH[r][cc] = h; MrbL[r][cc] = bfr(vv - bff(h));
        }
        __syncthreads();
        // ---- C: ni==0: O += Mrk@V ; ni==1: rhT += V^T@Mak^T, write rhT ----
        {
            s16x8 vt0 = frag42(VT, 0);
            if (ni == 0) {
                oac = MF(frag42(MrkL, mi * 16), vt0,
                         MF(frag42(MrkH, mi * 16), vt0, oac));
            } else {
                rhT = MF(vt0, frag42(MakL, mi * 16),
                         MF(vt0, frag42(MakH, mi * 16), rhT));
#pragma unroll
                for (int q = 0; q < 4; q++) {
                    const int r = lq * 4 + q, cc = mi * 16 + lr;
                    unsigned short h = bfr(rhT[q]);
                    rhTH[r][cc] = h; rhTL[r][cc] = bfr(rhT[q] - bff(h));
                }
            }
        }
        __syncthreads();
        // ---- E (ni==1): SAT[v][t_out mi] = rhT @ Minv^T, overwrite MakH/L ----
        if (ni == 1) {
            s16x8 rh0 = frag42(rhTH, 0), rl0 = frag42(rhTL, 0);
            s16x8 mvh = *reinterpret_cast<const s16x8*>(&stMh[buf][mi * 16 + lr][lq * 8]);
            s16x8 mvl = *reinterpret_cast<const s16x8*>(&stMl[buf][mi * 16 + lr][lq * 8]);
            f32x4v sat = MF(rl0, mvh, MF(rh0, mvl, MF(rh0, mvh, z4)));
#pragma unroll
            for (int q = 0; q < 4; q++) {
                const int r = lq * 4 + q, cc = mi * 16 + lr;
                unsigned short h = bfr(sat[q]);
                MakH[r][cc] = h;
                MakL[r][cc] = bfr(sat[q] - bff(h));
            }
        }
        __syncthreads();
        // ---- G: ni==0: O += Mrb@SA -> global; all: state update ----
        {
            s16x8 sath = frag42(MakH, 0), satl = frag42(MakL, 0);
            if (ni == 0) {
                s16x8 rbh = frag42(MrbH, mi * 16), rbl = frag42(MrbL, mi * 16);
                oac = MF(rbl, sath, MF(rbh, satl, MF(rbh, sath, oac)));
#pragma unroll
                for (int q = 0; q < 4; q++) {
                    const int t = c * CCH + mi * 16 + lq * 4 + q;
                    Ob[rowoff + (size_t)t * HID + vq * 16 + lr] = oac[q];
                }
            }
            s16x8 btf = frag42(BtT, w * 16);
            s16x8 ktf = frag42(KtT, w * 16);
            s16x8 vta = frag42(VT, 0);
            const float ed = stEd[buf][w * 16 + lr];
            Sacc = MF(sath, btf, Sacc);
            Sacc = MF(satl, btf, Sacc);
            Sacc = MF(vta, ktf, Sacc);
#pragma unroll
            for (int q = 0; q < 4; q++) {
                Sacc[q] *= ed;
                unsigned short h = bfr(Sacc[q]);
                Shi[lq * 4 + q][w * 16 + lr] = h;
                Slo[lq * 4 + q][w * 16 + lr] = bfr(Sacc[q] - bff(h));
            }
        }
        asm volatile("s_waitcnt vmcnt(0)" ::: "memory");
        __syncthreads();
        buf ^= 1;
    }
}

// ---------------------------------------------------------------------------
// post (unchanged): y = (GN_perhead(o)*gn_w + gn_b + s3*v) * g -> bf16 Y
// ---------------------------------------------------------------------------
__global__ __launch_bounds__(256) void post_kernel(
        const float* __restrict__ Ob, const unsigned short* __restrict__ V16,
        const float* __restrict__ G, const float* __restrict__ SB,
        const float* __restrict__ gnw, const float* __restrict__ gnb,
        unsigned short* __restrict__ Y16) {
    const int row = blockIdx.x;
    const int tid = threadIdx.x;
    const int c   = tid * 4;
    const size_t off = (size_t)row * HID + c;
    float4 o4 = ld4(Ob + off), g4 = ld4(G + off);
    ushort4 vu = *reinterpret_cast<const ushort4*>(V16 + off);
    float v[4]  = {bff(vu.x), bff(vu.y), bff(vu.z), bff(vu.w)};
    const int hh = tid >> 4;
    const int bb = row >> 11, t = row & (TSEQ - 1);
    const float s3 = SB[((size_t)(bb * 16 + hh)) * TSEQ + t];

    float s1 = o4.x + o4.y + o4.z + o4.w;
    float s2 = o4.x*o4.x + o4.y*o4.y + o4.z*o4.z + o4.w*o4.w;
#pragma unroll
    for (int m = 1; m < 16; m <<= 1) {
        s1 += __shfl_xor(s1, m); s2 += __shfl_xor(s2, m);
    }
    const float mu  = s1 * (1.0f / 64.0f);
    const float var = s2 * (1.0f / 64.0f) - mu * mu;
    const float inv = rsqrtf(var + GN_EPS);
    float4 gw = ld4(gnw + c), gb = ld4(gnb + c);
    ushort4 y;
    y.x = bfr((fmaf((o4.x - mu) * inv, gw.x, gb.x) + s3 * v[0]) * g4.x);
    y.y = bfr((fmaf((o4.y - mu) * inv, gw.y, gb.y) + s3 * v[1]) * g4.y);
    y.z = bfr((fmaf((o4.z - mu) * inv, gw.z, gb.z) + s3 * v[2]) * g4.z);
    y.w = bfr((fmaf((o4.w - mu) * inv, gw.w, gb.w) + s3 * v[3]) * g4.w);
    *reinterpret_cast<ushort4*>(Y16 + off) = y;
}

// ---------------------------------------------------------------------------
extern "C" void kernel_launch(void* const* d_in, const int* in_sizes, int n_in,
                              void* d_out, int out_size, void* d_ws, size_t ws_size,
                              hipStream_t stream) {
    const float* x   = (const float*)d_in[0];
    const float* vf  = (const float*)d_in[1];
    const float* x_r = (const float*)d_in[2];
    const float* x_w = (const float*)d_in[3];
    const float* x_k = (const float*)d_in[4];
    const float* x_v = (const float*)d_in[5];
    const float* x_a = (const float*)d_in[6];
    const float* x_g = (const float*)d_in[7];
    const float* k_k = (const float*)d_in[8];
    const float* k_a = (const float*)d_in[9];
    const float* r_k = (const float*)d_in[10];
    const float* W_r = (const float*)d_in[11];
    const float* W_k = (const float*)d_in[12];
    const float* W_v = (const float*)d_in[13];
    const float* W_o = (const float*)d_in[14];
    const float* wA  = (const float*)d_in[15];
    const float* wB  = (const float*)d_in[16];
    const float* wb  = (const float*)d_in[17];
    const float* aA  = (const float*)d_in[18];
    const float* aB  = (const float*)d_in[19];
    const float* ab  = (const float*)d_in[20];
    const float* vA  = (const float*)d_in[21];
    const float* vB  = (const float*)d_in[22];
    const float* vb  = (const float*)d_in[23];
    const float* gA  = (const float*)d_in[24];
    const float* gB  = (const float*)d_in[25];
    const float* gnw = (const float*)d_in[26];
    const float* gnb = (const float*)d_in[27];
    float* out = (float*)d_out;

    float* ws = (float*)d_ws;
    const size_t SZ = (size_t)BTOT * HID;
    const size_t HH = (size_t)HID * HID;
    float*          WL   = ws;            // log-decay f32 -> Minv region -> G
    unsigned short* P    = (unsigned short*)(ws + SZ);
    unsigned short* R16  = P;             // r -> Rt  -> later Y (bf16)
    unsigned short* K16  = P + 1 * SZ;    // k -> kn -> Kt
    unsigned short* V16  = P + 2 * SZ;    // v
    unsigned short* A16  = P + 3 * SZ;    // a -> b -> Bt
    unsigned short* KK16 = P + 4 * SZ;    // kk -> At
    unsigned short* H1   = P + 5 * SZ;    // lora hidden bf16 [BTOT,<=160]
    unsigned short* WR   = H1 + (size_t)BTOT * 160;
    unsigned short* Wr16 = WR;
    unsigned short* Wk16 = WR + 1 * HH;
    unsigned short* Wv16 = WR + 2 * HH;
    unsigned short* Wo16 = WR + 3 * HH;
    unsigned short* wA16 = WR + 4 * HH;
    unsigned short* wB16 = wA16 + 65536;
    unsigned short* aA16 = wB16 + 65536;
    unsigned short* aB16 = aA16 + 65536;
    unsigned short* vA16 = aB16 + 65536;
    unsigned short* vB16 = vA16 + 65536;
    unsigned short* gA16 = vB16 + 65536;
    unsigned short* gB16 = gA16 + 163840;
    float*          SB   = (float*)(gB16 + 163840);    // [128][2048] f32
    float*          Ed   = SB + (size_t)128 * TSEQ;    // [128][64][64] f32
    // Minv aliased INTO the WL region (WL dead after chunkprep; G written
    // only after recchunk completes). 32 MB needed <= 64 MB available.
    unsigned short* MinvH = (unsigned short*)WL;
    unsigned short* MinvL = MinvH + (size_t)128 * NCH * 1024;
    unsigned short* Y16  = R16;           // reuse
    float*          G    = WL;            // reuse (after recchunk)

    const dim3 blk(256);
    const dim3 gBig(128, 8);
    const dim3 gL64(256, 1);
    const dim3 gL160(256, 3);
    const float* np = nullptr;
    const unsigned short* nu = nullptr;

    auto CAST = [&](const float* s, unsigned short* d, int n) {
        cast_kernel<<<dim3((n / 4 + 255) / 256), blk, 0, stream>>>(s, d, n);
    };
    CAST(W_r, Wr16, (int)HH); CAST(W_k, Wk16, (int)HH);
    CAST(W_v, Wv16, (int)HH); CAST(W_o, Wo16, (int)HH);
    CAST(wA, wA16, 65536); CAST(wB, wB16, 65536);
    CAST(aA, aA16, 65536); CAST(aB, aB16, 65536);
    CAST(vA, vA16, 65536); CAST(vB, vB16, 65536);
    CAST(gA, gA16, 163840); CAST(gB, gB16, 163840);

    // r, k, v0 projections (mix fused into A staging)
    mgemm<128,128,0,true,true><<<gBig, blk, 0, stream>>>(
        x, x_r, Wr16, R16, HID, HID, np, nu, np);
    mgemm<128,128,0,true,true><<<gBig, blk, 0, stream>>>(
        x, x_k, Wk16, K16, HID, HID, np, nu, np);
    mgemm<128,128,0,true,true><<<gBig, blk, 0, stream>>>(
        x, x_v, Wv16, V16, HID, HID, np, nu, np);
    // v = v0 + (v_first - v0) * sigmoid(lora_v(xv) + vb)
    mgemm<64,64,0,true,true><<<gL64, blk, 0, stream>>>(
        x, x_v, vA16, H1, 64, HID, np, nu, np);
    mgemm<128,128,5,false,true><<<gBig, blk, 0, stream>>>(
        H1, np, vB16, V16, HID, 64, vb, V16, vf);
    // w (LOG decay, f32) = W_SCALE * sigmoid(tanh(xw@wA^T)@wB^T + wb)
    mgemm<64,64,1,true,true><<<gL64, blk, 0, stream>>>(
        x, x_w, wA16, H1, 64, HID, np, nu, np);
    mgemm<128,128,6,false,false><<<gBig, blk, 0, stream>>>(
        H1, np, wB16, WL, HID, 64, wb, nu, np);
    // a = sigmoid(xa@aA^T@aB^T + ab)
    mgemm<64,64,0,true,true><<<gL64, blk, 0, stream>>>(
        x, x_a, aA16, H1, 64, HID, np, nu, np);
    mgemm<128,128,4,false,true><<<gBig, blk, 0, stream>>>(
        H1, np, aB16, A16, HID, 64, ab, nu, np);
    // prep then chunkprep (consumes WL) then minv (writes into WL region)
    prep_kernel<<<dim3(BTOT), blk, 0, stream>>>(
        K16, A16, R16, k_k, k_a, r_k, KK16, SB);
    chunkprep_kernel<<<dim3(128 * NCH), dim3(64), 0, stream>>>(
        KK16, A16, K16, R16, WL, Ed);
    minv_kernel<<<dim3(128 * NCH), dim3(64), 0, stream>>>(
        KK16, A16, MinvH, MinvL);
    // chunked recurrence -> o (d_out f32); 512 blocks = 2/CU
    recchunk_kernel<<<dim3(512), blk, 0, stream>>>(
        KK16, A16, K16, R16, V16, Ed, MinvH, MinvL, out);
    // g = sigmoid(xg@gA^T) @ gB^T  (fp32, overwrites WL/Minv region)
    mgemm<64,64,2,true,true><<<gL160, blk, 0, stream>>>(
        x, x_g, gA16, H1, 160, HID, np, nu, np);
    mgemm<128,128,0,false,false><<<gBig, blk, 0, stream>>>(
        H1, np, gB16, G, HID, 160, np, nu, np);
    // y = (GN(o) + s3*v) * g -> bf16 Y
    post_kernel<<<dim3(BTOT), blk, 0, stream>>>(
        out, V16, G, SB, gnw, gnb, Y16);
    // out = y @ W_o^T
    mgemm<128,128,0,false,false><<<gBig, blk, 0, stream>>>(
        Y16, np, Wo16, out, HID, HID, np, nu, np);
    (void)in_sizes; (void)n_in; (void)out_size; (void)ws_size;
}

// Round 12
// 1139.897 us; speedup vs baseline: 3.2638x; 1.0635x over previous
//
#include <hip/hip_runtime.h>
#include <hip/hip_bf16.h>

// ---------------------------------------------------------------------------
// RWKV7 attention block — Round 12.
// - proj3: fused r/k/v projection GEMM (x staged once, 3 mixes, 3 B tensors).
// - cprep: fused prep+chunkprep+minv (one wave per (bh,chunk); decay stored
//   bf16 in W16 so Minv fits in the same 64MB region).
// - recchunk (v-quarter, 512 blocks) unchanged from R11.
// B=8, T=2048, H=1024, NH=16, DK=DV=64. ws ~242 MB.
// ---------------------------------------------------------------------------

#define DEVI __device__ __forceinline__

constexpr int TSEQ = 2048;
constexpr int HID  = 1024;
constexpr int BTOT = 16384;   // B*T
constexpr int CCH  = 32;      // chunk length
constexpr int NCH  = TSEQ / CCH;
constexpr float W_SCALE = -0.6065306597126334f;
constexpr float GN_EPS  = 6.4e-4f;   // 64 * 1e-5

using s16x8  = __attribute__((ext_vector_type(8))) short;   // 8 bf16 (4 VGPR)
using f32x4v = __attribute__((ext_vector_type(4))) float;   // MFMA acc

DEVI float4 ld4(const float* p) { return *reinterpret_cast<const float4*>(p); }
DEVI void   st4(float* p, float4 v) { *reinterpret_cast<float4*>(p) = v; }
DEVI float  sigf(float x) { return 1.0f / (1.0f + __expf(-x)); }
// bf16 <-> f32 (RNE)
DEVI unsigned short bfr(float f) {
    unsigned int u = __float_as_uint(f);
    return (unsigned short)((u + 0x7fffu + ((u >> 16) & 1u)) >> 16);
}
DEVI float bff(unsigned short s) { return __uint_as_float(((unsigned int)s) << 16); }
DEVI unsigned int pk2(float lo, float hi) {
    return ((unsigned int)bfr(hi) << 16) | (unsigned int)bfr(lo);
}
DEVI f32x4v MF(s16x8 a, s16x8 b, f32x4v c) {
    return __builtin_amdgcn_mfma_f32_16x16x32_bf16(a, b, c, 0, 0, 0);
}
// async global->LDS
DEVI void gl16(const void* g, void* l) {
    __builtin_amdgcn_global_load_lds(
        (const __attribute__((address_space(1))) unsigned int*)g,
        (__attribute__((address_space(3))) unsigned int*)l, 16, 0, 0);
}
DEVI void gl4(const void* g, void* l) {
    __builtin_amdgcn_global_load_lds(
        (const __attribute__((address_space(1))) unsigned int*)g,
        (__attribute__((address_space(3))) unsigned int*)l, 4, 0, 0);
}

// ---------------------------------------------------------------------------
// f32 -> bf16 cast (weights)
// ---------------------------------------------------------------------------
__global__ __launch_bounds__(256) void cast_kernel(
        const float* __restrict__ s, unsigned short* __restrict__ d, int n) {
    int i = (blockIdx.x * 256 + threadIdx.x) * 4;
    if (i >= n) return;
    float4 v = ld4(s + i);
    ushort4 o; o.x = bfr(v.x); o.y = bfr(v.y); o.z = bfr(v.z); o.w = bfr(v.w);
    *reinterpret_cast<ushort4*>(d + i) = o;
}

// ---------------------------------------------------------------------------
// proj3: fused r/k/v projections. C_p[M,1024] = mix_p(x) @ W_p^T, p=0..2.
// BM=64, BN=128, BK=32; 4 waves 2x2 (WTM=32, WTN=64). x staged once per
// K-step; 3 mixed bf16 A-variants in LDS; B via global_load_lds.
// grid (BTOT/64, HID/128) -> XCD co-location on bm.
// ---------------------------------------------------------------------------
__global__ __launch_bounds__(256) void proj3_kernel(
        const float* __restrict__ x,
        const float* __restrict__ cr, const float* __restrict__ ck,
        const float* __restrict__ cv,
        const unsigned short* __restrict__ Wr, const unsigned short* __restrict__ Wk,
        const unsigned short* __restrict__ Wv,
        unsigned short* __restrict__ Ro, unsigned short* __restrict__ Ko,
        unsigned short* __restrict__ Vo) {
    __shared__ __align__(16) unsigned short As[3][64 * 32];
    __shared__ __align__(16) unsigned short Bs[3][128 * 32];
    const int tid = threadIdx.x;
    const int w = tid >> 6, l = tid & 63;
    const int bm = blockIdx.x * 64, bn = blockIdx.y * 128;
    const int wm = w >> 1, wn = w & 1;
    const int lr = l & 15, lq = l >> 4, lk = lq * 8;

    f32x4v acc[3][2][4];
#pragma unroll
    for (int p = 0; p < 3; p++)
#pragma unroll
        for (int i = 0; i < 2; i++)
#pragma unroll
            for (int j = 0; j < 4; j++)
#pragma unroll
                for (int q = 0; q < 4; q++) acc[p][i][j][q] = 0.f;

    const float* cvs[3] = {cr, ck, cv};
    const unsigned short* Ws[3] = {Wr, Wk, Wv};

    for (int k0 = 0; k0 < HID; k0 += 32) {
        // ---- A: one x read, 3 mixed bf16 variants ----
        {
            const int row = tid >> 2, kp = (tid & 3) * 8;
            const int gr = bm + row;
            const float* xp = x + (size_t)gr * HID + k0 + kp;
            float4 x0 = ld4(xp), x1 = ld4(xp + 4);
            float4 p0 = make_float4(0.f, 0.f, 0.f, 0.f), p1 = p0;
            if ((gr & (TSEQ - 1)) != 0) { p0 = ld4(xp - HID); p1 = ld4(xp - HID + 4); }
            float xb[8] = {x0.x, x0.y, x0.z, x0.w, x1.x, x1.y, x1.z, x1.w};
            float dx[8] = {p0.x - x0.x, p0.y - x0.y, p0.z - x0.z, p0.w - x0.w,
                           p1.x - x1.x, p1.y - x1.y, p1.z - x1.z, p1.w - x1.w};
#pragma unroll
            for (int p = 0; p < 3; p++) {
                float4 c0 = ld4(cvs[p] + k0 + kp), c1 = ld4(cvs[p] + k0 + kp + 4);
                float cc[8] = {c0.x, c0.y, c0.z, c0.w, c1.x, c1.y, c1.z, c1.w};
                uint4 u;
                u.x = pk2(fmaf(dx[0], cc[0], xb[0]), fmaf(dx[1], cc[1], xb[1]));
                u.y = pk2(fmaf(dx[2], cc[2], xb[2]), fmaf(dx[3], cc[3], xb[3]));
                u.z = pk2(fmaf(dx[4], cc[4], xb[4]), fmaf(dx[5], cc[5], xb[5]));
                u.w = pk2(fmaf(dx[6], cc[6], xb[6]), fmaf(dx[7], cc[7], xb[7]));
                *reinterpret_cast<uint4*>(&As[p][row * 32 + kp]) = u;
            }
        }
        // ---- B: 3 weight tiles via global_load_lds ----
#pragma unroll
        for (int p = 0; p < 3; p++)
#pragma unroll
            for (int c = 0; c < 2; c++) {
                int idx = c * 256 + tid;
                int rw = idx >> 2, kp2 = (idx & 3) * 8;
                gl16(Ws[p] + (size_t)(bn + rw) * HID + k0 + kp2,
                     &Bs[p][c * 2048 + w * 512]);
            }
        __syncthreads();
#pragma unroll
        for (int p = 0; p < 3; p++) {
            s16x8 af[2], bf4[4];
#pragma unroll
            for (int i = 0; i < 2; i++)
                af[i] = *reinterpret_cast<const s16x8*>(
                    &As[p][(wm * 32 + i * 16 + lr) * 32 + lk]);
#pragma unroll
            for (int j = 0; j < 4; j++)
                bf4[j] = *reinterpret_cast<const s16x8*>(
                    &Bs[p][(wn * 64 + j * 16 + lr) * 32 + lk]);
#pragma unroll
            for (int i = 0; i < 2; i++)
#pragma unroll
                for (int j = 0; j < 4; j++)
                    acc[p][i][j] = MF(af[i], bf4[j], acc[p][i][j]);
        }
        __syncthreads();
    }

    unsigned short* dsts[3] = {Ro, Ko, Vo};
#pragma unroll
    for (int p = 0; p < 3; p++)
#pragma unroll
        for (int i = 0; i < 2; i++)
#pragma unroll
            for (int j = 0; j < 4; j++)
#pragma unroll
                for (int q = 0; q < 4; q++) {
                    const int grow = bm + wm * 32 + i * 16 + lq * 4 + q;
                    const int gcol = bn + wn * 64 + j * 16 + lr;
                    dsts[p][(size_t)grow * HID + gcol] = bfr(acc[p][i][j][q]);
                }
}

// ---------------------------------------------------------------------------
// MFMA bf16 GEMM (R11). MODE 6: log-decay (now OUTBF -> bf16 W16).
// ---------------------------------------------------------------------------
template<int BM, int BN, int MODE, bool MIXA, bool OUTBF>
__global__ __launch_bounds__(256) void mgemm(
        const void* __restrict__ Ap, const float* __restrict__ cvec,
        const unsigned short* __restrict__ Bw, void* Cout,
        int N, int K,
        const float* __restrict__ bias,
        const unsigned short* aux1, const float* __restrict__ aux2) {
    constexpr int BK = 32;
    constexpr int WM_ = (BN == 128) ? 2 : (BM == 128 ? 4 : 2);
    constexpr int WN_ = (BN == 128) ? 2 : (BM == 128 ? 1 : 2);
    constexpr int WTM = BM / WM_, WTN = BN / WN_;
    constexpr int MF_ = WTM / 16, NF = WTN / 16;
    constexpr int ACALLS = (BM * BK) / 2048;
    constexpr int BCALLS = (BN * BK) / 2048;
    __shared__ __align__(16) unsigned short As[BM * BK];
    __shared__ __align__(16) unsigned short Bs[BN * BK];
    const int tid = threadIdx.x;
    const int w = tid >> 6, l = tid & 63;
    const int bm = blockIdx.x * BM, bn = blockIdx.y * BN;
    const int wm = w / WN_, wn = w % WN_;
    const int lr = l & 15, lk = (l >> 4) * 8;

    f32x4v acc[MF_][NF];
#pragma unroll
    for (int i = 0; i < MF_; i++)
#pragma unroll
        for (int j = 0; j < NF; j++)
#pragma unroll
            for (int q = 0; q < 4; q++) acc[i][j][q] = 0.f;

    for (int k0 = 0; k0 < K; k0 += BK) {
        if (MIXA) {
            const float* Axf = (const float*)Ap;
#pragma unroll
            for (int c = 0; c < ACALLS; c++) {
                int idx = c * 256 + tid;
                int row = idx >> 2, kp = (idx & 3) * 8;
                int gr = bm + row;
                const float* xp = Axf + (size_t)gr * K + k0 + kp;
                float4 x0 = ld4(xp), x1 = ld4(xp + 4);
                float4 p0 = make_float4(0.f,0.f,0.f,0.f), p1 = p0;
                if ((gr & (TSEQ - 1)) != 0) { p0 = ld4(xp - HID); p1 = ld4(xp - HID + 4); }
                float4 c0 = ld4(cvec + k0 + kp), c1 = ld4(cvec + k0 + kp + 4);
                uint4 u;
                u.x = pk2(fmaf(p0.x - x0.x, c0.x, x0.x), fmaf(p0.y - x0.y, c0.y, x0.y));
                u.y = pk2(fmaf(p0.z - x0.z, c0.z, x0.z), fmaf(p0.w - x0.w, c0.w, x0.w));
                u.z = pk2(fmaf(p1.x - x1.x, c1.x, x1.x), fmaf(p1.y - x1.y, c1.y, x1.y));
                u.w = pk2(fmaf(p1.z - x1.z, c1.z, x1.z), fmaf(p1.w - x1.w, c1.w, x1.w));
                *reinterpret_cast<uint4*>(&As[idx * 8]) = u;
            }
        } else {
            const unsigned short* Ab = (const unsigned short*)Ap;
#pragma unroll
            for (int c = 0; c < ACALLS; c++) {
                int idx = c * 256 + tid;
                int row = idx >> 2, kp = (idx & 3) * 8;
                gl16(Ab + (size_t)(bm + row) * K + k0 + kp, &As[c * 2048 + w * 512]);
            }
        }
#pragma unroll
        for (int c = 0; c < BCALLS; c++) {
            int idx = c * 256 + tid;
            int row = idx >> 2, kp = (idx & 3) * 8;
            int gc = bn + row; if (gc > N - 1) gc = N - 1;
            gl16(Bw + (size_t)gc * K + k0 + kp, &Bs[c * 2048 + w * 512]);
        }
        __syncthreads();
        s16x8 afx[MF_], bfx[NF];
#pragma unroll
        for (int i = 0; i < MF_; i++)
            afx[i] = *reinterpret_cast<const s16x8*>(&As[(wm * WTM + i * 16 + lr) * BK + lk]);
#pragma unroll
        for (int j = 0; j < NF; j++)
            bfx[j] = *reinterpret_cast<const s16x8*>(&Bs[(wn * WTN + j * 16 + lr) * BK + lk]);
#pragma unroll
        for (int i = 0; i < MF_; i++)
#pragma unroll
            for (int j = 0; j < NF; j++)
                acc[i][j] = __builtin_amdgcn_mfma_f32_16x16x32_bf16(
                    afx[i], bfx[j], acc[i][j], 0, 0, 0);
        __syncthreads();
    }

#pragma unroll
    for (int i = 0; i < MF_; i++) {
        const int grow0 = bm + wm * WTM + i * 16 + (l >> 4) * 4;
#pragma unroll
        for (int j = 0; j < NF; j++) {
            const int gcol = bn + wn * WTN + j * 16 + lr;
            if (gcol >= N) continue;
            const float bsv = (MODE >= 3) ? bias[gcol] : 0.f;
#pragma unroll
            for (int q = 0; q < 4; q++) {
                const int grow = grow0 + q;
                float d = acc[i][j][q];
                if (MODE == 1) d = tanhf(d);
                else if (MODE == 2) d = sigf(d);
                else if (MODE == 3) d = __expf(W_SCALE * sigf(d + bsv));
                else if (MODE == 4) d = sigf(d + bsv);
                else if (MODE == 5) {
                    float v0 = bff(aux1[(size_t)grow * N + gcol]);
                    d = fmaf(aux2[(size_t)grow * N + gcol] - v0, sigf(d + bsv), v0);
                }
                else if (MODE == 6) d = W_SCALE * sigf(d + bsv);
                if (OUTBF) ((unsigned short*)Cout)[(size_t)grow * N + gcol] = bfr(d);
                else       ((float*)Cout)[(size_t)grow * N + gcol] = d;
            }
        }
    }
}

// ---------------------------------------------------------------------------
// cprep: fused prep + chunkprep + minv. 1 wave per (bh, chunk), grid 8192.
// Per row (serial, 32): kk-norm (64-lane reduce), b, kn, s3 (reduce),
// prefix log-decay scaling -> At/Bt/Kt/Rt in place (+ LDS copies of At/Bt),
// Ed. Then Mab = strict_lower(At@Bt^T) via MFMA + identity-column fsub
// -> Minv hi/lo bf16 (stored in second half of the decay region).
// ---------------------------------------------------------------------------
__global__ __launch_bounds__(64) void cprep_kernel(
        unsigned short* __restrict__ K16, unsigned short* __restrict__ A16,
        unsigned short* __restrict__ R16, unsigned short* __restrict__ KK16,
        const unsigned short* __restrict__ W16,
        const float* __restrict__ kkc, const float* __restrict__ kac,
        const float* __restrict__ rkw,
        float* __restrict__ SB, float* __restrict__ Ed,
        unsigned short* __restrict__ MvH, unsigned short* __restrict__ MvL) {
    __shared__ __align__(16) unsigned short sA[32][64], sB[32][64];
    __shared__ __align__(16) float Mab[32][36];
    const int bid = blockIdx.x;
    const int bh = bid >> 6, ch = bid & 63;
    const int bb = bh >> 4, hh = bh & 15;
    const int l = threadIdx.x;
    const int chn = hh * 64 + l;
    const float kkcv = kkc[chn], kacv = kac[chn], rkv = rkw[chn];
    size_t off = ((size_t)(bb * TSEQ) + ch * CCH) * HID + chn;
    float cw = 0.f, er = 1.f;
    for (int i = 0; i < CCH; i++, off += HID) {
        const float k = bff(K16[off]);
        const float a = bff(A16[off]);
        const float r = bff(R16[off]);
        const float wv = bff(W16[off]);
        const float kr = k * kkcv;
        float ss = kr * kr;
        ss += __shfl_xor(ss, 1);  ss += __shfl_xor(ss, 2);
        ss += __shfl_xor(ss, 4);  ss += __shfl_xor(ss, 8);
        ss += __shfl_xor(ss, 16); ss += __shfl_xor(ss, 32);
        const float inv = 1.0f / fmaxf(sqrtf(ss), 1e-12f);
        const float kk = kr * inv;
        const float b  = kk * a;
        const float kn = k * fmaf(a - 1.0f, kacv, 1.0f);
        float s3 = r * kn * rkv;
        s3 += __shfl_xor(s3, 1);  s3 += __shfl_xor(s3, 2);
        s3 += __shfl_xor(s3, 4);  s3 += __shfl_xor(s3, 8);
        s3 += __shfl_xor(s3, 16); s3 += __shfl_xor(s3, 32);
        if (l == 0) SB[(size_t)bh * TSEQ + ch * CCH + i] = s3;
        const float cwp = cw; cw += wv;
        const float ea = __expf(cwp), ei = __expf(-cw);
        er = __expf(cw);
        const unsigned short At = bfr(-kk * ea);
        const unsigned short Bt = bfr(b * ei);
        KK16[off] = At;
        A16[off]  = Bt;
        K16[off]  = bfr(kn * ei);
        R16[off]  = bfr(r * er);
        sA[i][l] = At; sB[i][l] = Bt;
    }
    Ed[((size_t)bh * NCH + ch) * 64 + l] = er;
    __syncthreads();
    // ---- Mab via MFMA, strict-lower mask ----
    const int lr = l & 15, lq = l >> 4;
    f32x4v z4; z4[0] = z4[1] = z4[2] = z4[3] = 0.f;
#pragma unroll
    for (int mi = 0; mi < 2; mi++)
#pragma unroll
        for (int ni = 0; ni < 2; ni++) {
            s16x8 a0 = *reinterpret_cast<const s16x8*>(&sA[mi * 16 + lr][lq * 8]);
            s16x8 a1 = *reinterpret_cast<const s16x8*>(&sA[mi * 16 + lr][32 + lq * 8]);
            s16x8 b0 = *reinterpret_cast<const s16x8*>(&sB[ni * 16 + lr][lq * 8]);
            s16x8 b1 = *reinterpret_cast<const s16x8*>(&sB[ni * 16 + lr][32 + lq * 8]);
            f32x4v m = MF(a1, b1, MF(a0, b0, z4));
#pragma unroll
            for (int q = 0; q < 4; q++) {
                int r = mi * 16 + lq * 4 + q, cc2 = ni * 16 + lr;
                Mab[r][cc2] = (cc2 < r) ? m[q] : 0.f;
            }
        }
    __syncthreads();
    // ---- identity-column forward substitution -> Minv hi/lo ----
    const int j = l & 31;
    float m[32];
#pragma unroll
    for (int i = 0; i < 32; i++) m[i] = (i == j) ? 1.f : 0.f;
#pragma unroll
    for (int i = 1; i < 32; i++) {
        float p0 = 0.f, p1 = 0.f, p2 = 0.f, p3 = 0.f;
#pragma unroll
        for (int k4_ = 0; k4_ < 32; k4_ += 4) {
            if (k4_ >= i) break;
            float4 L4 = *reinterpret_cast<const float4*>(&Mab[i][k4_]);
            p0 = fmaf(L4.x, m[k4_ + 0], p0);
            if (k4_ + 1 < i) p1 = fmaf(L4.y, m[k4_ + 1], p1);
            if (k4_ + 2 < i) p2 = fmaf(L4.z, m[k4_ + 2], p2);
            if (k4_ + 3 < i) p3 = fmaf(L4.w, m[k4_ + 3], p3);
        }
        m[i] += (p0 + p1) + (p2 + p3);
    }
    if (l < 32) {
        unsigned short* dH = MvH + (size_t)(bh * NCH + ch) * 1024;
        unsigned short* dL = MvL + (size_t)(bh * NCH + ch) * 1024;
#pragma unroll
        for (int i = 0; i < 32; i++) {
            unsigned short h = bfr(m[i]);
            dH[i * 32 + j] = h;
            dL[i * 32 + j] = bfr(m[i] - bff(h));
        }
    }
}

// ---------------------------------------------------------------------------
// Chunked recurrence, v-QUARTER blocks (unchanged from R11).
// ---------------------------------------------------------------------------
__global__ __launch_bounds__(256) void recchunk_kernel(
        const unsigned short* __restrict__ AtG, const unsigned short* __restrict__ BtG,
        const unsigned short* __restrict__ KtG, const unsigned short* __restrict__ RtG,
        const unsigned short* __restrict__ V16, const float* __restrict__ Ed,
        const unsigned short* __restrict__ MvH, const unsigned short* __restrict__ MvL,
        float* __restrict__ Ob) {
    __shared__ __align__(16) unsigned short stT[2][4][CCH][64];
    __shared__ __align__(16) unsigned short stMh[2][32][32], stMl[2][32][32];
    __shared__ __align__(16) unsigned short stV[2][CCH][16];
    __shared__ __align__(16) float stEd[2][64];
    __shared__ __align__(16) unsigned short Shi[16][74], Slo[16][74];
    __shared__ __align__(16) unsigned short BtT[64][42], KtT[64][42];
    __shared__ __align__(16) unsigned short VT[16][42];
    __shared__ __align__(16) unsigned short MakH[32][42], MakL[32][42];
    __shared__ __align__(16) unsigned short MrkH[32][42], MrkL[32][42];
    __shared__ __align__(16) unsigned short MrbH[32][42], MrbL[32][42];
    __shared__ __align__(16) unsigned short rhTH[16][42], rhTL[16][42];

    const int bid = blockIdx.x;
    const int vq = bid >> 7, bh = bid & 127;
    const int tid = threadIdx.x;
    const int w = tid >> 6, l = tid & 63;
    const int lr = l & 15, lq = l >> 4;
    const int bb = bh >> 4, hh = bh & 15;
    const size_t rowoff = ((size_t)bb * TSEQ) * HID + hh * 64;
    const int mi = w >> 1, ni = w & 1;

    const int r8 = l >> 3, ck = l & 7;
    const int swz8 = (ck ^ r8) * 8;

    auto STAGE = [&](int buf, int cn) {
        if (cn >= NCH) return;
        const size_t cb = rowoff + (size_t)(cn * CCH) * HID;
        const unsigned short* srcs[4] = {AtG, BtG, KtG, RtG};
        const unsigned short* T = srcs[w];
#pragma unroll
        for (int c = 0; c < 4; c++)
            gl16(T + cb + (size_t)(c * 8 + r8) * HID + swz8, &stT[buf][w][c * 8][0]);
        if (w == 0) {
            gl16(V16 + cb + (size_t)(l >> 1) * HID + vq * 16 + (l & 1) * 8,
                 &stV[buf][0][0]);
            gl4(Ed + ((size_t)bh * NCH + cn) * 64 + l, &stEd[buf][0]);
        } else if (w == 1) {
#pragma unroll
            for (int c = 0; c < 2; c++)
                gl16(MvH + (size_t)(bh * NCH + cn) * 1024 + c * 512 + l * 8,
                     (char*)&stMh[buf][0][0] + c * 1024);
        } else if (w == 2) {
#pragma unroll
            for (int c = 0; c < 2; c++)
                gl16(MvL + (size_t)(bh * NCH + cn) * 1024 + c * 512 + l * 8,
                     (char*)&stMl[buf][0][0] + c * 1024);
        }
    };

    for (int idx = tid; idx < 16 * 74; idx += 256) {
        ((unsigned short*)Shi)[idx] = 0;
        ((unsigned short*)Slo)[idx] = 0;
    }
    STAGE(0, 0);
    asm volatile("s_waitcnt vmcnt(0)" ::: "memory");
    __syncthreads();

    auto fragT = [&](int bf, int tn, int rbase, int kb) -> s16x8 {
        int row = rbase + lr;
        int chv = ((kb >> 3) + lq) ^ (row & 7);
        return *reinterpret_cast<const s16x8*>(
            (const char*)&stT[bf][tn][0][0] + row * 128 + chv * 16);
    };
    auto fragS = [&](const unsigned short (*Sx)[74], int kb) -> s16x8 {
        return *reinterpret_cast<const s16x8*>(&Sx[lr][kb + lq * 8]);
    };
    auto frag42 = [&](const unsigned short (*T)[42], int rbase) -> s16x8 {
        return *reinterpret_cast<const s16x8*>(&T[rbase + lr][lq * 8]);
    };

    f32x4v Sacc;
#pragma unroll
    for (int q = 0; q < 4; q++) Sacc[q] = 0.f;
    f32x4v z4; z4[0] = z4[1] = z4[2] = z4[3] = 0.f;

    int buf = 0;
    for (int c = 0; c < NCH; c++) {
        STAGE(buf ^ 1, c + 1);
        {
            const int tt = tid & 31, g8 = tid >> 5;
            const int ch = g8 ^ (tt & 7);
            uint4 bu = *reinterpret_cast<const uint4*>(&stT[buf][1][tt][ch * 8]);
            uint4 ku = *reinterpret_cast<const uint4*>(&stT[buf][2][tt][ch * 8]);
            unsigned int bw[4] = {bu.x, bu.y, bu.z, bu.w};
            unsigned int kw[4] = {ku.x, ku.y, ku.z, ku.w};
#pragma unroll
            for (int e = 0; e < 4; e++) {
                BtT[g8 * 8 + 2 * e][tt]     = (unsigned short)(bw[e] & 0xffffu);
                BtT[g8 * 8 + 2 * e + 1][tt] = (unsigned short)(bw[e] >> 16);
                KtT[g8 * 8 + 2 * e][tt]     = (unsigned short)(kw[e] & 0xffffu);
                KtT[g8 * 8 + 2 * e + 1][tt] = (unsigned short)(kw[e] >> 16);
            }
            if (g8 < 4) {
                ushort4 vu = *reinterpret_cast<const ushort4*>(&stV[buf][tt][g8 * 4]);
                VT[g8 * 4 + 0][tt] = vu.x; VT[g8 * 4 + 1][tt] = vu.y;
                VT[g8 * 4 + 2][tt] = vu.z; VT[g8 * 4 + 3][tt] = vu.w;
            }
        }
        s16x8 atm0 = fragT(buf, 0, mi * 16, 0), atm1 = fragT(buf, 0, mi * 16, 32);
        s16x8 rt0  = fragT(buf, 3, mi * 16, 0), rt1  = fragT(buf, 3, mi * 16, 32);
        s16x8 bt0  = fragT(buf, 1, ni * 16, 0), bt1  = fragT(buf, 1, ni * 16, 32);
        s16x8 kt0  = fragT(buf, 2, ni * 16, 0), kt1  = fragT(buf, 2, ni * 16, 32);
        f32x4v mak = MF(atm1, kt1, MF(atm0, kt0, z4));
        f32x4v mrk = MF(rt1, kt1, MF(rt0, kt0, z4));
        f32x4v mrb = MF(rt1, bt1, MF(rt0, bt0, z4));
        f32x4v oac = z4, rhT = z4;
        {
            s16x8 sh0 = fragS(Shi, 0), sh1 = fragS(Shi, 32);
            s16x8 sl0 = fragS(Slo, 0), sl1 = fragS(Slo, 32);
            if (ni == 0) {
                oac = MF(rt1, sl1, MF(rt0, sl0, MF(rt1, sh1, MF(rt0, sh0, z4))));
            } else {
                rhT = MF(sl1, atm1, MF(sl0, atm0, MF(sh1, atm1, MF(sh0, atm0, z4))));
            }
        }
#pragma unroll
        for (int q = 0; q < 4; q++) {
            const int r = mi * 16 + lq * 4 + q, cc = ni * 16 + lr;
            float vv = (cc < r) ? mak[q] : 0.f;
            unsigned short h = bfr(vv);
            MakH[r][cc] = h; MakL[r][cc] = bfr(vv - bff(h));
            vv = (cc <= r) ? mrk[q] : 0.f; h = bfr(vv);
            MrkH[r][cc] = h; MrkL[r][cc] = bfr(vv - bff(h));
            vv = (cc <= r) ? mrb[q] : 0.f; h = bfr(vv);
            MrbH[r][cc] = h; MrbL[r][cc] = bfr(vv - bff(h));
        }
        __syncthreads();
        {
            s16x8 vt0 = frag42(VT, 0);
            if (ni == 0) {
                oac = MF(frag42(MrkL, mi * 16), vt0,
                         MF(frag42(MrkH, mi * 16), vt0, oac));
            } else {
                rhT = MF(vt0, frag42(MakL, mi * 16),
                         MF(vt0, frag42(MakH, mi * 16), rhT));
#pragma unroll
                for (int q = 0; q < 4; q++) {
                    const int r = lq * 4 + q, cc = mi * 16 + lr;
                    unsigned short h = bfr(rhT[q]);
                    rhTH[r][cc] = h; rhTL[r][cc] = bfr(rhT[q] - bff(h));
                }
            }
        }
        __syncthreads();
        if (ni == 1) {
            s16x8 rh0 = frag42(rhTH, 0), rl0 = frag42(rhTL, 0);
            s16x8 mvh = *reinterpret_cast<const s16x8*>(&stMh[buf][mi * 16 + lr][lq * 8]);
            s16x8 mvl = *reinterpret_cast<const s16x8*>(&stMl[buf][mi * 16 + lr][lq * 8]);
            f32x4v sat = MF(rl0, mvh, MF(rh0, mvl, MF(rh0, mvh, z4)));
#pragma unroll
            for (int q = 0; q < 4; q++) {
                const int r = lq * 4 + q, cc = mi * 16 + lr;
                unsigned short h = bfr(sat[q]);
                MakH[r][cc] = h;
                MakL[r][cc] = bfr(sat[q] - bff(h));
            }
        }
        __syncthreads();
        {
            s16x8 sath = frag42(MakH, 0), satl = frag42(MakL, 0);
            if (ni == 0) {
                s16x8 rbh = frag42(MrbH, mi * 16), rbl = frag42(MrbL, mi * 16);
                oac = MF(rbl, sath, MF(rbh, satl, MF(rbh, sath, oac)));
#pragma unroll
                for (int q = 0; q < 4; q++) {
                    const int t = c * CCH + mi * 16 + lq * 4 + q;
                    Ob[rowoff + (size_t)t * HID + vq * 16 + lr] = oac[q];
                }
            }
            s16x8 btf = frag42(BtT, w * 16);
            s16x8 ktf = frag42(KtT, w * 16);
            s16x8 vta = frag42(VT, 0);
            const float ed = stEd[buf][w * 16 + lr];
            Sacc = MF(sath, btf, Sacc);
            Sacc = MF(satl, btf, Sacc);
            Sacc = MF(vta, ktf, Sacc);
#pragma unroll
            for (int q = 0; q < 4; q++) {
                Sacc[q] *= ed;
                unsigned short h = bfr(Sacc[q]);
                Shi[lq * 4 + q][w * 16 + lr] = h;
                Slo[lq * 4 + q][w * 16 + lr] = bfr(Sacc[q] - bff(h));
            }
        }
        asm volatile("s_waitcnt vmcnt(0)" ::: "memory");
        __syncthreads();
        buf ^= 1;
    }
}

// ---------------------------------------------------------------------------
// post (unchanged): y = (GN_perhead(o)*gn_w + gn_b + s3*v) * g -> bf16 Y
// ---------------------------------------------------------------------------
__global__ __launch_bounds__(256) void post_kernel(
        const float* __restrict__ Ob, const unsigned short* __restrict__ V16,
        const float* __restrict__ G, const float* __restrict__ SB,
        const float* __restrict__ gnw, const float* __restrict__ gnb,
        unsigned short* __restrict__ Y16) {
    const int row = blockIdx.x;
    const int tid = threadIdx.x;
    const int c   = tid * 4;
    const size_t off = (size_t)row * HID + c;
    float4 o4 = ld4(Ob + off), g4 = ld4(G + off);
    ushort4 vu = *reinterpret_cast<const ushort4*>(V16 + off);
    float v[4]  = {bff(vu.x), bff(vu.y), bff(vu.z), bff(vu.w)};
    const int hh = tid >> 4;
    const int bb = row >> 11, t = row & (TSEQ - 1);
    const float s3 = SB[((size_t)(bb * 16 + hh)) * TSEQ + t];

    float s1 = o4.x + o4.y + o4.z + o4.w;
    float s2 = o4.x*o4.x + o4.y*o4.y + o4.z*o4.z + o4.w*o4.w;
#pragma unroll
    for (int m = 1; m < 16; m <<= 1) {
        s1 += __shfl_xor(s1, m); s2 += __shfl_xor(s2, m);
    }
    const float mu  = s1 * (1.0f / 64.0f);
    const float var = s2 * (1.0f / 64.0f) - mu * mu;
    const float inv = rsqrtf(var + GN_EPS);
    float4 gw = ld4(gnw + c), gb = ld4(gnb + c);
    ushort4 y;
    y.x = bfr((fmaf((o4.x - mu) * inv, gw.x, gb.x) + s3 * v[0]) * g4.x);
    y.y = bfr((fmaf((o4.y - mu) * inv, gw.y, gb.y) + s3 * v[1]) * g4.y);
    y.z = bfr((fmaf((o4.z - mu) * inv, gw.z, gb.z) + s3 * v[2]) * g4.z);
    y.w = bfr((fmaf((o4.w - mu) * inv, gw.w, gb.w) + s3 * v[3]) * g4.w);
    *reinterpret_cast<ushort4*>(Y16 + off) = y;
}

// ---------------------------------------------------------------------------
extern "C" void kernel_launch(void* const* d_in, const int* in_sizes, int n_in,
                              void* d_out, int out_size, void* d_ws, size_t ws_size,
                              hipStream_t stream) {
    const float* x   = (const float*)d_in[0];
    const float* vf  = (const float*)d_in[1];
    const float* x_r = (const float*)d_in[2];
    const float* x_w = (const float*)d_in[3];
    const float* x_k = (const float*)d_in[4];
    const float* x_v = (const float*)d_in[5];
    const float* x_a = (const float*)d_in[6];
    const float* x_g = (const float*)d_in[7];
    const float* k_k = (const float*)d_in[8];
    const float* k_a = (const float*)d_in[9];
    const float* r_k = (const float*)d_in[10];
    const float* W_r = (const float*)d_in[11];
    const float* W_k = (const float*)d_in[12];
    const float* W_v = (const float*)d_in[13];
    const float* W_o = (const float*)d_in[14];
    const float* wA  = (const float*)d_in[15];
    const float* wB  = (const float*)d_in[16];
    const float* wb  = (const float*)d_in[17];
    const float* aA  = (const float*)d_in[18];
    const float* aB  = (const float*)d_in[19];
    const float* ab  = (const float*)d_in[20];
    const float* vA  = (const float*)d_in[21];
    const float* vB  = (const float*)d_in[22];
    const float* vb  = (const float*)d_in[23];
    const float* gA  = (const float*)d_in[24];
    const float* gB  = (const float*)d_in[25];
    const float* gnw = (const float*)d_in[26];
    const float* gnb = (const float*)d_in[27];
    float* out = (float*)d_out;

    float* ws = (float*)d_ws;
    const size_t SZ = (size_t)BTOT * HID;
    const size_t HH = (size_t)HID * HID;
    float*          REG  = ws;            // 64MB region: W16 | MinvH | MinvL -> G
    unsigned short* P    = (unsigned short*)(ws + SZ);
    unsigned short* R16  = P;             // r -> Rt  -> later Y (bf16)
    unsigned short* K16  = P + 1 * SZ;    // k -> Kt
    unsigned short* V16  = P + 2 * SZ;    // v
    unsigned short* A16  = P + 3 * SZ;    // a -> Bt
    unsigned short* KK16 = P + 4 * SZ;    // At
    unsigned short* H1   = P + 5 * SZ;    // lora hidden bf16 [BTOT,<=160]
    unsigned short* WR   = H1 + (size_t)BTOT * 160;
    unsigned short* Wr16 = WR;
    unsigned short* Wk16 = WR + 1 * HH;
    unsigned short* Wv16 = WR + 2 * HH;
    unsigned short* Wo16 = WR + 3 * HH;
    unsigned short* wA16 = WR + 4 * HH;
    unsigned short* wB16 = wA16 + 65536;
    unsigned short* aA16 = wB16 + 65536;
    unsigned short* aB16 = aA16 + 65536;
    unsigned short* vA16 = aB16 + 65536;
    unsigned short* vB16 = vA16 + 65536;
    unsigned short* gA16 = vB16 + 65536;
    unsigned short* gB16 = gA16 + 163840;
    float*          SB   = (float*)(gB16 + 163840);    // [128][2048] f32
    float*          Ed   = SB + (size_t)128 * TSEQ;    // [128][64][64] f32
    // 64MB region timeline: W16 bf16 (first 32MB, born w-stage2) +
    // Minv hi/lo (last 32MB, born cprep) -> dead after recchunk -> G f32.
    unsigned short* W16   = (unsigned short*)REG;
    unsigned short* MinvH = (unsigned short*)(REG + 8 * 1024 * 1024);
    unsigned short* MinvL = MinvH + (size_t)128 * NCH * 1024;
    unsigned short* Y16  = R16;           // reuse
    float*          G    = REG;           // reuse (after recchunk)

    const dim3 blk(256);
    const dim3 gBig(128, 8);
    const dim3 gP3(BTOT / 64, 8);
    const dim3 gL64(256, 1);
    const dim3 gL160(256, 3);
    const float* np = nullptr;
    const unsigned short* nu = nullptr;

    auto CAST = [&](const float* s, unsigned short* d, int n) {
        cast_kernel<<<dim3((n / 4 + 255) / 256), blk, 0, stream>>>(s, d, n);
    };
    CAST(W_r, Wr16, (int)HH); CAST(W_k, Wk16, (int)HH);
    CAST(W_v, Wv16, (int)HH); CAST(W_o, Wo16, (int)HH);
    CAST(wA, wA16, 65536); CAST(wB, wB16, 65536);
    CAST(aA, aA16, 65536); CAST(aB, aB16, 65536);
    CAST(vA, vA16, 65536); CAST(vB, vB16, 65536);
    CAST(gA, gA16, 163840); CAST(gB, gB16, 163840);

    // fused r, k, v0 projections (x staged once, 3 mixes)
    proj3_kernel<<<gP3, blk, 0, stream>>>(
        x, x_r, x_k, x_v, Wr16, Wk16, Wv16, R16, K16, V16);
    // v = v0 + (v_first - v0) * sigmoid(lora_v(xv) + vb)
    mgemm<64,64,0,true,true><<<gL64, blk, 0, stream>>>(
        x, x_v, vA16, H1, 64, HID, np, nu, np);
    mgemm<128,128,5,false,true><<<gBig, blk, 0, stream>>>(
        H1, np, vB16, V16, HID, 64, vb, V16, vf);
    // w (LOG decay, bf16 W16) = W_SCALE * sigmoid(tanh(xw@wA^T)@wB^T + wb)
    mgemm<64,64,1,true,true><<<gL64, blk, 0, stream>>>(
        x, x_w, wA16, H1, 64, HID, np, nu, np);
    mgemm<128,128,6,false,true><<<gBig, blk, 0, stream>>>(
        H1, np, wB16, W16, HID, 64, wb, nu, np);
    // a = sigmoid(xa@aA^T@aB^T + ab)
    mgemm<64,64,0,true,true><<<gL64, blk, 0, stream>>>(
        x, x_a, aA16, H1, 64, HID, np, nu, np);
    mgemm<128,128,4,false,true><<<gBig, blk, 0, stream>>>(
        H1, np, aB16, A16, HID, 64, ab, nu, np);
    // fused prep + chunkprep + minv
    cprep_kernel<<<dim3(128 * NCH), dim3(64), 0, stream>>>(
        K16, A16, R16, KK16, W16, k_k, k_a, r_k, SB, Ed, MinvH, MinvL);
    // chunked recurrence -> o (d_out f32); 512 blocks = 2/CU
    recchunk_kernel<<<dim3(512), blk, 0, stream>>>(
        KK16, A16, K16, R16, V16, Ed, MinvH, MinvL, out);
    // g = sigmoid(xg@gA^T) @ gB^T  (fp32, overwrites the 64MB region)
    mgemm<64,64,2,true,true><<<gL160, blk, 0, stream>>>(
        x, x_g, gA16, H1, 160, HID, np, nu, np);
    mgemm<128,128,0,false,false><<<gBig, blk, 0, stream>>>(
        H1, np, gB16, G, HID, 160, np, nu, np);
    // y = (GN(o) + s3*v) * g -> bf16 Y
    post_kernel<<<dim3(BTOT), blk, 0, stream>>>(
        out, V16, G, SB, gnw, gnb, Y16);
    // out = y @ W_o^T
    mgemm<128,128,0,false,false><<<gBig, blk, 0, stream>>>(
        Y16, np, Wo16, out, HID, HID, np, nu, np);
    (void)in_sizes; (void)n_in; (void)out_size; (void)ws_size;
}

// Round 13
// 1051.438 us; speedup vs baseline: 3.5384x; 1.0841x over previous
//
#include <hip/hip_runtime.h>
#include <hip/hip_bf16.h>

// ---------------------------------------------------------------------------
// RWKV7 attention block — Round 13.
// - proj3: fused r/k/v projections (R12).
// - lora4: fused v/w/a/g lora stage-1 (x read once, 4 mixes, combined
//   weights LW[352][1024], combined hidden H1[BTOT][352]).
// - mgemm gains lda (stage-2 reads H1 column groups).
// - g stored bf16 (G16).  cprep/recchunk unchanged from R12.
// B=8, T=2048, H=1024, NH=16, DK=DV=64. ws ~248.5 MB.
// ---------------------------------------------------------------------------

#define DEVI __device__ __forceinline__

constexpr int TSEQ = 2048;
constexpr int HID  = 1024;
constexpr int BTOT = 16384;   // B*T
constexpr int CCH  = 32;      // chunk length
constexpr int NCH  = TSEQ / CCH;
constexpr int L4N  = 352;     // combined lora hidden width (64+64+64+160)
constexpr float W_SCALE = -0.6065306597126334f;
constexpr float GN_EPS  = 6.4e-4f;   // 64 * 1e-5

using s16x8  = __attribute__((ext_vector_type(8))) short;   // 8 bf16 (4 VGPR)
using f32x4v = __attribute__((ext_vector_type(4))) float;   // MFMA acc

DEVI float4 ld4(const float* p) { return *reinterpret_cast<const float4*>(p); }
DEVI void   st4(float* p, float4 v) { *reinterpret_cast<float4*>(p) = v; }
DEVI float  sigf(float x) { return 1.0f / (1.0f + __expf(-x)); }
// bf16 <-> f32 (RNE)
DEVI unsigned short bfr(float f) {
    unsigned int u = __float_as_uint(f);
    return (unsigned short)((u + 0x7fffu + ((u >> 16) & 1u)) >> 16);
}
DEVI float bff(unsigned short s) { return __uint_as_float(((unsigned int)s) << 16); }
DEVI unsigned int pk2(float lo, float hi) {
    return ((unsigned int)bfr(hi) << 16) | (unsigned int)bfr(lo);
}
DEVI f32x4v MF(s16x8 a, s16x8 b, f32x4v c) {
    return __builtin_amdgcn_mfma_f32_16x16x32_bf16(a, b, c, 0, 0, 0);
}
// async global->LDS
DEVI void gl16(const void* g, void* l) {
    __builtin_amdgcn_global_load_lds(
        (const __attribute__((address_space(1))) unsigned int*)g,
        (__attribute__((address_space(3))) unsigned int*)l, 16, 0, 0);
}
DEVI void gl4(const void* g, void* l) {
    __builtin_amdgcn_global_load_lds(
        (const __attribute__((address_space(1))) unsigned int*)g,
        (__attribute__((address_space(3))) unsigned int*)l, 4, 0, 0);
}

// ---------------------------------------------------------------------------
// f32 -> bf16 cast (weights)
// ---------------------------------------------------------------------------
__global__ __launch_bounds__(256) void cast_kernel(
        const float* __restrict__ s, unsigned short* __restrict__ d, int n) {
    int i = (blockIdx.x * 256 + threadIdx.x) * 4;
    if (i >= n) return;
    float4 v = ld4(s + i);
    ushort4 o; o.x = bfr(v.x); o.y = bfr(v.y); o.z = bfr(v.z); o.w = bfr(v.w);
    *reinterpret_cast<ushort4*>(d + i) = o;
}

// ---------------------------------------------------------------------------
// proj3: fused r/k/v projections (unchanged from R12).
// ---------------------------------------------------------------------------
__global__ __launch_bounds__(256) void proj3_kernel(
        const float* __restrict__ x,
        const float* __restrict__ cr, const float* __restrict__ ck,
        const float* __restrict__ cv,
        const unsigned short* __restrict__ Wr, const unsigned short* __restrict__ Wk,
        const unsigned short* __restrict__ Wv,
        unsigned short* __restrict__ Ro, unsigned short* __restrict__ Ko,
        unsigned short* __restrict__ Vo) {
    __shared__ __align__(16) unsigned short As[3][64 * 32];
    __shared__ __align__(16) unsigned short Bs[3][128 * 32];
    const int tid = threadIdx.x;
    const int w = tid >> 6, l = tid & 63;
    const int bm = blockIdx.x * 64, bn = blockIdx.y * 128;
    const int wm = w >> 1, wn = w & 1;
    const int lr = l & 15, lq = l >> 4, lk = lq * 8;

    f32x4v acc[3][2][4];
#pragma unroll
    for (int p = 0; p < 3; p++)
#pragma unroll
        for (int i = 0; i < 2; i++)
#pragma unroll
            for (int j = 0; j < 4; j++)
#pragma unroll
                for (int q = 0; q < 4; q++) acc[p][i][j][q] = 0.f;

    const float* cvs[3] = {cr, ck, cv};
    const unsigned short* Ws[3] = {Wr, Wk, Wv};

    for (int k0 = 0; k0 < HID; k0 += 32) {
        {
            const int row = tid >> 2, kp = (tid & 3) * 8;
            const int gr = bm + row;
            const float* xp = x + (size_t)gr * HID + k0 + kp;
            float4 x0 = ld4(xp), x1 = ld4(xp + 4);
            float4 p0 = make_float4(0.f, 0.f, 0.f, 0.f), p1 = p0;
            if ((gr & (TSEQ - 1)) != 0) { p0 = ld4(xp - HID); p1 = ld4(xp - HID + 4); }
            float xb[8] = {x0.x, x0.y, x0.z, x0.w, x1.x, x1.y, x1.z, x1.w};
            float dx[8] = {p0.x - x0.x, p0.y - x0.y, p0.z - x0.z, p0.w - x0.w,
                           p1.x - x1.x, p1.y - x1.y, p1.z - x1.z, p1.w - x1.w};
#pragma unroll
            for (int p = 0; p < 3; p++) {
                float4 c0 = ld4(cvs[p] + k0 + kp), c1 = ld4(cvs[p] + k0 + kp + 4);
                float cc[8] = {c0.x, c0.y, c0.z, c0.w, c1.x, c1.y, c1.z, c1.w};
                uint4 u;
                u.x = pk2(fmaf(dx[0], cc[0], xb[0]), fmaf(dx[1], cc[1], xb[1]));
                u.y = pk2(fmaf(dx[2], cc[2], xb[2]), fmaf(dx[3], cc[3], xb[3]));
                u.z = pk2(fmaf(dx[4], cc[4], xb[4]), fmaf(dx[5], cc[5], xb[5]));
                u.w = pk2(fmaf(dx[6], cc[6], xb[6]), fmaf(dx[7], cc[7], xb[7]));
                *reinterpret_cast<uint4*>(&As[p][row * 32 + kp]) = u;
            }
        }
#pragma unroll
        for (int p = 0; p < 3; p++)
#pragma unroll
            for (int c = 0; c < 2; c++) {
                int idx = c * 256 + tid;
                int rw = idx >> 2, kp2 = (idx & 3) * 8;
                gl16(Ws[p] + (size_t)(bn + rw) * HID + k0 + kp2,
                     &Bs[p][c * 2048 + w * 512]);
            }
        __syncthreads();
#pragma unroll
        for (int p = 0; p < 3; p++) {
            s16x8 af[2], bf4[4];
#pragma unroll
            for (int i = 0; i < 2; i++)
                af[i] = *reinterpret_cast<const s16x8*>(
                    &As[p][(wm * 32 + i * 16 + lr) * 32 + lk]);
#pragma unroll
            for (int j = 0; j < 4; j++)
                bf4[j] = *reinterpret_cast<const s16x8*>(
                    &Bs[p][(wn * 64 + j * 16 + lr) * 32 + lk]);
#pragma unroll
            for (int i = 0; i < 2; i++)
#pragma unroll
                for (int j = 0; j < 4; j++)
                    acc[p][i][j] = MF(af[i], bf4[j], acc[p][i][j]);
        }
        __syncthreads();
    }

    unsigned short* dsts[3] = {Ro, Ko, Vo};
#pragma unroll
    for (int p = 0; p < 3; p++)
#pragma unroll
        for (int i = 0; i < 2; i++)
#pragma unroll
            for (int j = 0; j < 4; j++)
#pragma unroll
                for (int q = 0; q < 4; q++) {
                    const int grow = bm + wm * 32 + i * 16 + lq * 4 + q;
                    const int gcol = bn + wn * 64 + j * 16 + lr;
                    dsts[p][(size_t)grow * HID + gcol] = bfr(acc[p][i][j][q]);
                }
}

// ---------------------------------------------------------------------------
// lora4: fused v/w/a/g lora stage-1.
// H1[M][352] = act_g( mix_g(x) @ LW_g^T ), groups: cols 0-63 v (none),
// 64-127 w (tanh), 128-191 a (none), 192-351 g (sigmoid).
// Block = 64 rows, full N=352; wave w owns rows w*16..w*16+15; grid 256.
// ---------------------------------------------------------------------------
__global__ __launch_bounds__(256) void lora4_kernel(
        const float* __restrict__ x,
        const float* __restrict__ cv_, const float* __restrict__ cw_,
        const float* __restrict__ ca_, const float* __restrict__ cg_,
        const unsigned short* __restrict__ LW, unsigned short* __restrict__ H1) {
    __shared__ __align__(16) unsigned short As[4][64 * 32];
    __shared__ __align__(16) unsigned short Bs[L4N * 32];
    const int tid = threadIdx.x;
    const int w = tid >> 6, l = tid & 63;
    const int lr = l & 15, lq = l >> 4, lk = lq * 8;
    const int bm = blockIdx.x * 64;
    const float* cvs[4] = {cv_, cw_, ca_, cg_};

    f32x4v acc[22];
#pragma unroll
    for (int j = 0; j < 22; j++)
#pragma unroll
        for (int q = 0; q < 4; q++) acc[j][q] = 0.f;

    for (int k0 = 0; k0 < HID; k0 += 32) {
        // A: one x read, 4 mixed bf16 variants
        {
            const int row = tid >> 2, kp = (tid & 3) * 8;
            const int gr = bm + row;
            const float* xp = x + (size_t)gr * HID + k0 + kp;
            float4 x0 = ld4(xp), x1 = ld4(xp + 4);
            float4 p0 = make_float4(0.f, 0.f, 0.f, 0.f), p1 = p0;
            if ((gr & (TSEQ - 1)) != 0) { p0 = ld4(xp - HID); p1 = ld4(xp - HID + 4); }
            float xb[8] = {x0.x, x0.y, x0.z, x0.w, x1.x, x1.y, x1.z, x1.w};
            float dx[8] = {p0.x - x0.x, p0.y - x0.y, p0.z - x0.z, p0.w - x0.w,
                           p1.x - x1.x, p1.y - x1.y, p1.z - x1.z, p1.w - x1.w};
#pragma unroll
            for (int p = 0; p < 4; p++) {
                float4 c0 = ld4(cvs[p] + k0 + kp), c1 = ld4(cvs[p] + k0 + kp + 4);
                float cc[8] = {c0.x, c0.y, c0.z, c0.w, c1.x, c1.y, c1.z, c1.w};
                uint4 u;
                u.x = pk2(fmaf(dx[0], cc[0], xb[0]), fmaf(dx[1], cc[1], xb[1]));
                u.y = pk2(fmaf(dx[2], cc[2], xb[2]), fmaf(dx[3], cc[3], xb[3]));
                u.z = pk2(fmaf(dx[4], cc[4], xb[4]), fmaf(dx[5], cc[5], xb[5]));
                u.w = pk2(fmaf(dx[6], cc[6], xb[6]), fmaf(dx[7], cc[7], xb[7]));
                *reinterpret_cast<uint4*>(&As[p][row * 32 + kp]) = u;
            }
        }
        // B: 352x32 tile from LW (1408 16B transfers)
#pragma unroll
        for (int c = 0; c < 6; c++) {
            int idx = c * 256 + tid;
            if (idx < L4N * 4) {
                gl16(LW + (size_t)(idx >> 2) * HID + (idx & 3) * 8 + k0,
                     (char*)&Bs[0] + (c * 256 + w * 64) * 16);
            }
        }
        __syncthreads();
        s16x8 af[4];
#pragma unroll
        for (int p = 0; p < 4; p++)
            af[p] = *reinterpret_cast<const s16x8*>(&As[p][(w * 16 + lr) * 32 + lk]);
#pragma unroll
        for (int j = 0; j < 22; j++) {
            const int grp = (j < 4) ? 0 : (j < 8) ? 1 : (j < 12) ? 2 : 3;
            s16x8 bf = *reinterpret_cast<const s16x8*>(&Bs[(j * 16 + lr) * 32 + lk]);
            acc[j] = MF(af[grp], bf, acc[j]);
        }
        __syncthreads();
    }

#pragma unroll
    for (int j = 0; j < 22; j++)
#pragma unroll
        for (int q = 0; q < 4; q++) {
            const int grow = bm + w * 16 + lq * 4 + q;
            const int gcol = j * 16 + lr;
            float d = acc[j][q];
            if (j >= 4 && j < 8) d = tanhf(d);
            else if (j >= 12) d = sigf(d);
            H1[(size_t)grow * L4N + gcol] = bfr(d);
        }
}

// ---------------------------------------------------------------------------
// MFMA bf16 GEMM with lda. MODE: 0 none | 4 sig(d+b) | 5 vmix | 6 logdecay.
// (modes 1/2/3 retired — handled in lora4 now.)
// ---------------------------------------------------------------------------
template<int BM, int BN, int MODE, bool OUTBF>
__global__ __launch_bounds__(256) void mgemm(
        const unsigned short* __restrict__ Ab, const unsigned short* __restrict__ Bw,
        void* Cout, int N, int K, int lda,
        const float* __restrict__ bias,
        const unsigned short* aux1, const float* __restrict__ aux2) {
    constexpr int BK = 32;
    constexpr int WM_ = (BN == 128) ? 2 : 4;
    constexpr int WN_ = (BN == 128) ? 2 : 1;
    constexpr int WTM = BM / WM_, WTN = BN / WN_;
    constexpr int MF_ = WTM / 16, NF = WTN / 16;
    constexpr int ACALLS = (BM * BK) / 2048;
    constexpr int BCALLS = (BN * BK) / 2048;
    __shared__ __align__(16) unsigned short As[BM * BK];
    __shared__ __align__(16) unsigned short Bs[BN * BK];
    const int tid = threadIdx.x;
    const int w = tid >> 6, l = tid & 63;
    const int bm = blockIdx.x * BM, bn = blockIdx.y * BN;
    const int wm = w / WN_, wn = w % WN_;
    const int lr = l & 15, lk = (l >> 4) * 8;

    f32x4v acc[MF_][NF];
#pragma unroll
    for (int i = 0; i < MF_; i++)
#pragma unroll
        for (int j = 0; j < NF; j++)
#pragma unroll
            for (int q = 0; q < 4; q++) acc[i][j][q] = 0.f;

    for (int k0 = 0; k0 < K; k0 += BK) {
#pragma unroll
        for (int c = 0; c < ACALLS; c++) {
            int idx = c * 256 + tid;
            int row = idx >> 2, kp = (idx & 3) * 8;
            gl16(Ab + (size_t)(bm + row) * lda + k0 + kp, &As[c * 2048 + w * 512]);
        }
#pragma unroll
        for (int c = 0; c < BCALLS; c++) {
            int idx = c * 256 + tid;
            int row = idx >> 2, kp = (idx & 3) * 8;
            int gc = bn + row; if (gc > N - 1) gc = N - 1;
            gl16(Bw + (size_t)gc * K + k0 + kp, &Bs[c * 2048 + w * 512]);
        }
        __syncthreads();
        s16x8 afx[MF_], bfx[NF];
#pragma unroll
        for (int i = 0; i < MF_; i++)
            afx[i] = *reinterpret_cast<const s16x8*>(&As[(wm * WTM + i * 16 + lr) * BK + lk]);
#pragma unroll
        for (int j = 0; j < NF; j++)
            bfx[j] = *reinterpret_cast<const s16x8*>(&Bs[(wn * WTN + j * 16 + lr) * BK + lk]);
#pragma unroll
        for (int i = 0; i < MF_; i++)
#pragma unroll
            for (int j = 0; j < NF; j++)
                acc[i][j] = __builtin_amdgcn_mfma_f32_16x16x32_bf16(
                    afx[i], bfx[j], acc[i][j], 0, 0, 0);
        __syncthreads();
    }

#pragma unroll
    for (int i = 0; i < MF_; i++) {
        const int grow0 = bm + wm * WTM + i * 16 + (l >> 4) * 4;
#pragma unroll
        for (int j = 0; j < NF; j++) {
            const int gcol = bn + wn * WTN + j * 16 + lr;
            if (gcol >= N) continue;
            const float bsv = (MODE >= 4) ? bias[gcol] : 0.f;
#pragma unroll
            for (int q = 0; q < 4; q++) {
                const int grow = grow0 + q;
                float d = acc[i][j][q];
                if (MODE == 4) d = sigf(d + bsv);
                else if (MODE == 5) {
                    float v0 = bff(aux1[(size_t)grow * N + gcol]);
                    d = fmaf(aux2[(size_t)grow * N + gcol] - v0, sigf(d + bsv), v0);
                }
                else if (MODE == 6) d = W_SCALE * sigf(d + bsv);
                if (OUTBF) ((unsigned short*)Cout)[(size_t)grow * N + gcol] = bfr(d);
                else       ((float*)Cout)[(size_t)grow * N + gcol] = d;
            }
        }
    }
}

// ---------------------------------------------------------------------------
// cprep (unchanged R12): fused prep + chunkprep + minv.
// ---------------------------------------------------------------------------
__global__ __launch_bounds__(64) void cprep_kernel(
        unsigned short* __restrict__ K16, unsigned short* __restrict__ A16,
        unsigned short* __restrict__ R16, unsigned short* __restrict__ KK16,
        const unsigned short* __restrict__ W16,
        const float* __restrict__ kkc, const float* __restrict__ kac,
        const float* __restrict__ rkw,
        float* __restrict__ SB, float* __restrict__ Ed,
        unsigned short* __restrict__ MvH, unsigned short* __restrict__ MvL) {
    __shared__ __align__(16) unsigned short sA[32][64], sB[32][64];
    __shared__ __align__(16) float Mab[32][36];
    const int bid = blockIdx.x;
    const int bh = bid >> 6, ch = bid & 63;
    const int bb = bh >> 4, hh = bh & 15;
    const int l = threadIdx.x;
    const int chn = hh * 64 + l;
    const float kkcv = kkc[chn], kacv = kac[chn], rkv = rkw[chn];
    size_t off = ((size_t)(bb * TSEQ) + ch * CCH) * HID + chn;
    float cw = 0.f, er = 1.f;
    for (int i = 0; i < CCH; i++, off += HID) {
        const float k = bff(K16[off]);
        const float a = bff(A16[off]);
        const float r = bff(R16[off]);
        const float wv = bff(W16[off]);
        const float kr = k * kkcv;
        float ss = kr * kr;
        ss += __shfl_xor(ss, 1);  ss += __shfl_xor(ss, 2);
        ss += __shfl_xor(ss, 4);  ss += __shfl_xor(ss, 8);
        ss += __shfl_xor(ss, 16); ss += __shfl_xor(ss, 32);
        const float inv = 1.0f / fmaxf(sqrtf(ss), 1e-12f);
        const float kk = kr * inv;
        const float b  = kk * a;
        const float kn = k * fmaf(a - 1.0f, kacv, 1.0f);
        float s3 = r * kn * rkv;
        s3 += __shfl_xor(s3, 1);  s3 += __shfl_xor(s3, 2);
        s3 += __shfl_xor(s3, 4);  s3 += __shfl_xor(s3, 8);
        s3 += __shfl_xor(s3, 16); s3 += __shfl_xor(s3, 32);
        if (l == 0) SB[(size_t)bh * TSEQ + ch * CCH + i] = s3;
        const float cwp = cw; cw += wv;
        const float ea = __expf(cwp), ei = __expf(-cw);
        er = __expf(cw);
        const unsigned short At = bfr(-kk * ea);
        const unsigned short Bt = bfr(b * ei);
        KK16[off] = At;
        A16[off]  = Bt;
        K16[off]  = bfr(kn * ei);
        R16[off]  = bfr(r * er);
        sA[i][l] = At; sB[i][l] = Bt;
    }
    Ed[((size_t)bh * NCH + ch) * 64 + l] = er;
    __syncthreads();
    const int lr = l & 15, lq = l >> 4;
    f32x4v z4; z4[0] = z4[1] = z4[2] = z4[3] = 0.f;
#pragma unroll
    for (int mi = 0; mi < 2; mi++)
#pragma unroll
        for (int ni = 0; ni < 2; ni++) {
            s16x8 a0 = *reinterpret_cast<const s16x8*>(&sA[mi * 16 + lr][lq * 8]);
            s16x8 a1 = *reinterpret_cast<const s16x8*>(&sA[mi * 16 + lr][32 + lq * 8]);
            s16x8 b0 = *reinterpret_cast<const s16x8*>(&sB[ni * 16 + lr][lq * 8]);
            s16x8 b1 = *reinterpret_cast<const s16x8*>(&sB[ni * 16 + lr][32 + lq * 8]);
            f32x4v m = MF(a1, b1, MF(a0, b0, z4));
#pragma unroll
            for (int q = 0; q < 4; q++) {
                int r = mi * 16 + lq * 4 + q, cc2 = ni * 16 + lr;
                Mab[r][cc2] = (cc2 < r) ? m[q] : 0.f;
            }
        }
    __syncthreads();
    const int j = l & 31;
    float m[32];
#pragma unroll
    for (int i = 0; i < 32; i++) m[i] = (i == j) ? 1.f : 0.f;
#pragma unroll
    for (int i = 1; i < 32; i++) {
        float p0 = 0.f, p1 = 0.f, p2 = 0.f, p3 = 0.f;
#pragma unroll
        for (int k4_ = 0; k4_ < 32; k4_ += 4) {
            if (k4_ >= i) break;
            float4 L4 = *reinterpret_cast<const float4*>(&Mab[i][k4_]);
            p0 = fmaf(L4.x, m[k4_ + 0], p0);
            if (k4_ + 1 < i) p1 = fmaf(L4.y, m[k4_ + 1], p1);
            if (k4_ + 2 < i) p2 = fmaf(L4.z, m[k4_ + 2], p2);
            if (k4_ + 3 < i) p3 = fmaf(L4.w, m[k4_ + 3], p3);
        }
        m[i] += (p0 + p1) + (p2 + p3);
    }
    if (l < 32) {
        unsigned short* dH = MvH + (size_t)(bh * NCH + ch) * 1024;
        unsigned short* dL = MvL + (size_t)(bh * NCH + ch) * 1024;
#pragma unroll
        for (int i = 0; i < 32; i++) {
            unsigned short h = bfr(m[i]);
            dH[i * 32 + j] = h;
            dL[i * 32 + j] = bfr(m[i] - bff(h));
        }
    }
}

// ---------------------------------------------------------------------------
// Chunked recurrence, v-QUARTER blocks (unchanged from R12).
// ---------------------------------------------------------------------------
__global__ __launch_bounds__(256) void recchunk_kernel(
        const unsigned short* __restrict__ AtG, const unsigned short* __restrict__ BtG,
        const unsigned short* __restrict__ KtG, const unsigned short* __restrict__ RtG,
        const unsigned short* __restrict__ V16, const float* __restrict__ Ed,
        const unsigned short* __restrict__ MvH, const unsigned short* __restrict__ MvL,
        float* __restrict__ Ob) {
    __shared__ __align__(16) unsigned short stT[2][4][CCH][64];
    __shared__ __align__(16) unsigned short stMh[2][32][32], stMl[2][32][32];
    __shared__ __align__(16) unsigned short stV[2][CCH][16];
    __shared__ __align__(16) float stEd[2][64];
    __shared__ __align__(16) unsigned short Shi[16][74], Slo[16][74];
    __shared__ __align__(16) unsigned short BtT[64][42], KtT[64][42];
    __shared__ __align__(16) unsigned short VT[16][42];
    __shared__ __align__(16) unsigned short MakH[32][42], MakL[32][42];
    __shared__ __align__(16) unsigned short MrkH[32][42], MrkL[32][42];
    __shared__ __align__(16) unsigned short MrbH[32][42], MrbL[32][42];
    __shared__ __align__(16) unsigned short rhTH[16][42], rhTL[16][42];

    const int bid = blockIdx.x;
    const int vq = bid >> 7, bh = bid & 127;
    const int tid = threadIdx.x;
    const int w = tid >> 6, l = tid & 63;
    const int lr = l & 15, lq = l >> 4;
    const int bb = bh >> 4, hh = bh & 15;
    const size_t rowoff = ((size_t)bb * TSEQ) * HID + hh * 64;
    const int mi = w >> 1, ni = w & 1;

    const int r8 = l >> 3, ck = l & 7;
    const int swz8 = (ck ^ r8) * 8;

    auto STAGE = [&](int buf, int cn) {
        if (cn >= NCH) return;
        const size_t cb = rowoff + (size_t)(cn * CCH) * HID;
        const unsigned short* srcs[4] = {AtG, BtG, KtG, RtG};
        const unsigned short* T = srcs[w];
#pragma unroll
        for (int c = 0; c < 4; c++)
            gl16(T + cb + (size_t)(c * 8 + r8) * HID + swz8, &stT[buf][w][c * 8][0]);
        if (w == 0) {
            gl16(V16 + cb + (size_t)(l >> 1) * HID + vq * 16 + (l & 1) * 8,
                 &stV[buf][0][0]);
            gl4(Ed + ((size_t)bh * NCH + cn) * 64 + l, &stEd[buf][0]);
        } else if (w == 1) {
#pragma unroll
            for (int c = 0; c < 2; c++)
                gl16(MvH + (size_t)(bh * NCH + cn) * 1024 + c * 512 + l * 8,
                     (char*)&stMh[buf][0][0] + c * 1024);
        } else if (w == 2) {
#pragma unroll
            for (int c = 0; c < 2; c++)
                gl16(MvL + (size_t)(bh * NCH + cn) * 1024 + c * 512 + l * 8,
                     (char*)&stMl[buf][0][0] + c * 1024);
        }
    };

    for (int idx = tid; idx < 16 * 74; idx += 256) {
        ((unsigned short*)Shi)[idx] = 0;
        ((unsigned short*)Slo)[idx] = 0;
    }
    STAGE(0, 0);
    asm volatile("s_waitcnt vmcnt(0)" ::: "memory");
    __syncthreads();

    auto fragT = [&](int bf, int tn, int rbase, int kb) -> s16x8 {
        int row = rbase + lr;
        int chv = ((kb >> 3) + lq) ^ (row & 7);
        return *reinterpret_cast<const s16x8*>(
            (const char*)&stT[bf][tn][0][0] + row * 128 + chv * 16);
    };
    auto fragS = [&](const unsigned short (*Sx)[74], int kb) -> s16x8 {
        return *reinterpret_cast<const s16x8*>(&Sx[lr][kb + lq * 8]);
    };
    auto frag42 = [&](const unsigned short (*T)[42], int rbase) -> s16x8 {
        return *reinterpret_cast<const s16x8*>(&T[rbase + lr][lq * 8]);
    };

    f32x4v Sacc;
#pragma unroll
    for (int q = 0; q < 4; q++) Sacc[q] = 0.f;
    f32x4v z4; z4[0] = z4[1] = z4[2] = z4[3] = 0.f;

    int buf = 0;
    for (int c = 0; c < NCH; c++) {
        STAGE(buf ^ 1, c + 1);
        {
            const int tt = tid & 31, g8 = tid >> 5;
            const int ch = g8 ^ (tt & 7);
            uint4 bu = *reinterpret_cast<const uint4*>(&stT[buf][1][tt][ch * 8]);
            uint4 ku = *reinterpret_cast<const uint4*>(&stT[buf][2][tt][ch * 8]);
            unsigned int bw[4] = {bu.x, bu.y, bu.z, bu.w};
            unsigned int kw[4] = {ku.x, ku.y, ku.z, ku.w};
#pragma unroll
            for (int e = 0; e < 4; e++) {
                BtT[g8 * 8 + 2 * e][tt]     = (unsigned short)(bw[e] & 0xffffu);
                BtT[g8 * 8 + 2 * e + 1][tt] = (unsigned short)(bw[e] >> 16);
                KtT[g8 * 8 + 2 * e][tt]     = (unsigned short)(kw[e] & 0xffffu);
                KtT[g8 * 8 + 2 * e + 1][tt] = (unsigned short)(kw[e] >> 16);
            }
            if (g8 < 4) {
                ushort4 vu = *reinterpret_cast<const ushort4*>(&stV[buf][tt][g8 * 4]);
                VT[g8 * 4 + 0][tt] = vu.x; VT[g8 * 4 + 1][tt] = vu.y;
                VT[g8 * 4 + 2][tt] = vu.z; VT[g8 * 4 + 3][tt] = vu.w;
            }
        }
        s16x8 atm0 = fragT(buf, 0, mi * 16, 0), atm1 = fragT(buf, 0, mi * 16, 32);
        s16x8 rt0  = fragT(buf, 3, mi * 16, 0), rt1  = fragT(buf, 3, mi * 16, 32);
        s16x8 bt0  = fragT(buf, 1, ni * 16, 0), bt1  = fragT(buf, 1, ni * 16, 32);
        s16x8 kt0  = fragT(buf, 2, ni * 16, 0), kt1  = fragT(buf, 2, ni * 16, 32);
        f32x4v mak = MF(atm1, kt1, MF(atm0, kt0, z4));
        f32x4v mrk = MF(rt1, kt1, MF(rt0, kt0, z4));
        f32x4v mrb = MF(rt1, bt1, MF(rt0, bt0, z4));
        f32x4v oac = z4, rhT = z4;
        {
            s16x8 sh0 = fragS(Shi, 0), sh1 = fragS(Shi, 32);
            s16x8 sl0 = fragS(Slo, 0), sl1 = fragS(Slo, 32);
            if (ni == 0) {
                oac = MF(rt1, sl1, MF(rt0, sl0, MF(rt1, sh1, MF(rt0, sh0, z4))));
            } else {
                rhT = MF(sl1, atm1, MF(sl0, atm0, MF(sh1, atm1, MF(sh0, atm0, z4))));
            }
        }
#pragma unroll
        for (int q = 0; q < 4; q++) {
            const int r = mi * 16 + lq * 4 + q, cc = ni * 16 + lr;
            float vv = (cc < r) ? mak[q] : 0.f;
            unsigned short h = bfr(vv);
            MakH[r][cc] = h; MakL[r][cc] = bfr(vv - bff(h));
            vv = (cc <= r) ? mrk[q] : 0.f; h = bfr(vv);
            MrkH[r][cc] = h; MrkL[r][cc] = bfr(vv - bff(h));
            vv = (cc <= r) ? mrb[q] : 0.f; h = bfr(vv);
            MrbH[r][cc] = h; MrbL[r][cc] = bfr(vv - bff(h));
        }
        __syncthreads();
        {
            s16x8 vt0 = frag42(VT, 0);
            if (ni == 0) {
                oac = MF(frag42(MrkL, mi * 16), vt0,
                         MF(frag42(MrkH, mi * 16), vt0, oac));
            } else {
                rhT = MF(vt0, frag42(MakL, mi * 16),
                         MF(vt0, frag42(MakH, mi * 16), rhT));
#pragma unroll
                for (int q = 0; q < 4; q++) {
                    const int r = lq * 4 + q, cc = mi * 16 + lr;
                    unsigned short h = bfr(rhT[q]);
                    rhTH[r][cc] = h; rhTL[r][cc] = bfr(rhT[q] - bff(h));
                }
            }
        }
        __syncthreads();
        if (ni == 1) {
            s16x8 rh0 = frag42(rhTH, 0), rl0 = frag42(rhTL, 0);
            s16x8 mvh = *reinterpret_cast<const s16x8*>(&stMh[buf][mi * 16 + lr][lq * 8]);
            s16x8 mvl = *reinterpret_cast<const s16x8*>(&stMl[buf][mi * 16 + lr][lq * 8]);
            f32x4v sat = MF(rl0, mvh, MF(rh0, mvl, MF(rh0, mvh, z4)));
#pragma unroll
            for (int q = 0; q < 4; q++) {
                const int r = lq * 4 + q, cc = mi * 16 + lr;
                unsigned short h = bfr(sat[q]);
                MakH[r][cc] = h;
                MakL[r][cc] = bfr(sat[q] - bff(h));
            }
        }
        __syncthreads();
        {
            s16x8 sath = frag42(MakH, 0), satl = frag42(MakL, 0);
            if (ni == 0) {
                s16x8 rbh = frag42(MrbH, mi * 16), rbl = frag42(MrbL, mi * 16);
                oac = MF(rbl, sath, MF(rbh, satl, MF(rbh, sath, oac)));
#pragma unroll
                for (int q = 0; q < 4; q++) {
                    const int t = c * CCH + mi * 16 + lq * 4 + q;
                    Ob[rowoff + (size_t)t * HID + vq * 16 + lr] = oac[q];
                }
            }
            s16x8 btf = frag42(BtT, w * 16);
            s16x8 ktf = frag42(KtT, w * 16);
            s16x8 vta = frag42(VT, 0);
            const float ed = stEd[buf][w * 16 + lr];
            Sacc = MF(sath, btf, Sacc);
            Sacc = MF(satl, btf, Sacc);
            Sacc = MF(vta, ktf, Sacc);
#pragma unroll
            for (int q = 0; q < 4; q++) {
                Sacc[q] *= ed;
                unsigned short h = bfr(Sacc[q]);
                Shi[lq * 4 + q][w * 16 + lr] = h;
                Slo[lq * 4 + q][w * 16 + lr] = bfr(Sacc[q] - bff(h));
            }
        }
        asm volatile("s_waitcnt vmcnt(0)" ::: "memory");
        __syncthreads();
        buf ^= 1;
    }
}

// ---------------------------------------------------------------------------
// post: y = (GN_perhead(o)*gn_w + gn_b + s3*v) * g -> bf16 Y  (g now bf16)
// ---------------------------------------------------------------------------
__global__ __launch_bounds__(256) void post_kernel(
        const float* __restrict__ Ob, const unsigned short* __restrict__ V16,
        const unsigned short* __restrict__ G16, const float* __restrict__ SB,
        const float* __restrict__ gnw, const float* __restrict__ gnb,
        unsigned short* __restrict__ Y16) {
    const int row = blockIdx.x;
    const int tid = threadIdx.x;
    const int c   = tid * 4;
    const size_t off = (size_t)row * HID + c;
    float4 o4 = ld4(Ob + off);
    ushort4 vu = *reinterpret_cast<const ushort4*>(V16 + off);
    ushort4 gu = *reinterpret_cast<const ushort4*>(G16 + off);
    float v[4] = {bff(vu.x), bff(vu.y), bff(vu.z), bff(vu.w)};
    float g[4] = {bff(gu.x), bff(gu.y), bff(gu.z), bff(gu.w)};
    const int hh = tid >> 4;
    const int bb = row >> 11, t = row & (TSEQ - 1);
    const float s3 = SB[((size_t)(bb * 16 + hh)) * TSEQ + t];

    float s1 = o4.x + o4.y + o4.z + o4.w;
    float s2 = o4.x*o4.x + o4.y*o4.y + o4.z*o4.z + o4.w*o4.w;
#pragma unroll
    for (int m = 1; m < 16; m <<= 1) {
        s1 += __shfl_xor(s1, m); s2 += __shfl_xor(s2, m);
    }
    const float mu  = s1 * (1.0f / 64.0f);
    const float var = s2 * (1.0f / 64.0f) - mu * mu;
    const float inv = rsqrtf(var + GN_EPS);
    float4 gw = ld4(gnw + c), gb = ld4(gnb + c);
    ushort4 y;
    y.x = bfr((fmaf((o4.x - mu) * inv, gw.x, gb.x) + s3 * v[0]) * g[0]);
    y.y = bfr((fmaf((o4.y - mu) * inv, gw.y, gb.y) + s3 * v[1]) * g[1]);
    y.z = bfr((fmaf((o4.z - mu) * inv, gw.z, gb.z) + s3 * v[2]) * g[2]);
    y.w = bfr((fmaf((o4.w - mu) * inv, gw.w, gb.w) + s3 * v[3]) * g[3]);
    *reinterpret_cast<ushort4*>(Y16 + off) = y;
}

// ---------------------------------------------------------------------------
extern "C" void kernel_launch(void* const* d_in, const int* in_sizes, int n_in,
                              void* d_out, int out_size, void* d_ws, size_t ws_size,
                              hipStream_t stream) {
    const float* x   = (const float*)d_in[0];
    const float* vf  = (const float*)d_in[1];
    const float* x_r = (const float*)d_in[2];
    const float* x_w = (const float*)d_in[3];
    const float* x_k = (const float*)d_in[4];
    const float* x_v = (const float*)d_in[5];
    const float* x_a = (const float*)d_in[6];
    const float* x_g = (const float*)d_in[7];
    const float* k_k = (const float*)d_in[8];
    const float* k_a = (const float*)d_in[9];
    const float* r_k = (const float*)d_in[10];
    const float* W_r = (const float*)d_in[11];
    const float* W_k = (const float*)d_in[12];
    const float* W_v = (const float*)d_in[13];
    const float* W_o = (const float*)d_in[14];
    const float* wA  = (const float*)d_in[15];
    const float* wB  = (const float*)d_in[16];
    const float* wb  = (const float*)d_in[17];
    const float* aA  = (const float*)d_in[18];
    const float* aB  = (const float*)d_in[19];
    const float* ab  = (const float*)d_in[20];
    const float* vA  = (const float*)d_in[21];
    const float* vB  = (const float*)d_in[22];
    const float* vb  = (const float*)d_in[23];
    const float* gA  = (const float*)d_in[24];
    const float* gB  = (const float*)d_in[25];
    const float* gnw = (const float*)d_in[26];
    const float* gnb = (const float*)d_in[27];
    float* out = (float*)d_out;

    float* ws = (float*)d_ws;
    const size_t SZ = (size_t)BTOT * HID;
    const size_t HH = (size_t)HID * HID;
    float*          REG  = ws;            // 64MB: W16 | MinvH | MinvL -> G16
    unsigned short* P    = (unsigned short*)(ws + SZ);
    unsigned short* R16  = P;             // r -> Rt  -> later Y (bf16)
    unsigned short* K16  = P + 1 * SZ;    // k -> Kt
    unsigned short* V16  = P + 2 * SZ;    // v
    unsigned short* A16  = P + 3 * SZ;    // a -> Bt
    unsigned short* KK16 = P + 4 * SZ;    // At
    unsigned short* H1   = P + 5 * SZ;    // combined lora hidden [BTOT][352]
    unsigned short* WR   = H1 + (size_t)BTOT * L4N;
    unsigned short* Wr16 = WR;
    unsigned short* Wk16 = WR + 1 * HH;
    unsigned short* Wv16 = WR + 2 * HH;
    unsigned short* Wo16 = WR + 3 * HH;
    unsigned short* LW   = WR + 4 * HH;            // [352][1024]
    unsigned short* vB16 = LW + (size_t)L4N * HID;
    unsigned short* wB16 = vB16 + 65536;
    unsigned short* aB16 = wB16 + 65536;
    unsigned short* gB16 = aB16 + 65536;
    float*          SB   = (float*)(gB16 + 163840);    // [128][2048] f32
    float*          Ed   = SB + (size_t)128 * TSEQ;    // [128][64][64] f32
    unsigned short* W16   = (unsigned short*)REG;
    unsigned short* MinvH = (unsigned short*)(REG + 8 * 1024 * 1024);
    unsigned short* MinvL = MinvH + (size_t)128 * NCH * 1024;
    unsigned short* Y16  = R16;           // reuse
    unsigned short* G16  = (unsigned short*)REG;   // reuse (after recchunk)

    const dim3 blk(256);
    const dim3 gBig(128, 8);
    const dim3 gP3(BTOT / 64, 8);
    const unsigned short* nu = nullptr;
    const float* np = nullptr;

    auto CAST = [&](const float* s, unsigned short* d, int n) {
        cast_kernel<<<dim3((n / 4 + 255) / 256), blk, 0, stream>>>(s, d, n);
    };
    CAST(W_r, Wr16, (int)HH); CAST(W_k, Wk16, (int)HH);
    CAST(W_v, Wv16, (int)HH); CAST(W_o, Wo16, (int)HH);
    CAST(vA, LW + 0 * 65536, 65536);
    CAST(wA, LW + 1 * 65536, 65536);
    CAST(aA, LW + 2 * 65536, 65536);
    CAST(gA, LW + 3 * 65536, 163840);
    CAST(vB, vB16, 65536); CAST(wB, wB16, 65536);
    CAST(aB, aB16, 65536); CAST(gB, gB16, 163840);

    // fused r, k, v0 projections
    proj3_kernel<<<gP3, blk, 0, stream>>>(
        x, x_r, x_k, x_v, Wr16, Wk16, Wv16, R16, K16, V16);
    // fused lora stage-1 (v,w,a,g) -> H1[BTOT][352]
    lora4_kernel<<<dim3(BTOT / 64), blk, 0, stream>>>(
        x, x_v, x_w, x_a, x_g, LW, H1);
    // v = v0 + (v_first - v0) * sigmoid(h_v @ vB^T + vb)
    mgemm<128,128,5,true><<<gBig, blk, 0, stream>>>(
        H1 + 0, vB16, V16, HID, 64, L4N, vb, V16, vf);
    // w (log decay, bf16) = W_SCALE * sigmoid(h_w @ wB^T + wb)
    mgemm<128,128,6,true><<<gBig, blk, 0, stream>>>(
        H1 + 64, wB16, W16, HID, 64, L4N, wb, nu, np);
    // a = sigmoid(h_a @ aB^T + ab)
    mgemm<128,128,4,true><<<gBig, blk, 0, stream>>>(
        H1 + 128, aB16, A16, HID, 64, L4N, ab, nu, np);
    // fused prep + chunkprep + minv
    cprep_kernel<<<dim3(128 * NCH), dim3(64), 0, stream>>>(
        K16, A16, R16, KK16, W16, k_k, k_a, r_k, SB, Ed, MinvH, MinvL);
    // chunked recurrence -> o (d_out f32); 512 blocks = 2/CU
    recchunk_kernel<<<dim3(512), blk, 0, stream>>>(
        KK16, A16, K16, R16, V16, Ed, MinvH, MinvL, out);
    // g = h_g @ gB^T  (bf16, overwrites the 64MB region)
    mgemm<128,128,0,true><<<gBig, blk, 0, stream>>>(
        H1 + 192, gB16, G16, HID, 160, L4N, np, nu, np);
    // y = (GN(o) + s3*v) * g -> bf16 Y
    post_kernel<<<dim3(BTOT), blk, 0, stream>>>(
        out, V16, G16, SB, gnw, gnb, Y16);
    // out = y @ W_o^T
    mgemm<128,128,0,false><<<gBig, blk, 0, stream>>>(
        Y16, Wo16, out, HID, HID, HID, np, nu, np);
    (void)in_sizes; (void)n_in; (void)out_size; (void)ws_size;
}

// Round 16
// 1045.305 us; speedup vs baseline: 3.5592x; 1.0059x over previous
//
#include <hip/hip_runtime.h>
#include <hip/hip_bf16.h>

// ---------------------------------------------------------------------------
// RWKV7 attention block — Round 16 (= R15 with cast_all segment-scan fixed:
// prefix-offset table instead of the non-monotone running scan that wrote
// out of bounds for descending segment sizes).
// 9 kernel launches.  B=8, T=2048, H=1024, NH=16. ws ~247.4 MB (R13-proven).
// ---------------------------------------------------------------------------

#define DEVI __device__ __forceinline__

constexpr int TSEQ = 2048;
constexpr int HID  = 1024;
constexpr int BTOT = 16384;   // B*T
constexpr int CCH  = 32;      // chunk length
constexpr int NCH  = TSEQ / CCH;
constexpr int L4N  = 352;     // combined lora hidden width
constexpr float W_SCALE = -0.6065306597126334f;
constexpr float GN_EPS  = 6.4e-4f;   // 64 * 1e-5

using s16x8  = __attribute__((ext_vector_type(8))) short;
using f32x4v = __attribute__((ext_vector_type(4))) float;

DEVI float4 ld4(const float* p) { return *reinterpret_cast<const float4*>(p); }
DEVI void   st4(float* p, float4 v) { *reinterpret_cast<float4*>(p) = v; }
DEVI float  sigf(float x) { return 1.0f / (1.0f + __expf(-x)); }
DEVI unsigned short bfr(float f) {
    unsigned int u = __float_as_uint(f);
    return (unsigned short)((u + 0x7fffu + ((u >> 16) & 1u)) >> 16);
}
DEVI float bff(unsigned short s) { return __uint_as_float(((unsigned int)s) << 16); }
DEVI unsigned int pk2(float lo, float hi) {
    return ((unsigned int)bfr(hi) << 16) | (unsigned int)bfr(lo);
}
DEVI void up8(uint4 u, float* f) {
    f[0]=bff((unsigned short)(u.x & 0xffffu)); f[1]=bff((unsigned short)(u.x >> 16));
    f[2]=bff((unsigned short)(u.y & 0xffffu)); f[3]=bff((unsigned short)(u.y >> 16));
    f[4]=bff((unsigned short)(u.z & 0xffffu)); f[5]=bff((unsigned short)(u.z >> 16));
    f[6]=bff((unsigned short)(u.w & 0xffffu)); f[7]=bff((unsigned short)(u.w >> 16));
}
DEVI f32x4v MF(s16x8 a, s16x8 b, f32x4v c) {
    return __builtin_amdgcn_mfma_f32_16x16x32_bf16(a, b, c, 0, 0, 0);
}
DEVI void gl16(const void* g, void* l) {
    __builtin_amdgcn_global_load_lds(
        (const __attribute__((address_space(1))) unsigned int*)g,
        (__attribute__((address_space(3))) unsigned int*)l, 16, 0, 0);
}
DEVI void gl4(const void* g, void* l) {
    __builtin_amdgcn_global_load_lds(
        (const __attribute__((address_space(1))) unsigned int*)g,
        (__attribute__((address_space(3))) unsigned int*)l, 4, 0, 0);
}

// ---------------------------------------------------------------------------
// cast_all: 12 f32->bf16 segments in one launch, prefix-offset table.
// ---------------------------------------------------------------------------
struct CastArgs {
    const float* src[12];
    unsigned short* dst[12];
    int start4[13];   // prefix offsets (float4 units); start4[12] = total
};
__global__ __launch_bounds__(256) void cast_all_kernel(CastArgs a) {
    int i4 = blockIdx.x * 256 + threadIdx.x;
    if (i4 >= a.start4[12]) return;
    int seg = 0;
#pragma unroll
    for (int s = 1; s < 12; s++) seg += (i4 >= a.start4[s]) ? 1 : 0;
    int off = (i4 - a.start4[seg]) * 4;
    float4 v = ld4(a.src[seg] + off);
    ushort4 o; o.x = bfr(v.x); o.y = bfr(v.y); o.z = bfr(v.z); o.w = bfr(v.w);
    *reinterpret_cast<ushort4*>(a.dst[seg] + off) = o;
}

// ---------------------------------------------------------------------------
// proj3 (unchanged): fused r/k/v projections.
// ---------------------------------------------------------------------------
__global__ __launch_bounds__(256) void proj3_kernel(
        const float* __restrict__ x,
        const float* __restrict__ cr, const float* __restrict__ ck,
        const float* __restrict__ cv,
        const unsigned short* __restrict__ Wr, const unsigned short* __restrict__ Wk,
        const unsigned short* __restrict__ Wv,
        unsigned short* __restrict__ Ro, unsigned short* __restrict__ Ko,
        unsigned short* __restrict__ Vo) {
    __shared__ __align__(16) unsigned short As[3][64 * 32];
    __shared__ __align__(16) unsigned short Bs[3][128 * 32];
    const int tid = threadIdx.x;
    const int w = tid >> 6, l = tid & 63;
    const int bm = blockIdx.x * 64, bn = blockIdx.y * 128;
    const int wm = w >> 1, wn = w & 1;
    const int lr = l & 15, lq = l >> 4, lk = lq * 8;

    f32x4v acc[3][2][4];
#pragma unroll
    for (int p = 0; p < 3; p++)
#pragma unroll
        for (int i = 0; i < 2; i++)
#pragma unroll
            for (int j = 0; j < 4; j++)
#pragma unroll
                for (int q = 0; q < 4; q++) acc[p][i][j][q] = 0.f;

    const float* cvs[3] = {cr, ck, cv};
    const unsigned short* Ws[3] = {Wr, Wk, Wv};

    for (int k0 = 0; k0 < HID; k0 += 32) {
        {
            const int row = tid >> 2, kp = (tid & 3) * 8;
            const int gr = bm + row;
            const float* xp = x + (size_t)gr * HID + k0 + kp;
            float4 x0 = ld4(xp), x1 = ld4(xp + 4);
            float4 p0 = make_float4(0.f, 0.f, 0.f, 0.f), p1 = p0;
            if ((gr & (TSEQ - 1)) != 0) { p0 = ld4(xp - HID); p1 = ld4(xp - HID + 4); }
            float xb[8] = {x0.x, x0.y, x0.z, x0.w, x1.x, x1.y, x1.z, x1.w};
            float dx[8] = {p0.x - x0.x, p0.y - x0.y, p0.z - x0.z, p0.w - x0.w,
                           p1.x - x1.x, p1.y - x1.y, p1.z - x1.z, p1.w - x1.w};
#pragma unroll
            for (int p = 0; p < 3; p++) {
                float4 c0 = ld4(cvs[p] + k0 + kp), c1 = ld4(cvs[p] + k0 + kp + 4);
                float cc[8] = {c0.x, c0.y, c0.z, c0.w, c1.x, c1.y, c1.z, c1.w};
                uint4 u;
                u.x = pk2(fmaf(dx[0], cc[0], xb[0]), fmaf(dx[1], cc[1], xb[1]));
                u.y = pk2(fmaf(dx[2], cc[2], xb[2]), fmaf(dx[3], cc[3], xb[3]));
                u.z = pk2(fmaf(dx[4], cc[4], xb[4]), fmaf(dx[5], cc[5], xb[5]));
                u.w = pk2(fmaf(dx[6], cc[6], xb[6]), fmaf(dx[7], cc[7], xb[7]));
                *reinterpret_cast<uint4*>(&As[p][row * 32 + kp]) = u;
            }
        }
#pragma unroll
        for (int p = 0; p < 3; p++)
#pragma unroll
            for (int c = 0; c < 2; c++) {
                int idx = c * 256 + tid;
                int rw = idx >> 2, kp2 = (idx & 3) * 8;
                gl16(Ws[p] + (size_t)(bn + rw) * HID + k0 + kp2,
                     &Bs[p][c * 2048 + w * 512]);
            }
        __syncthreads();
#pragma unroll
        for (int p = 0; p < 3; p++) {
            s16x8 af[2], bf4[4];
#pragma unroll
            for (int i = 0; i < 2; i++)
                af[i] = *reinterpret_cast<const s16x8*>(
                    &As[p][(wm * 32 + i * 16 + lr) * 32 + lk]);
#pragma unroll
            for (int j = 0; j < 4; j++)
                bf4[j] = *reinterpret_cast<const s16x8*>(
                    &Bs[p][(wn * 64 + j * 16 + lr) * 32 + lk]);
#pragma unroll
            for (int i = 0; i < 2; i++)
#pragma unroll
                for (int j = 0; j < 4; j++)
                    acc[p][i][j] = MF(af[i], bf4[j], acc[p][i][j]);
        }
        __syncthreads();
    }

    unsigned short* dsts[3] = {Ro, Ko, Vo};
#pragma unroll
    for (int p = 0; p < 3; p++)
#pragma unroll
        for (int i = 0; i < 2; i++)
#pragma unroll
            for (int j = 0; j < 4; j++)
#pragma unroll
                for (int q = 0; q < 4; q++) {
                    const int grow = bm + wm * 32 + i * 16 + lq * 4 + q;
                    const int gcol = bn + wn * 64 + j * 16 + lr;
                    dsts[p][(size_t)grow * HID + gcol] = bfr(acc[p][i][j][q]);
                }
}

// ---------------------------------------------------------------------------
// lora4 (unchanged): fused v/w/a/g lora stage-1 -> H1[BTOT][352].
// ---------------------------------------------------------------------------
__global__ __launch_bounds__(256) void lora4_kernel(
        const float* __restrict__ x,
        const float* __restrict__ cv_, const float* __restrict__ cw_,
        const float* __restrict__ ca_, const float* __restrict__ cg_,
        const unsigned short* __restrict__ LW, unsigned short* __restrict__ H1) {
    __shared__ __align__(16) unsigned short As[4][64 * 32];
    __shared__ __align__(16) unsigned short Bs[L4N * 32];
    const int tid = threadIdx.x;
    const int w = tid >> 6, l = tid & 63;
    const int lr = l & 15, lq = l >> 4, lk = lq * 8;
    const int bm = blockIdx.x * 64;
    const float* cvs[4] = {cv_, cw_, ca_, cg_};

    f32x4v acc[22];
#pragma unroll
    for (int j = 0; j < 22; j++)
#pragma unroll
        for (int q = 0; q < 4; q++) acc[j][q] = 0.f;

    for (int k0 = 0; k0 < HID; k0 += 32) {
        {
            const int row = tid >> 2, kp = (tid & 3) * 8;
            const int gr = bm + row;
            const float* xp = x + (size_t)gr * HID + k0 + kp;
            float4 x0 = ld4(xp), x1 = ld4(xp + 4);
            float4 p0 = make_float4(0.f, 0.f, 0.f, 0.f), p1 = p0;
            if ((gr & (TSEQ - 1)) != 0) { p0 = ld4(xp - HID); p1 = ld4(xp - HID + 4); }
            float xb[8] = {x0.x, x0.y, x0.z, x0.w, x1.x, x1.y, x1.z, x1.w};
            float dx[8] = {p0.x - x0.x, p0.y - x0.y, p0.z - x0.z, p0.w - x0.w,
                           p1.x - x1.x, p1.y - x1.y, p1.z - x1.z, p1.w - x1.w};
#pragma unroll
            for (int p = 0; p < 4; p++) {
                float4 c0 = ld4(cvs[p] + k0 + kp), c1 = ld4(cvs[p] + k0 + kp + 4);
                float cc[8] = {c0.x, c0.y, c0.z, c0.w, c1.x, c1.y, c1.z, c1.w};
                uint4 u;
                u.x = pk2(fmaf(dx[0], cc[0], xb[0]), fmaf(dx[1], cc[1], xb[1]));
                u.y = pk2(fmaf(dx[2], cc[2], xb[2]), fmaf(dx[3], cc[3], xb[3]));
                u.z = pk2(fmaf(dx[4], cc[4], xb[4]), fmaf(dx[5], cc[5], xb[5]));
                u.w = pk2(fmaf(dx[6], cc[6], xb[6]), fmaf(dx[7], cc[7], xb[7]));
                *reinterpret_cast<uint4*>(&As[p][row * 32 + kp]) = u;
            }
        }
#pragma unroll
        for (int c = 0; c < 6; c++) {
            int idx = c * 256 + tid;
            if (idx < L4N * 4) {
                gl16(LW + (size_t)(idx >> 2) * HID + (idx & 3) * 8 + k0,
                     (char*)&Bs[0] + (c * 256 + w * 64) * 16);
            }
        }
        __syncthreads();
        s16x8 af[4];
#pragma unroll
        for (int p = 0; p < 4; p++)
            af[p] = *reinterpret_cast<const s16x8*>(&As[p][(w * 16 + lr) * 32 + lk]);
#pragma unroll
        for (int j = 0; j < 22; j++) {
            const int grp = (j < 4) ? 0 : (j < 8) ? 1 : (j < 12) ? 2 : 3;
            s16x8 bf = *reinterpret_cast<const s16x8*>(&Bs[(j * 16 + lr) * 32 + lk]);
            acc[j] = MF(af[grp], bf, acc[j]);
        }
        __syncthreads();
    }

#pragma unroll
    for (int j = 0; j < 22; j++)
#pragma unroll
        for (int q = 0; q < 4; q++) {
            const int grow = bm + w * 16 + lq * 4 + q;
            const int gcol = j * 16 + lr;
            float d = acc[j][q];
            if (j >= 4 && j < 8) d = tanhf(d);
            else if (j >= 12) d = sigf(d);
            H1[(size_t)grow * L4N + gcol] = bfr(d);
        }
}

// ---------------------------------------------------------------------------
// stage2 (unchanged R15): v/w/a lora stage-2 in one launch (blockIdx.z).
// ---------------------------------------------------------------------------
__global__ __launch_bounds__(256) void stage2_kernel(
        const unsigned short* __restrict__ H1,
        const unsigned short* __restrict__ vB16, const unsigned short* __restrict__ wB16,
        const unsigned short* __restrict__ aB16,
        const float* __restrict__ vb, const float* __restrict__ wb,
        const float* __restrict__ ab,
        unsigned short* __restrict__ Vout, unsigned short* __restrict__ Wout,
        unsigned short* __restrict__ Aout,
        const unsigned short* __restrict__ aux1, const float* __restrict__ aux2) {
    const int z = blockIdx.z;
    const unsigned short* Bw = (z == 0) ? vB16 : (z == 1) ? wB16 : aB16;
    const float* bias = (z == 0) ? vb : (z == 1) ? wb : ab;
    unsigned short* Cout = (z == 0) ? Vout : (z == 1) ? Wout : Aout;
    const int aoff = z * 64;
    __shared__ __align__(16) unsigned short As[128 * 32];
    __shared__ __align__(16) unsigned short Bs[128 * 32];
    const int tid = threadIdx.x;
    const int w = tid >> 6, l = tid & 63;
    const int bm = blockIdx.x * 128, bn = blockIdx.y * 128;
    const int wm = w >> 1, wn = w & 1;
    const int lr = l & 15, lk = (l >> 4) * 8;

    f32x4v acc[4][4];
#pragma unroll
    for (int i = 0; i < 4; i++)
#pragma unroll
        for (int j = 0; j < 4; j++)
#pragma unroll
            for (int q = 0; q < 4; q++) acc[i][j][q] = 0.f;

    for (int k0 = 0; k0 < 64; k0 += 32) {
#pragma unroll
        for (int c = 0; c < 2; c++) {
            int idx = c * 256 + tid;
            int row = idx >> 2, kp = (idx & 3) * 8;
            gl16(H1 + (size_t)(bm + row) * L4N + aoff + k0 + kp,
                 &As[c * 2048 + w * 512]);
        }
#pragma unroll
        for (int c = 0; c < 2; c++) {
            int idx = c * 256 + tid;
            int row = idx >> 2, kp = (idx & 3) * 8;
            gl16(Bw + (size_t)(bn + row) * 64 + k0 + kp, &Bs[c * 2048 + w * 512]);
        }
        __syncthreads();
        s16x8 afx[4], bfx[4];
#pragma unroll
        for (int i = 0; i < 4; i++)
            afx[i] = *reinterpret_cast<const s16x8*>(&As[(wm * 64 + i * 16 + lr) * 32 + lk]);
#pragma unroll
        for (int j = 0; j < 4; j++)
            bfx[j] = *reinterpret_cast<const s16x8*>(&Bs[(wn * 64 + j * 16 + lr) * 32 + lk]);
#pragma unroll
        for (int i = 0; i < 4; i++)
#pragma unroll
            for (int j = 0; j < 4; j++)
                acc[i][j] = MF(afx[i], bfx[j], acc[i][j]);
        __syncthreads();
    }

#pragma unroll
    for (int i = 0; i < 4; i++) {
        const int grow0 = bm + wm * 64 + i * 16 + (l >> 4) * 4;
#pragma unroll
        for (int j = 0; j < 4; j++) {
            const int gcol = bn + wn * 64 + j * 16 + lr;
            const float bsv = bias[gcol];
#pragma unroll
            for (int q = 0; q < 4; q++) {
                const int grow = grow0 + q;
                float d = acc[i][j][q];
                if (z == 0) {
                    float v0 = bff(aux1[(size_t)grow * HID + gcol]);
                    d = fmaf(aux2[(size_t)grow * HID + gcol] - v0, sigf(d + bsv), v0);
                } else if (z == 1) {
                    d = W_SCALE * sigf(d + bsv);
                } else {
                    d = sigf(d + bsv);
                }
                Cout[(size_t)grow * HID + gcol] = bfr(d);
            }
        }
    }
}

// ---------------------------------------------------------------------------
// mgemm (bf16 A via lda, MODE 0 — the g stage-2).
// ---------------------------------------------------------------------------
template<int BM, int BN, int MODE, bool OUTBF>
__global__ __launch_bounds__(256) void mgemm(
        const unsigned short* __restrict__ Ab, const unsigned short* __restrict__ Bw,
        void* Cout, int N, int K, int lda,
        const float* __restrict__ bias,
        const unsigned short* aux1, const float* __restrict__ aux2) {
    constexpr int BK = 32;
    constexpr int WM_ = (BN == 128) ? 2 : 4;
    constexpr int WN_ = (BN == 128) ? 2 : 1;
    constexpr int WTM = BM / WM_, WTN = BN / WN_;
    constexpr int MF_ = WTM / 16, NF = WTN / 16;
    constexpr int ACALLS = (BM * BK) / 2048;
    constexpr int BCALLS = (BN * BK) / 2048;
    __shared__ __align__(16) unsigned short As[BM * BK];
    __shared__ __align__(16) unsigned short Bs[BN * BK];
    const int tid = threadIdx.x;
    const int w = tid >> 6, l = tid & 63;
    const int bm = blockIdx.x * BM, bn = blockIdx.y * BN;
    const int wm = w / WN_, wn = w % WN_;
    const int lr = l & 15, lk = (l >> 4) * 8;

    f32x4v acc[MF_][NF];
#pragma unroll
    for (int i = 0; i < MF_; i++)
#pragma unroll
        for (int j = 0; j < NF; j++)
#pragma unroll
            for (int q = 0; q < 4; q++) acc[i][j][q] = 0.f;

    for (int k0 = 0; k0 < K; k0 += BK) {
#pragma unroll
        for (int c = 0; c < ACALLS; c++) {
            int idx = c * 256 + tid;
            int row = idx >> 2, kp = (idx & 3) * 8;
            gl16(Ab + (size_t)(bm + row) * lda + k0 + kp, &As[c * 2048 + w * 512]);
        }
#pragma unroll
        for (int c = 0; c < BCALLS; c++) {
            int idx = c * 256 + tid;
            int row = idx >> 2, kp = (idx & 3) * 8;
            int gc = bn + row; if (gc > N - 1) gc = N - 1;
            gl16(Bw + (size_t)gc * K + k0 + kp, &Bs[c * 2048 + w * 512]);
        }
        __syncthreads();
        s16x8 afx[MF_], bfx[NF];
#pragma unroll
        for (int i = 0; i < MF_; i++)
            afx[i] = *reinterpret_cast<const s16x8*>(&As[(wm * WTM + i * 16 + lr) * BK + lk]);
#pragma unroll
        for (int j = 0; j < NF; j++)
            bfx[j] = *reinterpret_cast<const s16x8*>(&Bs[(wn * WTN + j * 16 + lr) * BK + lk]);
#pragma unroll
        for (int i = 0; i < MF_; i++)
#pragma unroll
            for (int j = 0; j < NF; j++)
                acc[i][j] = __builtin_amdgcn_mfma_f32_16x16x32_bf16(
                    afx[i], bfx[j], acc[i][j], 0, 0, 0);
        __syncthreads();
    }

#pragma unroll
    for (int i = 0; i < MF_; i++) {
        const int grow0 = bm + wm * WTM + i * 16 + (l >> 4) * 4;
#pragma unroll
        for (int j = 0; j < NF; j++) {
            const int gcol = bn + wn * WTN + j * 16 + lr;
            if (gcol >= N) continue;
#pragma unroll
            for (int q = 0; q < 4; q++) {
                const int grow = grow0 + q;
                float d = acc[i][j][q];
                if (OUTBF) ((unsigned short*)Cout)[(size_t)grow * N + gcol] = bfr(d);
                else       ((float*)Cout)[(size_t)grow * N + gcol] = d;
            }
        }
    }
}

// ---------------------------------------------------------------------------
// cprep (unchanged): fused prep + chunkprep + minv.
// ---------------------------------------------------------------------------
__global__ __launch_bounds__(64) void cprep_kernel(
        unsigned short* __restrict__ K16, unsigned short* __restrict__ A16,
        unsigned short* __restrict__ R16, unsigned short* __restrict__ KK16,
        const unsigned short* __restrict__ W16,
        const float* __restrict__ kkc, const float* __restrict__ kac,
        const float* __restrict__ rkw,
        float* __restrict__ SB, float* __restrict__ Ed,
        unsigned short* __restrict__ MvH, unsigned short* __restrict__ MvL) {
    __shared__ __align__(16) unsigned short sA[32][64], sB[32][64];
    __shared__ __align__(16) float Mab[32][36];
    const int bid = blockIdx.x;
    const int bh = bid >> 6, ch = bid & 63;
    const int bb = bh >> 4, hh = bh & 15;
    const int l = threadIdx.x;
    const int chn = hh * 64 + l;
    const float kkcv = kkc[chn], kacv = kac[chn], rkv = rkw[chn];
    size_t off = ((size_t)(bb * TSEQ) + ch * CCH) * HID + chn;
    float cw = 0.f, er = 1.f;
    for (int i = 0; i < CCH; i++, off += HID) {
        const float k = bff(K16[off]);
        const float a = bff(A16[off]);
        const float r = bff(R16[off]);
        const float wv = bff(W16[off]);
        const float kr = k * kkcv;
        float ss = kr * kr;
        ss += __shfl_xor(ss, 1);  ss += __shfl_xor(ss, 2);
        ss += __shfl_xor(ss, 4);  ss += __shfl_xor(ss, 8);
        ss += __shfl_xor(ss, 16); ss += __shfl_xor(ss, 32);
        const float inv = 1.0f / fmaxf(sqrtf(ss), 1e-12f);
        const float kk = kr * inv;
        const float b  = kk * a;
        const float kn = k * fmaf(a - 1.0f, kacv, 1.0f);
        float s3 = r * kn * rkv;
        s3 += __shfl_xor(s3, 1);  s3 += __shfl_xor(s3, 2);
        s3 += __shfl_xor(s3, 4);  s3 += __shfl_xor(s3, 8);
        s3 += __shfl_xor(s3, 16); s3 += __shfl_xor(s3, 32);
        if (l == 0) SB[(size_t)bh * TSEQ + ch * CCH + i] = s3;
        const float cwp = cw; cw += wv;
        const float ea = __expf(cwp), ei = __expf(-cw);
        er = __expf(cw);
        const unsigned short At = bfr(-kk * ea);
        const unsigned short Bt = bfr(b * ei);
        KK16[off] = At;
        A16[off]  = Bt;
        K16[off]  = bfr(kn * ei);
        R16[off]  = bfr(r * er);
        sA[i][l] = At; sB[i][l] = Bt;
    }
    Ed[((size_t)bh * NCH + ch) * 64 + l] = er;
    __syncthreads();
    const int lr = l & 15, lq = l >> 4;
    f32x4v z4; z4[0] = z4[1] = z4[2] = z4[3] = 0.f;
#pragma unroll
    for (int mi = 0; mi < 2; mi++)
#pragma unroll
        for (int ni = 0; ni < 2; ni++) {
            s16x8 a0 = *reinterpret_cast<const s16x8*>(&sA[mi * 16 + lr][lq * 8]);
            s16x8 a1 = *reinterpret_cast<const s16x8*>(&sA[mi * 16 + lr][32 + lq * 8]);
            s16x8 b0 = *reinterpret_cast<const s16x8*>(&sB[ni * 16 + lr][lq * 8]);
            s16x8 b1 = *reinterpret_cast<const s16x8*>(&sB[ni * 16 + lr][32 + lq * 8]);
            f32x4v m = MF(a1, b1, MF(a0, b0, z4));
#pragma unroll
            for (int q = 0; q < 4; q++) {
                int r = mi * 16 + lq * 4 + q, cc2 = ni * 16 + lr;
                Mab[r][cc2] = (cc2 < r) ? m[q] : 0.f;
            }
        }
    __syncthreads();
    const int j = l & 31;
    float m[32];
#pragma unroll
    for (int i = 0; i < 32; i++) m[i] = (i == j) ? 1.f : 0.f;
#pragma unroll
    for (int i = 1; i < 32; i++) {
        float p0 = 0.f, p1 = 0.f, p2 = 0.f, p3 = 0.f;
#pragma unroll
        for (int k4_ = 0; k4_ < 32; k4_ += 4) {
            if (k4_ >= i) break;
            float4 L4 = *reinterpret_cast<const float4*>(&Mab[i][k4_]);
            p0 = fmaf(L4.x, m[k4_ + 0], p0);
            if (k4_ + 1 < i) p1 = fmaf(L4.y, m[k4_ + 1], p1);
            if (k4_ + 2 < i) p2 = fmaf(L4.z, m[k4_ + 2], p2);
            if (k4_ + 3 < i) p3 = fmaf(L4.w, m[k4_ + 3], p3);
        }
        m[i] += (p0 + p1) + (p2 + p3);
    }
    if (l < 32) {
        unsigned short* dH = MvH + (size_t)(bh * NCH + ch) * 1024;
        unsigned short* dL = MvL + (size_t)(bh * NCH + ch) * 1024;
#pragma unroll
        for (int i = 0; i < 32; i++) {
            unsigned short h = bfr(m[i]);
            dH[i * 32 + j] = h;
            dL[i * 32 + j] = bfr(m[i] - bff(h));
        }
    }
}

// ---------------------------------------------------------------------------
// Chunked recurrence (unchanged R15; o stored bf16 -> O16).
// ---------------------------------------------------------------------------
__global__ __launch_bounds__(256) void recchunk_kernel(
        const unsigned short* __restrict__ AtG, const unsigned short* __restrict__ BtG,
        const unsigned short* __restrict__ KtG, const unsigned short* __restrict__ RtG,
        const unsigned short* __restrict__ V16, const float* __restrict__ Ed,
        const unsigned short* __restrict__ MvH, const unsigned short* __restrict__ MvL,
        unsigned short* __restrict__ Ob16) {
    __shared__ __align__(16) unsigned short stT[2][4][CCH][64];
    __shared__ __align__(16) unsigned short stMh[2][32][32], stMl[2][32][32];
    __shared__ __align__(16) unsigned short stV[2][CCH][16];
    __shared__ __align__(16) float stEd[2][64];
    __shared__ __align__(16) unsigned short Shi[16][74], Slo[16][74];
    __shared__ __align__(16) unsigned short BtT[64][42], KtT[64][42];
    __shared__ __align__(16) unsigned short VT[16][42];
    __shared__ __align__(16) unsigned short MakH[32][42], MakL[32][42];
    __shared__ __align__(16) unsigned short MrkH[32][42], MrkL[32][42];
    __shared__ __align__(16) unsigned short MrbH[32][42], MrbL[32][42];
    __shared__ __align__(16) unsigned short rhTH[16][42], rhTL[16][42];

    const int bid = blockIdx.x;
    const int vq = bid >> 7, bh = bid & 127;
    const int tid = threadIdx.x;
    const int w = tid >> 6, l = tid & 63;
    const int lr = l & 15, lq = l >> 4;
    const int bb = bh >> 4, hh = bh & 15;
    const size_t rowoff = ((size_t)bb * TSEQ) * HID + hh * 64;
    const int mi = w >> 1, ni = w & 1;

    const int r8 = l >> 3, ck = l & 7;
    const int swz8 = (ck ^ r8) * 8;

    auto STAGE = [&](int buf, int cn) {
        if (cn >= NCH) return;
        const size_t cb = rowoff + (size_t)(cn * CCH) * HID;
        const unsigned short* srcs[4] = {AtG, BtG, KtG, RtG};
        const unsigned short* T = srcs[w];
#pragma unroll
        for (int c = 0; c < 4; c++)
            gl16(T + cb + (size_t)(c * 8 + r8) * HID + swz8, &stT[buf][w][c * 8][0]);
        if (w == 0) {
            gl16(V16 + cb + (size_t)(l >> 1) * HID + vq * 16 + (l & 1) * 8,
                 &stV[buf][0][0]);
            gl4(Ed + ((size_t)bh * NCH + cn) * 64 + l, &stEd[buf][0]);
        } else if (w == 1) {
#pragma unroll
            for (int c = 0; c < 2; c++)
                gl16(MvH + (size_t)(bh * NCH + cn) * 1024 + c * 512 + l * 8,
                     (char*)&stMh[buf][0][0] + c * 1024);
        } else if (w == 2) {
#pragma unroll
            for (int c = 0; c < 2; c++)
                gl16(MvL + (size_t)(bh * NCH + cn) * 1024 + c * 512 + l * 8,
                     (char*)&stMl[buf][0][0] + c * 1024);
        }
    };

    for (int idx = tid; idx < 16 * 74; idx += 256) {
        ((unsigned short*)Shi)[idx] = 0;
        ((unsigned short*)Slo)[idx] = 0;
    }
    STAGE(0, 0);
    asm volatile("s_waitcnt vmcnt(0)" ::: "memory");
    __syncthreads();

    auto fragT = [&](int bf, int tn, int rbase, int kb) -> s16x8 {
        int row = rbase + lr;
        int chv = ((kb >> 3) + lq) ^ (row & 7);
        return *reinterpret_cast<const s16x8*>(
            (const char*)&stT[bf][tn][0][0] + row * 128 + chv * 16);
    };
    auto fragS = [&](const unsigned short (*Sx)[74], int kb) -> s16x8 {
        return *reinterpret_cast<const s16x8*>(&Sx[lr][kb + lq * 8]);
    };
    auto frag42 = [&](const unsigned short (*T)[42], int rbase) -> s16x8 {
        return *reinterpret_cast<const s16x8*>(&T[rbase + lr][lq * 8]);
    };

    f32x4v Sacc;
#pragma unroll
    for (int q = 0; q < 4; q++) Sacc[q] = 0.f;
    f32x4v z4; z4[0] = z4[1] = z4[2] = z4[3] = 0.f;

    int buf = 0;
    for (int c = 0; c < NCH; c++) {
        STAGE(buf ^ 1, c + 1);
        {
            const int tt = tid & 31, g8 = tid >> 5;
            const int ch = g8 ^ (tt & 7);
            uint4 bu = *reinterpret_cast<const uint4*>(&stT[buf][1][tt][ch * 8]);
            uint4 ku = *reinterpret_cast<const uint4*>(&stT[buf][2][tt][ch * 8]);
            unsigned int bw[4] = {bu.x, bu.y, bu.z, bu.w};
            unsigned int kw[4] = {ku.x, ku.y, ku.z, ku.w};
#pragma unroll
            for (int e = 0; e < 4; e++) {
                BtT[g8 * 8 + 2 * e][tt]     = (unsigned short)(bw[e] & 0xffffu);
                BtT[g8 * 8 + 2 * e + 1][tt] = (unsigned short)(bw[e] >> 16);
                KtT[g8 * 8 + 2 * e][tt]     = (unsigned short)(kw[e] & 0xffffu);
                KtT[g8 * 8 + 2 * e + 1][tt] = (unsigned short)(kw[e] >> 16);
            }
            if (g8 < 4) {
                ushort4 vu = *reinterpret_cast<const ushort4*>(&stV[buf][tt][g8 * 4]);
                VT[g8 * 4 + 0][tt] = vu.x; VT[g8 * 4 + 1][tt] = vu.y;
                VT[g8 * 4 + 2][tt] = vu.z; VT[g8 * 4 + 3][tt] = vu.w;
            }
        }
        s16x8 atm0 = fragT(buf, 0, mi * 16, 0), atm1 = fragT(buf, 0, mi * 16, 32);
        s16x8 rt0  = fragT(buf, 3, mi * 16, 0), rt1  = fragT(buf, 3, mi * 16, 32);
        s16x8 bt0  = fragT(buf, 1, ni * 16, 0), bt1  = fragT(buf, 1, ni * 16, 32);
        s16x8 kt0  = fragT(buf, 2, ni * 16, 0), kt1  = fragT(buf, 2, ni * 16, 32);
        f32x4v mak = MF(atm1, kt1, MF(atm0, kt0, z4));
        f32x4v mrk = MF(rt1, kt1, MF(rt0, kt0, z4));
        f32x4v mrb = MF(rt1, bt1, MF(rt0, bt0, z4));
        f32x4v oac = z4, rhT = z4;
        {
            s16x8 sh0 = fragS(Shi, 0), sh1 = fragS(Shi, 32);
            s16x8 sl0 = fragS(Slo, 0), sl1 = fragS(Slo, 32);
            if (ni == 0) {
                oac = MF(rt1, sl1, MF(rt0, sl0, MF(rt1, sh1, MF(rt0, sh0, z4))));
            } else {
                rhT = MF(sl1, atm1, MF(sl0, atm0, MF(sh1, atm1, MF(sh0, atm0, z4))));
            }
        }
#pragma unroll
        for (int q = 0; q < 4; q++) {
            const int r = mi * 16 + lq * 4 + q, cc = ni * 16 + lr;
            float vv = (cc < r) ? mak[q] : 0.f;
            unsigned short h = bfr(vv);
            MakH[r][cc] = h; MakL[r][cc] = bfr(vv - bff(h));
            vv = (cc <= r) ? mrk[q] : 0.f; h = bfr(vv);
            MrkH[r][cc] = h; MrkL[r][cc] = bfr(vv - bff(h));
            vv = (cc <= r) ? mrb[q] : 0.f; h = bfr(vv);
            MrbH[r][cc] = h; MrbL[r][cc] = bfr(vv - bff(h));
        }
        __syncthreads();
        {
            s16x8 vt0 = frag42(VT, 0);
            if (ni == 0) {
                oac = MF(frag42(MrkL, mi * 16), vt0,
                         MF(frag42(MrkH, mi * 16), vt0, oac));
            } else {
                rhT = MF(vt0, frag42(MakL, mi * 16),
                         MF(vt0, frag42(MakH, mi * 16), rhT));
#pragma unroll
                for (int q = 0; q < 4; q++) {
                    const int r = lq * 4 + q, cc = mi * 16 + lr;
                    unsigned short h = bfr(rhT[q]);
                    rhTH[r][cc] = h; rhTL[r][cc] = bfr(rhT[q] - bff(h));
                }
            }
        }
        __syncthreads();
        if (ni == 1) {
            s16x8 rh0 = frag42(rhTH, 0), rl0 = frag42(rhTL, 0);
            s16x8 mvh = *reinterpret_cast<const s16x8*>(&stMh[buf][mi * 16 + lr][lq * 8]);
            s16x8 mvl = *reinterpret_cast<const s16x8*>(&stMl[buf][mi * 16 + lr][lq * 8]);
            f32x4v sat = MF(rl0, mvh, MF(rh0, mvl, MF(rh0, mvh, z4)));
#pragma unroll
            for (int q = 0; q < 4; q++) {
                const int r = lq * 4 + q, cc = mi * 16 + lr;
                unsigned short h = bfr(sat[q]);
                MakH[r][cc] = h;
                MakL[r][cc] = bfr(sat[q] - bff(h));
            }
        }
        __syncthreads();
        {
            s16x8 sath = frag42(MakH, 0), satl = frag42(MakL, 0);
            if (ni == 0) {
                s16x8 rbh = frag42(MrbH, mi * 16), rbl = frag42(MrbL, mi * 16);
                oac = MF(rbl, sath, MF(rbh, satl, MF(rbh, sath, oac)));
#pragma unroll
                for (int q = 0; q < 4; q++) {
                    const int t = c * CCH + mi * 16 + lq * 4 + q;
                    Ob16[rowoff + (size_t)t * HID + vq * 16 + lr] = bfr(oac[q]);
                }
            }
            s16x8 btf = frag42(BtT, w * 16);
            s16x8 ktf = frag42(KtT, w * 16);
            s16x8 vta = frag42(VT, 0);
            const float ed = stEd[buf][w * 16 + lr];
            Sacc = MF(sath, btf, Sacc);
            Sacc = MF(satl, btf, Sacc);
            Sacc = MF(vta, ktf, Sacc);
#pragma unroll
            for (int q = 0; q < 4; q++) {
                Sacc[q] *= ed;
                unsigned short h = bfr(Sacc[q]);
                Shi[lq * 4 + q][w * 16 + lr] = h;
                Slo[lq * 4 + q][w * 16 + lr] = bfr(Sacc[q] - bff(h));
            }
        }
        asm volatile("s_waitcnt vmcnt(0)" ::: "memory");
        __syncthreads();
        buf ^= 1;
    }
}

// ---------------------------------------------------------------------------
// stats: per (row, head) GroupNorm mu and rsqrt(var+eps) -> MS (= dead Ed).
// ---------------------------------------------------------------------------
__global__ __launch_bounds__(256) void stats_kernel(
        const unsigned short* __restrict__ O16, float* __restrict__ MS) {
    const int row = blockIdx.x;
    const int tid = threadIdx.x;
    const int c = tid * 4;
    ushort4 ou = *reinterpret_cast<const ushort4*>(O16 + (size_t)row * HID + c);
    float o[4] = {bff(ou.x), bff(ou.y), bff(ou.z), bff(ou.w)};
    float s1 = o[0] + o[1] + o[2] + o[3];
    float s2 = o[0]*o[0] + o[1]*o[1] + o[2]*o[2] + o[3]*o[3];
#pragma unroll
    for (int m = 1; m < 16; m <<= 1) {
        s1 += __shfl_xor(s1, m); s2 += __shfl_xor(s2, m);
    }
    if ((tid & 15) == 0) {
        const int hh = tid >> 4;
        const float mu = s1 * (1.0f / 64.0f);
        const float var = s2 * (1.0f / 64.0f) - mu * mu;
        float2 v; v.x = mu; v.y = rsqrtf(var + GN_EPS);
        *reinterpret_cast<float2*>(MS + (size_t)row * 32 + hh * 2) = v;
    }
}

// ---------------------------------------------------------------------------
// wogemm: out = y @ W_o^T with y computed in A-staging.
// ---------------------------------------------------------------------------
__global__ __launch_bounds__(256) void wogemm_kernel(
        const unsigned short* __restrict__ O16, const unsigned short* __restrict__ V16,
        const unsigned short* __restrict__ G16, const float* __restrict__ SB,
        const float* __restrict__ MS, const float* __restrict__ gnw,
        const float* __restrict__ gnb, const unsigned short* __restrict__ Wo,
        float* __restrict__ out) {
    __shared__ __align__(16) unsigned short As[128 * 32];
    __shared__ __align__(16) unsigned short Bs[128 * 32];
    const int tid = threadIdx.x;
    const int w = tid >> 6, l = tid & 63;
    const int bm = blockIdx.x * 128, bn = blockIdx.y * 128;
    const int wm = w >> 1, wn = w & 1;
    const int lr = l & 15, lk = (l >> 4) * 8;

    f32x4v acc[4][4];
#pragma unroll
    for (int i = 0; i < 4; i++)
#pragma unroll
        for (int j = 0; j < 4; j++)
#pragma unroll
            for (int q = 0; q < 4; q++) acc[i][j][q] = 0.f;

    for (int k0 = 0; k0 < HID; k0 += 32) {
#pragma unroll
        for (int c = 0; c < 2; c++) {
            int idx = c * 256 + tid;
            int row = idx >> 2, kp = (idx & 3) * 8;
            const int gr = bm + row;
            const size_t rb = (size_t)gr * HID + k0 + kp;
            uint4 ou = *reinterpret_cast<const uint4*>(O16 + rb);
            uint4 vu = *reinterpret_cast<const uint4*>(V16 + rb);
            uint4 gu = *reinterpret_cast<const uint4*>(G16 + rb);
            float o8[8], v8[8], g8[8];
            up8(ou, o8); up8(vu, v8); up8(gu, g8);
            const int hh = (k0 + kp) >> 6;
            float2 ms = *reinterpret_cast<const float2*>(MS + (size_t)gr * 32 + hh * 2);
            const float s3 = SB[((size_t)(gr >> 11) * 16 + hh) * TSEQ + (gr & (TSEQ - 1))];
            float4 w0 = ld4(gnw + k0 + kp), w1 = ld4(gnw + k0 + kp + 4);
            float4 b0 = ld4(gnb + k0 + kp), b1 = ld4(gnb + k0 + kp + 4);
            float wn8[8] = {w0.x, w0.y, w0.z, w0.w, w1.x, w1.y, w1.z, w1.w};
            float bn8[8] = {b0.x, b0.y, b0.z, b0.w, b1.x, b1.y, b1.z, b1.w};
            float y[8];
#pragma unroll
            for (int e = 0; e < 8; e++)
                y[e] = (fmaf((o8[e] - ms.x) * ms.y, wn8[e], bn8[e]) + s3 * v8[e]) * g8[e];
            uint4 u;
            u.x = pk2(y[0], y[1]); u.y = pk2(y[2], y[3]);
            u.z = pk2(y[4], y[5]); u.w = pk2(y[6], y[7]);
            *reinterpret_cast<uint4*>(&As[idx * 8]) = u;
        }
#pragma unroll
        for (int c = 0; c < 2; c++) {
            int idx = c * 256 + tid;
            int row = idx >> 2, kp = (idx & 3) * 8;
            gl16(Wo + (size_t)(bn + row) * HID + k0 + kp, &Bs[c * 2048 + w * 512]);
        }
        __syncthreads();
        s16x8 afx[4], bfx[4];
#pragma unroll
        for (int i = 0; i < 4; i++)
            afx[i] = *reinterpret_cast<const s16x8*>(&As[(wm * 64 + i * 16 + lr) * 32 + lk]);
#pragma unroll
        for (int j = 0; j < 4; j++)
            bfx[j] = *reinterpret_cast<const s16x8*>(&Bs[(wn * 64 + j * 16 + lr) * 32 + lk]);
#pragma unroll
        for (int i = 0; i < 4; i++)
#pragma unroll
            for (int j = 0; j < 4; j++)
                acc[i][j] = MF(afx[i], bfx[j], acc[i][j]);
        __syncthreads();
    }

#pragma unroll
    for (int i = 0; i < 4; i++) {
        const int grow0 = bm + wm * 64 + i * 16 + (l >> 4) * 4;
#pragma unroll
        for (int j = 0; j < 4; j++) {
            const int gcol = bn + wn * 64 + j * 16 + lr;
#pragma unroll
            for (int q = 0; q < 4; q++)
                out[(size_t)(grow0 + q) * HID + gcol] = acc[i][j][q];
        }
    }
}

// ---------------------------------------------------------------------------
extern "C" void kernel_launch(void* const* d_in, const int* in_sizes, int n_in,
                              void* d_out, int out_size, void* d_ws, size_t ws_size,
                              hipStream_t stream) {
    const float* x   = (const float*)d_in[0];
    const float* vf  = (const float*)d_in[1];
    const float* x_r = (const float*)d_in[2];
    const float* x_w = (const float*)d_in[3];
    const float* x_k = (const float*)d_in[4];
    const float* x_v = (const float*)d_in[5];
    const float* x_a = (const float*)d_in[6];
    const float* x_g = (const float*)d_in[7];
    const float* k_k = (const float*)d_in[8];
    const float* k_a = (const float*)d_in[9];
    const float* r_k = (const float*)d_in[10];
    const float* W_r = (const float*)d_in[11];
    const float* W_k = (const float*)d_in[12];
    const float* W_v = (const float*)d_in[13];
    const float* W_o = (const float*)d_in[14];
    const float* wA  = (const float*)d_in[15];
    const float* wB  = (const float*)d_in[16];
    const float* wb  = (const float*)d_in[17];
    const float* aA  = (const float*)d_in[18];
    const float* aB  = (const float*)d_in[19];
    const float* ab  = (const float*)d_in[20];
    const float* vA  = (const float*)d_in[21];
    const float* vB  = (const float*)d_in[22];
    const float* vb  = (const float*)d_in[23];
    const float* gA  = (const float*)d_in[24];
    const float* gB  = (const float*)d_in[25];
    const float* gnw = (const float*)d_in[26];
    const float* gnb = (const float*)d_in[27];
    float* out = (float*)d_out;

    float* ws = (float*)d_ws;
    const size_t SZ = (size_t)BTOT * HID;
    const size_t HH = (size_t)HID * HID;
    float*          REG  = ws;   // 64MB: [W16|O16 first 32MB][Minv|G16 last 32MB]
    unsigned short* P    = (unsigned short*)(ws + SZ);
    unsigned short* R16  = P;
    unsigned short* K16  = P + 1 * SZ;
    unsigned short* V16  = P + 2 * SZ;
    unsigned short* A16  = P + 3 * SZ;
    unsigned short* KK16 = P + 4 * SZ;
    unsigned short* H1   = P + 5 * SZ;               // [BTOT][352]
    unsigned short* WR   = H1 + (size_t)BTOT * L4N;
    unsigned short* Wr16 = WR;
    unsigned short* Wk16 = WR + 1 * HH;
    unsigned short* Wv16 = WR + 2 * HH;
    unsigned short* Wo16 = WR + 3 * HH;
    unsigned short* LW   = WR + 4 * HH;              // [352][1024]
    unsigned short* vB16 = LW + (size_t)L4N * HID;
    unsigned short* wB16 = vB16 + 65536;
    unsigned short* aB16 = wB16 + 65536;
    unsigned short* gB16 = aB16 + 65536;
    float*          SB   = (float*)(gB16 + 163840);  // [128][2048]
    float*          Ed   = SB + (size_t)128 * TSEQ;  // [128][64][64]
    float*          MS   = Ed;   // ALIAS: Ed dead after recchunk; MS born at stats
    unsigned short* W16   = (unsigned short*)REG;          // decay (pre-cprep)
    unsigned short* O16   = (unsigned short*)REG;          // o (post-cprep)
    unsigned short* MinvH = (unsigned short*)(REG + 8 * 1024 * 1024);
    unsigned short* MinvL = MinvH + (size_t)128 * NCH * 1024;
    unsigned short* G16   = (unsigned short*)(REG + 8 * 1024 * 1024);  // post-rec

    const dim3 blk(256);
    const dim3 gBig(128, 8);
    const dim3 gP3(BTOT / 64, 8);
    const unsigned short* nu = nullptr;
    const float* np = nullptr;

    // --- single cast launch (prefix-offset table) ---
    CastArgs ca;
    const float* srcs[12] = {W_r, W_k, W_v, W_o, vA, wA, aA, gA, vB, wB, aB, gB};
    unsigned short* dsts[12] = {Wr16, Wk16, Wv16, Wo16,
                                LW, LW + 65536, LW + 131072, LW + 196608,
                                vB16, wB16, aB16, gB16};
    int cnts[12] = {(int)HH, (int)HH, (int)HH, (int)HH,
                    65536, 65536, 65536, 163840, 65536, 65536, 65536, 163840};
    int acc4 = 0;
    for (int s = 0; s < 12; s++) {
        ca.src[s] = srcs[s]; ca.dst[s] = dsts[s];
        ca.start4[s] = acc4;
        acc4 += cnts[s] / 4;
    }
    ca.start4[12] = acc4;
    cast_all_kernel<<<dim3((acc4 + 255) / 256), blk, 0, stream>>>(ca);

    // fused r, k, v0 projections
    proj3_kernel<<<gP3, blk, 0, stream>>>(
        x, x_r, x_k, x_v, Wr16, Wk16, Wv16, R16, K16, V16);
    // fused lora stage-1 (v,w,a,g) -> H1
    lora4_kernel<<<dim3(BTOT / 64), blk, 0, stream>>>(
        x, x_v, x_w, x_a, x_g, LW, H1);
    // v/w/a stage-2 in one launch
    stage2_kernel<<<dim3(128, 8, 3), blk, 0, stream>>>(
        H1, vB16, wB16, aB16, vb, wb, ab, V16, W16, A16, V16, vf);
    // fused prep + chunkprep + minv
    cprep_kernel<<<dim3(128 * NCH), dim3(64), 0, stream>>>(
        K16, A16, R16, KK16, W16, k_k, k_a, r_k, SB, Ed, MinvH, MinvL);
    // chunked recurrence -> o bf16 (O16 over dead W16 region)
    recchunk_kernel<<<dim3(512), blk, 0, stream>>>(
        KK16, A16, K16, R16, V16, Ed, MinvH, MinvL, O16);
    // g = h_g @ gB^T (bf16, over dead Minv region)
    mgemm<128,128,0,true><<<gBig, blk, 0, stream>>>(
        H1 + 192, gB16, G16, HID, 160, L4N, np, nu, np);
    // GroupNorm stats (MS over dead Ed region)
    stats_kernel<<<dim3(BTOT), blk, 0, stream>>>(O16, MS);
    // out = y @ W_o^T with fused y-compute
    wogemm_kernel<<<gBig, blk, 0, stream>>>(
        O16, V16, G16, SB, MS, gnw, gnb, Wo16, out);
    (void)in_sizes; (void)n_in; (void)out_size; (void)ws_size;
}